// Round 1
// baseline (2374.070 us; speedup 1.0000x reference)
//
#include <hip/hip_runtime.h>
#include <math.h>

#define S     1536
#define DM    1024
#define NH    16
#define H2N   32
#define HD    64
#define KVC   256
#define QC    384
#define DFF   4096
#define SPP   384
#define DQK   48
#define EPS_RMS  1.1920929e-07f
#define ATTN_EPS 1e-5f
#define SCALING  0.14433756729740643f   /* 48^-0.5 */

// ---------------- RMSNorm (generic, optional in-place) ----------------
__global__ __launch_bounds__(256) void rmsnorm_k(const float* __restrict__ in,
    const float* __restrict__ w, float* __restrict__ out,
    int cols, int ldin, int ldout, float eps) {
  const int row = blockIdx.x;
  const float* xr = in + (size_t)row * ldin;
  float* yr = out + (size_t)row * ldout;
  const int tid = threadIdx.x;
  float ss = 0.f;
  for (int c = tid << 2; c < cols; c += 1024) {
    float4 v = *reinterpret_cast<const float4*>(xr + c);
    ss += v.x*v.x + v.y*v.y + v.z*v.z + v.w*v.w;
  }
#pragma unroll
  for (int mm = 1; mm < 64; mm <<= 1) ss += __shfl_xor(ss, mm, 64);
  __shared__ float red[4];
  if ((tid & 63) == 0) red[tid >> 6] = ss;
  __syncthreads();
  float tot = red[0] + red[1] + red[2] + red[3];
  float scale = rsqrtf(tot / (float)cols + eps);
  for (int c = tid << 2; c < cols; c += 1024) {
    float4 v = *reinterpret_cast<const float4*>(xr + c);
    float4 wv = *reinterpret_cast<const float4*>(w + c);
    float4 ov = make_float4(v.x*scale*wv.x, v.y*scale*wv.y, v.z*scale*wv.z, v.w*scale*wv.w);
    *reinterpret_cast<float4*>(yr + c) = ov;
  }
}

// ---------------- SGEMM: C[M,N] = A[M,K] @ B[N,K]^T (+ src) ----------------
template<int ADD>
__global__ __launch_bounds__(256) void sgemm_nt(const float* __restrict__ A,
    const float* __restrict__ B, const float* __restrict__ src, float* __restrict__ C,
    int M, int N, int K, int lda, int ldb, int ldc) {
  __shared__ __align__(16) float As[16][64];
  __shared__ __align__(16) float Bs[16][64];
  const int bm = blockIdx.y * 64, bn = blockIdx.x * 64;
  const int tid = threadIdx.x;
  const int tx = tid & 15, ty = tid >> 4;
  const int lr = tid >> 2, lk = (tid & 3) << 2;
  const int arow = bm + lr, brow = bn + lr;
  float acc[4][4] = {};
  for (int k0 = 0; k0 < K; k0 += 16) {
    float4 av = make_float4(0.f,0.f,0.f,0.f), bv = make_float4(0.f,0.f,0.f,0.f);
    if (arow < M) av = *reinterpret_cast<const float4*>(A + (size_t)arow*lda + k0 + lk);
    if (brow < N) bv = *reinterpret_cast<const float4*>(B + (size_t)brow*ldb + k0 + lk);
    __syncthreads();
    As[lk+0][lr]=av.x; As[lk+1][lr]=av.y; As[lk+2][lr]=av.z; As[lk+3][lr]=av.w;
    Bs[lk+0][lr]=bv.x; Bs[lk+1][lr]=bv.y; Bs[lk+2][lr]=bv.z; Bs[lk+3][lr]=bv.w;
    __syncthreads();
#pragma unroll
    for (int k = 0; k < 16; ++k) {
      float4 a = *reinterpret_cast<const float4*>(&As[k][ty << 2]);
      float4 b = *reinterpret_cast<const float4*>(&Bs[k][tx << 2]);
      float ar[4] = {a.x,a.y,a.z,a.w};
      float br[4] = {b.x,b.y,b.z,b.w};
#pragma unroll
      for (int i = 0; i < 4; ++i)
#pragma unroll
        for (int j = 0; j < 4; ++j) acc[i][j] = fmaf(ar[i], br[j], acc[i][j]);
    }
  }
#pragma unroll
  for (int i = 0; i < 4; ++i) {
    int row = bm + (ty << 2) + i;
    if (row >= M) continue;
#pragma unroll
    for (int j = 0; j < 4; ++j) {
      int col = bn + (tx << 2) + j;
      if (col < N) {
        float v = acc[i][j];
        if (ADD) v += src[(size_t)row*ldc + col];
        C[(size_t)row*ldc + col] = v;
      }
    }
  }
}

// ------------- Fused SwiGLU GEMM: C = (A@Bu^T) * silu(A@Bv^T) -------------
// Bu = B rows [0,N), Bv = B rows [N,2N)
__global__ __launch_bounds__(256) void sgemm_glu(const float* __restrict__ A,
    const float* __restrict__ B, float* __restrict__ C,
    int M, int N, int K, int lda, int ldb, int ldc) {
  __shared__ __align__(16) float As[16][64];
  __shared__ __align__(16) float Bu[16][64];
  __shared__ __align__(16) float Bv[16][64];
  const int bm = blockIdx.y * 64, bn = blockIdx.x * 64;
  const int tid = threadIdx.x;
  const int tx = tid & 15, ty = tid >> 4;
  const int lr = tid >> 2, lk = (tid & 3) << 2;
  const int arow = bm + lr, brow = bn + lr;
  float au[4][4] = {}; float avv[4][4] = {};
  for (int k0 = 0; k0 < K; k0 += 16) {
    float4 a = make_float4(0.f,0.f,0.f,0.f);
    float4 u = make_float4(0.f,0.f,0.f,0.f);
    float4 v = make_float4(0.f,0.f,0.f,0.f);
    if (arow < M) a = *reinterpret_cast<const float4*>(A + (size_t)arow*lda + k0 + lk);
    if (brow < N) {
      u = *reinterpret_cast<const float4*>(B + (size_t)brow*ldb + k0 + lk);
      v = *reinterpret_cast<const float4*>(B + (size_t)(N + brow)*ldb + k0 + lk);
    }
    __syncthreads();
    As[lk+0][lr]=a.x; As[lk+1][lr]=a.y; As[lk+2][lr]=a.z; As[lk+3][lr]=a.w;
    Bu[lk+0][lr]=u.x; Bu[lk+1][lr]=u.y; Bu[lk+2][lr]=u.z; Bu[lk+3][lr]=u.w;
    Bv[lk+0][lr]=v.x; Bv[lk+1][lr]=v.y; Bv[lk+2][lr]=v.z; Bv[lk+3][lr]=v.w;
    __syncthreads();
#pragma unroll
    for (int k = 0; k < 16; ++k) {
      float4 a4 = *reinterpret_cast<const float4*>(&As[k][ty << 2]);
      float4 u4 = *reinterpret_cast<const float4*>(&Bu[k][tx << 2]);
      float4 v4 = *reinterpret_cast<const float4*>(&Bv[k][tx << 2]);
      float ar[4] = {a4.x,a4.y,a4.z,a4.w};
      float ur[4] = {u4.x,u4.y,u4.z,u4.w};
      float vr[4] = {v4.x,v4.y,v4.z,v4.w};
#pragma unroll
      for (int i = 0; i < 4; ++i)
#pragma unroll
        for (int j = 0; j < 4; ++j) {
          au[i][j]  = fmaf(ar[i], ur[j], au[i][j]);
          avv[i][j] = fmaf(ar[i], vr[j], avv[i][j]);
        }
    }
  }
#pragma unroll
  for (int i = 0; i < 4; ++i) {
    int row = bm + (ty << 2) + i;
    if (row >= M) continue;
#pragma unroll
    for (int j = 0; j < 4; ++j) {
      int col = bn + (tx << 2) + j;
      if (col < N) {
        float uu = au[i][j], vg = avv[i][j];
        float sig = 1.0f / (1.0f + __expf(-vg));
        C[(size_t)row*ldc + col] = uu * vg * sig;
      }
    }
  }
}

// ---------------- Build Q/K (split heads + RoPE) ----------------
// Qb/Kb layout: [h2][t][48]  (32 dims content + 16 dims rotated rope)
__global__ __launch_bounds__(256) void build_qk(const float* __restrict__ qf,
    const float* __restrict__ kvb, const float* __restrict__ ckv,
    const float* __restrict__ fc, const float* __restrict__ fs,
    float* __restrict__ Qb, float* __restrict__ Kb) {
  int t = blockIdx.x * 256 + threadIdx.x;
  int h2 = blockIdx.y;
  if (t >= S) return;
  int hh = h2 >> 1, par = h2 & 1;
  const float* qrow = qf + (size_t)t*1536 + hh*96;
  const float* krow = kvb + (size_t)t*2048 + hh*128;
  float* qo = Qb + ((size_t)h2*S + t)*DQK;
  float* ko = Kb + ((size_t)h2*S + t)*DQK;
#pragma unroll
  for (int xq = 0; xq < 8; ++xq) {
    *reinterpret_cast<float4*>(qo + (xq<<2)) =
      *reinterpret_cast<const float4*>(qrow + par*32 + (xq<<2));
    *reinterpret_cast<float4*>(ko + (xq<<2)) =
      *reinterpret_cast<const float4*>(krow + par*32 + (xq<<2));
  }
  int p = t >> 2;  // rope position: s splits as (spp, NUM_SEQ) with spp OUTER
  const float* qr = qrow + 64 + par*16;
  const float* kr = ckv + (size_t)t*288 + 256 + par*16;
#pragma unroll
  for (int mq = 0; mq < 8; ++mq) {
    float c = 1.f, sn = 0.f;
    if (p > 0) { c = fc[(p-1)*8 + mq]; sn = fs[(p-1)*8 + mq]; }
    float q0 = qr[2*mq], q1 = qr[2*mq+1];
    qo[32 + 2*mq]     = q0*c - q1*sn;
    qo[32 + 2*mq + 1] = q0*sn + q1*c;
    float k0 = kr[2*mq], k1 = kr[2*mq+1];
    ko[32 + 2*mq]     = k0*c - k1*sn;
    ko[32 + 2*mq + 1] = k0*sn + k1*c;
  }
}

// ---------------- lambda scalar ----------------
__global__ void compute_lam(const float* __restrict__ lq1, const float* __restrict__ lk1,
                            const float* __restrict__ lq2, const float* __restrict__ lk2,
                            float* __restrict__ lamp) {
  int t = threadIdx.x;  // 32 threads
  float a = lq1[t]*lk1[t];
  float b = lq2[t]*lk2[t];
#pragma unroll
  for (int mm = 1; mm < 32; mm <<= 1) { a += __shfl_xor(a, mm, 32); b += __shfl_xor(b, mm, 32); }
  if (t == 0) lamp[0] = expf(a) - expf(b) + 0.2f;  // LAMBDA_INIT = 0.2
}

// ---------------- Flash attention pass 1 (per-row m,l + PV for 32 half-heads) ----
// grid (48, 32); 256 thr; 8-thread group per query row (32 rows/block)
__global__ __launch_bounds__(256) void flash_fwd(const float* __restrict__ Qb,
    const float* __restrict__ Kb, const float* __restrict__ kvb,
    float* __restrict__ Ob, float* __restrict__ rowm, float* __restrict__ rowl) {
  const int h2 = blockIdx.y;
  const int i0 = blockIdx.x << 5;
  const int tid = threadIdx.x;
  const int g = tid >> 3, sub = tid & 7;
  const int i = i0 + g;
  const int ri = i % SPP;
  const int hh = h2 >> 1;
  __shared__ __align__(16) float Ks[32][DQK];
  __shared__ __align__(16) float Vs[32][HD];
  __shared__ float Ps[32][32];
  float q[DQK];
  {
    const float* qrow = Qb + ((size_t)h2*S + i)*DQK;
#pragma unroll
    for (int xq = 0; xq < 12; ++xq) {
      float4 v = *reinterpret_cast<const float4*>(qrow + (xq<<2));
      q[xq*4+0]=v.x; q[xq*4+1]=v.y; q[xq*4+2]=v.z; q[xq*4+3]=v.w;
    }
  }
  float m = -1e30f, l = 0.f;
  float o[8] = {0.f,0.f,0.f,0.f,0.f,0.f,0.f,0.f};
  for (int j0 = 0; j0 < S; j0 += 32) {
    for (int idx = tid; idx < 384; idx += 256) {
      int r = idx / 12, c = (idx % 12) << 2;
      *reinterpret_cast<float4*>(&Ks[r][c]) =
        *reinterpret_cast<const float4*>(Kb + ((size_t)h2*S + j0 + r)*DQK + c);
    }
    for (int idx = tid; idx < 512; idx += 256) {
      int r = idx >> 4, c = (idx & 15) << 2;
      *reinterpret_cast<float4*>(&Vs[r][c]) =
        *reinterpret_cast<const float4*>(kvb + (size_t)(j0 + r)*2048 + hh*128 + 64 + c);
    }
    __syncthreads();
    float sv[4];
#pragma unroll
    for (int u = 0; u < 4; ++u) {
      int jj = (sub << 2) + u;
      float acc = 0.f;
#pragma unroll
      for (int kk = 0; kk < DQK; ++kk) acc = fmaf(q[kk], Ks[jj][kk], acc);
      int rj = (j0 + jj) % SPP;
      sv[u] = (rj <= ri) ? acc * SCALING : -1e30f;  // chunk0 always has a live key
    }
    float cm = fmaxf(fmaxf(sv[0], sv[1]), fmaxf(sv[2], sv[3]));
#pragma unroll
    for (int dlt = 1; dlt < 8; dlt <<= 1) cm = fmaxf(cm, __shfl_xor(cm, dlt, 8));
    float mnew = fmaxf(m, cm);
    float scale = __expf(m - mnew);
    l *= scale;
#pragma unroll
    for (int dd = 0; dd < 8; ++dd) o[dd] *= scale;
    float ps = 0.f;
#pragma unroll
    for (int u = 0; u < 4; ++u) {
      float p = __expf(sv[u] - mnew);
      Ps[g][(sub << 2) + u] = p;
      ps += p;
    }
#pragma unroll
    for (int dlt = 1; dlt < 8; dlt <<= 1) ps += __shfl_xor(ps, dlt, 8);
    l += ps;
    m = mnew;
#pragma unroll
    for (int jj = 0; jj < 32; ++jj) {       // same-wave Ps visibility: in-order LDS
      float p = Ps[g][jj];
      float4 va = *reinterpret_cast<const float4*>(&Vs[jj][sub << 3]);
      float4 vb = *reinterpret_cast<const float4*>(&Vs[jj][(sub << 3) + 4]);
      o[0]=fmaf(p,va.x,o[0]); o[1]=fmaf(p,va.y,o[1]); o[2]=fmaf(p,va.z,o[2]); o[3]=fmaf(p,va.w,o[3]);
      o[4]=fmaf(p,vb.x,o[4]); o[5]=fmaf(p,vb.y,o[5]); o[6]=fmaf(p,vb.z,o[6]); o[7]=fmaf(p,vb.w,o[7]);
    }
    __syncthreads();
  }
  float invl = 1.0f / l;
  size_t base = ((size_t)h2*S + i)*HD + (sub << 3);
  *reinterpret_cast<float4*>(Ob + base)     = make_float4(o[0]*invl,o[1]*invl,o[2]*invl,o[3]*invl);
  *reinterpret_cast<float4*>(Ob + base + 4) = make_float4(o[4]*invl,o[5]*invl,o[6]*invl,o[7]*invl);
  if (sub == 0) { rowm[h2*S + i] = m; rowl[h2*S + i] = l; }
}

// ---------------- pass 2: column sums of even-half-head probs ----------------
// gcol[hh][j] = (1/S) * sum_i P(2hh)[i,j];  grid (12, 16), 128 thr
__global__ __launch_bounds__(128) void colsum_g(const float* __restrict__ Qb,
    const float* __restrict__ Kb, const float* __restrict__ rowm,
    const float* __restrict__ rowl, float* __restrict__ gcol) {
  const int hh = blockIdx.y, h2 = hh * 2;
  const int j = blockIdx.x * 128 + threadIdx.x;
  float kreg[DQK];
  {
    const float* krow = Kb + ((size_t)h2*S + j)*DQK;
#pragma unroll
    for (int xq = 0; xq < 12; ++xq) {
      float4 v = *reinterpret_cast<const float4*>(krow + (xq<<2));
      kreg[xq*4+0]=v.x; kreg[xq*4+1]=v.y; kreg[xq*4+2]=v.z; kreg[xq*4+3]=v.w;
    }
  }
  const int rj = j % SPP;
  __shared__ __align__(16) float Qs[32][DQK];
  __shared__ float Ms[32], Ls[32];
  float acc = 0.f;
  for (int i0 = 0; i0 < S; i0 += 32) {
    for (int idx = threadIdx.x; idx < 384; idx += 128) {
      int r = idx / 12, c = (idx % 12) << 2;
      *reinterpret_cast<float4*>(&Qs[r][c]) =
        *reinterpret_cast<const float4*>(Qb + ((size_t)h2*S + i0 + r)*DQK + c);
    }
    if (threadIdx.x < 32) {
      Ms[threadIdx.x] = rowm[h2*S + i0 + threadIdx.x];
      Ls[threadIdx.x] = 1.0f / rowl[h2*S + i0 + threadIdx.x];
    }
    __syncthreads();
#pragma unroll 4
    for (int r = 0; r < 32; ++r) {
      int ri = (i0 + r) % SPP;
      if (rj <= ri) {
        float s = 0.f;
#pragma unroll
        for (int kk = 0; kk < DQK; ++kk) s = fmaf(kreg[kk], Qs[r][kk], s);
        acc += __expf(s * SCALING - Ms[r]) * Ls[r];
      }
    }
    __syncthreads();
  }
  gcol[hh*S + j] = acc * (1.0f / (float)S);
}

// ---------------- Wpre: masked prefix of g-weighted V ----------------
// Wpre[hh][r][d] = sum_{r'<=r} sum_{b=0..3} g[hh][b*384+r'] * v[b*384+r'][hh][d]
__global__ __launch_bounds__(256) void build_wpre(const float* __restrict__ gcol,
    const float* __restrict__ kvb, float* __restrict__ Wpre) {
  const int hh = blockIdx.x >> 2;
  const int dq = (blockIdx.x & 3) << 4;
  __shared__ float Wt[SPP][16];
  const int tid = threadIdx.x;
  for (int idx = tid; idx < SPP*16; idx += 256) {
    int r = idx >> 4, dd = idx & 15;
    float val = 0.f;
#pragma unroll
    for (int b2 = 0; b2 < 4; ++b2) {
      int j = b2*SPP + r;
      val = fmaf(gcol[hh*S + j], kvb[(size_t)j*2048 + hh*128 + 64 + dq + dd], val);
    }
    Wt[r][dd] = val;
  }
  __syncthreads();
  if (tid < 16) {
    float run = 0.f;
    for (int r = 0; r < SPP; ++r) { run += Wt[r][tid]; Wt[r][tid] = run; }
  }
  __syncthreads();
  for (int idx = tid; idx < SPP*16; idx += 256) {
    int r = idx >> 4, dd = idx & 15;
    Wpre[((size_t)hh*SPP + r)*HD + dq + dd] = Wt[r][dd];
  }
}

// ---------------- combine (diff-attn) + per-head RMSNorm + scrambled reshape ----
__global__ __launch_bounds__(64) void combine_rms(const float* __restrict__ Ob,
    const float* __restrict__ Wpre, const float* __restrict__ lamp,
    const float* __restrict__ anw, float* __restrict__ attno) {
  const int t = blockIdx.x, h = blockIdx.y, d = threadIdx.x;
  const float lam = lamp[0];
  const float o1 = Ob[((size_t)(2*h)*S + t)*HD + d];
  const float o2 = Ob[((size_t)(2*h+1)*S + t)*HD + d];
  const float w3 = Wpre[((size_t)h*SPP + (t % SPP))*HD + d];
  float val = o1 - lam*o2 + lam*w3;
  float ss = val*val;
#pragma unroll
  for (int mm = 1; mm < 64; mm <<= 1) ss += __shfl_xor(ss, mm, 64);
  float scale = rsqrtf(ss * (1.0f/HD) + ATTN_EPS) * anw[d];
  // reference reshapes (b,16,s,64)->(b,s,1024) WITHOUT transpose:
  int tn = h*96 + (t >> 4);
  int cn = ((t & 15) << 6) + d;
  attno[(size_t)tn*DM + cn] = val * scale;
}

// =========================== launch ===========================
extern "C" void kernel_launch(void* const* d_in, const int* in_sizes, int n_in,
                              void* d_out, int out_size, void* d_ws, size_t ws_size,
                              hipStream_t stream) {
  (void)in_sizes; (void)n_in; (void)out_size;
  const float* x    = (const float*)d_in[0];
  const float* fc   = (const float*)d_in[1];
  const float* fs   = (const float*)d_in[2];
  const float* n1w  = (const float*)d_in[3];
  const float* n2w  = (const float*)d_in[4];
  const float* kvdw = (const float*)d_in[5];
  const float* qdw  = (const float*)d_in[6];
  const float* kvnw = (const float*)d_in[7];
  const float* qnw  = (const float*)d_in[8];
  const float* kvuw = (const float*)d_in[9];
  const float* quw  = (const float*)d_in[10];
  const float* lq1  = (const float*)d_in[11];
  const float* lk1  = (const float*)d_in[12];
  const float* lq2  = (const float*)d_in[13];
  const float* lk2  = (const float*)d_in[14];
  const float* anw  = (const float*)d_in[15];
  const float* ow   = (const float*)d_in[16];
  const float* ffiw = (const float*)d_in[17];
  const float* ffow = (const float*)d_in[18];
  float* out = (float*)d_out;
  float* ws  = (float*)d_ws;

  // workspace map (floats); total 18,063,376 floats = 72.3 MB
  float* xin   = ws;
  float* ckv   = xin   + (size_t)S*DM;
  float* qmid  = ckv   + (size_t)S*288;
  float* kvb   = qmid  + (size_t)S*QC;
  float* qf    = kvb   + (size_t)S*2048;
  float* Qb    = qf    + (size_t)S*1536;
  float* Kb    = Qb    + (size_t)H2N*S*DQK;
  float* Obuf  = Kb    + (size_t)H2N*S*DQK;
  float* rowm  = Obuf  + (size_t)H2N*S*HD;
  float* rowl  = rowm  + (size_t)H2N*S;
  float* gcol  = rowl  + (size_t)H2N*S;
  float* Wpre  = gcol  + (size_t)NH*S;
  float* attno = Wpre  + (size_t)NH*SPP*HD;
  float* lamp  = attno + (size_t)S*DM;
  float* fbuf  = kvb;  // FFN activation reuses kv/qf region (free after attention)
  if (ws_size < (size_t)18063376 * sizeof(float)) return;  // would corrupt; bail

  rmsnorm_k<<<S, 256, 0, stream>>>(x, n1w, xin, DM, DM, DM, EPS_RMS);
  { dim3 g(5, 24);  sgemm_nt<0><<<g, 256, 0, stream>>>(xin, kvdw, nullptr, ckv, S, 288, DM, DM, DM, 288); }
  { dim3 g(6, 24);  sgemm_nt<0><<<g, 256, 0, stream>>>(xin, qdw,  nullptr, qmid, S, QC, DM, DM, DM, QC); }
  rmsnorm_k<<<S, 256, 0, stream>>>(ckv,  kvnw, ckv,  KVC, 288, 288, EPS_RMS);
  rmsnorm_k<<<S, 256, 0, stream>>>(qmid, qnw,  qmid, QC,  QC,  QC,  EPS_RMS);
  { dim3 g(32, 24); sgemm_nt<0><<<g, 256, 0, stream>>>(ckv,  kvuw, nullptr, kvb, S, 2048, KVC, 288, KVC, 2048); }
  { dim3 g(24, 24); sgemm_nt<0><<<g, 256, 0, stream>>>(qmid, quw,  nullptr, qf,  S, 1536, QC,  QC,  QC,  1536); }
  { dim3 g(6, 32);  build_qk<<<g, 256, 0, stream>>>(qf, kvb, ckv, fc, fs, Qb, Kb); }
  compute_lam<<<1, 32, 0, stream>>>(lq1, lk1, lq2, lk2, lamp);
  { dim3 g(48, 32); flash_fwd<<<g, 256, 0, stream>>>(Qb, Kb, kvb, Obuf, rowm, rowl); }
  { dim3 g(12, 16); colsum_g<<<g, 128, 0, stream>>>(Qb, Kb, rowm, rowl, gcol); }
  build_wpre<<<64, 256, 0, stream>>>(gcol, kvb, Wpre);
  { dim3 g(S, 16);  combine_rms<<<g, 64, 0, stream>>>(Obuf, Wpre, lamp, anw, attno); }
  { dim3 g(16, 24); sgemm_nt<1><<<g, 256, 0, stream>>>(attno, ow, x, out, S, DM, DM, DM, DM, DM); }
  rmsnorm_k<<<S, 256, 0, stream>>>(out, n2w, xin, DM, DM, DM, EPS_RMS);
  { dim3 g(64, 24); sgemm_glu<<<g, 256, 0, stream>>>(xin, ffiw, fbuf, S, DFF, DM, DM, DM, DFF); }
  { dim3 g(16, 24); sgemm_nt<1><<<g, 256, 0, stream>>>(fbuf, ffow, out, out, S, DM, DFF, DFF, DFF, DM); }
}

// Round 2
// 1740.831 us; speedup vs baseline: 1.3638x; 1.3638x over previous
//
#include <hip/hip_runtime.h>
#include <math.h>

#define S     1536
#define DM    1024
#define NH    16
#define H2N   32
#define HD    64
#define KVC   256
#define QC    384
#define DFF   4096
#define SPP   384
#define DQK   48
#define EPS_RMS  1.1920929e-07f
#define ATTN_EPS 1e-5f
#define SCALING  0.14433756729740643f   /* 48^-0.5 */

// ---------------- RMSNorm (generic, optional in-place) ----------------
__global__ __launch_bounds__(256) void rmsnorm_k(const float* __restrict__ in,
    const float* __restrict__ w, float* __restrict__ out,
    int cols, int ldin, int ldout, float eps) {
  const int row = blockIdx.x;
  const float* xr = in + (size_t)row * ldin;
  float* yr = out + (size_t)row * ldout;
  const int tid = threadIdx.x;
  float ss = 0.f;
  for (int c = tid << 2; c < cols; c += 1024) {
    float4 v = *reinterpret_cast<const float4*>(xr + c);
    ss += v.x*v.x + v.y*v.y + v.z*v.z + v.w*v.w;
  }
#pragma unroll
  for (int mm = 1; mm < 64; mm <<= 1) ss += __shfl_xor(ss, mm, 64);
  __shared__ float red[4];
  if ((tid & 63) == 0) red[tid >> 6] = ss;
  __syncthreads();
  float tot = red[0] + red[1] + red[2] + red[3];
  float scale = rsqrtf(tot / (float)cols + eps);
  for (int c = tid << 2; c < cols; c += 1024) {
    float4 v = *reinterpret_cast<const float4*>(xr + c);
    float4 wv = *reinterpret_cast<const float4*>(w + c);
    float4 ov = make_float4(v.x*scale*wv.x, v.y*scale*wv.y, v.z*scale*wv.z, v.w*scale*wv.w);
    *reinterpret_cast<float4*>(yr + c) = ov;
  }
}

// ---------------- SGEMM: C[M,N] = A[M,K] @ B[N,K]^T (+ src) ----------------
template<int ADD>
__global__ __launch_bounds__(256) void sgemm_nt(const float* __restrict__ A,
    const float* __restrict__ B, const float* __restrict__ src, float* __restrict__ C,
    int M, int N, int K, int lda, int ldb, int ldc) {
  __shared__ __align__(16) float As[16][64];
  __shared__ __align__(16) float Bs[16][64];
  const int bm = blockIdx.y * 64, bn = blockIdx.x * 64;
  const int tid = threadIdx.x;
  const int tx = tid & 15, ty = tid >> 4;
  const int lr = tid >> 2, lk = (tid & 3) << 2;
  const int arow = bm + lr, brow = bn + lr;
  float acc[4][4] = {};
  for (int k0 = 0; k0 < K; k0 += 16) {
    float4 av = make_float4(0.f,0.f,0.f,0.f), bv = make_float4(0.f,0.f,0.f,0.f);
    if (arow < M) av = *reinterpret_cast<const float4*>(A + (size_t)arow*lda + k0 + lk);
    if (brow < N) bv = *reinterpret_cast<const float4*>(B + (size_t)brow*ldb + k0 + lk);
    __syncthreads();
    As[lk+0][lr]=av.x; As[lk+1][lr]=av.y; As[lk+2][lr]=av.z; As[lk+3][lr]=av.w;
    Bs[lk+0][lr]=bv.x; Bs[lk+1][lr]=bv.y; Bs[lk+2][lr]=bv.z; Bs[lk+3][lr]=bv.w;
    __syncthreads();
#pragma unroll
    for (int k = 0; k < 16; ++k) {
      float4 a = *reinterpret_cast<const float4*>(&As[k][ty << 2]);
      float4 b = *reinterpret_cast<const float4*>(&Bs[k][tx << 2]);
      float ar[4] = {a.x,a.y,a.z,a.w};
      float br[4] = {b.x,b.y,b.z,b.w};
#pragma unroll
      for (int i = 0; i < 4; ++i)
#pragma unroll
        for (int j = 0; j < 4; ++j) acc[i][j] = fmaf(ar[i], br[j], acc[i][j]);
    }
  }
#pragma unroll
  for (int i = 0; i < 4; ++i) {
    int row = bm + (ty << 2) + i;
    if (row >= M) continue;
#pragma unroll
    for (int j = 0; j < 4; ++j) {
      int col = bn + (tx << 2) + j;
      if (col < N) {
        float v = acc[i][j];
        if (ADD) v += src[(size_t)row*ldc + col];
        C[(size_t)row*ldc + col] = v;
      }
    }
  }
}

// ------------- Fused SwiGLU GEMM: C = (A@Bu^T) * silu(A@Bv^T) -------------
// Bu = B rows [0,N), Bv = B rows [N,2N)
__global__ __launch_bounds__(256) void sgemm_glu(const float* __restrict__ A,
    const float* __restrict__ B, float* __restrict__ C,
    int M, int N, int K, int lda, int ldb, int ldc) {
  __shared__ __align__(16) float As[16][64];
  __shared__ __align__(16) float Bu[16][64];
  __shared__ __align__(16) float Bv[16][64];
  const int bm = blockIdx.y * 64, bn = blockIdx.x * 64;
  const int tid = threadIdx.x;
  const int tx = tid & 15, ty = tid >> 4;
  const int lr = tid >> 2, lk = (tid & 3) << 2;
  const int arow = bm + lr, brow = bn + lr;
  float au[4][4] = {}; float avv[4][4] = {};
  for (int k0 = 0; k0 < K; k0 += 16) {
    float4 a = make_float4(0.f,0.f,0.f,0.f);
    float4 u = make_float4(0.f,0.f,0.f,0.f);
    float4 v = make_float4(0.f,0.f,0.f,0.f);
    if (arow < M) a = *reinterpret_cast<const float4*>(A + (size_t)arow*lda + k0 + lk);
    if (brow < N) {
      u = *reinterpret_cast<const float4*>(B + (size_t)brow*ldb + k0 + lk);
      v = *reinterpret_cast<const float4*>(B + (size_t)(N + brow)*ldb + k0 + lk);
    }
    __syncthreads();
    As[lk+0][lr]=a.x; As[lk+1][lr]=a.y; As[lk+2][lr]=a.z; As[lk+3][lr]=a.w;
    Bu[lk+0][lr]=u.x; Bu[lk+1][lr]=u.y; Bu[lk+2][lr]=u.z; Bu[lk+3][lr]=u.w;
    Bv[lk+0][lr]=v.x; Bv[lk+1][lr]=v.y; Bv[lk+2][lr]=v.z; Bv[lk+3][lr]=v.w;
    __syncthreads();
#pragma unroll
    for (int k = 0; k < 16; ++k) {
      float4 a4 = *reinterpret_cast<const float4*>(&As[k][ty << 2]);
      float4 u4 = *reinterpret_cast<const float4*>(&Bu[k][tx << 2]);
      float4 v4 = *reinterpret_cast<const float4*>(&Bv[k][tx << 2]);
      float ar[4] = {a4.x,a4.y,a4.z,a4.w};
      float ur[4] = {u4.x,u4.y,u4.z,u4.w};
      float vr[4] = {v4.x,v4.y,v4.z,v4.w};
#pragma unroll
      for (int i = 0; i < 4; ++i)
#pragma unroll
        for (int j = 0; j < 4; ++j) {
          au[i][j]  = fmaf(ar[i], ur[j], au[i][j]);
          avv[i][j] = fmaf(ar[i], vr[j], avv[i][j]);
        }
    }
  }
#pragma unroll
  for (int i = 0; i < 4; ++i) {
    int row = bm + (ty << 2) + i;
    if (row >= M) continue;
#pragma unroll
    for (int j = 0; j < 4; ++j) {
      int col = bn + (tx << 2) + j;
      if (col < N) {
        float uu = au[i][j], vg = avv[i][j];
        float sig = 1.0f / (1.0f + __expf(-vg));
        C[(size_t)row*ldc + col] = uu * vg * sig;
      }
    }
  }
}

// ---------------- Build Q/K (split heads + RoPE) ----------------
// Qb/Kb layout: [h2][t][48]  (32 dims content + 16 dims rotated rope)
__global__ __launch_bounds__(256) void build_qk(const float* __restrict__ qf,
    const float* __restrict__ kvb, const float* __restrict__ ckv,
    const float* __restrict__ fc, const float* __restrict__ fs,
    float* __restrict__ Qb, float* __restrict__ Kb) {
  int t = blockIdx.x * 256 + threadIdx.x;
  int h2 = blockIdx.y;
  if (t >= S) return;
  int hh = h2 >> 1, par = h2 & 1;
  const float* qrow = qf + (size_t)t*1536 + hh*96;
  const float* krow = kvb + (size_t)t*2048 + hh*128;
  float* qo = Qb + ((size_t)h2*S + t)*DQK;
  float* ko = Kb + ((size_t)h2*S + t)*DQK;
#pragma unroll
  for (int xq = 0; xq < 8; ++xq) {
    *reinterpret_cast<float4*>(qo + (xq<<2)) =
      *reinterpret_cast<const float4*>(qrow + par*32 + (xq<<2));
    *reinterpret_cast<float4*>(ko + (xq<<2)) =
      *reinterpret_cast<const float4*>(krow + par*32 + (xq<<2));
  }
  int p = t >> 2;  // rope position: s splits as (spp, NUM_SEQ) with spp OUTER
  const float* qr = qrow + 64 + par*16;
  const float* kr = ckv + (size_t)t*288 + 256 + par*16;
#pragma unroll
  for (int mq = 0; mq < 8; ++mq) {
    float c = 1.f, sn = 0.f;
    if (p > 0) { c = fc[(p-1)*8 + mq]; sn = fs[(p-1)*8 + mq]; }
    float q0 = qr[2*mq], q1 = qr[2*mq+1];
    qo[32 + 2*mq]     = q0*c - q1*sn;
    qo[32 + 2*mq + 1] = q0*sn + q1*c;
    float k0 = kr[2*mq], k1 = kr[2*mq+1];
    ko[32 + 2*mq]     = k0*c - k1*sn;
    ko[32 + 2*mq + 1] = k0*sn + k1*c;
  }
}

// ---------------- lambda scalar ----------------
__global__ void compute_lam(const float* __restrict__ lq1, const float* __restrict__ lk1,
                            const float* __restrict__ lq2, const float* __restrict__ lk2,
                            float* __restrict__ lamp) {
  int t = threadIdx.x;  // 32 threads
  float a = lq1[t]*lk1[t];
  float b = lq2[t]*lk2[t];
#pragma unroll
  for (int mm = 1; mm < 32; mm <<= 1) { a += __shfl_xor(a, mm, 32); b += __shfl_xor(b, mm, 32); }
  if (t == 0) lamp[0] = expf(a) - expf(b) + 0.2f;  // LAMBDA_INIT = 0.2
}

// ---------------- Flash attention pass 1 ----------------
// grid (24, 32); 256 thr; 8-thread group per query row; 2 rows per thread
// (64 rows/block). Conflict-free LDS: Ks[32][52] (b128 starts 8 disjoint
// 4-bank spans for jj=sub+8u), Vs[32][64] (broadcast), Ps[64][36].
__global__ __launch_bounds__(256) void flash_fwd(const float* __restrict__ Qb,
    const float* __restrict__ Kb, const float* __restrict__ kvb,
    float* __restrict__ Ob, float* __restrict__ rowm, float* __restrict__ rowl) {
  const int h2 = blockIdx.y;
  const int i0 = blockIdx.x << 6;
  const int tid = threadIdx.x;
  const int g = tid >> 3, sub = tid & 7;
  const int ia = i0 + g, ib = i0 + 32 + g;
  const int ria = ia % SPP, rib = ib % SPP;
  const int hh = h2 >> 1;
  __shared__ __align__(16) float Ks[32][52];
  __shared__ __align__(16) float Vs[32][64];
  __shared__ __align__(16) float Ps[64][36];
  float qa[DQK], qb[DQK];
  {
    const float* qra = Qb + ((size_t)h2*S + ia)*DQK;
    const float* qrb = Qb + ((size_t)h2*S + ib)*DQK;
#pragma unroll
    for (int xq = 0; xq < 12; ++xq) {
      float4 v = *reinterpret_cast<const float4*>(qra + (xq<<2));
      qa[xq*4+0]=v.x; qa[xq*4+1]=v.y; qa[xq*4+2]=v.z; qa[xq*4+3]=v.w;
      float4 w = *reinterpret_cast<const float4*>(qrb + (xq<<2));
      qb[xq*4+0]=w.x; qb[xq*4+1]=w.y; qb[xq*4+2]=w.z; qb[xq*4+3]=w.w;
    }
  }
  float ma = -1e30f, la = 0.f, mb = -1e30f, lb = 0.f;
  float oa[8] = {0.f,0.f,0.f,0.f,0.f,0.f,0.f,0.f};
  float ob[8] = {0.f,0.f,0.f,0.f,0.f,0.f,0.f,0.f};
  for (int j0 = 0; j0 < S; j0 += 32) {
    for (int idx = tid; idx < 384; idx += 256) {
      int r = idx / 12, cq = (idx % 12) << 2;
      *reinterpret_cast<float4*>(&Ks[r][cq]) =
        *reinterpret_cast<const float4*>(Kb + ((size_t)h2*S + j0 + r)*DQK + cq);
    }
    for (int idx = tid; idx < 512; idx += 256) {
      int r = idx >> 4, c = (idx & 15) << 2;
      *reinterpret_cast<float4*>(&Vs[r][c]) =
        *reinterpret_cast<const float4*>(kvb + (size_t)(j0 + r)*2048 + hh*128 + 64 + c);
    }
    __syncthreads();
    float sa[4], sb[4];
#pragma unroll
    for (int u = 0; u < 4; ++u) {
      const int jj = sub + (u << 3);
      float aca = 0.f, acb = 0.f;
#pragma unroll
      for (int kq = 0; kq < 12; ++kq) {
        float4 k4 = *reinterpret_cast<const float4*>(&Ks[jj][kq << 2]);
        aca = fmaf(qa[kq*4+0], k4.x, aca); acb = fmaf(qb[kq*4+0], k4.x, acb);
        aca = fmaf(qa[kq*4+1], k4.y, aca); acb = fmaf(qb[kq*4+1], k4.y, acb);
        aca = fmaf(qa[kq*4+2], k4.z, aca); acb = fmaf(qb[kq*4+2], k4.z, acb);
        aca = fmaf(qa[kq*4+3], k4.w, aca); acb = fmaf(qb[kq*4+3], k4.w, acb);
      }
      int rj = (j0 + jj) % SPP;
      sa[u] = (rj <= ria) ? aca * SCALING : -1e30f;
      sb[u] = (rj <= rib) ? acb * SCALING : -1e30f;
    }
    // row a softmax update
    {
      float cm = fmaxf(fmaxf(sa[0], sa[1]), fmaxf(sa[2], sa[3]));
#pragma unroll
      for (int dlt = 1; dlt < 8; dlt <<= 1) cm = fmaxf(cm, __shfl_xor(cm, dlt, 8));
      float mnew = fmaxf(ma, cm);
      float scale = __expf(ma - mnew);
      la *= scale;
#pragma unroll
      for (int dd = 0; dd < 8; ++dd) oa[dd] *= scale;
      float ps = 0.f;
#pragma unroll
      for (int u = 0; u < 4; ++u) {
        float p = __expf(sa[u] - mnew);
        Ps[g][sub + (u << 3)] = p;
        ps += p;
      }
#pragma unroll
      for (int dlt = 1; dlt < 8; dlt <<= 1) ps += __shfl_xor(ps, dlt, 8);
      la += ps;
      ma = mnew;
    }
    // row b softmax update
    {
      float cm = fmaxf(fmaxf(sb[0], sb[1]), fmaxf(sb[2], sb[3]));
#pragma unroll
      for (int dlt = 1; dlt < 8; dlt <<= 1) cm = fmaxf(cm, __shfl_xor(cm, dlt, 8));
      float mnew = fmaxf(mb, cm);
      float scale = __expf(mb - mnew);
      lb *= scale;
#pragma unroll
      for (int dd = 0; dd < 8; ++dd) ob[dd] *= scale;
      float ps = 0.f;
#pragma unroll
      for (int u = 0; u < 4; ++u) {
        float p = __expf(sb[u] - mnew);
        Ps[32 + g][sub + (u << 3)] = p;
        ps += p;
      }
#pragma unroll
      for (int dlt = 1; dlt < 8; dlt <<= 1) ps += __shfl_xor(ps, dlt, 8);
      lb += ps;
      mb = mnew;
    }
    // PV: same-wave LDS (in-order) — no barrier needed before reads
#pragma unroll
    for (int j4 = 0; j4 < 8; ++j4) {
      float4 pa4 = *reinterpret_cast<const float4*>(&Ps[g][j4 << 2]);
      float4 pb4 = *reinterpret_cast<const float4*>(&Ps[32 + g][j4 << 2]);
      float par_[4] = {pa4.x, pa4.y, pa4.z, pa4.w};
      float pbr_[4] = {pb4.x, pb4.y, pb4.z, pb4.w};
#pragma unroll
      for (int e = 0; e < 4; ++e) {
        int jj = (j4 << 2) + e;
        float pav = par_[e], pbv = pbr_[e];
        float4 va = *reinterpret_cast<const float4*>(&Vs[jj][sub << 3]);
        float4 vb = *reinterpret_cast<const float4*>(&Vs[jj][(sub << 3) + 4]);
        oa[0]=fmaf(pav,va.x,oa[0]); oa[1]=fmaf(pav,va.y,oa[1]);
        oa[2]=fmaf(pav,va.z,oa[2]); oa[3]=fmaf(pav,va.w,oa[3]);
        oa[4]=fmaf(pav,vb.x,oa[4]); oa[5]=fmaf(pav,vb.y,oa[5]);
        oa[6]=fmaf(pav,vb.z,oa[6]); oa[7]=fmaf(pav,vb.w,oa[7]);
        ob[0]=fmaf(pbv,va.x,ob[0]); ob[1]=fmaf(pbv,va.y,ob[1]);
        ob[2]=fmaf(pbv,va.z,ob[2]); ob[3]=fmaf(pbv,va.w,ob[3]);
        ob[4]=fmaf(pbv,vb.x,ob[4]); ob[5]=fmaf(pbv,vb.y,ob[5]);
        ob[6]=fmaf(pbv,vb.z,ob[6]); ob[7]=fmaf(pbv,vb.w,ob[7]);
      }
    }
    __syncthreads();
  }
  {
    float invl = 1.0f / la;
    size_t base = ((size_t)h2*S + ia)*HD + (sub << 3);
    *reinterpret_cast<float4*>(Ob + base)     = make_float4(oa[0]*invl,oa[1]*invl,oa[2]*invl,oa[3]*invl);
    *reinterpret_cast<float4*>(Ob + base + 4) = make_float4(oa[4]*invl,oa[5]*invl,oa[6]*invl,oa[7]*invl);
  }
  {
    float invl = 1.0f / lb;
    size_t base = ((size_t)h2*S + ib)*HD + (sub << 3);
    *reinterpret_cast<float4*>(Ob + base)     = make_float4(ob[0]*invl,ob[1]*invl,ob[2]*invl,ob[3]*invl);
    *reinterpret_cast<float4*>(Ob + base + 4) = make_float4(ob[4]*invl,ob[5]*invl,ob[6]*invl,ob[7]*invl);
  }
  if (sub == 0) {
    rowm[h2*S + ia] = ma; rowl[h2*S + ia] = la;
    rowm[h2*S + ib] = mb; rowl[h2*S + ib] = lb;
  }
}

// ---------------- pass 2: column sums of even-half-head probs ----------------
// gcol[hh][j] = (1/S) * sum_i P(2hh)[i,j];  grid (12, 16), 128 thr
__global__ __launch_bounds__(128) void colsum_g(const float* __restrict__ Qb,
    const float* __restrict__ Kb, const float* __restrict__ rowm,
    const float* __restrict__ rowl, float* __restrict__ gcol) {
  const int hh = blockIdx.y, h2 = hh * 2;
  const int j = blockIdx.x * 128 + threadIdx.x;
  float kreg[DQK];
  {
    const float* krow = Kb + ((size_t)h2*S + j)*DQK;
#pragma unroll
    for (int xq = 0; xq < 12; ++xq) {
      float4 v = *reinterpret_cast<const float4*>(krow + (xq<<2));
      kreg[xq*4+0]=v.x; kreg[xq*4+1]=v.y; kreg[xq*4+2]=v.z; kreg[xq*4+3]=v.w;
    }
  }
  const int rj = j % SPP;
  __shared__ __align__(16) float Qs[32][DQK];
  __shared__ float Ms[32], Ls[32];
  float acc = 0.f;
  for (int i0 = 0; i0 < S; i0 += 32) {
    for (int idx = threadIdx.x; idx < 384; idx += 128) {
      int r = idx / 12, c = (idx % 12) << 2;
      *reinterpret_cast<float4*>(&Qs[r][c]) =
        *reinterpret_cast<const float4*>(Qb + ((size_t)h2*S + i0 + r)*DQK + c);
    }
    if (threadIdx.x < 32) {
      Ms[threadIdx.x] = rowm[h2*S + i0 + threadIdx.x];
      Ls[threadIdx.x] = 1.0f / rowl[h2*S + i0 + threadIdx.x];
    }
    __syncthreads();
#pragma unroll 4
    for (int r = 0; r < 32; ++r) {
      int ri = (i0 + r) % SPP;
      if (rj <= ri) {
        float s = 0.f;
#pragma unroll
        for (int kk = 0; kk < DQK; ++kk) s = fmaf(kreg[kk], Qs[r][kk], s);
        acc += __expf(s * SCALING - Ms[r]) * Ls[r];
      }
    }
    __syncthreads();
  }
  gcol[hh*S + j] = acc * (1.0f / (float)S);
}

// ---------------- Wpre: masked prefix of g-weighted V ----------------
// Wpre[hh][r][d] = sum_{r'<=r} sum_{b=0..3} g[hh][b*384+r'] * v[b*384+r'][hh][d]
__global__ __launch_bounds__(256) void build_wpre(const float* __restrict__ gcol,
    const float* __restrict__ kvb, float* __restrict__ Wpre) {
  const int hh = blockIdx.x >> 2;
  const int dq = (blockIdx.x & 3) << 4;
  __shared__ float Wt[SPP][16];
  const int tid = threadIdx.x;
  for (int idx = tid; idx < SPP*16; idx += 256) {
    int r = idx >> 4, dd = idx & 15;
    float val = 0.f;
#pragma unroll
    for (int b2 = 0; b2 < 4; ++b2) {
      int j = b2*SPP + r;
      val = fmaf(gcol[hh*S + j], kvb[(size_t)j*2048 + hh*128 + 64 + dq + dd], val);
    }
    Wt[r][dd] = val;
  }
  __syncthreads();
  if (tid < 16) {
    float run = 0.f;
    for (int r = 0; r < SPP; ++r) { run += Wt[r][tid]; Wt[r][tid] = run; }
  }
  __syncthreads();
  for (int idx = tid; idx < SPP*16; idx += 256) {
    int r = idx >> 4, dd = idx & 15;
    Wpre[((size_t)hh*SPP + r)*HD + dq + dd] = Wt[r][dd];
  }
}

// ---------------- combine (diff-attn) + per-head RMSNorm + scrambled reshape ----
__global__ __launch_bounds__(64) void combine_rms(const float* __restrict__ Ob,
    const float* __restrict__ Wpre, const float* __restrict__ lamp,
    const float* __restrict__ anw, float* __restrict__ attno) {
  const int t = blockIdx.x, h = blockIdx.y, d = threadIdx.x;
  const float lam = lamp[0];
  const float o1 = Ob[((size_t)(2*h)*S + t)*HD + d];
  const float o2 = Ob[((size_t)(2*h+1)*S + t)*HD + d];
  const float w3 = Wpre[((size_t)h*SPP + (t % SPP))*HD + d];
  float val = o1 - lam*o2 + lam*w3;
  float ss = val*val;
#pragma unroll
  for (int mm = 1; mm < 64; mm <<= 1) ss += __shfl_xor(ss, mm, 64);
  float scale = rsqrtf(ss * (1.0f/HD) + ATTN_EPS) * anw[d];
  // reference reshapes (b,16,s,64)->(b,s,1024) WITHOUT transpose:
  int tn = h*96 + (t >> 4);
  int cn = ((t & 15) << 6) + d;
  attno[(size_t)tn*DM + cn] = val * scale;
}

// =========================== launch ===========================
extern "C" void kernel_launch(void* const* d_in, const int* in_sizes, int n_in,
                              void* d_out, int out_size, void* d_ws, size_t ws_size,
                              hipStream_t stream) {
  (void)in_sizes; (void)n_in; (void)out_size;
  const float* x    = (const float*)d_in[0];
  const float* fc   = (const float*)d_in[1];
  const float* fs   = (const float*)d_in[2];
  const float* n1w  = (const float*)d_in[3];
  const float* n2w  = (const float*)d_in[4];
  const float* kvdw = (const float*)d_in[5];
  const float* qdw  = (const float*)d_in[6];
  const float* kvnw = (const float*)d_in[7];
  const float* qnw  = (const float*)d_in[8];
  const float* kvuw = (const float*)d_in[9];
  const float* quw  = (const float*)d_in[10];
  const float* lq1  = (const float*)d_in[11];
  const float* lk1  = (const float*)d_in[12];
  const float* lq2  = (const float*)d_in[13];
  const float* lk2  = (const float*)d_in[14];
  const float* anw  = (const float*)d_in[15];
  const float* ow   = (const float*)d_in[16];
  const float* ffiw = (const float*)d_in[17];
  const float* ffow = (const float*)d_in[18];
  float* out = (float*)d_out;
  float* ws  = (float*)d_ws;

  // workspace map (floats); total 18,063,376 floats = 72.3 MB
  float* xin   = ws;
  float* ckv   = xin   + (size_t)S*DM;
  float* qmid  = ckv   + (size_t)S*288;
  float* kvb   = qmid  + (size_t)S*QC;
  float* qf    = kvb   + (size_t)S*2048;
  float* Qb    = qf    + (size_t)S*1536;
  float* Kb    = Qb    + (size_t)H2N*S*DQK;
  float* Obuf  = Kb    + (size_t)H2N*S*DQK;
  float* rowm  = Obuf  + (size_t)H2N*S*HD;
  float* rowl  = rowm  + (size_t)H2N*S;
  float* gcol  = rowl  + (size_t)H2N*S;
  float* Wpre  = gcol  + (size_t)NH*S;
  float* attno = Wpre  + (size_t)NH*SPP*HD;
  float* lamp  = attno + (size_t)S*DM;
  float* fbuf  = kvb;  // FFN activation reuses kv/qf region (free after attention)
  if (ws_size < (size_t)18063376 * sizeof(float)) return;  // would corrupt; bail

  rmsnorm_k<<<S, 256, 0, stream>>>(x, n1w, xin, DM, DM, DM, EPS_RMS);
  { dim3 g(5, 24);  sgemm_nt<0><<<g, 256, 0, stream>>>(xin, kvdw, nullptr, ckv, S, 288, DM, DM, DM, 288); }
  { dim3 g(6, 24);  sgemm_nt<0><<<g, 256, 0, stream>>>(xin, qdw,  nullptr, qmid, S, QC, DM, DM, DM, QC); }
  rmsnorm_k<<<S, 256, 0, stream>>>(ckv,  kvnw, ckv,  KVC, 288, 288, EPS_RMS);
  rmsnorm_k<<<S, 256, 0, stream>>>(qmid, qnw,  qmid, QC,  QC,  QC,  EPS_RMS);
  { dim3 g(32, 24); sgemm_nt<0><<<g, 256, 0, stream>>>(ckv,  kvuw, nullptr, kvb, S, 2048, KVC, 288, KVC, 2048); }
  { dim3 g(24, 24); sgemm_nt<0><<<g, 256, 0, stream>>>(qmid, quw,  nullptr, qf,  S, 1536, QC,  QC,  QC,  1536); }
  { dim3 g(6, 32);  build_qk<<<g, 256, 0, stream>>>(qf, kvb, ckv, fc, fs, Qb, Kb); }
  compute_lam<<<1, 32, 0, stream>>>(lq1, lk1, lq2, lk2, lamp);
  { dim3 g(24, 32); flash_fwd<<<g, 256, 0, stream>>>(Qb, Kb, kvb, Obuf, rowm, rowl); }
  { dim3 g(12, 16); colsum_g<<<g, 128, 0, stream>>>(Qb, Kb, rowm, rowl, gcol); }
  build_wpre<<<64, 256, 0, stream>>>(gcol, kvb, Wpre);
  { dim3 g(S, 16);  combine_rms<<<g, 64, 0, stream>>>(Obuf, Wpre, lamp, anw, attno); }
  { dim3 g(16, 24); sgemm_nt<1><<<g, 256, 0, stream>>>(attno, ow, x, out, S, DM, DM, DM, DM, DM); }
  rmsnorm_k<<<S, 256, 0, stream>>>(out, n2w, xin, DM, DM, DM, EPS_RMS);
  { dim3 g(64, 24); sgemm_glu<<<g, 256, 0, stream>>>(xin, ffiw, fbuf, S, DFF, DM, DM, DM, DFF); }
  { dim3 g(16, 24); sgemm_nt<1><<<g, 256, 0, stream>>>(fbuf, ffow, out, out, S, DM, DFF, DFF, DFF, DM); }
}

// Round 3
// 1337.438 us; speedup vs baseline: 1.7751x; 1.3016x over previous
//
#include <hip/hip_runtime.h>
#include <math.h>

#define S     1536
#define DM    1024
#define NH    16
#define H2N   32
#define HD    64
#define KVC   256
#define QC    384
#define DFF   4096
#define SPP   384
#define DQK   48
#define EPS_RMS  1.1920929e-07f
#define ATTN_EPS 1e-5f
#define SCALING  0.14433756729740643f   /* 48^-0.5 */

// ---------------- RMSNorm (generic, optional in-place) ----------------
__global__ __launch_bounds__(256) void rmsnorm_k(const float* __restrict__ in,
    const float* __restrict__ w, float* __restrict__ out,
    int cols, int ldin, int ldout, float eps) {
  const int row = blockIdx.x;
  const float* xr = in + (size_t)row * ldin;
  float* yr = out + (size_t)row * ldout;
  const int tid = threadIdx.x;
  float ss = 0.f;
  for (int c = tid << 2; c < cols; c += 1024) {
    float4 v = *reinterpret_cast<const float4*>(xr + c);
    ss += v.x*v.x + v.y*v.y + v.z*v.z + v.w*v.w;
  }
#pragma unroll
  for (int mm = 1; mm < 64; mm <<= 1) ss += __shfl_xor(ss, mm, 64);
  __shared__ float red[4];
  if ((tid & 63) == 0) red[tid >> 6] = ss;
  __syncthreads();
  float tot = red[0] + red[1] + red[2] + red[3];
  float scale = rsqrtf(tot / (float)cols + eps);
  for (int c = tid << 2; c < cols; c += 1024) {
    float4 v = *reinterpret_cast<const float4*>(xr + c);
    float4 wv = *reinterpret_cast<const float4*>(w + c);
    float4 ov = make_float4(v.x*scale*wv.x, v.y*scale*wv.y, v.z*scale*wv.z, v.w*scale*wv.w);
    *reinterpret_cast<float4*>(yr + c) = ov;
  }
}

// ---------------- SGEMM: C[M,N] = A[M,K] @ B[N,K]^T (+ src) ----------------
template<int ADD>
__global__ __launch_bounds__(256) void sgemm_nt(const float* __restrict__ A,
    const float* __restrict__ B, const float* __restrict__ src, float* __restrict__ C,
    int M, int N, int K, int lda, int ldb, int ldc) {
  __shared__ __align__(16) float As[16][64];
  __shared__ __align__(16) float Bs[16][64];
  const int bm = blockIdx.y * 64, bn = blockIdx.x * 64;
  const int tid = threadIdx.x;
  const int tx = tid & 15, ty = tid >> 4;
  const int lr = tid >> 2, lk = (tid & 3) << 2;
  const int arow = bm + lr, brow = bn + lr;
  float acc[4][4] = {};
  for (int k0 = 0; k0 < K; k0 += 16) {
    float4 av = make_float4(0.f,0.f,0.f,0.f), bv = make_float4(0.f,0.f,0.f,0.f);
    if (arow < M) av = *reinterpret_cast<const float4*>(A + (size_t)arow*lda + k0 + lk);
    if (brow < N) bv = *reinterpret_cast<const float4*>(B + (size_t)brow*ldb + k0 + lk);
    __syncthreads();
    As[lk+0][lr]=av.x; As[lk+1][lr]=av.y; As[lk+2][lr]=av.z; As[lk+3][lr]=av.w;
    Bs[lk+0][lr]=bv.x; Bs[lk+1][lr]=bv.y; Bs[lk+2][lr]=bv.z; Bs[lk+3][lr]=bv.w;
    __syncthreads();
#pragma unroll
    for (int k = 0; k < 16; ++k) {
      float4 a = *reinterpret_cast<const float4*>(&As[k][ty << 2]);
      float4 b = *reinterpret_cast<const float4*>(&Bs[k][tx << 2]);
      float ar[4] = {a.x,a.y,a.z,a.w};
      float br[4] = {b.x,b.y,b.z,b.w};
#pragma unroll
      for (int i = 0; i < 4; ++i)
#pragma unroll
        for (int j = 0; j < 4; ++j) acc[i][j] = fmaf(ar[i], br[j], acc[i][j]);
    }
  }
#pragma unroll
  for (int i = 0; i < 4; ++i) {
    int row = bm + (ty << 2) + i;
    if (row >= M) continue;
#pragma unroll
    for (int j = 0; j < 4; ++j) {
      int col = bn + (tx << 2) + j;
      if (col < N) {
        float v = acc[i][j];
        if (ADD) v += src[(size_t)row*ldc + col];
        C[(size_t)row*ldc + col] = v;
      }
    }
  }
}

// ------------- Fused SwiGLU GEMM: C = (A@Bu^T) * silu(A@Bv^T) -------------
// Bu = B rows [0,N), Bv = B rows [N,2N)
__global__ __launch_bounds__(256) void sgemm_glu(const float* __restrict__ A,
    const float* __restrict__ B, float* __restrict__ C,
    int M, int N, int K, int lda, int ldb, int ldc) {
  __shared__ __align__(16) float As[16][64];
  __shared__ __align__(16) float Bu[16][64];
  __shared__ __align__(16) float Bv[16][64];
  const int bm = blockIdx.y * 64, bn = blockIdx.x * 64;
  const int tid = threadIdx.x;
  const int tx = tid & 15, ty = tid >> 4;
  const int lr = tid >> 2, lk = (tid & 3) << 2;
  const int arow = bm + lr, brow = bn + lr;
  float au[4][4] = {}; float avv[4][4] = {};
  for (int k0 = 0; k0 < K; k0 += 16) {
    float4 a = make_float4(0.f,0.f,0.f,0.f);
    float4 u = make_float4(0.f,0.f,0.f,0.f);
    float4 v = make_float4(0.f,0.f,0.f,0.f);
    if (arow < M) a = *reinterpret_cast<const float4*>(A + (size_t)arow*lda + k0 + lk);
    if (brow < N) {
      u = *reinterpret_cast<const float4*>(B + (size_t)brow*ldb + k0 + lk);
      v = *reinterpret_cast<const float4*>(B + (size_t)(N + brow)*ldb + k0 + lk);
    }
    __syncthreads();
    As[lk+0][lr]=a.x; As[lk+1][lr]=a.y; As[lk+2][lr]=a.z; As[lk+3][lr]=a.w;
    Bu[lk+0][lr]=u.x; Bu[lk+1][lr]=u.y; Bu[lk+2][lr]=u.z; Bu[lk+3][lr]=u.w;
    Bv[lk+0][lr]=v.x; Bv[lk+1][lr]=v.y; Bv[lk+2][lr]=v.z; Bv[lk+3][lr]=v.w;
    __syncthreads();
#pragma unroll
    for (int k = 0; k < 16; ++k) {
      float4 a4 = *reinterpret_cast<const float4*>(&As[k][ty << 2]);
      float4 u4 = *reinterpret_cast<const float4*>(&Bu[k][tx << 2]);
      float4 v4 = *reinterpret_cast<const float4*>(&Bv[k][tx << 2]);
      float ar[4] = {a4.x,a4.y,a4.z,a4.w};
      float ur[4] = {u4.x,u4.y,u4.z,u4.w};
      float vr[4] = {v4.x,v4.y,v4.z,v4.w};
#pragma unroll
      for (int i = 0; i < 4; ++i)
#pragma unroll
        for (int j = 0; j < 4; ++j) {
          au[i][j]  = fmaf(ar[i], ur[j], au[i][j]);
          avv[i][j] = fmaf(ar[i], vr[j], avv[i][j]);
        }
    }
  }
#pragma unroll
  for (int i = 0; i < 4; ++i) {
    int row = bm + (ty << 2) + i;
    if (row >= M) continue;
#pragma unroll
    for (int j = 0; j < 4; ++j) {
      int col = bn + (tx << 2) + j;
      if (col < N) {
        float uu = au[i][j], vg = avv[i][j];
        float sig = 1.0f / (1.0f + __expf(-vg));
        C[(size_t)row*ldc + col] = uu * vg * sig;
      }
    }
  }
}

// ---------------- Build Q/K (split heads + RoPE) ----------------
// Qb/Kb layout: [h2][t][48]  (32 dims content + 16 dims rotated rope)
__global__ __launch_bounds__(256) void build_qk(const float* __restrict__ qf,
    const float* __restrict__ kvb, const float* __restrict__ ckv,
    const float* __restrict__ fc, const float* __restrict__ fs,
    float* __restrict__ Qb, float* __restrict__ Kb) {
  int t = blockIdx.x * 256 + threadIdx.x;
  int h2 = blockIdx.y;
  if (t >= S) return;
  int hh = h2 >> 1, par = h2 & 1;
  const float* qrow = qf + (size_t)t*1536 + hh*96;
  const float* krow = kvb + (size_t)t*2048 + hh*128;
  float* qo = Qb + ((size_t)h2*S + t)*DQK;
  float* ko = Kb + ((size_t)h2*S + t)*DQK;
#pragma unroll
  for (int xq = 0; xq < 8; ++xq) {
    *reinterpret_cast<float4*>(qo + (xq<<2)) =
      *reinterpret_cast<const float4*>(qrow + par*32 + (xq<<2));
    *reinterpret_cast<float4*>(ko + (xq<<2)) =
      *reinterpret_cast<const float4*>(krow + par*32 + (xq<<2));
  }
  int p = t >> 2;  // rope position: s splits as (spp, NUM_SEQ) with spp OUTER
  const float* qr = qrow + 64 + par*16;
  const float* kr = ckv + (size_t)t*288 + 256 + par*16;
#pragma unroll
  for (int mq = 0; mq < 8; ++mq) {
    float c = 1.f, sn = 0.f;
    if (p > 0) { c = fc[(p-1)*8 + mq]; sn = fs[(p-1)*8 + mq]; }
    float q0 = qr[2*mq], q1 = qr[2*mq+1];
    qo[32 + 2*mq]     = q0*c - q1*sn;
    qo[32 + 2*mq + 1] = q0*sn + q1*c;
    float k0 = kr[2*mq], k1 = kr[2*mq+1];
    ko[32 + 2*mq]     = k0*c - k1*sn;
    ko[32 + 2*mq + 1] = k0*sn + k1*c;
  }
}

// ---------------- lambda scalar ----------------
__global__ void compute_lam(const float* __restrict__ lq1, const float* __restrict__ lk1,
                            const float* __restrict__ lq2, const float* __restrict__ lk2,
                            float* __restrict__ lamp) {
  int t = threadIdx.x;  // 32 threads
  float a = lq1[t]*lk1[t];
  float b = lq2[t]*lk2[t];
#pragma unroll
  for (int mm = 1; mm < 32; mm <<= 1) { a += __shfl_xor(a, mm, 32); b += __shfl_xor(b, mm, 32); }
  if (t == 0) lamp[0] = expf(a) - expf(b) + 0.2f;  // LAMBDA_INIT = 0.2
}

// ---------------- Flash attention pass 1 ----------------
// grid (24, 32); 256 thr; 8-thread group per query row; 2 rows per thread
// (64 rows/block). Conflict-free LDS: Ks[32][52] (b128 starts 8 disjoint
// 4-bank spans for jj=sub+8u), Vs[32][64] (broadcast), Ps[64][36].
__global__ __launch_bounds__(256) void flash_fwd(const float* __restrict__ Qb,
    const float* __restrict__ Kb, const float* __restrict__ kvb,
    float* __restrict__ Ob, float* __restrict__ rowm, float* __restrict__ rowl) {
  const int h2 = blockIdx.y;
  const int i0 = blockIdx.x << 6;
  const int tid = threadIdx.x;
  const int g = tid >> 3, sub = tid & 7;
  const int ia = i0 + g, ib = i0 + 32 + g;
  const int ria = ia % SPP, rib = ib % SPP;
  const int hh = h2 >> 1;
  __shared__ __align__(16) float Ks[32][52];
  __shared__ __align__(16) float Vs[32][64];
  __shared__ __align__(16) float Ps[64][36];
  float qa[DQK], qb[DQK];
  {
    const float* qra = Qb + ((size_t)h2*S + ia)*DQK;
    const float* qrb = Qb + ((size_t)h2*S + ib)*DQK;
#pragma unroll
    for (int xq = 0; xq < 12; ++xq) {
      float4 v = *reinterpret_cast<const float4*>(qra + (xq<<2));
      qa[xq*4+0]=v.x; qa[xq*4+1]=v.y; qa[xq*4+2]=v.z; qa[xq*4+3]=v.w;
      float4 w = *reinterpret_cast<const float4*>(qrb + (xq<<2));
      qb[xq*4+0]=w.x; qb[xq*4+1]=w.y; qb[xq*4+2]=w.z; qb[xq*4+3]=w.w;
    }
  }
  float ma = -1e30f, la = 0.f, mb = -1e30f, lb = 0.f;
  float oa[8] = {0.f,0.f,0.f,0.f,0.f,0.f,0.f,0.f};
  float ob[8] = {0.f,0.f,0.f,0.f,0.f,0.f,0.f,0.f};
  for (int j0 = 0; j0 < S; j0 += 32) {
    for (int idx = tid; idx < 384; idx += 256) {
      int r = idx / 12, cq = (idx % 12) << 2;
      *reinterpret_cast<float4*>(&Ks[r][cq]) =
        *reinterpret_cast<const float4*>(Kb + ((size_t)h2*S + j0 + r)*DQK + cq);
    }
    for (int idx = tid; idx < 512; idx += 256) {
      int r = idx >> 4, c = (idx & 15) << 2;
      *reinterpret_cast<float4*>(&Vs[r][c]) =
        *reinterpret_cast<const float4*>(kvb + (size_t)(j0 + r)*2048 + hh*128 + 64 + c);
    }
    __syncthreads();
    float sa[4], sb[4];
#pragma unroll
    for (int u = 0; u < 4; ++u) {
      const int jj = sub + (u << 3);
      float aca = 0.f, acb = 0.f;
#pragma unroll
      for (int kq = 0; kq < 12; ++kq) {
        float4 k4 = *reinterpret_cast<const float4*>(&Ks[jj][kq << 2]);
        aca = fmaf(qa[kq*4+0], k4.x, aca); acb = fmaf(qb[kq*4+0], k4.x, acb);
        aca = fmaf(qa[kq*4+1], k4.y, aca); acb = fmaf(qb[kq*4+1], k4.y, acb);
        aca = fmaf(qa[kq*4+2], k4.z, aca); acb = fmaf(qb[kq*4+2], k4.z, acb);
        aca = fmaf(qa[kq*4+3], k4.w, aca); acb = fmaf(qb[kq*4+3], k4.w, acb);
      }
      int rj = (j0 + jj) % SPP;
      sa[u] = (rj <= ria) ? aca * SCALING : -1e30f;
      sb[u] = (rj <= rib) ? acb * SCALING : -1e30f;
    }
    // row a softmax update
    {
      float cm = fmaxf(fmaxf(sa[0], sa[1]), fmaxf(sa[2], sa[3]));
#pragma unroll
      for (int dlt = 1; dlt < 8; dlt <<= 1) cm = fmaxf(cm, __shfl_xor(cm, dlt, 8));
      float mnew = fmaxf(ma, cm);
      float scale = __expf(ma - mnew);
      la *= scale;
#pragma unroll
      for (int dd = 0; dd < 8; ++dd) oa[dd] *= scale;
      float ps = 0.f;
#pragma unroll
      for (int u = 0; u < 4; ++u) {
        float p = __expf(sa[u] - mnew);
        Ps[g][sub + (u << 3)] = p;
        ps += p;
      }
#pragma unroll
      for (int dlt = 1; dlt < 8; dlt <<= 1) ps += __shfl_xor(ps, dlt, 8);
      la += ps;
      ma = mnew;
    }
    // row b softmax update
    {
      float cm = fmaxf(fmaxf(sb[0], sb[1]), fmaxf(sb[2], sb[3]));
#pragma unroll
      for (int dlt = 1; dlt < 8; dlt <<= 1) cm = fmaxf(cm, __shfl_xor(cm, dlt, 8));
      float mnew = fmaxf(mb, cm);
      float scale = __expf(mb - mnew);
      lb *= scale;
#pragma unroll
      for (int dd = 0; dd < 8; ++dd) ob[dd] *= scale;
      float ps = 0.f;
#pragma unroll
      for (int u = 0; u < 4; ++u) {
        float p = __expf(sb[u] - mnew);
        Ps[32 + g][sub + (u << 3)] = p;
        ps += p;
      }
#pragma unroll
      for (int dlt = 1; dlt < 8; dlt <<= 1) ps += __shfl_xor(ps, dlt, 8);
      lb += ps;
      mb = mnew;
    }
    // PV: same-wave LDS (in-order) — no barrier needed before reads
#pragma unroll
    for (int j4 = 0; j4 < 8; ++j4) {
      float4 pa4 = *reinterpret_cast<const float4*>(&Ps[g][j4 << 2]);
      float4 pb4 = *reinterpret_cast<const float4*>(&Ps[32 + g][j4 << 2]);
      float par_[4] = {pa4.x, pa4.y, pa4.z, pa4.w};
      float pbr_[4] = {pb4.x, pb4.y, pb4.z, pb4.w};
#pragma unroll
      for (int e = 0; e < 4; ++e) {
        int jj = (j4 << 2) + e;
        float pav = par_[e], pbv = pbr_[e];
        float4 va = *reinterpret_cast<const float4*>(&Vs[jj][sub << 3]);
        float4 vb = *reinterpret_cast<const float4*>(&Vs[jj][(sub << 3) + 4]);
        oa[0]=fmaf(pav,va.x,oa[0]); oa[1]=fmaf(pav,va.y,oa[1]);
        oa[2]=fmaf(pav,va.z,oa[2]); oa[3]=fmaf(pav,va.w,oa[3]);
        oa[4]=fmaf(pav,vb.x,oa[4]); oa[5]=fmaf(pav,vb.y,oa[5]);
        oa[6]=fmaf(pav,vb.z,oa[6]); oa[7]=fmaf(pav,vb.w,oa[7]);
        ob[0]=fmaf(pbv,va.x,ob[0]); ob[1]=fmaf(pbv,va.y,ob[1]);
        ob[2]=fmaf(pbv,va.z,ob[2]); ob[3]=fmaf(pbv,va.w,ob[3]);
        ob[4]=fmaf(pbv,vb.x,ob[4]); ob[5]=fmaf(pbv,vb.y,ob[5]);
        ob[6]=fmaf(pbv,vb.z,ob[6]); ob[7]=fmaf(pbv,vb.w,ob[7]);
      }
    }
    __syncthreads();
  }
  {
    float invl = 1.0f / la;
    size_t base = ((size_t)h2*S + ia)*HD + (sub << 3);
    *reinterpret_cast<float4*>(Ob + base)     = make_float4(oa[0]*invl,oa[1]*invl,oa[2]*invl,oa[3]*invl);
    *reinterpret_cast<float4*>(Ob + base + 4) = make_float4(oa[4]*invl,oa[5]*invl,oa[6]*invl,oa[7]*invl);
  }
  {
    float invl = 1.0f / lb;
    size_t base = ((size_t)h2*S + ib)*HD + (sub << 3);
    *reinterpret_cast<float4*>(Ob + base)     = make_float4(ob[0]*invl,ob[1]*invl,ob[2]*invl,ob[3]*invl);
    *reinterpret_cast<float4*>(Ob + base + 4) = make_float4(ob[4]*invl,ob[5]*invl,ob[6]*invl,ob[7]*invl);
  }
  if (sub == 0) {
    rowm[h2*S + ia] = ma; rowl[h2*S + ia] = la;
    rowm[h2*S + ib] = mb; rowl[h2*S + ib] = lb;
  }
}

// ---------------- pass 2a: partial column sums of even-half-head probs ----
// gpart[zc][hh][j] = sum_{i in chunk zc} P(2hh)[i,j]; grid (12, 16, 12), 128 thr
__global__ __launch_bounds__(128) void colsum_part(const float* __restrict__ Qb,
    const float* __restrict__ Kb, const float* __restrict__ rowm,
    const float* __restrict__ rowl, float* __restrict__ gpart) {
  const int hh = blockIdx.y, h2 = hh * 2;
  const int j = blockIdx.x * 128 + threadIdx.x;
  const int zc = blockIdx.z;
  float kreg[DQK];
  {
    const float* krow = Kb + ((size_t)h2*S + j)*DQK;
#pragma unroll
    for (int xq = 0; xq < 12; ++xq) {
      float4 v = *reinterpret_cast<const float4*>(krow + (xq<<2));
      kreg[xq*4+0]=v.x; kreg[xq*4+1]=v.y; kreg[xq*4+2]=v.z; kreg[xq*4+3]=v.w;
    }
  }
  const int rj = j % SPP;
  __shared__ __align__(16) float Qs[32][DQK];
  __shared__ float Ms[32], Ls[32];
  float acc = 0.f;
  const int ibeg = zc << 7, iend = ibeg + 128;
  for (int i0 = ibeg; i0 < iend; i0 += 32) {
    for (int idx = threadIdx.x; idx < 384; idx += 128) {
      int r = idx / 12, c = (idx % 12) << 2;
      *reinterpret_cast<float4*>(&Qs[r][c]) =
        *reinterpret_cast<const float4*>(Qb + ((size_t)h2*S + i0 + r)*DQK + c);
    }
    if (threadIdx.x < 32) {
      Ms[threadIdx.x] = rowm[h2*S + i0 + threadIdx.x];
      Ls[threadIdx.x] = 1.0f / rowl[h2*S + i0 + threadIdx.x];
    }
    __syncthreads();
#pragma unroll 4
    for (int r = 0; r < 32; ++r) {
      int ri = (i0 + r) % SPP;
      if (rj <= ri) {
        float s = 0.f;
#pragma unroll
        for (int kq = 0; kq < 12; ++kq) {
          float4 q4 = *reinterpret_cast<const float4*>(&Qs[r][kq << 2]);
          s = fmaf(kreg[kq*4+0], q4.x, s);
          s = fmaf(kreg[kq*4+1], q4.y, s);
          s = fmaf(kreg[kq*4+2], q4.z, s);
          s = fmaf(kreg[kq*4+3], q4.w, s);
        }
        acc += __expf(s * SCALING - Ms[r]) * Ls[r];
      }
    }
    __syncthreads();
  }
  gpart[((size_t)zc*NH + hh)*S + j] = acc;
}

// ---------------- pass 2b: reduce partials ----------------
// gcol[hh*S+j] = (1/S) * sum_zc gpart[zc][hh][j]; grid (96), 256 thr
__global__ __launch_bounds__(256) void colsum_reduce(const float* __restrict__ gpart,
    float* __restrict__ gcol) {
  const int idx = blockIdx.x * 256 + threadIdx.x;  // over NH*S = 24576
  float s = 0.f;
#pragma unroll
  for (int zc = 0; zc < 12; ++zc) s += gpart[(size_t)zc*NH*S + idx];
  gcol[idx] = s * (1.0f / (float)S);
}

// ---------------- Wpre: masked prefix of g-weighted V ----------------
// Wpre[hh][r][d] = sum_{r'<=r} sum_{b=0..3} g[hh][b*384+r'] * v[b*384+r'][hh][d]
__global__ __launch_bounds__(256) void build_wpre(const float* __restrict__ gcol,
    const float* __restrict__ kvb, float* __restrict__ Wpre) {
  const int hh = blockIdx.x >> 2;
  const int dq = (blockIdx.x & 3) << 4;
  __shared__ float Wt[SPP][16];
  const int tid = threadIdx.x;
  for (int idx = tid; idx < SPP*16; idx += 256) {
    int r = idx >> 4, dd = idx & 15;
    float val = 0.f;
#pragma unroll
    for (int b2 = 0; b2 < 4; ++b2) {
      int j = b2*SPP + r;
      val = fmaf(gcol[hh*S + j], kvb[(size_t)j*2048 + hh*128 + 64 + dq + dd], val);
    }
    Wt[r][dd] = val;
  }
  __syncthreads();
  if (tid < 16) {
    float run = 0.f;
    for (int r = 0; r < SPP; ++r) { run += Wt[r][tid]; Wt[r][tid] = run; }
  }
  __syncthreads();
  for (int idx = tid; idx < SPP*16; idx += 256) {
    int r = idx >> 4, dd = idx & 15;
    Wpre[((size_t)hh*SPP + r)*HD + dq + dd] = Wt[r][dd];
  }
}

// ---------------- combine (diff-attn) + per-head RMSNorm + scrambled reshape ----
__global__ __launch_bounds__(64) void combine_rms(const float* __restrict__ Ob,
    const float* __restrict__ Wpre, const float* __restrict__ lamp,
    const float* __restrict__ anw, float* __restrict__ attno) {
  const int t = blockIdx.x, h = blockIdx.y, d = threadIdx.x;
  const float lam = lamp[0];
  const float o1 = Ob[((size_t)(2*h)*S + t)*HD + d];
  const float o2 = Ob[((size_t)(2*h+1)*S + t)*HD + d];
  const float w3 = Wpre[((size_t)h*SPP + (t % SPP))*HD + d];
  float val = o1 - lam*o2 + lam*w3;
  float ss = val*val;
#pragma unroll
  for (int mm = 1; mm < 64; mm <<= 1) ss += __shfl_xor(ss, mm, 64);
  float scale = rsqrtf(ss * (1.0f/HD) + ATTN_EPS) * anw[d];
  // reference reshapes (b,16,s,64)->(b,s,1024) WITHOUT transpose:
  int tn = h*96 + (t >> 4);
  int cn = ((t & 15) << 6) + d;
  attno[(size_t)tn*DM + cn] = val * scale;
}

// =========================== launch ===========================
extern "C" void kernel_launch(void* const* d_in, const int* in_sizes, int n_in,
                              void* d_out, int out_size, void* d_ws, size_t ws_size,
                              hipStream_t stream) {
  (void)in_sizes; (void)n_in; (void)out_size;
  const float* x    = (const float*)d_in[0];
  const float* fc   = (const float*)d_in[1];
  const float* fs   = (const float*)d_in[2];
  const float* n1w  = (const float*)d_in[3];
  const float* n2w  = (const float*)d_in[4];
  const float* kvdw = (const float*)d_in[5];
  const float* qdw  = (const float*)d_in[6];
  const float* kvnw = (const float*)d_in[7];
  const float* qnw  = (const float*)d_in[8];
  const float* kvuw = (const float*)d_in[9];
  const float* quw  = (const float*)d_in[10];
  const float* lq1  = (const float*)d_in[11];
  const float* lk1  = (const float*)d_in[12];
  const float* lq2  = (const float*)d_in[13];
  const float* lk2  = (const float*)d_in[14];
  const float* anw  = (const float*)d_in[15];
  const float* ow   = (const float*)d_in[16];
  const float* ffiw = (const float*)d_in[17];
  const float* ffow = (const float*)d_in[18];
  float* out = (float*)d_out;
  float* ws  = (float*)d_ws;

  // workspace map (floats); total 18,063,376 floats = 72.3 MB
  float* xin   = ws;
  float* ckv   = xin   + (size_t)S*DM;
  float* qmid  = ckv   + (size_t)S*288;
  float* kvb   = qmid  + (size_t)S*QC;
  float* qf    = kvb   + (size_t)S*2048;
  float* Qb    = qf    + (size_t)S*1536;
  float* Kb    = Qb    + (size_t)H2N*S*DQK;
  float* Obuf  = Kb    + (size_t)H2N*S*DQK;
  float* rowm  = Obuf  + (size_t)H2N*S*HD;
  float* rowl  = rowm  + (size_t)H2N*S;
  float* gcol  = rowl  + (size_t)H2N*S;
  float* Wpre  = gcol  + (size_t)NH*S;
  float* attno = Wpre  + (size_t)NH*SPP*HD;
  float* lamp  = attno + (size_t)S*DM;
  float* fbuf  = kvb;   // FFN activation reuses kv/qf region (free after attention)
  float* gpart = attno; // 12*NH*S = 294912 floats, overlays attno (written later)
  if (ws_size < (size_t)18063376 * sizeof(float)) return;  // would corrupt; bail

  rmsnorm_k<<<S, 256, 0, stream>>>(x, n1w, xin, DM, DM, DM, EPS_RMS);
  { dim3 g(5, 24);  sgemm_nt<0><<<g, 256, 0, stream>>>(xin, kvdw, nullptr, ckv, S, 288, DM, DM, DM, 288); }
  { dim3 g(6, 24);  sgemm_nt<0><<<g, 256, 0, stream>>>(xin, qdw,  nullptr, qmid, S, QC, DM, DM, DM, QC); }
  rmsnorm_k<<<S, 256, 0, stream>>>(ckv,  kvnw, ckv,  KVC, 288, 288, EPS_RMS);
  rmsnorm_k<<<S, 256, 0, stream>>>(qmid, qnw,  qmid, QC,  QC,  QC,  EPS_RMS);
  { dim3 g(32, 24); sgemm_nt<0><<<g, 256, 0, stream>>>(ckv,  kvuw, nullptr, kvb, S, 2048, KVC, 288, KVC, 2048); }
  { dim3 g(24, 24); sgemm_nt<0><<<g, 256, 0, stream>>>(qmid, quw,  nullptr, qf,  S, 1536, QC,  QC,  QC,  1536); }
  { dim3 g(6, 32);  build_qk<<<g, 256, 0, stream>>>(qf, kvb, ckv, fc, fs, Qb, Kb); }
  compute_lam<<<1, 32, 0, stream>>>(lq1, lk1, lq2, lk2, lamp);
  { dim3 g(24, 32); flash_fwd<<<g, 256, 0, stream>>>(Qb, Kb, kvb, Obuf, rowm, rowl); }
  { dim3 g(12, 16, 12); colsum_part<<<g, 128, 0, stream>>>(Qb, Kb, rowm, rowl, gpart); }
  colsum_reduce<<<96, 256, 0, stream>>>(gpart, gcol);
  build_wpre<<<64, 256, 0, stream>>>(gcol, kvb, Wpre);
  { dim3 g(S, 16);  combine_rms<<<g, 64, 0, stream>>>(Obuf, Wpre, lamp, anw, attno); }
  { dim3 g(16, 24); sgemm_nt<1><<<g, 256, 0, stream>>>(attno, ow, x, out, S, DM, DM, DM, DM, DM); }
  rmsnorm_k<<<S, 256, 0, stream>>>(out, n2w, xin, DM, DM, DM, EPS_RMS);
  { dim3 g(64, 24); sgemm_glu<<<g, 256, 0, stream>>>(xin, ffiw, fbuf, S, DFF, DM, DM, DM, DFF); }
  { dim3 g(16, 24); sgemm_nt<1><<<g, 256, 0, stream>>>(fbuf, ffow, out, out, S, DM, DFF, DFF, DFF, DM); }
}

// Round 4
// 747.178 us; speedup vs baseline: 3.1774x; 1.7900x over previous
//
#include <hip/hip_runtime.h>
#include <math.h>

#define S     1536
#define DM    1024
#define NH    16
#define H2N   32
#define HD    64
#define KVC   256
#define QC    384
#define DFF   4096
#define SPP   384
#define DQK   48
#define EPS_RMS  1.1920929e-07f
#define ATTN_EPS 1e-5f
#define SCALING  0.14433756729740643f   /* 48^-0.5 */

typedef float f32x4 __attribute__((ext_vector_type(4)));
typedef short bf16x8 __attribute__((ext_vector_type(8)));

__device__ __forceinline__ short cvt_bf16(float f) {
  union { float f; unsigned u; } x; x.f = f;
  unsigned r = x.u + 0x7FFFu + ((x.u >> 16) & 1u);
  return (short)(r >> 16);
}

// ---------------- RMSNorm (generic, optional in-place) ----------------
__global__ __launch_bounds__(256) void rmsnorm_k(const float* __restrict__ in,
    const float* __restrict__ w, float* __restrict__ out,
    int cols, int ldin, int ldout, float eps) {
  const int row = blockIdx.x;
  const float* xr = in + (size_t)row * ldin;
  float* yr = out + (size_t)row * ldout;
  const int tid = threadIdx.x;
  float ss = 0.f;
  for (int c = tid << 2; c < cols; c += 1024) {
    float4 v = *reinterpret_cast<const float4*>(xr + c);
    ss += v.x*v.x + v.y*v.y + v.z*v.z + v.w*v.w;
  }
#pragma unroll
  for (int mm = 1; mm < 64; mm <<= 1) ss += __shfl_xor(ss, mm, 64);
  __shared__ float red[4];
  if ((tid & 63) == 0) red[tid >> 6] = ss;
  __syncthreads();
  float tot = red[0] + red[1] + red[2] + red[3];
  float scale = rsqrtf(tot / (float)cols + eps);
  for (int c = tid << 2; c < cols; c += 1024) {
    float4 v = *reinterpret_cast<const float4*>(xr + c);
    float4 wv = *reinterpret_cast<const float4*>(w + c);
    float4 ov = make_float4(v.x*scale*wv.x, v.y*scale*wv.y, v.z*scale*wv.z, v.w*scale*wv.w);
    *reinterpret_cast<float4*>(yr + c) = ov;
  }
}

// ------------- bf16 MFMA GEMM: C[M,N] = A[M,K] @ B[N,K]^T (+ src) -------------
// fp32 inputs, converted to bf16 during LDS staging; fp32 accumulate.
// 64x64 block tile, 4 waves (2x2), each wave 32x32 via 2x2 16x16x32 MFMA.
template<int ADD>
__global__ __launch_bounds__(256) void mgemm_nt(const float* __restrict__ A,
    const float* __restrict__ B, const float* __restrict__ src, float* __restrict__ C,
    int M, int N, int K, int lda, int ldb, int ldc) {
  __shared__ short As[64][40];   // 80B row stride: 16B-aligned frag reads, 2-way banks (free)
  __shared__ short Bs[64][40];
  const int bm = blockIdx.y * 64, bn = blockIdx.x * 64;
  const int tid = threadIdx.x;
  const int w = tid >> 6, lane = tid & 63;
  const int wr = (w >> 1) << 5, wc = (w & 1) << 5;
  const int srow = tid >> 2, sk = (tid & 3) << 3;
  const int lrow = lane & 15, lk8 = (lane >> 4) << 3;
  const int arow = bm + srow, brow = bn + srow;
  const bool bvalid = brow < N;
  f32x4 acc[2][2];
#pragma unroll
  for (int i = 0; i < 2; ++i)
#pragma unroll
    for (int j = 0; j < 2; ++j) acc[i][j] = (f32x4){0.f, 0.f, 0.f, 0.f};

  for (int k0 = 0; k0 < K; k0 += 32) {
    __syncthreads();
    {
      bf16x8 va, vb;
      const float* ap = A + (size_t)arow * lda + k0 + sk;
      float4 f0 = *reinterpret_cast<const float4*>(ap);
      float4 f1 = *reinterpret_cast<const float4*>(ap + 4);
      va[0]=cvt_bf16(f0.x); va[1]=cvt_bf16(f0.y); va[2]=cvt_bf16(f0.z); va[3]=cvt_bf16(f0.w);
      va[4]=cvt_bf16(f1.x); va[5]=cvt_bf16(f1.y); va[6]=cvt_bf16(f1.z); va[7]=cvt_bf16(f1.w);
      if (bvalid) {
        const float* bp = B + (size_t)brow * ldb + k0 + sk;
        float4 g0 = *reinterpret_cast<const float4*>(bp);
        float4 g1 = *reinterpret_cast<const float4*>(bp + 4);
        vb[0]=cvt_bf16(g0.x); vb[1]=cvt_bf16(g0.y); vb[2]=cvt_bf16(g0.z); vb[3]=cvt_bf16(g0.w);
        vb[4]=cvt_bf16(g1.x); vb[5]=cvt_bf16(g1.y); vb[6]=cvt_bf16(g1.z); vb[7]=cvt_bf16(g1.w);
      } else {
        vb = (bf16x8){0,0,0,0,0,0,0,0};
      }
      *reinterpret_cast<bf16x8*>(&As[srow][sk]) = va;
      *reinterpret_cast<bf16x8*>(&Bs[srow][sk]) = vb;
    }
    __syncthreads();
    bf16x8 af0 = *reinterpret_cast<bf16x8*>(&As[wr + lrow][lk8]);
    bf16x8 af1 = *reinterpret_cast<bf16x8*>(&As[wr + 16 + lrow][lk8]);
    bf16x8 bf0 = *reinterpret_cast<bf16x8*>(&Bs[wc + lrow][lk8]);
    bf16x8 bf1 = *reinterpret_cast<bf16x8*>(&Bs[wc + 16 + lrow][lk8]);
    acc[0][0] = __builtin_amdgcn_mfma_f32_16x16x32_bf16(af0, bf0, acc[0][0], 0, 0, 0);
    acc[0][1] = __builtin_amdgcn_mfma_f32_16x16x32_bf16(af0, bf1, acc[0][1], 0, 0, 0);
    acc[1][0] = __builtin_amdgcn_mfma_f32_16x16x32_bf16(af1, bf0, acc[1][0], 0, 0, 0);
    acc[1][1] = __builtin_amdgcn_mfma_f32_16x16x32_bf16(af1, bf1, acc[1][1], 0, 0, 0);
  }
  // C/D layout: col = lane&15, row = (lane>>4)*4 + reg  [m89-verified]
  const int crow0 = bm + wr + ((lane >> 4) << 2);
  const int ccol0 = bn + wc + lrow;
#pragma unroll
  for (int mi = 0; mi < 2; ++mi)
#pragma unroll
    for (int ni = 0; ni < 2; ++ni) {
      int colc = ccol0 + (ni << 4);
      if (colc < N) {
#pragma unroll
        for (int r = 0; r < 4; ++r) {
          int rowc = crow0 + (mi << 4) + r;
          float v = acc[mi][ni][r];
          if (ADD) v += src[(size_t)rowc * ldc + colc];
          C[(size_t)rowc * ldc + colc] = v;
        }
      }
    }
}

// ------------- bf16 MFMA SwiGLU GEMM: C = (A@Bu^T) * silu(A@Bv^T) -------------
// Bu = B rows [0,N), Bv = B rows [N,2N). N=4096 exact (no guards).
__global__ __launch_bounds__(256) void mgemm_glu(const float* __restrict__ A,
    const float* __restrict__ B, float* __restrict__ C,
    int M, int N, int K, int lda, int ldb, int ldc) {
  __shared__ short As[64][40];
  __shared__ short Bu[64][40];
  __shared__ short Bv[64][40];
  const int bm = blockIdx.y * 64, bn = blockIdx.x * 64;
  const int tid = threadIdx.x;
  const int w = tid >> 6, lane = tid & 63;
  const int wr = (w >> 1) << 5, wc = (w & 1) << 5;
  const int srow = tid >> 2, sk = (tid & 3) << 3;
  const int lrow = lane & 15, lk8 = (lane >> 4) << 3;
  const int arow = bm + srow, brow = bn + srow;
  f32x4 au[2][2], av[2][2];
#pragma unroll
  for (int i = 0; i < 2; ++i)
#pragma unroll
    for (int j = 0; j < 2; ++j) {
      au[i][j] = (f32x4){0.f, 0.f, 0.f, 0.f};
      av[i][j] = (f32x4){0.f, 0.f, 0.f, 0.f};
    }
  for (int k0 = 0; k0 < K; k0 += 32) {
    __syncthreads();
    {
      const float* ap = A + (size_t)arow * lda + k0 + sk;
      const float* up = B + (size_t)brow * ldb + k0 + sk;
      const float* vp = B + (size_t)(N + brow) * ldb + k0 + sk;
      float4 f0 = *reinterpret_cast<const float4*>(ap);
      float4 f1 = *reinterpret_cast<const float4*>(ap + 4);
      float4 u0 = *reinterpret_cast<const float4*>(up);
      float4 u1 = *reinterpret_cast<const float4*>(up + 4);
      float4 v0 = *reinterpret_cast<const float4*>(vp);
      float4 v1 = *reinterpret_cast<const float4*>(vp + 4);
      bf16x8 a8, u8, v8;
      a8[0]=cvt_bf16(f0.x); a8[1]=cvt_bf16(f0.y); a8[2]=cvt_bf16(f0.z); a8[3]=cvt_bf16(f0.w);
      a8[4]=cvt_bf16(f1.x); a8[5]=cvt_bf16(f1.y); a8[6]=cvt_bf16(f1.z); a8[7]=cvt_bf16(f1.w);
      u8[0]=cvt_bf16(u0.x); u8[1]=cvt_bf16(u0.y); u8[2]=cvt_bf16(u0.z); u8[3]=cvt_bf16(u0.w);
      u8[4]=cvt_bf16(u1.x); u8[5]=cvt_bf16(u1.y); u8[6]=cvt_bf16(u1.z); u8[7]=cvt_bf16(u1.w);
      v8[0]=cvt_bf16(v0.x); v8[1]=cvt_bf16(v0.y); v8[2]=cvt_bf16(v0.z); v8[3]=cvt_bf16(v0.w);
      v8[4]=cvt_bf16(v1.x); v8[5]=cvt_bf16(v1.y); v8[6]=cvt_bf16(v1.z); v8[7]=cvt_bf16(v1.w);
      *reinterpret_cast<bf16x8*>(&As[srow][sk]) = a8;
      *reinterpret_cast<bf16x8*>(&Bu[srow][sk]) = u8;
      *reinterpret_cast<bf16x8*>(&Bv[srow][sk]) = v8;
    }
    __syncthreads();
    bf16x8 af0 = *reinterpret_cast<bf16x8*>(&As[wr + lrow][lk8]);
    bf16x8 af1 = *reinterpret_cast<bf16x8*>(&As[wr + 16 + lrow][lk8]);
    bf16x8 uf0 = *reinterpret_cast<bf16x8*>(&Bu[wc + lrow][lk8]);
    bf16x8 uf1 = *reinterpret_cast<bf16x8*>(&Bu[wc + 16 + lrow][lk8]);
    bf16x8 vf0 = *reinterpret_cast<bf16x8*>(&Bv[wc + lrow][lk8]);
    bf16x8 vf1 = *reinterpret_cast<bf16x8*>(&Bv[wc + 16 + lrow][lk8]);
    au[0][0] = __builtin_amdgcn_mfma_f32_16x16x32_bf16(af0, uf0, au[0][0], 0, 0, 0);
    au[0][1] = __builtin_amdgcn_mfma_f32_16x16x32_bf16(af0, uf1, au[0][1], 0, 0, 0);
    au[1][0] = __builtin_amdgcn_mfma_f32_16x16x32_bf16(af1, uf0, au[1][0], 0, 0, 0);
    au[1][1] = __builtin_amdgcn_mfma_f32_16x16x32_bf16(af1, uf1, au[1][1], 0, 0, 0);
    av[0][0] = __builtin_amdgcn_mfma_f32_16x16x32_bf16(af0, vf0, av[0][0], 0, 0, 0);
    av[0][1] = __builtin_amdgcn_mfma_f32_16x16x32_bf16(af0, vf1, av[0][1], 0, 0, 0);
    av[1][0] = __builtin_amdgcn_mfma_f32_16x16x32_bf16(af1, vf0, av[1][0], 0, 0, 0);
    av[1][1] = __builtin_amdgcn_mfma_f32_16x16x32_bf16(af1, vf1, av[1][1], 0, 0, 0);
  }
  const int crow0 = bm + wr + ((lane >> 4) << 2);
  const int ccol0 = bn + wc + lrow;
#pragma unroll
  for (int mi = 0; mi < 2; ++mi)
#pragma unroll
    for (int ni = 0; ni < 2; ++ni) {
      int colc = ccol0 + (ni << 4);
#pragma unroll
      for (int r = 0; r < 4; ++r) {
        int rowc = crow0 + (mi << 4) + r;
        float uu = au[mi][ni][r], vg = av[mi][ni][r];
        float sig = 1.0f / (1.0f + __expf(-vg));
        C[(size_t)rowc * ldc + colc] = uu * vg * sig;
      }
    }
}

// ---------------- Build Q/K (split heads + RoPE) ----------------
// Qb/Kb layout: [h2][t][48]  (32 dims content + 16 dims rotated rope)
__global__ __launch_bounds__(256) void build_qk(const float* __restrict__ qf,
    const float* __restrict__ kvb, const float* __restrict__ ckv,
    const float* __restrict__ fc, const float* __restrict__ fs,
    float* __restrict__ Qb, float* __restrict__ Kb) {
  int t = blockIdx.x * 256 + threadIdx.x;
  int h2 = blockIdx.y;
  if (t >= S) return;
  int hh = h2 >> 1, par = h2 & 1;
  const float* qrow = qf + (size_t)t*1536 + hh*96;
  const float* krow = kvb + (size_t)t*2048 + hh*128;
  float* qo = Qb + ((size_t)h2*S + t)*DQK;
  float* ko = Kb + ((size_t)h2*S + t)*DQK;
#pragma unroll
  for (int xq = 0; xq < 8; ++xq) {
    *reinterpret_cast<float4*>(qo + (xq<<2)) =
      *reinterpret_cast<const float4*>(qrow + par*32 + (xq<<2));
    *reinterpret_cast<float4*>(ko + (xq<<2)) =
      *reinterpret_cast<const float4*>(krow + par*32 + (xq<<2));
  }
  int p = t >> 2;  // rope position: s splits as (spp, NUM_SEQ) with spp OUTER
  const float* qr = qrow + 64 + par*16;
  const float* kr = ckv + (size_t)t*288 + 256 + par*16;
#pragma unroll
  for (int mq = 0; mq < 8; ++mq) {
    float c = 1.f, sn = 0.f;
    if (p > 0) { c = fc[(p-1)*8 + mq]; sn = fs[(p-1)*8 + mq]; }
    float q0 = qr[2*mq], q1 = qr[2*mq+1];
    qo[32 + 2*mq]     = q0*c - q1*sn;
    qo[32 + 2*mq + 1] = q0*sn + q1*c;
    float k0 = kr[2*mq], k1 = kr[2*mq+1];
    ko[32 + 2*mq]     = k0*c - k1*sn;
    ko[32 + 2*mq + 1] = k0*sn + k1*c;
  }
}

// ---------------- lambda scalar ----------------
__global__ void compute_lam(const float* __restrict__ lq1, const float* __restrict__ lk1,
                            const float* __restrict__ lq2, const float* __restrict__ lk2,
                            float* __restrict__ lamp) {
  int t = threadIdx.x;  // 32 threads
  float a = lq1[t]*lk1[t];
  float b = lq2[t]*lk2[t];
#pragma unroll
  for (int mm = 1; mm < 32; mm <<= 1) { a += __shfl_xor(a, mm, 32); b += __shfl_xor(b, mm, 32); }
  if (t == 0) lamp[0] = expf(a) - expf(b) + 0.2f;  // LAMBDA_INIT = 0.2
}

// ---------------- Flash attention pass 1 ----------------
// grid (24, 32); 256 thr; 8-thread group per query row; 2 rows per thread
// (64 rows/block). Conflict-free LDS: Ks[32][52] (b128 starts 8 disjoint
// 4-bank spans for jj=sub+8u), Vs[32][64] (broadcast), Ps[64][36].
__global__ __launch_bounds__(256) void flash_fwd(const float* __restrict__ Qb,
    const float* __restrict__ Kb, const float* __restrict__ kvb,
    float* __restrict__ Ob, float* __restrict__ rowm, float* __restrict__ rowl) {
  const int h2 = blockIdx.y;
  const int i0 = blockIdx.x << 6;
  const int tid = threadIdx.x;
  const int g = tid >> 3, sub = tid & 7;
  const int ia = i0 + g, ib = i0 + 32 + g;
  const int ria = ia % SPP, rib = ib % SPP;
  const int hh = h2 >> 1;
  __shared__ __align__(16) float Ks[32][52];
  __shared__ __align__(16) float Vs[32][64];
  __shared__ __align__(16) float Ps[64][36];
  float qa[DQK], qb[DQK];
  {
    const float* qra = Qb + ((size_t)h2*S + ia)*DQK;
    const float* qrb = Qb + ((size_t)h2*S + ib)*DQK;
#pragma unroll
    for (int xq = 0; xq < 12; ++xq) {
      float4 v = *reinterpret_cast<const float4*>(qra + (xq<<2));
      qa[xq*4+0]=v.x; qa[xq*4+1]=v.y; qa[xq*4+2]=v.z; qa[xq*4+3]=v.w;
      float4 w = *reinterpret_cast<const float4*>(qrb + (xq<<2));
      qb[xq*4+0]=w.x; qb[xq*4+1]=w.y; qb[xq*4+2]=w.z; qb[xq*4+3]=w.w;
    }
  }
  float ma = -1e30f, la = 0.f, mb = -1e30f, lb = 0.f;
  float oa[8] = {0.f,0.f,0.f,0.f,0.f,0.f,0.f,0.f};
  float ob[8] = {0.f,0.f,0.f,0.f,0.f,0.f,0.f,0.f};
  for (int j0 = 0; j0 < S; j0 += 32) {
    for (int idx = tid; idx < 384; idx += 256) {
      int r = idx / 12, cq = (idx % 12) << 2;
      *reinterpret_cast<float4*>(&Ks[r][cq]) =
        *reinterpret_cast<const float4*>(Kb + ((size_t)h2*S + j0 + r)*DQK + cq);
    }
    for (int idx = tid; idx < 512; idx += 256) {
      int r = idx >> 4, c = (idx & 15) << 2;
      *reinterpret_cast<float4*>(&Vs[r][c]) =
        *reinterpret_cast<const float4*>(kvb + (size_t)(j0 + r)*2048 + hh*128 + 64 + c);
    }
    __syncthreads();
    float sa[4], sb[4];
#pragma unroll
    for (int u = 0; u < 4; ++u) {
      const int jj = sub + (u << 3);
      float aca = 0.f, acb = 0.f;
#pragma unroll
      for (int kq = 0; kq < 12; ++kq) {
        float4 k4 = *reinterpret_cast<const float4*>(&Ks[jj][kq << 2]);
        aca = fmaf(qa[kq*4+0], k4.x, aca); acb = fmaf(qb[kq*4+0], k4.x, acb);
        aca = fmaf(qa[kq*4+1], k4.y, aca); acb = fmaf(qb[kq*4+1], k4.y, acb);
        aca = fmaf(qa[kq*4+2], k4.z, aca); acb = fmaf(qb[kq*4+2], k4.z, acb);
        aca = fmaf(qa[kq*4+3], k4.w, aca); acb = fmaf(qb[kq*4+3], k4.w, acb);
      }
      int rj = (j0 + jj) % SPP;
      sa[u] = (rj <= ria) ? aca * SCALING : -1e30f;
      sb[u] = (rj <= rib) ? acb * SCALING : -1e30f;
    }
    // row a softmax update
    {
      float cm = fmaxf(fmaxf(sa[0], sa[1]), fmaxf(sa[2], sa[3]));
#pragma unroll
      for (int dlt = 1; dlt < 8; dlt <<= 1) cm = fmaxf(cm, __shfl_xor(cm, dlt, 8));
      float mnew = fmaxf(ma, cm);
      float scale = __expf(ma - mnew);
      la *= scale;
#pragma unroll
      for (int dd = 0; dd < 8; ++dd) oa[dd] *= scale;
      float ps = 0.f;
#pragma unroll
      for (int u = 0; u < 4; ++u) {
        float p = __expf(sa[u] - mnew);
        Ps[g][sub + (u << 3)] = p;
        ps += p;
      }
#pragma unroll
      for (int dlt = 1; dlt < 8; dlt <<= 1) ps += __shfl_xor(ps, dlt, 8);
      la += ps;
      ma = mnew;
    }
    // row b softmax update
    {
      float cm = fmaxf(fmaxf(sb[0], sb[1]), fmaxf(sb[2], sb[3]));
#pragma unroll
      for (int dlt = 1; dlt < 8; dlt <<= 1) cm = fmaxf(cm, __shfl_xor(cm, dlt, 8));
      float mnew = fmaxf(mb, cm);
      float scale = __expf(mb - mnew);
      lb *= scale;
#pragma unroll
      for (int dd = 0; dd < 8; ++dd) ob[dd] *= scale;
      float ps = 0.f;
#pragma unroll
      for (int u = 0; u < 4; ++u) {
        float p = __expf(sb[u] - mnew);
        Ps[32 + g][sub + (u << 3)] = p;
        ps += p;
      }
#pragma unroll
      for (int dlt = 1; dlt < 8; dlt <<= 1) ps += __shfl_xor(ps, dlt, 8);
      lb += ps;
      mb = mnew;
    }
    // PV: same-wave LDS (in-order) — no barrier needed before reads
#pragma unroll
    for (int j4 = 0; j4 < 8; ++j4) {
      float4 pa4 = *reinterpret_cast<const float4*>(&Ps[g][j4 << 2]);
      float4 pb4 = *reinterpret_cast<const float4*>(&Ps[32 + g][j4 << 2]);
      float par_[4] = {pa4.x, pa4.y, pa4.z, pa4.w};
      float pbr_[4] = {pb4.x, pb4.y, pb4.z, pb4.w};
#pragma unroll
      for (int e = 0; e < 4; ++e) {
        int jj = (j4 << 2) + e;
        float pav = par_[e], pbv = pbr_[e];
        float4 va = *reinterpret_cast<const float4*>(&Vs[jj][sub << 3]);
        float4 vb = *reinterpret_cast<const float4*>(&Vs[jj][(sub << 3) + 4]);
        oa[0]=fmaf(pav,va.x,oa[0]); oa[1]=fmaf(pav,va.y,oa[1]);
        oa[2]=fmaf(pav,va.z,oa[2]); oa[3]=fmaf(pav,va.w,oa[3]);
        oa[4]=fmaf(pav,vb.x,oa[4]); oa[5]=fmaf(pav,vb.y,oa[5]);
        oa[6]=fmaf(pav,vb.z,oa[6]); oa[7]=fmaf(pav,vb.w,oa[7]);
        ob[0]=fmaf(pbv,va.x,ob[0]); ob[1]=fmaf(pbv,va.y,ob[1]);
        ob[2]=fmaf(pbv,va.z,ob[2]); ob[3]=fmaf(pbv,va.w,ob[3]);
        ob[4]=fmaf(pbv,vb.x,ob[4]); ob[5]=fmaf(pbv,vb.y,ob[5]);
        ob[6]=fmaf(pbv,vb.z,ob[6]); ob[7]=fmaf(pbv,vb.w,ob[7]);
      }
    }
    __syncthreads();
  }
  {
    float invl = 1.0f / la;
    size_t base = ((size_t)h2*S + ia)*HD + (sub << 3);
    *reinterpret_cast<float4*>(Ob + base)     = make_float4(oa[0]*invl,oa[1]*invl,oa[2]*invl,oa[3]*invl);
    *reinterpret_cast<float4*>(Ob + base + 4) = make_float4(oa[4]*invl,oa[5]*invl,oa[6]*invl,oa[7]*invl);
  }
  {
    float invl = 1.0f / lb;
    size_t base = ((size_t)h2*S + ib)*HD + (sub << 3);
    *reinterpret_cast<float4*>(Ob + base)     = make_float4(ob[0]*invl,ob[1]*invl,ob[2]*invl,ob[3]*invl);
    *reinterpret_cast<float4*>(Ob + base + 4) = make_float4(ob[4]*invl,ob[5]*invl,ob[6]*invl,ob[7]*invl);
  }
  if (sub == 0) {
    rowm[h2*S + ia] = ma; rowl[h2*S + ia] = la;
    rowm[h2*S + ib] = mb; rowl[h2*S + ib] = lb;
  }
}

// ---------------- pass 2a: partial column sums of even-half-head probs ----
// gpart[zc][hh][j] = sum_{i in chunk zc} P(2hh)[i,j]; grid (12, 16, 12), 128 thr
__global__ __launch_bounds__(128) void colsum_part(const float* __restrict__ Qb,
    const float* __restrict__ Kb, const float* __restrict__ rowm,
    const float* __restrict__ rowl, float* __restrict__ gpart) {
  const int hh = blockIdx.y, h2 = hh * 2;
  const int j = blockIdx.x * 128 + threadIdx.x;
  const int zc = blockIdx.z;
  float kreg[DQK];
  {
    const float* krow = Kb + ((size_t)h2*S + j)*DQK;
#pragma unroll
    for (int xq = 0; xq < 12; ++xq) {
      float4 v = *reinterpret_cast<const float4*>(krow + (xq<<2));
      kreg[xq*4+0]=v.x; kreg[xq*4+1]=v.y; kreg[xq*4+2]=v.z; kreg[xq*4+3]=v.w;
    }
  }
  const int rj = j % SPP;
  __shared__ __align__(16) float Qs[32][DQK];
  __shared__ float Ms[32], Ls[32];
  float acc = 0.f;
  const int ibeg = zc << 7, iend = ibeg + 128;
  for (int i0 = ibeg; i0 < iend; i0 += 32) {
    for (int idx = threadIdx.x; idx < 384; idx += 128) {
      int r = idx / 12, c = (idx % 12) << 2;
      *reinterpret_cast<float4*>(&Qs[r][c]) =
        *reinterpret_cast<const float4*>(Qb + ((size_t)h2*S + i0 + r)*DQK + c);
    }
    if (threadIdx.x < 32) {
      Ms[threadIdx.x] = rowm[h2*S + i0 + threadIdx.x];
      Ls[threadIdx.x] = 1.0f / rowl[h2*S + i0 + threadIdx.x];
    }
    __syncthreads();
#pragma unroll 4
    for (int r = 0; r < 32; ++r) {
      int ri = (i0 + r) % SPP;
      if (rj <= ri) {
        float s = 0.f;
#pragma unroll
        for (int kq = 0; kq < 12; ++kq) {
          float4 q4 = *reinterpret_cast<const float4*>(&Qs[r][kq << 2]);
          s = fmaf(kreg[kq*4+0], q4.x, s);
          s = fmaf(kreg[kq*4+1], q4.y, s);
          s = fmaf(kreg[kq*4+2], q4.z, s);
          s = fmaf(kreg[kq*4+3], q4.w, s);
        }
        acc += __expf(s * SCALING - Ms[r]) * Ls[r];
      }
    }
    __syncthreads();
  }
  gpart[((size_t)zc*NH + hh)*S + j] = acc;
}

// ---------------- pass 2b: reduce partials ----------------
// gcol[hh*S+j] = (1/S) * sum_zc gpart[zc][hh][j]; grid (96), 256 thr
__global__ __launch_bounds__(256) void colsum_reduce(const float* __restrict__ gpart,
    float* __restrict__ gcol) {
  const int idx = blockIdx.x * 256 + threadIdx.x;  // over NH*S = 24576
  float s = 0.f;
#pragma unroll
  for (int zc = 0; zc < 12; ++zc) s += gpart[(size_t)zc*NH*S + idx];
  gcol[idx] = s * (1.0f / (float)S);
}

// ---------------- Wpre: masked prefix of g-weighted V ----------------
// Wpre[hh][r][d] = sum_{r'<=r} sum_{b=0..3} g[hh][b*384+r'] * v[b*384+r'][hh][d]
__global__ __launch_bounds__(256) void build_wpre(const float* __restrict__ gcol,
    const float* __restrict__ kvb, float* __restrict__ Wpre) {
  const int hh = blockIdx.x >> 2;
  const int dq = (blockIdx.x & 3) << 4;
  __shared__ float Wt[SPP][16];
  const int tid = threadIdx.x;
  for (int idx = tid; idx < SPP*16; idx += 256) {
    int r = idx >> 4, dd = idx & 15;
    float val = 0.f;
#pragma unroll
    for (int b2 = 0; b2 < 4; ++b2) {
      int j = b2*SPP + r;
      val = fmaf(gcol[hh*S + j], kvb[(size_t)j*2048 + hh*128 + 64 + dq + dd], val);
    }
    Wt[r][dd] = val;
  }
  __syncthreads();
  if (tid < 16) {
    float run = 0.f;
    for (int r = 0; r < SPP; ++r) { run += Wt[r][tid]; Wt[r][tid] = run; }
  }
  __syncthreads();
  for (int idx = tid; idx < SPP*16; idx += 256) {
    int r = idx >> 4, dd = idx & 15;
    Wpre[((size_t)hh*SPP + r)*HD + dq + dd] = Wt[r][dd];
  }
}

// ---------------- combine (diff-attn) + per-head RMSNorm + scrambled reshape ----
__global__ __launch_bounds__(64) void combine_rms(const float* __restrict__ Ob,
    const float* __restrict__ Wpre, const float* __restrict__ lamp,
    const float* __restrict__ anw, float* __restrict__ attno) {
  const int t = blockIdx.x, h = blockIdx.y, d = threadIdx.x;
  const float lam = lamp[0];
  const float o1 = Ob[((size_t)(2*h)*S + t)*HD + d];
  const float o2 = Ob[((size_t)(2*h+1)*S + t)*HD + d];
  const float w3 = Wpre[((size_t)h*SPP + (t % SPP))*HD + d];
  float val = o1 - lam*o2 + lam*w3;
  float ss = val*val;
#pragma unroll
  for (int mm = 1; mm < 64; mm <<= 1) ss += __shfl_xor(ss, mm, 64);
  float scale = rsqrtf(ss * (1.0f/HD) + ATTN_EPS) * anw[d];
  // reference reshapes (b,16,s,64)->(b,s,1024) WITHOUT transpose:
  int tn = h*96 + (t >> 4);
  int cn = ((t & 15) << 6) + d;
  attno[(size_t)tn*DM + cn] = val * scale;
}

// =========================== launch ===========================
extern "C" void kernel_launch(void* const* d_in, const int* in_sizes, int n_in,
                              void* d_out, int out_size, void* d_ws, size_t ws_size,
                              hipStream_t stream) {
  (void)in_sizes; (void)n_in; (void)out_size;
  const float* x    = (const float*)d_in[0];
  const float* fc   = (const float*)d_in[1];
  const float* fs   = (const float*)d_in[2];
  const float* n1w  = (const float*)d_in[3];
  const float* n2w  = (const float*)d_in[4];
  const float* kvdw = (const float*)d_in[5];
  const float* qdw  = (const float*)d_in[6];
  const float* kvnw = (const float*)d_in[7];
  const float* qnw  = (const float*)d_in[8];
  const float* kvuw = (const float*)d_in[9];
  const float* quw  = (const float*)d_in[10];
  const float* lq1  = (const float*)d_in[11];
  const float* lk1  = (const float*)d_in[12];
  const float* lq2  = (const float*)d_in[13];
  const float* lk2  = (const float*)d_in[14];
  const float* anw  = (const float*)d_in[15];
  const float* ow   = (const float*)d_in[16];
  const float* ffiw = (const float*)d_in[17];
  const float* ffow = (const float*)d_in[18];
  float* out = (float*)d_out;
  float* ws  = (float*)d_ws;

  // workspace map (floats); total 18,063,376 floats = 72.3 MB
  float* xin   = ws;
  float* ckv   = xin   + (size_t)S*DM;
  float* qmid  = ckv   + (size_t)S*288;
  float* kvb   = qmid  + (size_t)S*QC;
  float* qf    = kvb   + (size_t)S*2048;
  float* Qb    = qf    + (size_t)S*1536;
  float* Kb    = Qb    + (size_t)H2N*S*DQK;
  float* Obuf  = Kb    + (size_t)H2N*S*DQK;
  float* rowm  = Obuf  + (size_t)H2N*S*HD;
  float* rowl  = rowm  + (size_t)H2N*S;
  float* gcol  = rowl  + (size_t)H2N*S;
  float* Wpre  = gcol  + (size_t)NH*S;
  float* attno = Wpre  + (size_t)NH*SPP*HD;
  float* lamp  = attno + (size_t)S*DM;
  float* fbuf  = kvb;   // FFN activation reuses kv/qf region (free after attention)
  float* gpart = attno; // 12*NH*S = 294912 floats, overlays attno (written later)
  if (ws_size < (size_t)18063376 * sizeof(float)) return;  // would corrupt; bail

  rmsnorm_k<<<S, 256, 0, stream>>>(x, n1w, xin, DM, DM, DM, EPS_RMS);
  { dim3 g(5, 24);  mgemm_nt<0><<<g, 256, 0, stream>>>(xin, kvdw, nullptr, ckv, S, 288, DM, DM, DM, 288); }
  { dim3 g(6, 24);  mgemm_nt<0><<<g, 256, 0, stream>>>(xin, qdw,  nullptr, qmid, S, QC, DM, DM, DM, QC); }
  rmsnorm_k<<<S, 256, 0, stream>>>(ckv,  kvnw, ckv,  KVC, 288, 288, EPS_RMS);
  rmsnorm_k<<<S, 256, 0, stream>>>(qmid, qnw,  qmid, QC,  QC,  QC,  EPS_RMS);
  { dim3 g(32, 24); mgemm_nt<0><<<g, 256, 0, stream>>>(ckv,  kvuw, nullptr, kvb, S, 2048, KVC, 288, KVC, 2048); }
  { dim3 g(24, 24); mgemm_nt<0><<<g, 256, 0, stream>>>(qmid, quw,  nullptr, qf,  S, 1536, QC,  QC,  QC,  1536); }
  { dim3 g(6, 32);  build_qk<<<g, 256, 0, stream>>>(qf, kvb, ckv, fc, fs, Qb, Kb); }
  compute_lam<<<1, 32, 0, stream>>>(lq1, lk1, lq2, lk2, lamp);
  { dim3 g(24, 32); flash_fwd<<<g, 256, 0, stream>>>(Qb, Kb, kvb, Obuf, rowm, rowl); }
  { dim3 g(12, 16, 12); colsum_part<<<g, 128, 0, stream>>>(Qb, Kb, rowm, rowl, gpart); }
  colsum_reduce<<<96, 256, 0, stream>>>(gpart, gcol);
  build_wpre<<<64, 256, 0, stream>>>(gcol, kvb, Wpre);
  { dim3 g(S, 16);  combine_rms<<<g, 64, 0, stream>>>(Obuf, Wpre, lamp, anw, attno); }
  { dim3 g(16, 24); mgemm_nt<1><<<g, 256, 0, stream>>>(attno, ow, x, out, S, DM, DM, DM, DM, DM); }
  rmsnorm_k<<<S, 256, 0, stream>>>(out, n2w, xin, DM, DM, DM, EPS_RMS);
  { dim3 g(64, 24); mgemm_glu<<<g, 256, 0, stream>>>(xin, ffiw, fbuf, S, DFF, DM, DM, DM, DFF); }
  { dim3 g(16, 24); mgemm_nt<1><<<g, 256, 0, stream>>>(fbuf, ffow, out, out, S, DM, DFF, DFF, DFF, DM); }
}

// Round 5
// 455.778 us; speedup vs baseline: 5.2088x; 1.6393x over previous
//
#include <hip/hip_runtime.h>
#include <math.h>

#define S     1536
#define DM    1024
#define NH    16
#define H2N   32
#define HD    64
#define KVC   256
#define QC    384
#define DFF   4096
#define SPP   384
#define DQK   48
#define EPS_RMS  1.1920929e-07f
#define ATTN_EPS 1e-5f
#define SCALING  0.14433756729740643f   /* 48^-0.5 */

typedef float f32x4 __attribute__((ext_vector_type(4)));
typedef float f32x16 __attribute__((ext_vector_type(16)));
typedef short bf16x8 __attribute__((ext_vector_type(8)));

__device__ __forceinline__ short cvt_bf16(float f) {
  union { float f; unsigned u; } x; x.f = f;
  unsigned r = x.u + 0x7FFFu + ((x.u >> 16) & 1u);
  return (short)(r >> 16);
}
__device__ __forceinline__ unsigned pk2(float a, float b) {
  return (unsigned)(unsigned short)cvt_bf16(a) |
         ((unsigned)(unsigned short)cvt_bf16(b) << 16);
}

// ---------------- RMSNorm (generic, optional in-place) ----------------
__global__ __launch_bounds__(256) void rmsnorm_k(const float* __restrict__ in,
    const float* __restrict__ w, float* __restrict__ out,
    int cols, int ldin, int ldout, float eps) {
  const int row = blockIdx.x;
  const float* xr = in + (size_t)row * ldin;
  float* yr = out + (size_t)row * ldout;
  const int tid = threadIdx.x;
  float ss = 0.f;
  for (int c = tid << 2; c < cols; c += 1024) {
    float4 v = *reinterpret_cast<const float4*>(xr + c);
    ss += v.x*v.x + v.y*v.y + v.z*v.z + v.w*v.w;
  }
#pragma unroll
  for (int mm = 1; mm < 64; mm <<= 1) ss += __shfl_xor(ss, mm, 64);
  __shared__ float red[4];
  if ((tid & 63) == 0) red[tid >> 6] = ss;
  __syncthreads();
  float tot = red[0] + red[1] + red[2] + red[3];
  float scale = rsqrtf(tot / (float)cols + eps);
  for (int c = tid << 2; c < cols; c += 1024) {
    float4 v = *reinterpret_cast<const float4*>(xr + c);
    float4 wv = *reinterpret_cast<const float4*>(w + c);
    float4 ov = make_float4(v.x*scale*wv.x, v.y*scale*wv.y, v.z*scale*wv.z, v.w*scale*wv.w);
    *reinterpret_cast<float4*>(yr + c) = ov;
  }
}

// ------------- bf16 MFMA GEMM: C[M,N] = A[M,K] @ B[N,K]^T (+ src) -------------
template<int ADD>
__global__ __launch_bounds__(256) void mgemm_nt(const float* __restrict__ A,
    const float* __restrict__ B, const float* __restrict__ src, float* __restrict__ C,
    int M, int N, int K, int lda, int ldb, int ldc) {
  __shared__ short As[64][40];
  __shared__ short Bs[64][40];
  const int bm = blockIdx.y * 64, bn = blockIdx.x * 64;
  const int tid = threadIdx.x;
  const int w = tid >> 6, lane = tid & 63;
  const int wr = (w >> 1) << 5, wc = (w & 1) << 5;
  const int srow = tid >> 2, sk = (tid & 3) << 3;
  const int lrow = lane & 15, lk8 = (lane >> 4) << 3;
  const int arow = bm + srow, brow = bn + srow;
  const bool bvalid = brow < N;
  f32x4 acc[2][2];
#pragma unroll
  for (int i = 0; i < 2; ++i)
#pragma unroll
    for (int j = 0; j < 2; ++j) acc[i][j] = (f32x4){0.f, 0.f, 0.f, 0.f};

  for (int k0 = 0; k0 < K; k0 += 32) {
    __syncthreads();
    {
      bf16x8 va, vb;
      const float* ap = A + (size_t)arow * lda + k0 + sk;
      float4 f0 = *reinterpret_cast<const float4*>(ap);
      float4 f1 = *reinterpret_cast<const float4*>(ap + 4);
      va[0]=cvt_bf16(f0.x); va[1]=cvt_bf16(f0.y); va[2]=cvt_bf16(f0.z); va[3]=cvt_bf16(f0.w);
      va[4]=cvt_bf16(f1.x); va[5]=cvt_bf16(f1.y); va[6]=cvt_bf16(f1.z); va[7]=cvt_bf16(f1.w);
      if (bvalid) {
        const float* bp = B + (size_t)brow * ldb + k0 + sk;
        float4 g0 = *reinterpret_cast<const float4*>(bp);
        float4 g1 = *reinterpret_cast<const float4*>(bp + 4);
        vb[0]=cvt_bf16(g0.x); vb[1]=cvt_bf16(g0.y); vb[2]=cvt_bf16(g0.z); vb[3]=cvt_bf16(g0.w);
        vb[4]=cvt_bf16(g1.x); vb[5]=cvt_bf16(g1.y); vb[6]=cvt_bf16(g1.z); vb[7]=cvt_bf16(g1.w);
      } else {
        vb = (bf16x8){0,0,0,0,0,0,0,0};
      }
      *reinterpret_cast<bf16x8*>(&As[srow][sk]) = va;
      *reinterpret_cast<bf16x8*>(&Bs[srow][sk]) = vb;
    }
    __syncthreads();
    bf16x8 af0 = *reinterpret_cast<bf16x8*>(&As[wr + lrow][lk8]);
    bf16x8 af1 = *reinterpret_cast<bf16x8*>(&As[wr + 16 + lrow][lk8]);
    bf16x8 bf0 = *reinterpret_cast<bf16x8*>(&Bs[wc + lrow][lk8]);
    bf16x8 bf1 = *reinterpret_cast<bf16x8*>(&Bs[wc + 16 + lrow][lk8]);
    acc[0][0] = __builtin_amdgcn_mfma_f32_16x16x32_bf16(af0, bf0, acc[0][0], 0, 0, 0);
    acc[0][1] = __builtin_amdgcn_mfma_f32_16x16x32_bf16(af0, bf1, acc[0][1], 0, 0, 0);
    acc[1][0] = __builtin_amdgcn_mfma_f32_16x16x32_bf16(af1, bf0, acc[1][0], 0, 0, 0);
    acc[1][1] = __builtin_amdgcn_mfma_f32_16x16x32_bf16(af1, bf1, acc[1][1], 0, 0, 0);
  }
  const int crow0 = bm + wr + ((lane >> 4) << 2);
  const int ccol0 = bn + wc + lrow;
#pragma unroll
  for (int mi = 0; mi < 2; ++mi)
#pragma unroll
    for (int ni = 0; ni < 2; ++ni) {
      int colc = ccol0 + (ni << 4);
      if (colc < N) {
#pragma unroll
        for (int r = 0; r < 4; ++r) {
          int rowc = crow0 + (mi << 4) + r;
          float v = acc[mi][ni][r];
          if (ADD) v += src[(size_t)rowc * ldc + colc];
          C[(size_t)rowc * ldc + colc] = v;
        }
      }
    }
}

// ------------- bf16 MFMA SwiGLU GEMM: C = (A@Bu^T) * silu(A@Bv^T) -------------
__global__ __launch_bounds__(256) void mgemm_glu(const float* __restrict__ A,
    const float* __restrict__ B, float* __restrict__ C,
    int M, int N, int K, int lda, int ldb, int ldc) {
  __shared__ short As[64][40];
  __shared__ short Bu[64][40];
  __shared__ short Bv[64][40];
  const int bm = blockIdx.y * 64, bn = blockIdx.x * 64;
  const int tid = threadIdx.x;
  const int w = tid >> 6, lane = tid & 63;
  const int wr = (w >> 1) << 5, wc = (w & 1) << 5;
  const int srow = tid >> 2, sk = (tid & 3) << 3;
  const int lrow = lane & 15, lk8 = (lane >> 4) << 3;
  const int arow = bm + srow, brow = bn + srow;
  f32x4 au[2][2], av[2][2];
#pragma unroll
  for (int i = 0; i < 2; ++i)
#pragma unroll
    for (int j = 0; j < 2; ++j) {
      au[i][j] = (f32x4){0.f, 0.f, 0.f, 0.f};
      av[i][j] = (f32x4){0.f, 0.f, 0.f, 0.f};
    }
  for (int k0 = 0; k0 < K; k0 += 32) {
    __syncthreads();
    {
      const float* ap = A + (size_t)arow * lda + k0 + sk;
      const float* up = B + (size_t)brow * ldb + k0 + sk;
      const float* vp = B + (size_t)(N + brow) * ldb + k0 + sk;
      float4 f0 = *reinterpret_cast<const float4*>(ap);
      float4 f1 = *reinterpret_cast<const float4*>(ap + 4);
      float4 u0 = *reinterpret_cast<const float4*>(up);
      float4 u1 = *reinterpret_cast<const float4*>(up + 4);
      float4 v0 = *reinterpret_cast<const float4*>(vp);
      float4 v1 = *reinterpret_cast<const float4*>(vp + 4);
      bf16x8 a8, u8, v8;
      a8[0]=cvt_bf16(f0.x); a8[1]=cvt_bf16(f0.y); a8[2]=cvt_bf16(f0.z); a8[3]=cvt_bf16(f0.w);
      a8[4]=cvt_bf16(f1.x); a8[5]=cvt_bf16(f1.y); a8[6]=cvt_bf16(f1.z); a8[7]=cvt_bf16(f1.w);
      u8[0]=cvt_bf16(u0.x); u8[1]=cvt_bf16(u0.y); u8[2]=cvt_bf16(u0.z); u8[3]=cvt_bf16(u0.w);
      u8[4]=cvt_bf16(u1.x); u8[5]=cvt_bf16(u1.y); u8[6]=cvt_bf16(u1.z); u8[7]=cvt_bf16(u1.w);
      v8[0]=cvt_bf16(v0.x); v8[1]=cvt_bf16(v0.y); v8[2]=cvt_bf16(v0.z); v8[3]=cvt_bf16(v0.w);
      v8[4]=cvt_bf16(v1.x); v8[5]=cvt_bf16(v1.y); v8[6]=cvt_bf16(v1.z); v8[7]=cvt_bf16(v1.w);
      *reinterpret_cast<bf16x8*>(&As[srow][sk]) = a8;
      *reinterpret_cast<bf16x8*>(&Bu[srow][sk]) = u8;
      *reinterpret_cast<bf16x8*>(&Bv[srow][sk]) = v8;
    }
    __syncthreads();
    bf16x8 af0 = *reinterpret_cast<bf16x8*>(&As[wr + lrow][lk8]);
    bf16x8 af1 = *reinterpret_cast<bf16x8*>(&As[wr + 16 + lrow][lk8]);
    bf16x8 uf0 = *reinterpret_cast<bf16x8*>(&Bu[wc + lrow][lk8]);
    bf16x8 uf1 = *reinterpret_cast<bf16x8*>(&Bu[wc + 16 + lrow][lk8]);
    bf16x8 vf0 = *reinterpret_cast<bf16x8*>(&Bv[wc + lrow][lk8]);
    bf16x8 vf1 = *reinterpret_cast<bf16x8*>(&Bv[wc + 16 + lrow][lk8]);
    au[0][0] = __builtin_amdgcn_mfma_f32_16x16x32_bf16(af0, uf0, au[0][0], 0, 0, 0);
    au[0][1] = __builtin_amdgcn_mfma_f32_16x16x32_bf16(af0, uf1, au[0][1], 0, 0, 0);
    au[1][0] = __builtin_amdgcn_mfma_f32_16x16x32_bf16(af1, uf0, au[1][0], 0, 0, 0);
    au[1][1] = __builtin_amdgcn_mfma_f32_16x16x32_bf16(af1, uf1, au[1][1], 0, 0, 0);
    av[0][0] = __builtin_amdgcn_mfma_f32_16x16x32_bf16(af0, vf0, av[0][0], 0, 0, 0);
    av[0][1] = __builtin_amdgcn_mfma_f32_16x16x32_bf16(af0, vf1, av[0][1], 0, 0, 0);
    av[1][0] = __builtin_amdgcn_mfma_f32_16x16x32_bf16(af1, vf0, av[1][0], 0, 0, 0);
    av[1][1] = __builtin_amdgcn_mfma_f32_16x16x32_bf16(af1, vf1, av[1][1], 0, 0, 0);
  }
  const int crow0 = bm + wr + ((lane >> 4) << 2);
  const int ccol0 = bn + wc + lrow;
#pragma unroll
  for (int mi = 0; mi < 2; ++mi)
#pragma unroll
    for (int ni = 0; ni < 2; ++ni) {
      int colc = ccol0 + (ni << 4);
#pragma unroll
      for (int r = 0; r < 4; ++r) {
        int rowc = crow0 + (mi << 4) + r;
        float uu = au[mi][ni][r], vg = av[mi][ni][r];
        float sig = 1.0f / (1.0f + __expf(-vg));
        C[(size_t)rowc * ldc + colc] = uu * vg * sig;
      }
    }
}

// ---------------- Build Q/K (split heads + RoPE) ----------------
__global__ __launch_bounds__(256) void build_qk(const float* __restrict__ qf,
    const float* __restrict__ kvb, const float* __restrict__ ckv,
    const float* __restrict__ fc, const float* __restrict__ fs,
    float* __restrict__ Qb, float* __restrict__ Kb) {
  int t = blockIdx.x * 256 + threadIdx.x;
  int h2 = blockIdx.y;
  if (t >= S) return;
  int hh = h2 >> 1, par = h2 & 1;
  const float* qrow = qf + (size_t)t*1536 + hh*96;
  const float* krow = kvb + (size_t)t*2048 + hh*128;
  float* qo = Qb + ((size_t)h2*S + t)*DQK;
  float* ko = Kb + ((size_t)h2*S + t)*DQK;
#pragma unroll
  for (int xq = 0; xq < 8; ++xq) {
    *reinterpret_cast<float4*>(qo + (xq<<2)) =
      *reinterpret_cast<const float4*>(qrow + par*32 + (xq<<2));
    *reinterpret_cast<float4*>(ko + (xq<<2)) =
      *reinterpret_cast<const float4*>(krow + par*32 + (xq<<2));
  }
  int p = t >> 2;
  const float* qr = qrow + 64 + par*16;
  const float* kr = ckv + (size_t)t*288 + 256 + par*16;
#pragma unroll
  for (int mq = 0; mq < 8; ++mq) {
    float c = 1.f, sn = 0.f;
    if (p > 0) { c = fc[(p-1)*8 + mq]; sn = fs[(p-1)*8 + mq]; }
    float q0 = qr[2*mq], q1 = qr[2*mq+1];
    qo[32 + 2*mq]     = q0*c - q1*sn;
    qo[32 + 2*mq + 1] = q0*sn + q1*c;
    float k0 = kr[2*mq], k1 = kr[2*mq+1];
    ko[32 + 2*mq]     = k0*c - k1*sn;
    ko[32 + 2*mq + 1] = k0*sn + k1*c;
  }
}

// ---------------- lambda scalar ----------------
__global__ void compute_lam(const float* __restrict__ lq1, const float* __restrict__ lk1,
                            const float* __restrict__ lq2, const float* __restrict__ lk2,
                            float* __restrict__ lamp) {
  int t = threadIdx.x;
  float a = lq1[t]*lk1[t];
  float b = lq2[t]*lk2[t];
#pragma unroll
  for (int mm = 1; mm < 32; mm <<= 1) { a += __shfl_xor(a, mm, 32); b += __shfl_xor(b, mm, 32); }
  if (t == 0) lamp[0] = expf(a) - expf(b) + 0.2f;
}

// ---------------- MFMA flash attention ----------------
// grid (12, 32); 256 thr = 4 waves; each wave owns 32 q-rows (S^T via
// mfma_32x32x16: col=lane&31=q, row=(r&3)+8*(r>>2)+4*(lane>>5)=k).
// K LDS [32][72] bf16; V transposed [64][40] bf16; per-wave Ot [32][68] f32.
// j-tiles with rj0 > ri0 skipped (mask structure); diag tile masked per-elem.
__global__ __launch_bounds__(256) void flash_mfma(const float* __restrict__ Qb,
    const float* __restrict__ Kb, const float* __restrict__ kvb,
    float* __restrict__ Ob, float* __restrict__ rowm, float* __restrict__ rowl) {
  const int h2 = blockIdx.y;
  const int hh = h2 >> 1;
  const int i0 = blockIdx.x << 7;          // 128 q-rows per block
  const int tid = threadIdx.x;
  const int w = tid >> 6, lane = tid & 63;
  const int ql = lane & 31, h = lane >> 5;
  const int qbase = i0 + (w << 5);
  const int rbase = i0 % SPP;              // i0 in {0,128,256} mod 384
  const int ri0w = rbase + (w << 5);
  const int jmaxb = rbase + 96;

  __shared__ __align__(16) short Ks[32][72];
  __shared__ __align__(16) short Vt[64][40];
  __shared__ __align__(16) float Ot[4][32][68];

  // Q fragments (B-operand: col=lane&31=q, d=(lane>>5)*8+e), 3 d-tiles of 16
  bf16x8 qf0, qf1, qf2;
  {
    const float* qp = Qb + ((size_t)h2*S + qbase + ql)*DQK + (h << 3);
#pragma unroll
    for (int dt = 0; dt < 3; ++dt) {
      float4 a = *reinterpret_cast<const float4*>(qp + (dt << 4));
      float4 b = *reinterpret_cast<const float4*>(qp + (dt << 4) + 4);
      bf16x8 q8;
      q8[0]=cvt_bf16(a.x); q8[1]=cvt_bf16(a.y); q8[2]=cvt_bf16(a.z); q8[3]=cvt_bf16(a.w);
      q8[4]=cvt_bf16(b.x); q8[5]=cvt_bf16(b.y); q8[6]=cvt_bf16(b.z); q8[7]=cvt_bf16(b.w);
      if (dt == 0) qf0 = q8; else if (dt == 1) qf1 = q8; else qf2 = q8;
    }
  }

  float m = -1e30f, l = 0.f;
  f32x16 o0, o1;
#pragma unroll
  for (int r = 0; r < 16; ++r) { o0[r] = 0.f; o1[r] = 0.f; }

  for (int c = 0; c < 4; ++c) {
    for (int jr = 0; jr <= jmaxb; jr += 32) {
      const int j0 = c*SPP + jr;
      __syncthreads();
      // ---- stage K tile (32 x 48) ----
      if (tid < 192) {
        int r = tid / 6, c8 = (tid % 6) << 3;
        const float* kp = Kb + ((size_t)h2*S + j0 + r)*DQK + c8;
        float4 a = *reinterpret_cast<const float4*>(kp);
        float4 b = *reinterpret_cast<const float4*>(kp + 4);
        bf16x8 k8;
        k8[0]=cvt_bf16(a.x); k8[1]=cvt_bf16(a.y); k8[2]=cvt_bf16(a.z); k8[3]=cvt_bf16(a.w);
        k8[4]=cvt_bf16(b.x); k8[5]=cvt_bf16(b.y); k8[6]=cvt_bf16(b.z); k8[7]=cvt_bf16(b.w);
        *reinterpret_cast<bf16x8*>(&Ks[r][c8]) = k8;
      }
      // ---- stage V tile transposed (Vt[d][k] = V[j0+k][d]) ----
      {
        int d = tid & 63, kb = (tid >> 6) << 3;
        const float* vp = kvb + (size_t)(j0 + kb)*2048 + hh*128 + 64 + d;
        bf16x8 v8;
#pragma unroll
        for (int e = 0; e < 8; ++e) v8[e] = cvt_bf16(vp[(size_t)e*2048]);
        *reinterpret_cast<bf16x8*>(&Vt[d][kb]) = v8;
      }
      __syncthreads();
      if (jr > ri0w) continue;             // fully masked for this wave
      const bool diag = (jr == ri0w);

      // ---- QK^T: S^T = K @ Q^T (3 MFMAs over d) ----
      bf16x8 kf0 = *reinterpret_cast<bf16x8*>(&Ks[ql][(h << 3)]);
      bf16x8 kf1 = *reinterpret_cast<bf16x8*>(&Ks[ql][16 + (h << 3)]);
      bf16x8 kf2 = *reinterpret_cast<bf16x8*>(&Ks[ql][32 + (h << 3)]);
      f32x16 st;
#pragma unroll
      for (int r = 0; r < 16; ++r) st[r] = 0.f;
      st = __builtin_amdgcn_mfma_f32_32x32x16_bf16(kf0, qf0, st, 0, 0, 0);
      st = __builtin_amdgcn_mfma_f32_32x32x16_bf16(kf1, qf1, st, 0, 0, 0);
      st = __builtin_amdgcn_mfma_f32_32x32x16_bf16(kf2, qf2, st, 0, 0, 0);

      if (diag) {
#pragma unroll
        for (int r = 0; r < 16; ++r) {
          int kl = (r & 3) + ((r >> 2) << 3) + (h << 2);
          st[r] = (kl <= ql) ? st[r] * SCALING : -1e30f;
        }
      } else {
#pragma unroll
        for (int r = 0; r < 16; ++r) st[r] *= SCALING;
      }

      // ---- online softmax (row q = lane&31 spread over lane and lane^32) ----
      float tm = st[0];
#pragma unroll
      for (int r = 1; r < 16; ++r) tm = fmaxf(tm, st[r]);
      tm = fmaxf(tm, __shfl_xor(tm, 32));
      float mnew = fmaxf(m, tm);
      float sc = __expf(m - mnew);
      m = mnew;
      float ps = 0.f;
#pragma unroll
      for (int r = 0; r < 16; ++r) { float p = __expf(st[r] - mnew); st[r] = p; ps += p; }
      ps += __shfl_xor(ps, 32);
      l = l * sc + ps;
#pragma unroll
      for (int r = 0; r < 16; ++r) { o0[r] *= sc; o1[r] *= sc; }

      // ---- repack P^T into PV B-operand fragments ----
      unsigned A0 = pk2(st[0],  st[1]),  B0 = pk2(st[2],  st[3]);
      unsigned C0 = pk2(st[4],  st[5]),  D0 = pk2(st[6],  st[7]);
      unsigned A1 = pk2(st[8],  st[9]),  B1 = pk2(st[10], st[11]);
      unsigned C1 = pk2(st[12], st[13]), D1 = pk2(st[14], st[15]);
      unsigned xA0 = (unsigned)__shfl_xor((int)A0, 32), xB0 = (unsigned)__shfl_xor((int)B0, 32);
      unsigned xC0 = (unsigned)__shfl_xor((int)C0, 32), xD0 = (unsigned)__shfl_xor((int)D0, 32);
      unsigned xA1 = (unsigned)__shfl_xor((int)A1, 32), xB1 = (unsigned)__shfl_xor((int)B1, 32);
      unsigned xC1 = (unsigned)__shfl_xor((int)C1, 32), xD1 = (unsigned)__shfl_xor((int)D1, 32);
      union { unsigned u[4]; bf16x8 v; } P0, P1;
      P0.u[0] = h ? xC0 : A0;  P0.u[1] = h ? xD0 : B0;
      P0.u[2] = h ? C0 : xA0;  P0.u[3] = h ? D0 : xB0;
      P1.u[0] = h ? xC1 : A1;  P1.u[1] = h ? xD1 : B1;
      P1.u[2] = h ? C1 : xA1;  P1.u[3] = h ? D1 : xB1;

      // ---- PV: O^T += V^T @ P^T (4 MFMAs: 2 d-tiles x 2 k-splits) ----
      bf16x8 v00 = *reinterpret_cast<bf16x8*>(&Vt[ql][(h << 3)]);
      bf16x8 v01 = *reinterpret_cast<bf16x8*>(&Vt[ql][16 + (h << 3)]);
      bf16x8 v10 = *reinterpret_cast<bf16x8*>(&Vt[32 + ql][(h << 3)]);
      bf16x8 v11 = *reinterpret_cast<bf16x8*>(&Vt[32 + ql][16 + (h << 3)]);
      o0 = __builtin_amdgcn_mfma_f32_32x32x16_bf16(v00, P0.v, o0, 0, 0, 0);
      o0 = __builtin_amdgcn_mfma_f32_32x32x16_bf16(v01, P1.v, o0, 0, 0, 0);
      o1 = __builtin_amdgcn_mfma_f32_32x32x16_bf16(v10, P0.v, o1, 0, 0, 0);
      o1 = __builtin_amdgcn_mfma_f32_32x32x16_bf16(v11, P1.v, o1, 0, 0, 0);
    }
  }

  // ---- epilogue: normalize, transpose via wave-private LDS, store ----
  float invl = 1.0f / l;
  float* ot = &Ot[w][0][0];
#pragma unroll
  for (int r = 0; r < 16; ++r) {
    int dl = (r & 3) + ((r >> 2) << 3) + (h << 2);
    ot[ql*68 + dl]      = o0[r] * invl;
    ot[ql*68 + 32 + dl] = o1[r] * invl;
  }
  // same-wave LDS in-order: no barrier needed
#pragma unroll
  for (int it = 0; it < 8; ++it) {
    int idx = lane + (it << 6);
    int row = idx >> 4, c4 = (idx & 15) << 2;
    float4 v = *reinterpret_cast<float4*>(&ot[row*68 + c4]);
    *reinterpret_cast<float4*>(&Ob[((size_t)h2*S + qbase + row)*HD + c4]) = v;
  }
  if (lane < 32) {
    rowm[h2*S + qbase + lane] = m;
    rowl[h2*S + qbase + lane] = l;
  }
}

// ---------------- pass 2a: partial column sums of even-half-head probs ----
__global__ __launch_bounds__(128) void colsum_part(const float* __restrict__ Qb,
    const float* __restrict__ Kb, const float* __restrict__ rowm,
    const float* __restrict__ rowl, float* __restrict__ gpart) {
  const int hh = blockIdx.y, h2 = hh * 2;
  const int j = blockIdx.x * 128 + threadIdx.x;
  const int zc = blockIdx.z;
  float kreg[DQK];
  {
    const float* krow = Kb + ((size_t)h2*S + j)*DQK;
#pragma unroll
    for (int xq = 0; xq < 12; ++xq) {
      float4 v = *reinterpret_cast<const float4*>(krow + (xq<<2));
      kreg[xq*4+0]=v.x; kreg[xq*4+1]=v.y; kreg[xq*4+2]=v.z; kreg[xq*4+3]=v.w;
    }
  }
  const int rj = j % SPP;
  __shared__ __align__(16) float Qs[32][DQK];
  __shared__ float Ms[32], Ls[32];
  float acc = 0.f;
  const int ibeg = zc << 7, iend = ibeg + 128;
  for (int i0 = ibeg; i0 < iend; i0 += 32) {
    for (int idx = threadIdx.x; idx < 384; idx += 128) {
      int r = idx / 12, c = (idx % 12) << 2;
      *reinterpret_cast<float4*>(&Qs[r][c]) =
        *reinterpret_cast<const float4*>(Qb + ((size_t)h2*S + i0 + r)*DQK + c);
    }
    if (threadIdx.x < 32) {
      Ms[threadIdx.x] = rowm[h2*S + i0 + threadIdx.x];
      Ls[threadIdx.x] = 1.0f / rowl[h2*S + i0 + threadIdx.x];
    }
    __syncthreads();
#pragma unroll 4
    for (int r = 0; r < 32; ++r) {
      int ri = (i0 + r) % SPP;
      if (rj <= ri) {
        float s = 0.f;
#pragma unroll
        for (int kq = 0; kq < 12; ++kq) {
          float4 q4 = *reinterpret_cast<const float4*>(&Qs[r][kq << 2]);
          s = fmaf(kreg[kq*4+0], q4.x, s);
          s = fmaf(kreg[kq*4+1], q4.y, s);
          s = fmaf(kreg[kq*4+2], q4.z, s);
          s = fmaf(kreg[kq*4+3], q4.w, s);
        }
        acc += __expf(s * SCALING - Ms[r]) * Ls[r];
      }
    }
    __syncthreads();
  }
  gpart[((size_t)zc*NH + hh)*S + j] = acc;
}

// ---------------- pass 2b: reduce partials ----------------
__global__ __launch_bounds__(256) void colsum_reduce(const float* __restrict__ gpart,
    float* __restrict__ gcol) {
  const int idx = blockIdx.x * 256 + threadIdx.x;
  float s = 0.f;
#pragma unroll
  for (int zc = 0; zc < 12; ++zc) s += gpart[(size_t)zc*NH*S + idx];
  gcol[idx] = s * (1.0f / (float)S);
}

// ---------------- Wpre: masked prefix of g-weighted V ----------------
__global__ __launch_bounds__(256) void build_wpre(const float* __restrict__ gcol,
    const float* __restrict__ kvb, float* __restrict__ Wpre) {
  const int hh = blockIdx.x >> 2;
  const int dq = (blockIdx.x & 3) << 4;
  __shared__ float Wt[SPP][16];
  const int tid = threadIdx.x;
  for (int idx = tid; idx < SPP*16; idx += 256) {
    int r = idx >> 4, dd = idx & 15;
    float val = 0.f;
#pragma unroll
    for (int b2 = 0; b2 < 4; ++b2) {
      int j = b2*SPP + r;
      val = fmaf(gcol[hh*S + j], kvb[(size_t)j*2048 + hh*128 + 64 + dq + dd], val);
    }
    Wt[r][dd] = val;
  }
  __syncthreads();
  if (tid < 16) {
    float run = 0.f;
    for (int r = 0; r < SPP; ++r) { run += Wt[r][tid]; Wt[r][tid] = run; }
  }
  __syncthreads();
  for (int idx = tid; idx < SPP*16; idx += 256) {
    int r = idx >> 4, dd = idx & 15;
    Wpre[((size_t)hh*SPP + r)*HD + dq + dd] = Wt[r][dd];
  }
}

// ---------------- combine (diff-attn) + per-head RMSNorm + scrambled reshape ----
__global__ __launch_bounds__(64) void combine_rms(const float* __restrict__ Ob,
    const float* __restrict__ Wpre, const float* __restrict__ lamp,
    const float* __restrict__ anw, float* __restrict__ attno) {
  const int t = blockIdx.x, h = blockIdx.y, d = threadIdx.x;
  const float lam = lamp[0];
  const float o1 = Ob[((size_t)(2*h)*S + t)*HD + d];
  const float o2 = Ob[((size_t)(2*h+1)*S + t)*HD + d];
  const float w3 = Wpre[((size_t)h*SPP + (t % SPP))*HD + d];
  float val = o1 - lam*o2 + lam*w3;
  float ss = val*val;
#pragma unroll
  for (int mm = 1; mm < 64; mm <<= 1) ss += __shfl_xor(ss, mm, 64);
  float scale = rsqrtf(ss * (1.0f/HD) + ATTN_EPS) * anw[d];
  int tn = h*96 + (t >> 4);
  int cn = ((t & 15) << 6) + d;
  attno[(size_t)tn*DM + cn] = val * scale;
}

// =========================== launch ===========================
extern "C" void kernel_launch(void* const* d_in, const int* in_sizes, int n_in,
                              void* d_out, int out_size, void* d_ws, size_t ws_size,
                              hipStream_t stream) {
  (void)in_sizes; (void)n_in; (void)out_size;
  const float* x    = (const float*)d_in[0];
  const float* fc   = (const float*)d_in[1];
  const float* fs   = (const float*)d_in[2];
  const float* n1w  = (const float*)d_in[3];
  const float* n2w  = (const float*)d_in[4];
  const float* kvdw = (const float*)d_in[5];
  const float* qdw  = (const float*)d_in[6];
  const float* kvnw = (const float*)d_in[7];
  const float* qnw  = (const float*)d_in[8];
  const float* kvuw = (const float*)d_in[9];
  const float* quw  = (const float*)d_in[10];
  const float* lq1  = (const float*)d_in[11];
  const float* lk1  = (const float*)d_in[12];
  const float* lq2  = (const float*)d_in[13];
  const float* lk2  = (const float*)d_in[14];
  const float* anw  = (const float*)d_in[15];
  const float* ow   = (const float*)d_in[16];
  const float* ffiw = (const float*)d_in[17];
  const float* ffow = (const float*)d_in[18];
  float* out = (float*)d_out;
  float* ws  = (float*)d_ws;

  float* xin   = ws;
  float* ckv   = xin   + (size_t)S*DM;
  float* qmid  = ckv   + (size_t)S*288;
  float* kvb   = qmid  + (size_t)S*QC;
  float* qf    = kvb   + (size_t)S*2048;
  float* Qb    = qf    + (size_t)S*1536;
  float* Kb    = Qb    + (size_t)H2N*S*DQK;
  float* Obuf  = Kb    + (size_t)H2N*S*DQK;
  float* rowm  = Obuf  + (size_t)H2N*S*HD;
  float* rowl  = rowm  + (size_t)H2N*S;
  float* gcol  = rowl  + (size_t)H2N*S;
  float* Wpre  = gcol  + (size_t)NH*S;
  float* attno = Wpre  + (size_t)NH*SPP*HD;
  float* lamp  = attno + (size_t)S*DM;
  float* fbuf  = kvb;
  float* gpart = attno;
  if (ws_size < (size_t)18063376 * sizeof(float)) return;

  rmsnorm_k<<<S, 256, 0, stream>>>(x, n1w, xin, DM, DM, DM, EPS_RMS);
  { dim3 g(5, 24);  mgemm_nt<0><<<g, 256, 0, stream>>>(xin, kvdw, nullptr, ckv, S, 288, DM, DM, DM, 288); }
  { dim3 g(6, 24);  mgemm_nt<0><<<g, 256, 0, stream>>>(xin, qdw,  nullptr, qmid, S, QC, DM, DM, DM, QC); }
  rmsnorm_k<<<S, 256, 0, stream>>>(ckv,  kvnw, ckv,  KVC, 288, 288, EPS_RMS);
  rmsnorm_k<<<S, 256, 0, stream>>>(qmid, qnw,  qmid, QC,  QC,  QC,  EPS_RMS);
  { dim3 g(32, 24); mgemm_nt<0><<<g, 256, 0, stream>>>(ckv,  kvuw, nullptr, kvb, S, 2048, KVC, 288, KVC, 2048); }
  { dim3 g(24, 24); mgemm_nt<0><<<g, 256, 0, stream>>>(qmid, quw,  nullptr, qf,  S, 1536, QC,  QC,  QC,  1536); }
  { dim3 g(6, 32);  build_qk<<<g, 256, 0, stream>>>(qf, kvb, ckv, fc, fs, Qb, Kb); }
  compute_lam<<<1, 32, 0, stream>>>(lq1, lk1, lq2, lk2, lamp);
  { dim3 g(12, 32); flash_mfma<<<g, 256, 0, stream>>>(Qb, Kb, kvb, Obuf, rowm, rowl); }
  { dim3 g(12, 16, 12); colsum_part<<<g, 128, 0, stream>>>(Qb, Kb, rowm, rowl, gpart); }
  colsum_reduce<<<96, 256, 0, stream>>>(gpart, gcol);
  build_wpre<<<64, 256, 0, stream>>>(gcol, kvb, Wpre);
  { dim3 g(S, 16);  combine_rms<<<g, 64, 0, stream>>>(Obuf, Wpre, lamp, anw, attno); }
  { dim3 g(16, 24); mgemm_nt<1><<<g, 256, 0, stream>>>(attno, ow, x, out, S, DM, DM, DM, DM, DM); }
  rmsnorm_k<<<S, 256, 0, stream>>>(out, n2w, xin, DM, DM, DM, EPS_RMS);
  { dim3 g(64, 24); mgemm_glu<<<g, 256, 0, stream>>>(xin, ffiw, fbuf, S, DFF, DM, DM, DM, DFF); }
  { dim3 g(16, 24); mgemm_nt<1><<<g, 256, 0, stream>>>(fbuf, ffow, out, out, S, DM, DFF, DFF, DFF, DM); }
}

// Round 6
// 417.298 us; speedup vs baseline: 5.6891x; 1.0922x over previous
//
#include <hip/hip_runtime.h>
#include <math.h>

#define S     1536
#define DM    1024
#define NH    16
#define H2N   32
#define HD    64
#define KVC   256
#define QC    384
#define DFF   4096
#define SPP   384
#define DQK   48
#define EPS_RMS  1.1920929e-07f
#define ATTN_EPS 1e-5f
#define SCALING  0.14433756729740643f   /* 48^-0.5 */

typedef float f32x4 __attribute__((ext_vector_type(4)));
typedef float f32x16 __attribute__((ext_vector_type(16)));
typedef short bf16x8 __attribute__((ext_vector_type(8)));

__device__ __forceinline__ short cvt_bf16(float f) {
  union { float f; unsigned u; } x; x.f = f;
  unsigned r = x.u + 0x7FFFu + ((x.u >> 16) & 1u);
  return (short)(r >> 16);
}
__device__ __forceinline__ unsigned pk2(float a, float b) {
  return (unsigned)(unsigned short)cvt_bf16(a) |
         ((unsigned)(unsigned short)cvt_bf16(b) << 16);
}
__device__ __forceinline__ bf16x8 cvt8(float4 a, float4 b) {
  bf16x8 v;
  v[0]=cvt_bf16(a.x); v[1]=cvt_bf16(a.y); v[2]=cvt_bf16(a.z); v[3]=cvt_bf16(a.w);
  v[4]=cvt_bf16(b.x); v[5]=cvt_bf16(b.y); v[6]=cvt_bf16(b.z); v[7]=cvt_bf16(b.w);
  return v;
}

// ---------------- RMSNorm (generic, optional in-place) ----------------
__global__ __launch_bounds__(256) void rmsnorm_k(const float* __restrict__ in,
    const float* __restrict__ w, float* __restrict__ out,
    int cols, int ldin, int ldout, float eps) {
  const int row = blockIdx.x;
  const float* xr = in + (size_t)row * ldin;
  float* yr = out + (size_t)row * ldout;
  const int tid = threadIdx.x;
  float ss = 0.f;
  for (int c = tid << 2; c < cols; c += 1024) {
    float4 v = *reinterpret_cast<const float4*>(xr + c);
    ss += v.x*v.x + v.y*v.y + v.z*v.z + v.w*v.w;
  }
#pragma unroll
  for (int mm = 1; mm < 64; mm <<= 1) ss += __shfl_xor(ss, mm, 64);
  __shared__ float red[4];
  if ((tid & 63) == 0) red[tid >> 6] = ss;
  __syncthreads();
  float tot = red[0] + red[1] + red[2] + red[3];
  float scale = rsqrtf(tot / (float)cols + eps);
  for (int c = tid << 2; c < cols; c += 1024) {
    float4 v = *reinterpret_cast<const float4*>(xr + c);
    float4 wv = *reinterpret_cast<const float4*>(w + c);
    float4 ov = make_float4(v.x*scale*wv.x, v.y*scale*wv.y, v.z*scale*wv.z, v.w*scale*wv.w);
    *reinterpret_cast<float4*>(yr + c) = ov;
  }
}

// ------------- bf16 MFMA GEMM, BK=64, register-prefetch pipeline -------------
// C[M,N] = A[M,K] @ B[N,K]^T (+ src). ABF: A is bf16 (lda in elements).
template<int ADD, int ABF>
__global__ __launch_bounds__(256) void mgemm_nt(const void* __restrict__ Av,
    const float* __restrict__ B, const float* __restrict__ src, float* __restrict__ C,
    int M, int N, int K, int lda, int ldb, int ldc) {
  __shared__ short As[64][72];
  __shared__ short Bs[64][72];
  const int bm = blockIdx.y * 64, bn = blockIdx.x * 64;
  const int tid = threadIdx.x;
  const int w = tid >> 6, lane = tid & 63;
  const int wr = (w >> 1) << 5, wc = (w & 1) << 5;
  const int srow = tid >> 2, sk = (tid & 3) << 4;
  const int lrow = lane & 15, lk8 = (lane >> 4) << 3;
  const int arow = bm + srow, brow = bn + srow;
  const bool bvalid = brow < N;
  const float* Af = (const float*)Av;
  const short* Ah = (const short*)Av;
  f32x4 acc[2][2];
#pragma unroll
  for (int i = 0; i < 2; ++i)
#pragma unroll
    for (int j = 0; j < 2; ++j) acc[i][j] = (f32x4){0.f, 0.f, 0.f, 0.f};

  float4 ra[4]; bf16x8 rah0, rah1; float4 rb[4];
  if (ABF) {
    const short* ap = Ah + (size_t)arow * lda + sk;
    rah0 = *reinterpret_cast<const bf16x8*>(ap);
    rah1 = *reinterpret_cast<const bf16x8*>(ap + 8);
  } else {
    const float* ap = Af + (size_t)arow * lda + sk;
    ra[0] = *reinterpret_cast<const float4*>(ap);
    ra[1] = *reinterpret_cast<const float4*>(ap + 4);
    ra[2] = *reinterpret_cast<const float4*>(ap + 8);
    ra[3] = *reinterpret_cast<const float4*>(ap + 12);
  }
  rb[0]=rb[1]=rb[2]=rb[3]=make_float4(0.f,0.f,0.f,0.f);
  if (bvalid) {
    const float* bp = B + (size_t)brow * ldb + sk;
    rb[0] = *reinterpret_cast<const float4*>(bp);
    rb[1] = *reinterpret_cast<const float4*>(bp + 4);
    rb[2] = *reinterpret_cast<const float4*>(bp + 8);
    rb[3] = *reinterpret_cast<const float4*>(bp + 12);
  }

  for (int k0 = 0; k0 < K; k0 += 64) {
    bf16x8 va0, va1;
    if (ABF) { va0 = rah0; va1 = rah1; }
    else     { va0 = cvt8(ra[0], ra[1]); va1 = cvt8(ra[2], ra[3]); }
    bf16x8 vb0 = cvt8(rb[0], rb[1]), vb1 = cvt8(rb[2], rb[3]);
    __syncthreads();
    *reinterpret_cast<bf16x8*>(&As[srow][sk])     = va0;
    *reinterpret_cast<bf16x8*>(&As[srow][sk + 8]) = va1;
    *reinterpret_cast<bf16x8*>(&Bs[srow][sk])     = vb0;
    *reinterpret_cast<bf16x8*>(&Bs[srow][sk + 8]) = vb1;
    __syncthreads();
    const int kn = k0 + 64;
    if (kn < K) {   // issue next-tile loads; vmcnt-waited at next iter's cvt
      if (ABF) {
        const short* ap = Ah + (size_t)arow * lda + kn + sk;
        rah0 = *reinterpret_cast<const bf16x8*>(ap);
        rah1 = *reinterpret_cast<const bf16x8*>(ap + 8);
      } else {
        const float* ap = Af + (size_t)arow * lda + kn + sk;
        ra[0] = *reinterpret_cast<const float4*>(ap);
        ra[1] = *reinterpret_cast<const float4*>(ap + 4);
        ra[2] = *reinterpret_cast<const float4*>(ap + 8);
        ra[3] = *reinterpret_cast<const float4*>(ap + 12);
      }
      if (bvalid) {
        const float* bp = B + (size_t)brow * ldb + kn + sk;
        rb[0] = *reinterpret_cast<const float4*>(bp);
        rb[1] = *reinterpret_cast<const float4*>(bp + 4);
        rb[2] = *reinterpret_cast<const float4*>(bp + 8);
        rb[3] = *reinterpret_cast<const float4*>(bp + 12);
      }
    }
#pragma unroll
    for (int kk = 0; kk < 2; ++kk) {
      bf16x8 af0 = *reinterpret_cast<bf16x8*>(&As[wr + lrow][(kk << 5) + lk8]);
      bf16x8 af1 = *reinterpret_cast<bf16x8*>(&As[wr + 16 + lrow][(kk << 5) + lk8]);
      bf16x8 bf0 = *reinterpret_cast<bf16x8*>(&Bs[wc + lrow][(kk << 5) + lk8]);
      bf16x8 bf1 = *reinterpret_cast<bf16x8*>(&Bs[wc + 16 + lrow][(kk << 5) + lk8]);
      acc[0][0] = __builtin_amdgcn_mfma_f32_16x16x32_bf16(af0, bf0, acc[0][0], 0, 0, 0);
      acc[0][1] = __builtin_amdgcn_mfma_f32_16x16x32_bf16(af0, bf1, acc[0][1], 0, 0, 0);
      acc[1][0] = __builtin_amdgcn_mfma_f32_16x16x32_bf16(af1, bf0, acc[1][0], 0, 0, 0);
      acc[1][1] = __builtin_amdgcn_mfma_f32_16x16x32_bf16(af1, bf1, acc[1][1], 0, 0, 0);
    }
  }
  const int crow0 = bm + wr + ((lane >> 4) << 2);
  const int ccol0 = bn + wc + lrow;
#pragma unroll
  for (int mi = 0; mi < 2; ++mi)
#pragma unroll
    for (int ni = 0; ni < 2; ++ni) {
      int colc = ccol0 + (ni << 4);
      if (colc < N) {
#pragma unroll
        for (int r = 0; r < 4; ++r) {
          int rowc = crow0 + (mi << 4) + r;
          float v = acc[mi][ni][r];
          if (ADD) v += src[(size_t)rowc * ldc + colc];
          C[(size_t)rowc * ldc + colc] = v;
        }
      }
    }
}

// ------------- bf16 MFMA SwiGLU GEMM (pipelined), bf16 output -------------
// C = (A@Bu^T) * silu(A@Bv^T); Bu = B rows [0,N), Bv = rows [N,2N). N exact.
__global__ __launch_bounds__(256) void mgemm_glu(const float* __restrict__ A,
    const float* __restrict__ B, short* __restrict__ C,
    int M, int N, int K, int lda, int ldb, int ldc) {
  __shared__ short As[64][72];
  __shared__ short Bu[64][72];
  __shared__ short Bv[64][72];
  const int bm = blockIdx.y * 64, bn = blockIdx.x * 64;
  const int tid = threadIdx.x;
  const int w = tid >> 6, lane = tid & 63;
  const int wr = (w >> 1) << 5, wc = (w & 1) << 5;
  const int srow = tid >> 2, sk = (tid & 3) << 4;
  const int lrow = lane & 15, lk8 = (lane >> 4) << 3;
  const int arow = bm + srow, brow = bn + srow;
  f32x4 au[2][2], av[2][2];
#pragma unroll
  for (int i = 0; i < 2; ++i)
#pragma unroll
    for (int j = 0; j < 2; ++j) {
      au[i][j] = (f32x4){0.f, 0.f, 0.f, 0.f};
      av[i][j] = (f32x4){0.f, 0.f, 0.f, 0.f};
    }
  float4 ra[4], ru[4], rv[4];
  {
    const float* ap = A + (size_t)arow * lda + sk;
    const float* up = B + (size_t)brow * ldb + sk;
    const float* vp = B + (size_t)(N + brow) * ldb + sk;
#pragma unroll
    for (int e = 0; e < 4; ++e) {
      ra[e] = *reinterpret_cast<const float4*>(ap + (e << 2));
      ru[e] = *reinterpret_cast<const float4*>(up + (e << 2));
      rv[e] = *reinterpret_cast<const float4*>(vp + (e << 2));
    }
  }
  for (int k0 = 0; k0 < K; k0 += 64) {
    bf16x8 a0 = cvt8(ra[0], ra[1]), a1 = cvt8(ra[2], ra[3]);
    bf16x8 u0 = cvt8(ru[0], ru[1]), u1 = cvt8(ru[2], ru[3]);
    bf16x8 v0 = cvt8(rv[0], rv[1]), v1 = cvt8(rv[2], rv[3]);
    __syncthreads();
    *reinterpret_cast<bf16x8*>(&As[srow][sk])     = a0;
    *reinterpret_cast<bf16x8*>(&As[srow][sk + 8]) = a1;
    *reinterpret_cast<bf16x8*>(&Bu[srow][sk])     = u0;
    *reinterpret_cast<bf16x8*>(&Bu[srow][sk + 8]) = u1;
    *reinterpret_cast<bf16x8*>(&Bv[srow][sk])     = v0;
    *reinterpret_cast<bf16x8*>(&Bv[srow][sk + 8]) = v1;
    __syncthreads();
    const int kn = k0 + 64;
    if (kn < K) {
      const float* ap = A + (size_t)arow * lda + kn + sk;
      const float* up = B + (size_t)brow * ldb + kn + sk;
      const float* vp = B + (size_t)(N + brow) * ldb + kn + sk;
#pragma unroll
      for (int e = 0; e < 4; ++e) {
        ra[e] = *reinterpret_cast<const float4*>(ap + (e << 2));
        ru[e] = *reinterpret_cast<const float4*>(up + (e << 2));
        rv[e] = *reinterpret_cast<const float4*>(vp + (e << 2));
      }
    }
#pragma unroll
    for (int kk = 0; kk < 2; ++kk) {
      bf16x8 af0 = *reinterpret_cast<bf16x8*>(&As[wr + lrow][(kk << 5) + lk8]);
      bf16x8 af1 = *reinterpret_cast<bf16x8*>(&As[wr + 16 + lrow][(kk << 5) + lk8]);
      bf16x8 uf0 = *reinterpret_cast<bf16x8*>(&Bu[wc + lrow][(kk << 5) + lk8]);
      bf16x8 uf1 = *reinterpret_cast<bf16x8*>(&Bu[wc + 16 + lrow][(kk << 5) + lk8]);
      bf16x8 vf0 = *reinterpret_cast<bf16x8*>(&Bv[wc + lrow][(kk << 5) + lk8]);
      bf16x8 vf1 = *reinterpret_cast<bf16x8*>(&Bv[wc + 16 + lrow][(kk << 5) + lk8]);
      au[0][0] = __builtin_amdgcn_mfma_f32_16x16x32_bf16(af0, uf0, au[0][0], 0, 0, 0);
      au[0][1] = __builtin_amdgcn_mfma_f32_16x16x32_bf16(af0, uf1, au[0][1], 0, 0, 0);
      au[1][0] = __builtin_amdgcn_mfma_f32_16x16x32_bf16(af1, uf0, au[1][0], 0, 0, 0);
      au[1][1] = __builtin_amdgcn_mfma_f32_16x16x32_bf16(af1, uf1, au[1][1], 0, 0, 0);
      av[0][0] = __builtin_amdgcn_mfma_f32_16x16x32_bf16(af0, vf0, av[0][0], 0, 0, 0);
      av[0][1] = __builtin_amdgcn_mfma_f32_16x16x32_bf16(af0, vf1, av[0][1], 0, 0, 0);
      av[1][0] = __builtin_amdgcn_mfma_f32_16x16x32_bf16(af1, vf0, av[1][0], 0, 0, 0);
      av[1][1] = __builtin_amdgcn_mfma_f32_16x16x32_bf16(af1, vf1, av[1][1], 0, 0, 0);
    }
  }
  const int crow0 = bm + wr + ((lane >> 4) << 2);
  const int ccol0 = bn + wc + lrow;
#pragma unroll
  for (int mi = 0; mi < 2; ++mi)
#pragma unroll
    for (int ni = 0; ni < 2; ++ni) {
      int colc = ccol0 + (ni << 4);
#pragma unroll
      for (int r = 0; r < 4; ++r) {
        int rowc = crow0 + (mi << 4) + r;
        float uu = au[mi][ni][r], vg = av[mi][ni][r];
        float sig = 1.0f / (1.0f + __expf(-vg));
        C[(size_t)rowc * ldc + colc] = cvt_bf16(uu * vg * sig);
      }
    }
}

// ---------------- Build Q/K (split heads + RoPE) ----------------
__global__ __launch_bounds__(256) void build_qk(const float* __restrict__ qf,
    const float* __restrict__ kvb, const float* __restrict__ ckv,
    const float* __restrict__ fc, const float* __restrict__ fs,
    float* __restrict__ Qb, float* __restrict__ Kb) {
  int t = blockIdx.x * 256 + threadIdx.x;
  int h2 = blockIdx.y;
  if (t >= S) return;
  int hh = h2 >> 1, par = h2 & 1;
  const float* qrow = qf + (size_t)t*1536 + hh*96;
  const float* krow = kvb + (size_t)t*2048 + hh*128;
  float* qo = Qb + ((size_t)h2*S + t)*DQK;
  float* ko = Kb + ((size_t)h2*S + t)*DQK;
#pragma unroll
  for (int xq = 0; xq < 8; ++xq) {
    *reinterpret_cast<float4*>(qo + (xq<<2)) =
      *reinterpret_cast<const float4*>(qrow + par*32 + (xq<<2));
    *reinterpret_cast<float4*>(ko + (xq<<2)) =
      *reinterpret_cast<const float4*>(krow + par*32 + (xq<<2));
  }
  int p = t >> 2;
  const float* qr = qrow + 64 + par*16;
  const float* kr = ckv + (size_t)t*288 + 256 + par*16;
#pragma unroll
  for (int mq = 0; mq < 8; ++mq) {
    float c = 1.f, sn = 0.f;
    if (p > 0) { c = fc[(p-1)*8 + mq]; sn = fs[(p-1)*8 + mq]; }
    float q0 = qr[2*mq], q1 = qr[2*mq+1];
    qo[32 + 2*mq]     = q0*c - q1*sn;
    qo[32 + 2*mq + 1] = q0*sn + q1*c;
    float k0 = kr[2*mq], k1 = kr[2*mq+1];
    ko[32 + 2*mq]     = k0*c - k1*sn;
    ko[32 + 2*mq + 1] = k0*sn + k1*c;
  }
}

// ---------------- lambda scalar ----------------
__global__ void compute_lam(const float* __restrict__ lq1, const float* __restrict__ lk1,
                            const float* __restrict__ lq2, const float* __restrict__ lk2,
                            float* __restrict__ lamp) {
  int t = threadIdx.x;
  float a = lq1[t]*lk1[t];
  float b = lq2[t]*lk2[t];
#pragma unroll
  for (int mm = 1; mm < 32; mm <<= 1) { a += __shfl_xor(a, mm, 32); b += __shfl_xor(b, mm, 32); }
  if (t == 0) lamp[0] = expf(a) - expf(b) + 0.2f;
}

// ---------------- MFMA flash attention ----------------
__global__ __launch_bounds__(256) void flash_mfma(const float* __restrict__ Qb,
    const float* __restrict__ Kb, const float* __restrict__ kvb,
    float* __restrict__ Ob, float* __restrict__ rowm, float* __restrict__ rowl) {
  const int h2 = blockIdx.y;
  const int hh = h2 >> 1;
  const int i0 = blockIdx.x << 7;
  const int tid = threadIdx.x;
  const int w = tid >> 6, lane = tid & 63;
  const int ql = lane & 31, h = lane >> 5;
  const int qbase = i0 + (w << 5);
  const int rbase = i0 % SPP;
  const int ri0w = rbase + (w << 5);
  const int jmaxb = rbase + 96;

  __shared__ __align__(16) short Ks[32][72];
  __shared__ __align__(16) short Vt[64][40];
  __shared__ __align__(16) float Ot[4][32][68];

  bf16x8 qf0, qf1, qf2;
  {
    const float* qp = Qb + ((size_t)h2*S + qbase + ql)*DQK + (h << 3);
#pragma unroll
    for (int dt = 0; dt < 3; ++dt) {
      float4 a = *reinterpret_cast<const float4*>(qp + (dt << 4));
      float4 b = *reinterpret_cast<const float4*>(qp + (dt << 4) + 4);
      bf16x8 q8 = cvt8(a, b);
      if (dt == 0) qf0 = q8; else if (dt == 1) qf1 = q8; else qf2 = q8;
    }
  }

  float m = -1e30f, l = 0.f;
  f32x16 o0, o1;
#pragma unroll
  for (int r = 0; r < 16; ++r) { o0[r] = 0.f; o1[r] = 0.f; }

  for (int c = 0; c < 4; ++c) {
    for (int jr = 0; jr <= jmaxb; jr += 32) {
      const int j0 = c*SPP + jr;
      __syncthreads();
      if (tid < 192) {
        int r = tid / 6, c8 = (tid % 6) << 3;
        const float* kp = Kb + ((size_t)h2*S + j0 + r)*DQK + c8;
        float4 a = *reinterpret_cast<const float4*>(kp);
        float4 b = *reinterpret_cast<const float4*>(kp + 4);
        *reinterpret_cast<bf16x8*>(&Ks[r][c8]) = cvt8(a, b);
      }
      {
        int d = tid & 63, kb = (tid >> 6) << 3;
        const float* vp = kvb + (size_t)(j0 + kb)*2048 + hh*128 + 64 + d;
        bf16x8 v8;
#pragma unroll
        for (int e = 0; e < 8; ++e) v8[e] = cvt_bf16(vp[(size_t)e*2048]);
        *reinterpret_cast<bf16x8*>(&Vt[d][kb]) = v8;
      }
      __syncthreads();
      if (jr > ri0w) continue;
      const bool diag = (jr == ri0w);

      bf16x8 kf0 = *reinterpret_cast<bf16x8*>(&Ks[ql][(h << 3)]);
      bf16x8 kf1 = *reinterpret_cast<bf16x8*>(&Ks[ql][16 + (h << 3)]);
      bf16x8 kf2 = *reinterpret_cast<bf16x8*>(&Ks[ql][32 + (h << 3)]);
      f32x16 st;
#pragma unroll
      for (int r = 0; r < 16; ++r) st[r] = 0.f;
      st = __builtin_amdgcn_mfma_f32_32x32x16_bf16(kf0, qf0, st, 0, 0, 0);
      st = __builtin_amdgcn_mfma_f32_32x32x16_bf16(kf1, qf1, st, 0, 0, 0);
      st = __builtin_amdgcn_mfma_f32_32x32x16_bf16(kf2, qf2, st, 0, 0, 0);

      if (diag) {
#pragma unroll
        for (int r = 0; r < 16; ++r) {
          int kl = (r & 3) + ((r >> 2) << 3) + (h << 2);
          st[r] = (kl <= ql) ? st[r] * SCALING : -1e30f;
        }
      } else {
#pragma unroll
        for (int r = 0; r < 16; ++r) st[r] *= SCALING;
      }

      float tm = st[0];
#pragma unroll
      for (int r = 1; r < 16; ++r) tm = fmaxf(tm, st[r]);
      tm = fmaxf(tm, __shfl_xor(tm, 32));
      float mnew = fmaxf(m, tm);
      float sc = __expf(m - mnew);
      m = mnew;
      float ps = 0.f;
#pragma unroll
      for (int r = 0; r < 16; ++r) { float p = __expf(st[r] - mnew); st[r] = p; ps += p; }
      ps += __shfl_xor(ps, 32);
      l = l * sc + ps;
#pragma unroll
      for (int r = 0; r < 16; ++r) { o0[r] *= sc; o1[r] *= sc; }

      unsigned A0 = pk2(st[0],  st[1]),  B0 = pk2(st[2],  st[3]);
      unsigned C0 = pk2(st[4],  st[5]),  D0 = pk2(st[6],  st[7]);
      unsigned A1 = pk2(st[8],  st[9]),  B1 = pk2(st[10], st[11]);
      unsigned C1 = pk2(st[12], st[13]), D1 = pk2(st[14], st[15]);
      unsigned xA0 = (unsigned)__shfl_xor((int)A0, 32), xB0 = (unsigned)__shfl_xor((int)B0, 32);
      unsigned xC0 = (unsigned)__shfl_xor((int)C0, 32), xD0 = (unsigned)__shfl_xor((int)D0, 32);
      unsigned xA1 = (unsigned)__shfl_xor((int)A1, 32), xB1 = (unsigned)__shfl_xor((int)B1, 32);
      unsigned xC1 = (unsigned)__shfl_xor((int)C1, 32), xD1 = (unsigned)__shfl_xor((int)D1, 32);
      union { unsigned u[4]; bf16x8 v; } P0, P1;
      P0.u[0] = h ? xC0 : A0;  P0.u[1] = h ? xD0 : B0;
      P0.u[2] = h ? C0 : xA0;  P0.u[3] = h ? D0 : xB0;
      P1.u[0] = h ? xC1 : A1;  P1.u[1] = h ? xD1 : B1;
      P1.u[2] = h ? C1 : xA1;  P1.u[3] = h ? D1 : xB1;

      bf16x8 v00 = *reinterpret_cast<bf16x8*>(&Vt[ql][(h << 3)]);
      bf16x8 v01 = *reinterpret_cast<bf16x8*>(&Vt[ql][16 + (h << 3)]);
      bf16x8 v10 = *reinterpret_cast<bf16x8*>(&Vt[32 + ql][(h << 3)]);
      bf16x8 v11 = *reinterpret_cast<bf16x8*>(&Vt[32 + ql][16 + (h << 3)]);
      o0 = __builtin_amdgcn_mfma_f32_32x32x16_bf16(v00, P0.v, o0, 0, 0, 0);
      o0 = __builtin_amdgcn_mfma_f32_32x32x16_bf16(v01, P1.v, o0, 0, 0, 0);
      o1 = __builtin_amdgcn_mfma_f32_32x32x16_bf16(v10, P0.v, o1, 0, 0, 0);
      o1 = __builtin_amdgcn_mfma_f32_32x32x16_bf16(v11, P1.v, o1, 0, 0, 0);
    }
  }

  float invl = 1.0f / l;
  float* ot = &Ot[w][0][0];
#pragma unroll
  for (int r = 0; r < 16; ++r) {
    int dl = (r & 3) + ((r >> 2) << 3) + (h << 2);
    ot[ql*68 + dl]      = o0[r] * invl;
    ot[ql*68 + 32 + dl] = o1[r] * invl;
  }
#pragma unroll
  for (int it = 0; it < 8; ++it) {
    int idx = lane + (it << 6);
    int row = idx >> 4, c4 = (idx & 15) << 2;
    float4 v = *reinterpret_cast<float4*>(&ot[row*68 + c4]);
    *reinterpret_cast<float4*>(&Ob[((size_t)h2*S + qbase + row)*HD + c4]) = v;
  }
  if (lane < 32) {
    rowm[h2*S + qbase + lane] = m;
    rowl[h2*S + qbase + lane] = l;
  }
}

// ---------------- pass 2a: partial column sums of even-half-head probs ----
__global__ __launch_bounds__(128) void colsum_part(const float* __restrict__ Qb,
    const float* __restrict__ Kb, const float* __restrict__ rowm,
    const float* __restrict__ rowl, float* __restrict__ gpart) {
  const int hh = blockIdx.y, h2 = hh * 2;
  const int j = blockIdx.x * 128 + threadIdx.x;
  const int zc = blockIdx.z;
  float kreg[DQK];
  {
    const float* krow = Kb + ((size_t)h2*S + j)*DQK;
#pragma unroll
    for (int xq = 0; xq < 12; ++xq) {
      float4 v = *reinterpret_cast<const float4*>(krow + (xq<<2));
      kreg[xq*4+0]=v.x; kreg[xq*4+1]=v.y; kreg[xq*4+2]=v.z; kreg[xq*4+3]=v.w;
    }
  }
  const int rj = j % SPP;
  __shared__ __align__(16) float Qs[32][DQK];
  __shared__ float Ms[32], Ls[32];
  float acc = 0.f;
  const int ibeg = zc << 7, iend = ibeg + 128;
  for (int i0 = ibeg; i0 < iend; i0 += 32) {
    for (int idx = threadIdx.x; idx < 384; idx += 128) {
      int r = idx / 12, c = (idx % 12) << 2;
      *reinterpret_cast<float4*>(&Qs[r][c]) =
        *reinterpret_cast<const float4*>(Qb + ((size_t)h2*S + i0 + r)*DQK + c);
    }
    if (threadIdx.x < 32) {
      Ms[threadIdx.x] = rowm[h2*S + i0 + threadIdx.x];
      Ls[threadIdx.x] = 1.0f / rowl[h2*S + i0 + threadIdx.x];
    }
    __syncthreads();
#pragma unroll 4
    for (int r = 0; r < 32; ++r) {
      int ri = (i0 + r) % SPP;
      if (rj <= ri) {
        float s = 0.f;
#pragma unroll
        for (int kq = 0; kq < 12; ++kq) {
          float4 q4 = *reinterpret_cast<const float4*>(&Qs[r][kq << 2]);
          s = fmaf(kreg[kq*4+0], q4.x, s);
          s = fmaf(kreg[kq*4+1], q4.y, s);
          s = fmaf(kreg[kq*4+2], q4.z, s);
          s = fmaf(kreg[kq*4+3], q4.w, s);
        }
        acc += __expf(s * SCALING - Ms[r]) * Ls[r];
      }
    }
    __syncthreads();
  }
  gpart[((size_t)zc*NH + hh)*S + j] = acc;
}

// ---------------- pass 2b: reduce partials ----------------
__global__ __launch_bounds__(256) void colsum_reduce(const float* __restrict__ gpart,
    float* __restrict__ gcol) {
  const int idx = blockIdx.x * 256 + threadIdx.x;
  float s = 0.f;
#pragma unroll
  for (int zc = 0; zc < 12; ++zc) s += gpart[(size_t)zc*NH*S + idx];
  gcol[idx] = s * (1.0f / (float)S);
}

// ---------------- Wpre: masked prefix of g-weighted V ----------------
__global__ __launch_bounds__(256) void build_wpre(const float* __restrict__ gcol,
    const float* __restrict__ kvb, float* __restrict__ Wpre) {
  const int hh = blockIdx.x >> 2;
  const int dq = (blockIdx.x & 3) << 4;
  __shared__ float Wt[SPP][16];
  const int tid = threadIdx.x;
  for (int idx = tid; idx < SPP*16; idx += 256) {
    int r = idx >> 4, dd = idx & 15;
    float val = 0.f;
#pragma unroll
    for (int b2 = 0; b2 < 4; ++b2) {
      int j = b2*SPP + r;
      val = fmaf(gcol[hh*S + j], kvb[(size_t)j*2048 + hh*128 + 64 + dq + dd], val);
    }
    Wt[r][dd] = val;
  }
  __syncthreads();
  if (tid < 16) {
    float run = 0.f;
    for (int r = 0; r < SPP; ++r) { run += Wt[r][tid]; Wt[r][tid] = run; }
  }
  __syncthreads();
  for (int idx = tid; idx < SPP*16; idx += 256) {
    int r = idx >> 4, dd = idx & 15;
    Wpre[((size_t)hh*SPP + r)*HD + dq + dd] = Wt[r][dd];
  }
}

// ---------------- combine (diff-attn) + per-head RMSNorm + scrambled reshape ----
__global__ __launch_bounds__(64) void combine_rms(const float* __restrict__ Ob,
    const float* __restrict__ Wpre, const float* __restrict__ lamp,
    const float* __restrict__ anw, float* __restrict__ attno) {
  const int t = blockIdx.x, h = blockIdx.y, d = threadIdx.x;
  const float lam = lamp[0];
  const float o1 = Ob[((size_t)(2*h)*S + t)*HD + d];
  const float o2 = Ob[((size_t)(2*h+1)*S + t)*HD + d];
  const float w3 = Wpre[((size_t)h*SPP + (t % SPP))*HD + d];
  float val = o1 - lam*o2 + lam*w3;
  float ss = val*val;
#pragma unroll
  for (int mm = 1; mm < 64; mm <<= 1) ss += __shfl_xor(ss, mm, 64);
  float scale = rsqrtf(ss * (1.0f/HD) + ATTN_EPS) * anw[d];
  int tn = h*96 + (t >> 4);
  int cn = ((t & 15) << 6) + d;
  attno[(size_t)tn*DM + cn] = val * scale;
}

// =========================== launch ===========================
extern "C" void kernel_launch(void* const* d_in, const int* in_sizes, int n_in,
                              void* d_out, int out_size, void* d_ws, size_t ws_size,
                              hipStream_t stream) {
  (void)in_sizes; (void)n_in; (void)out_size;
  const float* x    = (const float*)d_in[0];
  const float* fc   = (const float*)d_in[1];
  const float* fs   = (const float*)d_in[2];
  const float* n1w  = (const float*)d_in[3];
  const float* n2w  = (const float*)d_in[4];
  const float* kvdw = (const float*)d_in[5];
  const float* qdw  = (const float*)d_in[6];
  const float* kvnw = (const float*)d_in[7];
  const float* qnw  = (const float*)d_in[8];
  const float* kvuw = (const float*)d_in[9];
  const float* quw  = (const float*)d_in[10];
  const float* lq1  = (const float*)d_in[11];
  const float* lk1  = (const float*)d_in[12];
  const float* lq2  = (const float*)d_in[13];
  const float* lk2  = (const float*)d_in[14];
  const float* anw  = (const float*)d_in[15];
  const float* ow   = (const float*)d_in[16];
  const float* ffiw = (const float*)d_in[17];
  const float* ffow = (const float*)d_in[18];
  float* out = (float*)d_out;
  float* ws  = (float*)d_ws;

  float* xin   = ws;
  float* ckv   = xin   + (size_t)S*DM;
  float* qmid  = ckv   + (size_t)S*288;
  float* kvb   = qmid  + (size_t)S*QC;
  float* qf    = kvb   + (size_t)S*2048;
  float* Qb    = qf    + (size_t)S*1536;
  float* Kb    = Qb    + (size_t)H2N*S*DQK;
  float* Obuf  = Kb    + (size_t)H2N*S*DQK;
  float* rowm  = Obuf  + (size_t)H2N*S*HD;
  float* rowl  = rowm  + (size_t)H2N*S;
  float* gcol  = rowl  + (size_t)H2N*S;
  float* Wpre  = gcol  + (size_t)NH*S;
  float* attno = Wpre  + (size_t)NH*SPP*HD;
  float* lamp  = attno + (size_t)S*DM;
  short* fbufs = (short*)kvb;   // bf16 FFN activation overlays kv region
  float* gpart = attno;
  if (ws_size < (size_t)18063376 * sizeof(float)) return;

  rmsnorm_k<<<S, 256, 0, stream>>>(x, n1w, xin, DM, DM, DM, EPS_RMS);
  { dim3 g(5, 24);  mgemm_nt<0,0><<<g, 256, 0, stream>>>(xin, kvdw, nullptr, ckv, S, 288, DM, DM, DM, 288); }
  { dim3 g(6, 24);  mgemm_nt<0,0><<<g, 256, 0, stream>>>(xin, qdw,  nullptr, qmid, S, QC, DM, DM, DM, QC); }
  rmsnorm_k<<<S, 256, 0, stream>>>(ckv,  kvnw, ckv,  KVC, 288, 288, EPS_RMS);
  rmsnorm_k<<<S, 256, 0, stream>>>(qmid, qnw,  qmid, QC,  QC,  QC,  EPS_RMS);
  { dim3 g(32, 24); mgemm_nt<0,0><<<g, 256, 0, stream>>>(ckv,  kvuw, nullptr, kvb, S, 2048, KVC, 288, KVC, 2048); }
  { dim3 g(24, 24); mgemm_nt<0,0><<<g, 256, 0, stream>>>(qmid, quw,  nullptr, qf,  S, 1536, QC,  QC,  QC,  1536); }
  { dim3 g(6, 32);  build_qk<<<g, 256, 0, stream>>>(qf, kvb, ckv, fc, fs, Qb, Kb); }
  compute_lam<<<1, 32, 0, stream>>>(lq1, lk1, lq2, lk2, lamp);
  { dim3 g(12, 32); flash_mfma<<<g, 256, 0, stream>>>(Qb, Kb, kvb, Obuf, rowm, rowl); }
  { dim3 g(12, 16, 12); colsum_part<<<g, 128, 0, stream>>>(Qb, Kb, rowm, rowl, gpart); }
  colsum_reduce<<<96, 256, 0, stream>>>(gpart, gcol);
  build_wpre<<<64, 256, 0, stream>>>(gcol, kvb, Wpre);
  { dim3 g(S, 16);  combine_rms<<<g, 64, 0, stream>>>(Obuf, Wpre, lamp, anw, attno); }
  { dim3 g(16, 24); mgemm_nt<1,0><<<g, 256, 0, stream>>>(attno, ow, x, out, S, DM, DM, DM, DM, DM); }
  rmsnorm_k<<<S, 256, 0, stream>>>(out, n2w, xin, DM, DM, DM, EPS_RMS);
  { dim3 g(64, 24); mgemm_glu<<<g, 256, 0, stream>>>(xin, ffiw, fbufs, S, DFF, DM, DM, DM, DFF); }
  { dim3 g(16, 24); mgemm_nt<1,1><<<g, 256, 0, stream>>>(fbufs, ffow, out, out, S, DM, DFF, DFF, DFF, DM); }
}

// Round 7
// 349.188 us; speedup vs baseline: 6.7988x; 1.1951x over previous
//
#include <hip/hip_runtime.h>
#include <math.h>

#define S     1536
#define DM    1024
#define NH    16
#define H2N   32
#define HD    64
#define KVC   256
#define QC    384
#define DFF   4096
#define SPP   384
#define DQK   48
#define EPS_RMS  1.1920929e-07f
#define ATTN_EPS 1e-5f
#define SCALING  0.14433756729740643f   /* 48^-0.5 */

typedef float f32x4 __attribute__((ext_vector_type(4)));
typedef float f32x16 __attribute__((ext_vector_type(16)));
typedef short bf16x8 __attribute__((ext_vector_type(8)));

__device__ __forceinline__ short cvt_bf16(float f) {
  union { float f; unsigned u; } x; x.f = f;
  unsigned r = x.u + 0x7FFFu + ((x.u >> 16) & 1u);
  return (short)(r >> 16);
}
__device__ __forceinline__ unsigned pk2(float a, float b) {
  return (unsigned)(unsigned short)cvt_bf16(a) |
         ((unsigned)(unsigned short)cvt_bf16(b) << 16);
}
__device__ __forceinline__ bf16x8 cvt8(float4 a, float4 b) {
  bf16x8 v;
  v[0]=cvt_bf16(a.x); v[1]=cvt_bf16(a.y); v[2]=cvt_bf16(a.z); v[3]=cvt_bf16(a.w);
  v[4]=cvt_bf16(b.x); v[5]=cvt_bf16(b.y); v[6]=cvt_bf16(b.z); v[7]=cvt_bf16(b.w);
  return v;
}

// ---------------- RMSNorm ----------------
__global__ __launch_bounds__(256) void rmsnorm_k(const float* __restrict__ in,
    const float* __restrict__ w, float* __restrict__ out,
    int cols, int ldin, int ldout, float eps) {
  const int row = blockIdx.x;
  const float* xr = in + (size_t)row * ldin;
  float* yr = out + (size_t)row * ldout;
  const int tid = threadIdx.x;
  float ss = 0.f;
  for (int c = tid << 2; c < cols; c += 1024) {
    float4 v = *reinterpret_cast<const float4*>(xr + c);
    ss += v.x*v.x + v.y*v.y + v.z*v.z + v.w*v.w;
  }
#pragma unroll
  for (int mm = 1; mm < 64; mm <<= 1) ss += __shfl_xor(ss, mm, 64);
  __shared__ float red[4];
  if ((tid & 63) == 0) red[tid >> 6] = ss;
  __syncthreads();
  float tot = red[0] + red[1] + red[2] + red[3];
  float scale = rsqrtf(tot / (float)cols + eps);
  for (int c = tid << 2; c < cols; c += 1024) {
    float4 v = *reinterpret_cast<const float4*>(xr + c);
    float4 wv = *reinterpret_cast<const float4*>(w + c);
    float4 ov = make_float4(v.x*scale*wv.x, v.y*scale*wv.y, v.z*scale*wv.z, v.w*scale*wv.w);
    *reinterpret_cast<float4*>(yr + c) = ov;
  }
}

// ------------- bf16 MFMA GEMM, BK=64, register-prefetch pipeline -------------
template<int ADD, int ABF>
__global__ __launch_bounds__(256) void mgemm_nt(const void* __restrict__ Av,
    const float* __restrict__ B, const float* __restrict__ src, float* __restrict__ C,
    int M, int N, int K, int lda, int ldb, int ldc) {
  __shared__ short As[64][72];
  __shared__ short Bs[64][72];
  const int bm = blockIdx.y * 64, bn = blockIdx.x * 64;
  const int tid = threadIdx.x;
  const int w = tid >> 6, lane = tid & 63;
  const int wr = (w >> 1) << 5, wc = (w & 1) << 5;
  const int srow = tid >> 2, sk = (tid & 3) << 4;
  const int lrow = lane & 15, lk8 = (lane >> 4) << 3;
  const int arow = bm + srow, brow = bn + srow;
  const bool bvalid = brow < N;
  const float* Af = (const float*)Av;
  const short* Ah = (const short*)Av;
  f32x4 acc[2][2];
#pragma unroll
  for (int i = 0; i < 2; ++i)
#pragma unroll
    for (int j = 0; j < 2; ++j) acc[i][j] = (f32x4){0.f, 0.f, 0.f, 0.f};

  float4 ra[4]; bf16x8 rah0, rah1; float4 rb[4];
  if (ABF) {
    const short* ap = Ah + (size_t)arow * lda + sk;
    rah0 = *reinterpret_cast<const bf16x8*>(ap);
    rah1 = *reinterpret_cast<const bf16x8*>(ap + 8);
  } else {
    const float* ap = Af + (size_t)arow * lda + sk;
    ra[0] = *reinterpret_cast<const float4*>(ap);
    ra[1] = *reinterpret_cast<const float4*>(ap + 4);
    ra[2] = *reinterpret_cast<const float4*>(ap + 8);
    ra[3] = *reinterpret_cast<const float4*>(ap + 12);
  }
  rb[0]=rb[1]=rb[2]=rb[3]=make_float4(0.f,0.f,0.f,0.f);
  if (bvalid) {
    const float* bp = B + (size_t)brow * ldb + sk;
    rb[0] = *reinterpret_cast<const float4*>(bp);
    rb[1] = *reinterpret_cast<const float4*>(bp + 4);
    rb[2] = *reinterpret_cast<const float4*>(bp + 8);
    rb[3] = *reinterpret_cast<const float4*>(bp + 12);
  }

  for (int k0 = 0; k0 < K; k0 += 64) {
    bf16x8 va0, va1;
    if (ABF) { va0 = rah0; va1 = rah1; }
    else     { va0 = cvt8(ra[0], ra[1]); va1 = cvt8(ra[2], ra[3]); }
    bf16x8 vb0 = cvt8(rb[0], rb[1]), vb1 = cvt8(rb[2], rb[3]);
    __syncthreads();
    *reinterpret_cast<bf16x8*>(&As[srow][sk])     = va0;
    *reinterpret_cast<bf16x8*>(&As[srow][sk + 8]) = va1;
    *reinterpret_cast<bf16x8*>(&Bs[srow][sk])     = vb0;
    *reinterpret_cast<bf16x8*>(&Bs[srow][sk + 8]) = vb1;
    __syncthreads();
    const int kn = k0 + 64;
    if (kn < K) {
      if (ABF) {
        const short* ap = Ah + (size_t)arow * lda + kn + sk;
        rah0 = *reinterpret_cast<const bf16x8*>(ap);
        rah1 = *reinterpret_cast<const bf16x8*>(ap + 8);
      } else {
        const float* ap = Af + (size_t)arow * lda + kn + sk;
        ra[0] = *reinterpret_cast<const float4*>(ap);
        ra[1] = *reinterpret_cast<const float4*>(ap + 4);
        ra[2] = *reinterpret_cast<const float4*>(ap + 8);
        ra[3] = *reinterpret_cast<const float4*>(ap + 12);
      }
      if (bvalid) {
        const float* bp = B + (size_t)brow * ldb + kn + sk;
        rb[0] = *reinterpret_cast<const float4*>(bp);
        rb[1] = *reinterpret_cast<const float4*>(bp + 4);
        rb[2] = *reinterpret_cast<const float4*>(bp + 8);
        rb[3] = *reinterpret_cast<const float4*>(bp + 12);
      }
    }
#pragma unroll
    for (int kk = 0; kk < 2; ++kk) {
      bf16x8 af0 = *reinterpret_cast<bf16x8*>(&As[wr + lrow][(kk << 5) + lk8]);
      bf16x8 af1 = *reinterpret_cast<bf16x8*>(&As[wr + 16 + lrow][(kk << 5) + lk8]);
      bf16x8 bf0 = *reinterpret_cast<bf16x8*>(&Bs[wc + lrow][(kk << 5) + lk8]);
      bf16x8 bf1 = *reinterpret_cast<bf16x8*>(&Bs[wc + 16 + lrow][(kk << 5) + lk8]);
      acc[0][0] = __builtin_amdgcn_mfma_f32_16x16x32_bf16(af0, bf0, acc[0][0], 0, 0, 0);
      acc[0][1] = __builtin_amdgcn_mfma_f32_16x16x32_bf16(af0, bf1, acc[0][1], 0, 0, 0);
      acc[1][0] = __builtin_amdgcn_mfma_f32_16x16x32_bf16(af1, bf0, acc[1][0], 0, 0, 0);
      acc[1][1] = __builtin_amdgcn_mfma_f32_16x16x32_bf16(af1, bf1, acc[1][1], 0, 0, 0);
    }
  }
  const int crow0 = bm + wr + ((lane >> 4) << 2);
  const int ccol0 = bn + wc + lrow;
#pragma unroll
  for (int mi = 0; mi < 2; ++mi)
#pragma unroll
    for (int ni = 0; ni < 2; ++ni) {
      int colc = ccol0 + (ni << 4);
      if (colc < N) {
#pragma unroll
        for (int r = 0; r < 4; ++r) {
          int rowc = crow0 + (mi << 4) + r;
          float v = acc[mi][ni][r];
          if (ADD) v += src[(size_t)rowc * ldc + colc];
          C[(size_t)rowc * ldc + colc] = v;
        }
      }
    }
}

// ------------- bf16 MFMA SwiGLU GEMM (pipelined), bf16 output -------------
__global__ __launch_bounds__(256) void mgemm_glu(const float* __restrict__ A,
    const float* __restrict__ B, short* __restrict__ C,
    int M, int N, int K, int lda, int ldb, int ldc) {
  __shared__ short As[64][72];
  __shared__ short Bu[64][72];
  __shared__ short Bv[64][72];
  const int bm = blockIdx.y * 64, bn = blockIdx.x * 64;
  const int tid = threadIdx.x;
  const int w = tid >> 6, lane = tid & 63;
  const int wr = (w >> 1) << 5, wc = (w & 1) << 5;
  const int srow = tid >> 2, sk = (tid & 3) << 4;
  const int lrow = lane & 15, lk8 = (lane >> 4) << 3;
  const int arow = bm + srow, brow = bn + srow;
  f32x4 au[2][2], av[2][2];
#pragma unroll
  for (int i = 0; i < 2; ++i)
#pragma unroll
    for (int j = 0; j < 2; ++j) {
      au[i][j] = (f32x4){0.f, 0.f, 0.f, 0.f};
      av[i][j] = (f32x4){0.f, 0.f, 0.f, 0.f};
    }
  float4 ra[4], ru[4], rv[4];
  {
    const float* ap = A + (size_t)arow * lda + sk;
    const float* up = B + (size_t)brow * ldb + sk;
    const float* vp = B + (size_t)(N + brow) * ldb + sk;
#pragma unroll
    for (int e = 0; e < 4; ++e) {
      ra[e] = *reinterpret_cast<const float4*>(ap + (e << 2));
      ru[e] = *reinterpret_cast<const float4*>(up + (e << 2));
      rv[e] = *reinterpret_cast<const float4*>(vp + (e << 2));
    }
  }
  for (int k0 = 0; k0 < K; k0 += 64) {
    bf16x8 a0 = cvt8(ra[0], ra[1]), a1 = cvt8(ra[2], ra[3]);
    bf16x8 u0 = cvt8(ru[0], ru[1]), u1 = cvt8(ru[2], ru[3]);
    bf16x8 v0 = cvt8(rv[0], rv[1]), v1 = cvt8(rv[2], rv[3]);
    __syncthreads();
    *reinterpret_cast<bf16x8*>(&As[srow][sk])     = a0;
    *reinterpret_cast<bf16x8*>(&As[srow][sk + 8]) = a1;
    *reinterpret_cast<bf16x8*>(&Bu[srow][sk])     = u0;
    *reinterpret_cast<bf16x8*>(&Bu[srow][sk + 8]) = u1;
    *reinterpret_cast<bf16x8*>(&Bv[srow][sk])     = v0;
    *reinterpret_cast<bf16x8*>(&Bv[srow][sk + 8]) = v1;
    __syncthreads();
    const int kn = k0 + 64;
    if (kn < K) {
      const float* ap = A + (size_t)arow * lda + kn + sk;
      const float* up = B + (size_t)brow * ldb + kn + sk;
      const float* vp = B + (size_t)(N + brow) * ldb + kn + sk;
#pragma unroll
      for (int e = 0; e < 4; ++e) {
        ra[e] = *reinterpret_cast<const float4*>(ap + (e << 2));
        ru[e] = *reinterpret_cast<const float4*>(up + (e << 2));
        rv[e] = *reinterpret_cast<const float4*>(vp + (e << 2));
      }
    }
#pragma unroll
    for (int kk = 0; kk < 2; ++kk) {
      bf16x8 af0 = *reinterpret_cast<bf16x8*>(&As[wr + lrow][(kk << 5) + lk8]);
      bf16x8 af1 = *reinterpret_cast<bf16x8*>(&As[wr + 16 + lrow][(kk << 5) + lk8]);
      bf16x8 uf0 = *reinterpret_cast<bf16x8*>(&Bu[wc + lrow][(kk << 5) + lk8]);
      bf16x8 uf1 = *reinterpret_cast<bf16x8*>(&Bu[wc + 16 + lrow][(kk << 5) + lk8]);
      bf16x8 vf0 = *reinterpret_cast<bf16x8*>(&Bv[wc + lrow][(kk << 5) + lk8]);
      bf16x8 vf1 = *reinterpret_cast<bf16x8*>(&Bv[wc + 16 + lrow][(kk << 5) + lk8]);
      au[0][0] = __builtin_amdgcn_mfma_f32_16x16x32_bf16(af0, uf0, au[0][0], 0, 0, 0);
      au[0][1] = __builtin_amdgcn_mfma_f32_16x16x32_bf16(af0, uf1, au[0][1], 0, 0, 0);
      au[1][0] = __builtin_amdgcn_mfma_f32_16x16x32_bf16(af1, uf0, au[1][0], 0, 0, 0);
      au[1][1] = __builtin_amdgcn_mfma_f32_16x16x32_bf16(af1, uf1, au[1][1], 0, 0, 0);
      av[0][0] = __builtin_amdgcn_mfma_f32_16x16x32_bf16(af0, vf0, av[0][0], 0, 0, 0);
      av[0][1] = __builtin_amdgcn_mfma_f32_16x16x32_bf16(af0, vf1, av[0][1], 0, 0, 0);
      av[1][0] = __builtin_amdgcn_mfma_f32_16x16x32_bf16(af1, vf0, av[1][0], 0, 0, 0);
      av[1][1] = __builtin_amdgcn_mfma_f32_16x16x32_bf16(af1, vf1, av[1][1], 0, 0, 0);
    }
  }
  const int crow0 = bm + wr + ((lane >> 4) << 2);
  const int ccol0 = bn + wc + lrow;
#pragma unroll
  for (int mi = 0; mi < 2; ++mi)
#pragma unroll
    for (int ni = 0; ni < 2; ++ni) {
      int colc = ccol0 + (ni << 4);
#pragma unroll
      for (int r = 0; r < 4; ++r) {
        int rowc = crow0 + (mi << 4) + r;
        float uu = au[mi][ni][r], vg = av[mi][ni][r];
        float sig = 1.0f / (1.0f + __expf(-vg));
        C[(size_t)rowc * ldc + colc] = cvt_bf16(uu * vg * sig);
      }
    }
}

// ---------------- Build Q/K (split heads + RoPE) ----------------
__global__ __launch_bounds__(256) void build_qk(const float* __restrict__ qf,
    const float* __restrict__ kvb, const float* __restrict__ ckv,
    const float* __restrict__ fc, const float* __restrict__ fs,
    float* __restrict__ Qb, float* __restrict__ Kb) {
  int t = blockIdx.x * 256 + threadIdx.x;
  int h2 = blockIdx.y;
  if (t >= S) return;
  int hh = h2 >> 1, par = h2 & 1;
  const float* qrow = qf + (size_t)t*1536 + hh*96;
  const float* krow = kvb + (size_t)t*2048 + hh*128;
  float* qo = Qb + ((size_t)h2*S + t)*DQK;
  float* ko = Kb + ((size_t)h2*S + t)*DQK;
#pragma unroll
  for (int xq = 0; xq < 8; ++xq) {
    *reinterpret_cast<float4*>(qo + (xq<<2)) =
      *reinterpret_cast<const float4*>(qrow + par*32 + (xq<<2));
    *reinterpret_cast<float4*>(ko + (xq<<2)) =
      *reinterpret_cast<const float4*>(krow + par*32 + (xq<<2));
  }
  int p = t >> 2;
  const float* qr = qrow + 64 + par*16;
  const float* kr = ckv + (size_t)t*288 + 256 + par*16;
#pragma unroll
  for (int mq = 0; mq < 8; ++mq) {
    float c = 1.f, sn = 0.f;
    if (p > 0) { c = fc[(p-1)*8 + mq]; sn = fs[(p-1)*8 + mq]; }
    float q0 = qr[2*mq], q1 = qr[2*mq+1];
    qo[32 + 2*mq]     = q0*c - q1*sn;
    qo[32 + 2*mq + 1] = q0*sn + q1*c;
    float k0 = kr[2*mq], k1 = kr[2*mq+1];
    ko[32 + 2*mq]     = k0*c - k1*sn;
    ko[32 + 2*mq + 1] = k0*sn + k1*c;
  }
}

// ---------------- lambda scalar ----------------
__global__ void compute_lam(const float* __restrict__ lq1, const float* __restrict__ lk1,
                            const float* __restrict__ lq2, const float* __restrict__ lk2,
                            float* __restrict__ lamp) {
  int t = threadIdx.x;
  float a = lq1[t]*lk1[t];
  float b = lq2[t]*lk2[t];
#pragma unroll
  for (int mm = 1; mm < 32; mm <<= 1) { a += __shfl_xor(a, mm, 32); b += __shfl_xor(b, mm, 32); }
  if (t == 0) lamp[0] = expf(a) - expf(b) + 0.2f;
}

// ---------------- MFMA flash attention, split over key-chunk halves ----------
// grid (12, 32, 2): z handles chunks {2z, 2z+1}. Outputs UNNORMALIZED partial
// O^T + (m,l). z=0 -> Ob/rm/rl; z=1 -> Ob1a (h2<16) / Ob1b (h2>=16), rm1/rl1.
__global__ __launch_bounds__(256) void flash_mfma(const float* __restrict__ Qb,
    const float* __restrict__ Kb, const float* __restrict__ kvb,
    float* __restrict__ Ob, float* __restrict__ rowm, float* __restrict__ rowl,
    float* __restrict__ Ob1a, float* __restrict__ Ob1b,
    float* __restrict__ rm1, float* __restrict__ rl1) {
  const int h2 = blockIdx.y;
  const int hh = h2 >> 1;
  const int i0 = blockIdx.x << 7;
  const int z  = blockIdx.z;
  const int tid = threadIdx.x;
  const int w = tid >> 6, lane = tid & 63;
  const int ql = lane & 31, h = lane >> 5;
  const int qbase = i0 + (w << 5);
  const int rbase = i0 % SPP;
  const int ri0w = rbase + (w << 5);
  const int jmaxb = rbase + 96;

  __shared__ __align__(16) short Ks[32][72];
  __shared__ __align__(16) short Vt[64][40];
  __shared__ __align__(16) float Ot[4][32][68];

  bf16x8 qf0, qf1, qf2;
  {
    const float* qp = Qb + ((size_t)h2*S + qbase + ql)*DQK + (h << 3);
#pragma unroll
    for (int dt = 0; dt < 3; ++dt) {
      float4 a = *reinterpret_cast<const float4*>(qp + (dt << 4));
      float4 b = *reinterpret_cast<const float4*>(qp + (dt << 4) + 4);
      bf16x8 q8 = cvt8(a, b);
      if (dt == 0) qf0 = q8; else if (dt == 1) qf1 = q8; else qf2 = q8;
    }
  }

  float m = -1e30f, l = 0.f;
  f32x16 o0, o1;
#pragma unroll
  for (int r = 0; r < 16; ++r) { o0[r] = 0.f; o1[r] = 0.f; }

  for (int c = (z << 1); c < (z << 1) + 2; ++c) {
    for (int jr = 0; jr <= jmaxb; jr += 32) {
      const int j0 = c*SPP + jr;
      __syncthreads();
      if (tid < 192) {
        int r = tid / 6, c8 = (tid % 6) << 3;
        const float* kp = Kb + ((size_t)h2*S + j0 + r)*DQK + c8;
        float4 a = *reinterpret_cast<const float4*>(kp);
        float4 b = *reinterpret_cast<const float4*>(kp + 4);
        *reinterpret_cast<bf16x8*>(&Ks[r][c8]) = cvt8(a, b);
      }
      {
        int d = tid & 63, kb = (tid >> 6) << 3;
        const float* vp = kvb + (size_t)(j0 + kb)*2048 + hh*128 + 64 + d;
        bf16x8 v8;
#pragma unroll
        for (int e = 0; e < 8; ++e) v8[e] = cvt_bf16(vp[(size_t)e*2048]);
        *reinterpret_cast<bf16x8*>(&Vt[d][kb]) = v8;
      }
      __syncthreads();
      if (jr > ri0w) continue;
      const bool diag = (jr == ri0w);

      bf16x8 kf0 = *reinterpret_cast<bf16x8*>(&Ks[ql][(h << 3)]);
      bf16x8 kf1 = *reinterpret_cast<bf16x8*>(&Ks[ql][16 + (h << 3)]);
      bf16x8 kf2 = *reinterpret_cast<bf16x8*>(&Ks[ql][32 + (h << 3)]);
      f32x16 st;
#pragma unroll
      for (int r = 0; r < 16; ++r) st[r] = 0.f;
      st = __builtin_amdgcn_mfma_f32_32x32x16_bf16(kf0, qf0, st, 0, 0, 0);
      st = __builtin_amdgcn_mfma_f32_32x32x16_bf16(kf1, qf1, st, 0, 0, 0);
      st = __builtin_amdgcn_mfma_f32_32x32x16_bf16(kf2, qf2, st, 0, 0, 0);

      if (diag) {
#pragma unroll
        for (int r = 0; r < 16; ++r) {
          int kl = (r & 3) + ((r >> 2) << 3) + (h << 2);
          st[r] = (kl <= ql) ? st[r] * SCALING : -1e30f;
        }
      } else {
#pragma unroll
        for (int r = 0; r < 16; ++r) st[r] *= SCALING;
      }

      float tm = st[0];
#pragma unroll
      for (int r = 1; r < 16; ++r) tm = fmaxf(tm, st[r]);
      tm = fmaxf(tm, __shfl_xor(tm, 32));
      float mnew = fmaxf(m, tm);
      float sc = __expf(m - mnew);
      m = mnew;
      float ps = 0.f;
#pragma unroll
      for (int r = 0; r < 16; ++r) { float p = __expf(st[r] - mnew); st[r] = p; ps += p; }
      ps += __shfl_xor(ps, 32);
      l = l * sc + ps;
#pragma unroll
      for (int r = 0; r < 16; ++r) { o0[r] *= sc; o1[r] *= sc; }

      unsigned A0 = pk2(st[0],  st[1]),  B0 = pk2(st[2],  st[3]);
      unsigned C0 = pk2(st[4],  st[5]),  D0 = pk2(st[6],  st[7]);
      unsigned A1 = pk2(st[8],  st[9]),  B1 = pk2(st[10], st[11]);
      unsigned C1 = pk2(st[12], st[13]), D1 = pk2(st[14], st[15]);
      unsigned xA0 = (unsigned)__shfl_xor((int)A0, 32), xB0 = (unsigned)__shfl_xor((int)B0, 32);
      unsigned xC0 = (unsigned)__shfl_xor((int)C0, 32), xD0 = (unsigned)__shfl_xor((int)D0, 32);
      unsigned xA1 = (unsigned)__shfl_xor((int)A1, 32), xB1 = (unsigned)__shfl_xor((int)B1, 32);
      unsigned xC1 = (unsigned)__shfl_xor((int)C1, 32), xD1 = (unsigned)__shfl_xor((int)D1, 32);
      union { unsigned u[4]; bf16x8 v; } P0, P1;
      P0.u[0] = h ? xC0 : A0;  P0.u[1] = h ? xD0 : B0;
      P0.u[2] = h ? C0 : xA0;  P0.u[3] = h ? D0 : xB0;
      P1.u[0] = h ? xC1 : A1;  P1.u[1] = h ? xD1 : B1;
      P1.u[2] = h ? C1 : xA1;  P1.u[3] = h ? D1 : xB1;

      bf16x8 v00 = *reinterpret_cast<bf16x8*>(&Vt[ql][(h << 3)]);
      bf16x8 v01 = *reinterpret_cast<bf16x8*>(&Vt[ql][16 + (h << 3)]);
      bf16x8 v10 = *reinterpret_cast<bf16x8*>(&Vt[32 + ql][(h << 3)]);
      bf16x8 v11 = *reinterpret_cast<bf16x8*>(&Vt[32 + ql][16 + (h << 3)]);
      o0 = __builtin_amdgcn_mfma_f32_32x32x16_bf16(v00, P0.v, o0, 0, 0, 0);
      o0 = __builtin_amdgcn_mfma_f32_32x32x16_bf16(v01, P1.v, o0, 0, 0, 0);
      o1 = __builtin_amdgcn_mfma_f32_32x32x16_bf16(v10, P0.v, o1, 0, 0, 0);
      o1 = __builtin_amdgcn_mfma_f32_32x32x16_bf16(v11, P1.v, o1, 0, 0, 0);
    }
  }

  // epilogue: UNNORMALIZED partial O, transpose via wave-private LDS, store
  float* ot = &Ot[w][0][0];
#pragma unroll
  for (int r = 0; r < 16; ++r) {
    int dl = (r & 3) + ((r >> 2) << 3) + (h << 2);
    ot[ql*68 + dl]      = o0[r];
    ot[ql*68 + 32 + dl] = o1[r];
  }
  float* orow;
  if (z == 0) orow = Ob + ((size_t)h2*S + qbase)*HD;
  else orow = (h2 < 16) ? Ob1a + ((size_t)h2*S + qbase)*HD
                        : Ob1b + ((size_t)(h2 - 16)*S + qbase)*HD;
#pragma unroll
  for (int it = 0; it < 8; ++it) {
    int idx = lane + (it << 6);
    int row = idx >> 4, c4 = (idx & 15) << 2;
    float4 v = *reinterpret_cast<float4*>(&ot[row*68 + c4]);
    *reinterpret_cast<float4*>(&orow[(size_t)row*HD + c4]) = v;
  }
  if (lane < 32) {
    if (z == 0) { rowm[h2*S + qbase + lane] = m; rowl[h2*S + qbase + lane] = l; }
    else        { rm1[h2*S + qbase + lane] = m;  rl1[h2*S + qbase + lane] = l; }
  }
}

// ---------------- merge the two flash partials, normalize ----------------
// grid (H2N*S/4) x 256thr; 64-thread group per (h2,t) row.
__global__ __launch_bounds__(256) void merge_flash(float* __restrict__ Ob,
    float* __restrict__ rowm, float* __restrict__ rowl,
    const float* __restrict__ Ob1a, const float* __restrict__ Ob1b,
    const float* __restrict__ rm1, const float* __restrict__ rl1) {
  const int gid = blockIdx.x * 4 + (threadIdx.x >> 6);
  const int d = threadIdx.x & 63;
  const int h2 = gid / S;
  float m0 = rowm[gid], l0 = rowl[gid], m1 = rm1[gid], l1 = rl1[gid];
  float m = fmaxf(m0, m1);
  float w0 = __expf(m0 - m), w1 = __expf(m1 - m);
  float linv = 1.0f / (l0*w0 + l1*w1);
  const float* o1 = (h2 < 16) ? (Ob1a + (size_t)gid*HD)
                              : (Ob1b + ((size_t)gid - (size_t)16*S)*HD);
  float v0 = Ob[(size_t)gid*HD + d];
  float v1 = o1[d];
  Ob[(size_t)gid*HD + d] = (v0*w0 + v1*w1) * linv;
  if (d == 0) { rowm[gid] = m; rowl[gid] = l0*w0 + l1*w1; }
}

// ---------------- colsum via MFMA: gcol[hh][j] = (1/S) sum_i P(2hh)[i,j] -----
// grid (48 j-tiles, 16 hh), 256 thr = 4 waves; K frags pinned in regs,
// waves split the allowed q-tile list; 32-lane reduce at the end.
__global__ __launch_bounds__(256) void colsum_mfma(const float* __restrict__ Qb,
    const float* __restrict__ Kb, const float* __restrict__ rowm,
    const float* __restrict__ rowl, float* __restrict__ gcol) {
  const int jt = blockIdx.x;
  const int hh = blockIdx.y, h2 = hh << 1;
  const int cK = jt / 12, jr32 = jt % 12;
  const int jr = jr32 << 5;
  const int j0 = cK*SPP + jr;
  const int tid = threadIdx.x;
  const int w = tid >> 6, lane = tid & 63;
  const int ql = lane & 31, h = lane >> 5;

  bf16x8 kf0, kf1, kf2;
  {
    const float* kp = Kb + ((size_t)h2*S + j0 + ql)*DQK + (h << 3);
    kf0 = cvt8(*reinterpret_cast<const float4*>(kp),
               *reinterpret_cast<const float4*>(kp + 4));
    kf1 = cvt8(*reinterpret_cast<const float4*>(kp + 16),
               *reinterpret_cast<const float4*>(kp + 20));
    kf2 = cvt8(*reinterpret_cast<const float4*>(kp + 32),
               *reinterpret_cast<const float4*>(kp + 36));
  }
  const int nt = 12 - jr32;
  const int T = nt << 2;
  float gs[16];
#pragma unroll
  for (int r = 0; r < 16; ++r) gs[r] = 0.f;

  for (int tt = w; tt < T; tt += 4) {
    int cq = tt / nt, qrem = tt - cq*nt;
    int qi = jr32 + qrem;
    int i0 = cq*SPP + (qi << 5);
    const bool diag = (qrem == 0);
    const float* qp = Qb + ((size_t)h2*S + i0 + ql)*DQK + (h << 3);
    bf16x8 qf0 = cvt8(*reinterpret_cast<const float4*>(qp),
                      *reinterpret_cast<const float4*>(qp + 4));
    bf16x8 qf1 = cvt8(*reinterpret_cast<const float4*>(qp + 16),
                      *reinterpret_cast<const float4*>(qp + 20));
    bf16x8 qf2 = cvt8(*reinterpret_cast<const float4*>(qp + 32),
                      *reinterpret_cast<const float4*>(qp + 36));
    f32x16 st;
#pragma unroll
    for (int r = 0; r < 16; ++r) st[r] = 0.f;
    st = __builtin_amdgcn_mfma_f32_32x32x16_bf16(kf0, qf0, st, 0, 0, 0);
    st = __builtin_amdgcn_mfma_f32_32x32x16_bf16(kf1, qf1, st, 0, 0, 0);
    st = __builtin_amdgcn_mfma_f32_32x32x16_bf16(kf2, qf2, st, 0, 0, 0);
    float Mq = rowm[h2*S + i0 + ql];
    float Lq = 1.0f / rowl[h2*S + i0 + ql];
    if (diag) {
#pragma unroll
      for (int r = 0; r < 16; ++r) {
        int kl = (r & 3) + ((r >> 2) << 3) + (h << 2);
        if (kl <= ql) gs[r] += __expf(st[r]*SCALING - Mq) * Lq;
      }
    } else {
#pragma unroll
      for (int r = 0; r < 16; ++r) gs[r] += __expf(st[r]*SCALING - Mq) * Lq;
    }
  }
  __shared__ float gw[4][32];
#pragma unroll
  for (int r = 0; r < 16; ++r) {
    float v = gs[r];
#pragma unroll
    for (int mm = 1; mm < 32; mm <<= 1) v += __shfl_xor(v, mm, 32);
    if (ql == 0) gw[w][(r & 3) + ((r >> 2) << 3) + (h << 2)] = v;
  }
  __syncthreads();
  if (tid < 32) {
    float s = gw[0][tid] + gw[1][tid] + gw[2][tid] + gw[3][tid];
    gcol[hh*S + j0 + tid] = s * (1.0f / (float)S);
  }
}

// ---------------- Wpre: masked prefix of g-weighted V ----------------
__global__ __launch_bounds__(256) void build_wpre(const float* __restrict__ gcol,
    const float* __restrict__ kvb, float* __restrict__ Wpre) {
  const int hh = blockIdx.x >> 2;
  const int dq = (blockIdx.x & 3) << 4;
  __shared__ float Wt[SPP][16];
  const int tid = threadIdx.x;
  for (int idx = tid; idx < SPP*16; idx += 256) {
    int r = idx >> 4, dd = idx & 15;
    float val = 0.f;
#pragma unroll
    for (int b2 = 0; b2 < 4; ++b2) {
      int j = b2*SPP + r;
      val = fmaf(gcol[hh*S + j], kvb[(size_t)j*2048 + hh*128 + 64 + dq + dd], val);
    }
    Wt[r][dd] = val;
  }
  __syncthreads();
  if (tid < 16) {
    float run = 0.f;
    for (int r = 0; r < SPP; ++r) { run += Wt[r][tid]; Wt[r][tid] = run; }
  }
  __syncthreads();
  for (int idx = tid; idx < SPP*16; idx += 256) {
    int r = idx >> 4, dd = idx & 15;
    Wpre[((size_t)hh*SPP + r)*HD + dq + dd] = Wt[r][dd];
  }
}

// ---------------- combine (diff-attn) + per-head RMSNorm + scrambled reshape ----
__global__ __launch_bounds__(64) void combine_rms(const float* __restrict__ Ob,
    const float* __restrict__ Wpre, const float* __restrict__ lamp,
    const float* __restrict__ anw, float* __restrict__ attno) {
  const int t = blockIdx.x, h = blockIdx.y, d = threadIdx.x;
  const float lam = lamp[0];
  const float o1 = Ob[((size_t)(2*h)*S + t)*HD + d];
  const float o2 = Ob[((size_t)(2*h+1)*S + t)*HD + d];
  const float w3 = Wpre[((size_t)h*SPP + (t % SPP))*HD + d];
  float val = o1 - lam*o2 + lam*w3;
  float ss = val*val;
#pragma unroll
  for (int mm = 1; mm < 64; mm <<= 1) ss += __shfl_xor(ss, mm, 64);
  float scale = rsqrtf(ss * (1.0f/HD) + ATTN_EPS) * anw[d];
  int tn = h*96 + (t >> 4);
  int cn = ((t & 15) << 6) + d;
  attno[(size_t)tn*DM + cn] = val * scale;
}

// =========================== launch ===========================
extern "C" void kernel_launch(void* const* d_in, const int* in_sizes, int n_in,
                              void* d_out, int out_size, void* d_ws, size_t ws_size,
                              hipStream_t stream) {
  (void)in_sizes; (void)n_in; (void)out_size;
  const float* x    = (const float*)d_in[0];
  const float* fc   = (const float*)d_in[1];
  const float* fs   = (const float*)d_in[2];
  const float* n1w  = (const float*)d_in[3];
  const float* n2w  = (const float*)d_in[4];
  const float* kvdw = (const float*)d_in[5];
  const float* qdw  = (const float*)d_in[6];
  const float* kvnw = (const float*)d_in[7];
  const float* qnw  = (const float*)d_in[8];
  const float* kvuw = (const float*)d_in[9];
  const float* quw  = (const float*)d_in[10];
  const float* lq1  = (const float*)d_in[11];
  const float* lk1  = (const float*)d_in[12];
  const float* lq2  = (const float*)d_in[13];
  const float* lk2  = (const float*)d_in[14];
  const float* anw  = (const float*)d_in[15];
  const float* ow   = (const float*)d_in[16];
  const float* ffiw = (const float*)d_in[17];
  const float* ffow = (const float*)d_in[18];
  float* out = (float*)d_out;
  float* ws  = (float*)d_ws;

  float* xin   = ws;
  float* ckv   = xin   + (size_t)S*DM;
  float* qmid  = ckv   + (size_t)S*288;
  float* kvb   = qmid  + (size_t)S*QC;
  float* qf    = kvb   + (size_t)S*2048;
  float* Qb    = qf    + (size_t)S*1536;
  float* Kb    = Qb    + (size_t)H2N*S*DQK;
  float* Obuf  = Kb    + (size_t)H2N*S*DQK;
  float* rowm  = Obuf  + (size_t)H2N*S*HD;
  float* rowl  = rowm  + (size_t)H2N*S;
  float* gcol  = rowl  + (size_t)H2N*S;
  float* Wpre  = gcol  + (size_t)NH*S;
  float* attno = Wpre  + (size_t)NH*SPP*HD;
  float* lamp  = attno + (size_t)S*DM;
  short* fbufs = (short*)kvb;   // bf16 FFN activation overlays kv region
  // z=1 flash partials live in buffers that are dead between build_qk and rmsnorm2:
  float* Ob1a = xin;                       // h2 in [0,16): 16*S*64 = S*DM floats
  float* Ob1b = qf;                        // h2 in [16,32): 1.57M of qf's 2.36M
  float* rm1  = qf + (size_t)16*S*HD;      // 49152 floats
  float* rl1  = rm1 + (size_t)H2N*S;       // 49152 floats (fits qf region)
  if (ws_size < (size_t)18063376 * sizeof(float)) return;

  rmsnorm_k<<<S, 256, 0, stream>>>(x, n1w, xin, DM, DM, DM, EPS_RMS);
  { dim3 g(5, 24);  mgemm_nt<0,0><<<g, 256, 0, stream>>>(xin, kvdw, nullptr, ckv, S, 288, DM, DM, DM, 288); }
  { dim3 g(6, 24);  mgemm_nt<0,0><<<g, 256, 0, stream>>>(xin, qdw,  nullptr, qmid, S, QC, DM, DM, DM, QC); }
  rmsnorm_k<<<S, 256, 0, stream>>>(ckv,  kvnw, ckv,  KVC, 288, 288, EPS_RMS);
  rmsnorm_k<<<S, 256, 0, stream>>>(qmid, qnw,  qmid, QC,  QC,  QC,  EPS_RMS);
  { dim3 g(32, 24); mgemm_nt<0,0><<<g, 256, 0, stream>>>(ckv,  kvuw, nullptr, kvb, S, 2048, KVC, 288, KVC, 2048); }
  { dim3 g(24, 24); mgemm_nt<0,0><<<g, 256, 0, stream>>>(qmid, quw,  nullptr, qf,  S, 1536, QC,  QC,  QC,  1536); }
  { dim3 g(6, 32);  build_qk<<<g, 256, 0, stream>>>(qf, kvb, ckv, fc, fs, Qb, Kb); }
  compute_lam<<<1, 32, 0, stream>>>(lq1, lk1, lq2, lk2, lamp);
  { dim3 g(12, 32, 2); flash_mfma<<<g, 256, 0, stream>>>(Qb, Kb, kvb, Obuf, rowm, rowl,
                                                         Ob1a, Ob1b, rm1, rl1); }
  merge_flash<<<(H2N*S)/4, 256, 0, stream>>>(Obuf, rowm, rowl, Ob1a, Ob1b, rm1, rl1);
  { dim3 g(48, 16); colsum_mfma<<<g, 256, 0, stream>>>(Qb, Kb, rowm, rowl, gcol); }
  build_wpre<<<64, 256, 0, stream>>>(gcol, kvb, Wpre);
  { dim3 g(S, 16);  combine_rms<<<g, 64, 0, stream>>>(Obuf, Wpre, lamp, anw, attno); }
  { dim3 g(16, 24); mgemm_nt<1,0><<<g, 256, 0, stream>>>(attno, ow, x, out, S, DM, DM, DM, DM, DM); }
  rmsnorm_k<<<S, 256, 0, stream>>>(out, n2w, xin, DM, DM, DM, EPS_RMS);
  { dim3 g(64, 24); mgemm_glu<<<g, 256, 0, stream>>>(xin, ffiw, fbufs, S, DFF, DM, DM, DM, DFF); }
  { dim3 g(16, 24); mgemm_nt<1,1><<<g, 256, 0, stream>>>(fbufs, ffow, out, out, S, DM, DFF, DFF, DFF, DM); }
}

// Round 8
// 298.130 us; speedup vs baseline: 7.9632x; 1.1713x over previous
//
#include <hip/hip_runtime.h>
#include <math.h>

#define S     1536
#define DM    1024
#define NH    16
#define H2N   32
#define HD    64
#define KVC   256
#define QC    384
#define DFF   4096
#define SPP   384
#define DQK   48
#define EPS_RMS  1.1920929e-07f
#define ATTN_EPS 1e-5f
#define SCALING  0.14433756729740643f   /* 48^-0.5 */

typedef float f32x4 __attribute__((ext_vector_type(4)));
typedef float f32x16 __attribute__((ext_vector_type(16)));
typedef short bf16x8 __attribute__((ext_vector_type(8)));

__device__ __forceinline__ short cvt_bf16(float f) {      // scalar fallback (epilogues)
  union { float f; unsigned u; } x; x.f = f;
  unsigned r = x.u + 0x7FFFu + ((x.u >> 16) & 1u);
  return (short)(r >> 16);
}
__device__ __forceinline__ unsigned pk2(float a, float b) { // HW RNE pack (T12)
  unsigned r;
  asm("v_cvt_pk_bf16_f32 %0, %1, %2" : "=v"(r) : "v"(a), "v"(b));
  return r;
}
__device__ __forceinline__ bf16x8 cvt8(float4 a, float4 b) {
  union { unsigned u[4]; bf16x8 v; } r;
  r.u[0] = pk2(a.x, a.y); r.u[1] = pk2(a.z, a.w);
  r.u[2] = pk2(b.x, b.y); r.u[3] = pk2(b.z, b.w);
  return r.v;
}

// ---------------- weight fp32 -> bf16 (up to 4 segments, sizes %2048==0) ----
__global__ __launch_bounds__(256) void cvt_w4(const float* __restrict__ s0, int n0,
    const float* __restrict__ s1, int n1, const float* __restrict__ s2, int n2,
    const float* __restrict__ s3, int n3, short* __restrict__ dst) {
  long base = (long)blockIdx.x * 2048 + (long)threadIdx.x * 8;
  const float* src; long off;
  if (base < n0) { src = s0; off = base; }
  else if (base < (long)n0 + n1) { src = s1; off = base - n0; }
  else if (base < (long)n0 + n1 + n2) { src = s2; off = base - n0 - n1; }
  else { src = s3; off = base - n0 - n1 - n2; }
  float4 a = *reinterpret_cast<const float4*>(src + off);
  float4 b = *reinterpret_cast<const float4*>(src + off + 4);
  *reinterpret_cast<bf16x8*>(dst + base) = cvt8(a, b);
}

// ---------------- RMSNorm ----------------
__global__ __launch_bounds__(256) void rmsnorm_k(const float* __restrict__ in,
    const float* __restrict__ w, float* __restrict__ out,
    int cols, int ldin, int ldout, float eps) {
  const int row = blockIdx.x;
  const float* xr = in + (size_t)row * ldin;
  float* yr = out + (size_t)row * ldout;
  const int tid = threadIdx.x;
  float ss = 0.f;
  for (int c = tid << 2; c < cols; c += 1024) {
    float4 v = *reinterpret_cast<const float4*>(xr + c);
    ss += v.x*v.x + v.y*v.y + v.z*v.z + v.w*v.w;
  }
#pragma unroll
  for (int mm = 1; mm < 64; mm <<= 1) ss += __shfl_xor(ss, mm, 64);
  __shared__ float red[4];
  if ((tid & 63) == 0) red[tid >> 6] = ss;
  __syncthreads();
  float tot = red[0] + red[1] + red[2] + red[3];
  float scale = rsqrtf(tot / (float)cols + eps);
  for (int c = tid << 2; c < cols; c += 1024) {
    float4 v = *reinterpret_cast<const float4*>(xr + c);
    float4 wv = *reinterpret_cast<const float4*>(w + c);
    float4 ov = make_float4(v.x*scale*wv.x, v.y*scale*wv.y, v.z*scale*wv.z, v.w*scale*wv.w);
    *reinterpret_cast<float4*>(yr + c) = ov;
  }
}

// ------------- bf16 MFMA GEMM, BK=64, register-prefetch; B is bf16 ----------
// C[M,N] = A[M,K] @ B[N,K]^T (+ src). ABF: A already bf16.
template<int ADD, int ABF>
__global__ __launch_bounds__(256) void mgemm_nt(const void* __restrict__ Av,
    const short* __restrict__ B, const float* __restrict__ src, float* __restrict__ C,
    int M, int N, int K, int lda, int ldb, int ldc) {
  __shared__ short As[64][72];
  __shared__ short Bs[64][72];
  const int bm = blockIdx.y * 64, bn = blockIdx.x * 64;
  const int tid = threadIdx.x;
  const int w = tid >> 6, lane = tid & 63;
  const int wr = (w >> 1) << 5, wc = (w & 1) << 5;
  const int srow = tid >> 2, sk = (tid & 3) << 4;
  const int lrow = lane & 15, lk8 = (lane >> 4) << 3;
  const int arow = bm + srow, brow = bn + srow;
  const bool bvalid = brow < N;
  const float* Af = (const float*)Av;
  const short* Ah = (const short*)Av;
  f32x4 acc[2][2];
#pragma unroll
  for (int i = 0; i < 2; ++i)
#pragma unroll
    for (int j = 0; j < 2; ++j) acc[i][j] = (f32x4){0.f, 0.f, 0.f, 0.f};

  float4 ra[4]; bf16x8 rah0, rah1, rbh0, rbh1;
  if (ABF) {
    const short* ap = Ah + (size_t)arow * lda + sk;
    rah0 = *reinterpret_cast<const bf16x8*>(ap);
    rah1 = *reinterpret_cast<const bf16x8*>(ap + 8);
  } else {
    const float* ap = Af + (size_t)arow * lda + sk;
    ra[0] = *reinterpret_cast<const float4*>(ap);
    ra[1] = *reinterpret_cast<const float4*>(ap + 4);
    ra[2] = *reinterpret_cast<const float4*>(ap + 8);
    ra[3] = *reinterpret_cast<const float4*>(ap + 12);
  }
  rbh0 = (bf16x8){0,0,0,0,0,0,0,0}; rbh1 = rbh0;
  if (bvalid) {
    const short* bp = B + (size_t)brow * ldb + sk;
    rbh0 = *reinterpret_cast<const bf16x8*>(bp);
    rbh1 = *reinterpret_cast<const bf16x8*>(bp + 8);
  }

  for (int k0 = 0; k0 < K; k0 += 64) {
    bf16x8 va0, va1;
    if (ABF) { va0 = rah0; va1 = rah1; }
    else     { va0 = cvt8(ra[0], ra[1]); va1 = cvt8(ra[2], ra[3]); }
    bf16x8 vb0 = rbh0, vb1 = rbh1;
    __syncthreads();
    *reinterpret_cast<bf16x8*>(&As[srow][sk])     = va0;
    *reinterpret_cast<bf16x8*>(&As[srow][sk + 8]) = va1;
    *reinterpret_cast<bf16x8*>(&Bs[srow][sk])     = vb0;
    *reinterpret_cast<bf16x8*>(&Bs[srow][sk + 8]) = vb1;
    __syncthreads();
    const int kn = k0 + 64;
    if (kn < K) {
      if (ABF) {
        const short* ap = Ah + (size_t)arow * lda + kn + sk;
        rah0 = *reinterpret_cast<const bf16x8*>(ap);
        rah1 = *reinterpret_cast<const bf16x8*>(ap + 8);
      } else {
        const float* ap = Af + (size_t)arow * lda + kn + sk;
        ra[0] = *reinterpret_cast<const float4*>(ap);
        ra[1] = *reinterpret_cast<const float4*>(ap + 4);
        ra[2] = *reinterpret_cast<const float4*>(ap + 8);
        ra[3] = *reinterpret_cast<const float4*>(ap + 12);
      }
      if (bvalid) {
        const short* bp = B + (size_t)brow * ldb + kn + sk;
        rbh0 = *reinterpret_cast<const bf16x8*>(bp);
        rbh1 = *reinterpret_cast<const bf16x8*>(bp + 8);
      }
    }
#pragma unroll
    for (int kk = 0; kk < 2; ++kk) {
      bf16x8 af0 = *reinterpret_cast<bf16x8*>(&As[wr + lrow][(kk << 5) + lk8]);
      bf16x8 af1 = *reinterpret_cast<bf16x8*>(&As[wr + 16 + lrow][(kk << 5) + lk8]);
      bf16x8 bf0 = *reinterpret_cast<bf16x8*>(&Bs[wc + lrow][(kk << 5) + lk8]);
      bf16x8 bf1 = *reinterpret_cast<bf16x8*>(&Bs[wc + 16 + lrow][(kk << 5) + lk8]);
      acc[0][0] = __builtin_amdgcn_mfma_f32_16x16x32_bf16(af0, bf0, acc[0][0], 0, 0, 0);
      acc[0][1] = __builtin_amdgcn_mfma_f32_16x16x32_bf16(af0, bf1, acc[0][1], 0, 0, 0);
      acc[1][0] = __builtin_amdgcn_mfma_f32_16x16x32_bf16(af1, bf0, acc[1][0], 0, 0, 0);
      acc[1][1] = __builtin_amdgcn_mfma_f32_16x16x32_bf16(af1, bf1, acc[1][1], 0, 0, 0);
    }
  }
  const int crow0 = bm + wr + ((lane >> 4) << 2);
  const int ccol0 = bn + wc + lrow;
#pragma unroll
  for (int mi = 0; mi < 2; ++mi)
#pragma unroll
    for (int ni = 0; ni < 2; ++ni) {
      int colc = ccol0 + (ni << 4);
      if (colc < N) {
#pragma unroll
        for (int r = 0; r < 4; ++r) {
          int rowc = crow0 + (mi << 4) + r;
          float v = acc[mi][ni][r];
          if (ADD) v += src[(size_t)rowc * ldc + colc];
          C[(size_t)rowc * ldc + colc] = v;
        }
      }
    }
}

// ------------- bf16 MFMA SwiGLU GEMM (pipelined), bf16 B + bf16 output ------
// C = (A@Bu^T) * silu(A@Bv^T); Bu = Bw rows [0,N), Bv = rows [N,2N). N exact.
__global__ __launch_bounds__(256) void mgemm_glu(const float* __restrict__ A,
    const short* __restrict__ Bw, short* __restrict__ C,
    int M, int N, int K, int lda, int ldb, int ldc) {
  __shared__ short As[64][72];
  __shared__ short Bu[64][72];
  __shared__ short Bv[64][72];
  const int bm = blockIdx.y * 64, bn = blockIdx.x * 64;
  const int tid = threadIdx.x;
  const int w = tid >> 6, lane = tid & 63;
  const int wr = (w >> 1) << 5, wc = (w & 1) << 5;
  const int srow = tid >> 2, sk = (tid & 3) << 4;
  const int lrow = lane & 15, lk8 = (lane >> 4) << 3;
  const int arow = bm + srow, brow = bn + srow;
  f32x4 au[2][2], av[2][2];
#pragma unroll
  for (int i = 0; i < 2; ++i)
#pragma unroll
    for (int j = 0; j < 2; ++j) {
      au[i][j] = (f32x4){0.f, 0.f, 0.f, 0.f};
      av[i][j] = (f32x4){0.f, 0.f, 0.f, 0.f};
    }
  float4 ra[4]; bf16x8 ru0, ru1, rv0, rv1;
  {
    const float* ap = A + (size_t)arow * lda + sk;
    const short* up = Bw + (size_t)brow * ldb + sk;
    const short* vp = Bw + (size_t)(N + brow) * ldb + sk;
#pragma unroll
    for (int e = 0; e < 4; ++e) ra[e] = *reinterpret_cast<const float4*>(ap + (e << 2));
    ru0 = *reinterpret_cast<const bf16x8*>(up);
    ru1 = *reinterpret_cast<const bf16x8*>(up + 8);
    rv0 = *reinterpret_cast<const bf16x8*>(vp);
    rv1 = *reinterpret_cast<const bf16x8*>(vp + 8);
  }
  for (int k0 = 0; k0 < K; k0 += 64) {
    bf16x8 a0 = cvt8(ra[0], ra[1]), a1 = cvt8(ra[2], ra[3]);
    bf16x8 u0 = ru0, u1 = ru1, v0 = rv0, v1 = rv1;
    __syncthreads();
    *reinterpret_cast<bf16x8*>(&As[srow][sk])     = a0;
    *reinterpret_cast<bf16x8*>(&As[srow][sk + 8]) = a1;
    *reinterpret_cast<bf16x8*>(&Bu[srow][sk])     = u0;
    *reinterpret_cast<bf16x8*>(&Bu[srow][sk + 8]) = u1;
    *reinterpret_cast<bf16x8*>(&Bv[srow][sk])     = v0;
    *reinterpret_cast<bf16x8*>(&Bv[srow][sk + 8]) = v1;
    __syncthreads();
    const int kn = k0 + 64;
    if (kn < K) {
      const float* ap = A + (size_t)arow * lda + kn + sk;
      const short* up = Bw + (size_t)brow * ldb + kn + sk;
      const short* vp = Bw + (size_t)(N + brow) * ldb + kn + sk;
#pragma unroll
      for (int e = 0; e < 4; ++e) ra[e] = *reinterpret_cast<const float4*>(ap + (e << 2));
      ru0 = *reinterpret_cast<const bf16x8*>(up);
      ru1 = *reinterpret_cast<const bf16x8*>(up + 8);
      rv0 = *reinterpret_cast<const bf16x8*>(vp);
      rv1 = *reinterpret_cast<const bf16x8*>(vp + 8);
    }
#pragma unroll
    for (int kk = 0; kk < 2; ++kk) {
      bf16x8 af0 = *reinterpret_cast<bf16x8*>(&As[wr + lrow][(kk << 5) + lk8]);
      bf16x8 af1 = *reinterpret_cast<bf16x8*>(&As[wr + 16 + lrow][(kk << 5) + lk8]);
      bf16x8 uf0 = *reinterpret_cast<bf16x8*>(&Bu[wc + lrow][(kk << 5) + lk8]);
      bf16x8 uf1 = *reinterpret_cast<bf16x8*>(&Bu[wc + 16 + lrow][(kk << 5) + lk8]);
      bf16x8 vf0 = *reinterpret_cast<bf16x8*>(&Bv[wc + lrow][(kk << 5) + lk8]);
      bf16x8 vf1 = *reinterpret_cast<bf16x8*>(&Bv[wc + 16 + lrow][(kk << 5) + lk8]);
      au[0][0] = __builtin_amdgcn_mfma_f32_16x16x32_bf16(af0, uf0, au[0][0], 0, 0, 0);
      au[0][1] = __builtin_amdgcn_mfma_f32_16x16x32_bf16(af0, uf1, au[0][1], 0, 0, 0);
      au[1][0] = __builtin_amdgcn_mfma_f32_16x16x32_bf16(af1, uf0, au[1][0], 0, 0, 0);
      au[1][1] = __builtin_amdgcn_mfma_f32_16x16x32_bf16(af1, uf1, au[1][1], 0, 0, 0);
      av[0][0] = __builtin_amdgcn_mfma_f32_16x16x32_bf16(af0, vf0, av[0][0], 0, 0, 0);
      av[0][1] = __builtin_amdgcn_mfma_f32_16x16x32_bf16(af0, vf1, av[0][1], 0, 0, 0);
      av[1][0] = __builtin_amdgcn_mfma_f32_16x16x32_bf16(af1, vf0, av[1][0], 0, 0, 0);
      av[1][1] = __builtin_amdgcn_mfma_f32_16x16x32_bf16(af1, vf1, av[1][1], 0, 0, 0);
    }
  }
  const int crow0 = bm + wr + ((lane >> 4) << 2);
  const int ccol0 = bn + wc + lrow;
#pragma unroll
  for (int mi = 0; mi < 2; ++mi)
#pragma unroll
    for (int ni = 0; ni < 2; ++ni) {
      int colc = ccol0 + (ni << 4);
#pragma unroll
      for (int r = 0; r < 4; ++r) {
        int rowc = crow0 + (mi << 4) + r;
        float uu = au[mi][ni][r], vg = av[mi][ni][r];
        float sig = 1.0f / (1.0f + __expf(-vg));
        C[(size_t)rowc * ldc + colc] = cvt_bf16(uu * vg * sig);
      }
    }
}

// ---------------- Build Q/K (split heads + RoPE) ----------------
__global__ __launch_bounds__(256) void build_qk(const float* __restrict__ qf,
    const float* __restrict__ kvb, const float* __restrict__ ckv,
    const float* __restrict__ fc, const float* __restrict__ fs,
    float* __restrict__ Qb, float* __restrict__ Kb) {
  int t = blockIdx.x * 256 + threadIdx.x;
  int h2 = blockIdx.y;
  if (t >= S) return;
  int hh = h2 >> 1, par = h2 & 1;
  const float* qrow = qf + (size_t)t*1536 + hh*96;
  const float* krow = kvb + (size_t)t*2048 + hh*128;
  float* qo = Qb + ((size_t)h2*S + t)*DQK;
  float* ko = Kb + ((size_t)h2*S + t)*DQK;
#pragma unroll
  for (int xq = 0; xq < 8; ++xq) {
    *reinterpret_cast<float4*>(qo + (xq<<2)) =
      *reinterpret_cast<const float4*>(qrow + par*32 + (xq<<2));
    *reinterpret_cast<float4*>(ko + (xq<<2)) =
      *reinterpret_cast<const float4*>(krow + par*32 + (xq<<2));
  }
  int p = t >> 2;
  const float* qr = qrow + 64 + par*16;
  const float* kr = ckv + (size_t)t*288 + 256 + par*16;
#pragma unroll
  for (int mq = 0; mq < 8; ++mq) {
    float c = 1.f, sn = 0.f;
    if (p > 0) { c = fc[(p-1)*8 + mq]; sn = fs[(p-1)*8 + mq]; }
    float q0 = qr[2*mq], q1 = qr[2*mq+1];
    qo[32 + 2*mq]     = q0*c - q1*sn;
    qo[32 + 2*mq + 1] = q0*sn + q1*c;
    float k0 = kr[2*mq], k1 = kr[2*mq+1];
    ko[32 + 2*mq]     = k0*c - k1*sn;
    ko[32 + 2*mq + 1] = k0*sn + k1*c;
  }
}

// ---------------- lambda scalar ----------------
__global__ void compute_lam(const float* __restrict__ lq1, const float* __restrict__ lk1,
                            const float* __restrict__ lq2, const float* __restrict__ lk2,
                            float* __restrict__ lamp) {
  int t = threadIdx.x;
  float a = lq1[t]*lk1[t];
  float b = lq2[t]*lk2[t];
#pragma unroll
  for (int mm = 1; mm < 32; mm <<= 1) { a += __shfl_xor(a, mm, 32); b += __shfl_xor(b, mm, 32); }
  if (t == 0) lamp[0] = expf(a) - expf(b) + 0.2f;
}

// ---------------- MFMA flash attention, split over key-chunk halves ----------
__global__ __launch_bounds__(256) void flash_mfma(const float* __restrict__ Qb,
    const float* __restrict__ Kb, const float* __restrict__ kvb,
    float* __restrict__ Ob, float* __restrict__ rowm, float* __restrict__ rowl,
    float* __restrict__ Ob1a, float* __restrict__ Ob1b,
    float* __restrict__ rm1, float* __restrict__ rl1) {
  const int h2 = blockIdx.y;
  const int hh = h2 >> 1;
  const int i0 = blockIdx.x << 7;
  const int z  = blockIdx.z;
  const int tid = threadIdx.x;
  const int w = tid >> 6, lane = tid & 63;
  const int ql = lane & 31, h = lane >> 5;
  const int qbase = i0 + (w << 5);
  const int rbase = i0 % SPP;
  const int ri0w = rbase + (w << 5);
  const int jmaxb = rbase + 96;

  __shared__ __align__(16) short Ks[32][72];
  __shared__ __align__(16) short Vt[64][40];
  __shared__ __align__(16) float Ot[4][32][68];

  bf16x8 qf0, qf1, qf2;
  {
    const float* qp = Qb + ((size_t)h2*S + qbase + ql)*DQK + (h << 3);
#pragma unroll
    for (int dt = 0; dt < 3; ++dt) {
      float4 a = *reinterpret_cast<const float4*>(qp + (dt << 4));
      float4 b = *reinterpret_cast<const float4*>(qp + (dt << 4) + 4);
      bf16x8 q8 = cvt8(a, b);
      if (dt == 0) qf0 = q8; else if (dt == 1) qf1 = q8; else qf2 = q8;
    }
  }

  float m = -1e30f, l = 0.f;
  f32x16 o0, o1;
#pragma unroll
  for (int r = 0; r < 16; ++r) { o0[r] = 0.f; o1[r] = 0.f; }

  for (int c = (z << 1); c < (z << 1) + 2; ++c) {
    for (int jr = 0; jr <= jmaxb; jr += 32) {
      const int j0 = c*SPP + jr;
      __syncthreads();
      if (tid < 192) {
        int r = tid / 6, c8 = (tid % 6) << 3;
        const float* kp = Kb + ((size_t)h2*S + j0 + r)*DQK + c8;
        float4 a = *reinterpret_cast<const float4*>(kp);
        float4 b = *reinterpret_cast<const float4*>(kp + 4);
        *reinterpret_cast<bf16x8*>(&Ks[r][c8]) = cvt8(a, b);
      }
      {
        int d = tid & 63, kb = (tid >> 6) << 3;
        const float* vp = kvb + (size_t)(j0 + kb)*2048 + hh*128 + 64 + d;
        float f0 = vp[0], f1 = vp[(size_t)1*2048], f2 = vp[(size_t)2*2048], f3 = vp[(size_t)3*2048];
        float f4 = vp[(size_t)4*2048], f5 = vp[(size_t)5*2048], f6 = vp[(size_t)6*2048], f7 = vp[(size_t)7*2048];
        union { unsigned u[4]; bf16x8 v; } vv;
        vv.u[0] = pk2(f0, f1); vv.u[1] = pk2(f2, f3);
        vv.u[2] = pk2(f4, f5); vv.u[3] = pk2(f6, f7);
        *reinterpret_cast<bf16x8*>(&Vt[d][kb]) = vv.v;
      }
      __syncthreads();
      if (jr > ri0w) continue;
      const bool diag = (jr == ri0w);

      bf16x8 kf0 = *reinterpret_cast<bf16x8*>(&Ks[ql][(h << 3)]);
      bf16x8 kf1 = *reinterpret_cast<bf16x8*>(&Ks[ql][16 + (h << 3)]);
      bf16x8 kf2 = *reinterpret_cast<bf16x8*>(&Ks[ql][32 + (h << 3)]);
      f32x16 st;
#pragma unroll
      for (int r = 0; r < 16; ++r) st[r] = 0.f;
      st = __builtin_amdgcn_mfma_f32_32x32x16_bf16(kf0, qf0, st, 0, 0, 0);
      st = __builtin_amdgcn_mfma_f32_32x32x16_bf16(kf1, qf1, st, 0, 0, 0);
      st = __builtin_amdgcn_mfma_f32_32x32x16_bf16(kf2, qf2, st, 0, 0, 0);

      if (diag) {
#pragma unroll
        for (int r = 0; r < 16; ++r) {
          int kl = (r & 3) + ((r >> 2) << 3) + (h << 2);
          st[r] = (kl <= ql) ? st[r] * SCALING : -1e30f;
        }
      } else {
#pragma unroll
        for (int r = 0; r < 16; ++r) st[r] *= SCALING;
      }

      float tm = st[0];
#pragma unroll
      for (int r = 1; r < 16; ++r) tm = fmaxf(tm, st[r]);
      tm = fmaxf(tm, __shfl_xor(tm, 32));
      float mnew = fmaxf(m, tm);
      float sc = __expf(m - mnew);
      m = mnew;
      float ps = 0.f;
#pragma unroll
      for (int r = 0; r < 16; ++r) { float p = __expf(st[r] - mnew); st[r] = p; ps += p; }
      ps += __shfl_xor(ps, 32);
      l = l * sc + ps;
#pragma unroll
      for (int r = 0; r < 16; ++r) { o0[r] *= sc; o1[r] *= sc; }

      unsigned A0 = pk2(st[0],  st[1]),  B0 = pk2(st[2],  st[3]);
      unsigned C0 = pk2(st[4],  st[5]),  D0 = pk2(st[6],  st[7]);
      unsigned A1 = pk2(st[8],  st[9]),  B1 = pk2(st[10], st[11]);
      unsigned C1 = pk2(st[12], st[13]), D1 = pk2(st[14], st[15]);
      unsigned xA0 = (unsigned)__shfl_xor((int)A0, 32), xB0 = (unsigned)__shfl_xor((int)B0, 32);
      unsigned xC0 = (unsigned)__shfl_xor((int)C0, 32), xD0 = (unsigned)__shfl_xor((int)D0, 32);
      unsigned xA1 = (unsigned)__shfl_xor((int)A1, 32), xB1 = (unsigned)__shfl_xor((int)B1, 32);
      unsigned xC1 = (unsigned)__shfl_xor((int)C1, 32), xD1 = (unsigned)__shfl_xor((int)D1, 32);
      union { unsigned u[4]; bf16x8 v; } P0, P1;
      P0.u[0] = h ? xC0 : A0;  P0.u[1] = h ? xD0 : B0;
      P0.u[2] = h ? C0 : xA0;  P0.u[3] = h ? D0 : xB0;
      P1.u[0] = h ? xC1 : A1;  P1.u[1] = h ? xD1 : B1;
      P1.u[2] = h ? C1 : xA1;  P1.u[3] = h ? D1 : xB1;

      bf16x8 v00 = *reinterpret_cast<bf16x8*>(&Vt[ql][(h << 3)]);
      bf16x8 v01 = *reinterpret_cast<bf16x8*>(&Vt[ql][16 + (h << 3)]);
      bf16x8 v10 = *reinterpret_cast<bf16x8*>(&Vt[32 + ql][(h << 3)]);
      bf16x8 v11 = *reinterpret_cast<bf16x8*>(&Vt[32 + ql][16 + (h << 3)]);
      o0 = __builtin_amdgcn_mfma_f32_32x32x16_bf16(v00, P0.v, o0, 0, 0, 0);
      o0 = __builtin_amdgcn_mfma_f32_32x32x16_bf16(v01, P1.v, o0, 0, 0, 0);
      o1 = __builtin_amdgcn_mfma_f32_32x32x16_bf16(v10, P0.v, o1, 0, 0, 0);
      o1 = __builtin_amdgcn_mfma_f32_32x32x16_bf16(v11, P1.v, o1, 0, 0, 0);
    }
  }

  float* ot = &Ot[w][0][0];
#pragma unroll
  for (int r = 0; r < 16; ++r) {
    int dl = (r & 3) + ((r >> 2) << 3) + (h << 2);
    ot[ql*68 + dl]      = o0[r];
    ot[ql*68 + 32 + dl] = o1[r];
  }
  float* orow;
  if (z == 0) orow = Ob + ((size_t)h2*S + qbase)*HD;
  else orow = (h2 < 16) ? Ob1a + ((size_t)h2*S + qbase)*HD
                        : Ob1b + ((size_t)(h2 - 16)*S + qbase)*HD;
#pragma unroll
  for (int it = 0; it < 8; ++it) {
    int idx = lane + (it << 6);
    int row = idx >> 4, c4 = (idx & 15) << 2;
    float4 v = *reinterpret_cast<float4*>(&ot[row*68 + c4]);
    *reinterpret_cast<float4*>(&orow[(size_t)row*HD + c4]) = v;
  }
  if (lane < 32) {
    if (z == 0) { rowm[h2*S + qbase + lane] = m; rowl[h2*S + qbase + lane] = l; }
    else        { rm1[h2*S + qbase + lane] = m;  rl1[h2*S + qbase + lane] = l; }
  }
}

// ---------------- merge the two flash partials, normalize ----------------
__global__ __launch_bounds__(256) void merge_flash(float* __restrict__ Ob,
    float* __restrict__ rowm, float* __restrict__ rowl,
    const float* __restrict__ Ob1a, const float* __restrict__ Ob1b,
    const float* __restrict__ rm1, const float* __restrict__ rl1) {
  const int gid = blockIdx.x * 4 + (threadIdx.x >> 6);
  const int d = threadIdx.x & 63;
  const int h2 = gid / S;
  float m0 = rowm[gid], l0 = rowl[gid], m1 = rm1[gid], l1 = rl1[gid];
  float m = fmaxf(m0, m1);
  float w0 = __expf(m0 - m), w1 = __expf(m1 - m);
  float linv = 1.0f / (l0*w0 + l1*w1);
  const float* o1 = (h2 < 16) ? (Ob1a + (size_t)gid*HD)
                              : (Ob1b + ((size_t)gid - (size_t)16*S)*HD);
  float v0 = Ob[(size_t)gid*HD + d];
  float v1 = o1[d];
  Ob[(size_t)gid*HD + d] = (v0*w0 + v1*w1) * linv;
  if (d == 0) { rowm[gid] = m; rowl[gid] = l0*w0 + l1*w1; }
}

// ---------------- colsum via MFMA ----------------
__global__ __launch_bounds__(256) void colsum_mfma(const float* __restrict__ Qb,
    const float* __restrict__ Kb, const float* __restrict__ rowm,
    const float* __restrict__ rowl, float* __restrict__ gcol) {
  const int jt = blockIdx.x;
  const int hh = blockIdx.y, h2 = hh << 1;
  const int cK = jt / 12, jr32 = jt % 12;
  const int jr = jr32 << 5;
  const int j0 = cK*SPP + jr;
  const int tid = threadIdx.x;
  const int w = tid >> 6, lane = tid & 63;
  const int ql = lane & 31, h = lane >> 5;

  bf16x8 kf0, kf1, kf2;
  {
    const float* kp = Kb + ((size_t)h2*S + j0 + ql)*DQK + (h << 3);
    kf0 = cvt8(*reinterpret_cast<const float4*>(kp),
               *reinterpret_cast<const float4*>(kp + 4));
    kf1 = cvt8(*reinterpret_cast<const float4*>(kp + 16),
               *reinterpret_cast<const float4*>(kp + 20));
    kf2 = cvt8(*reinterpret_cast<const float4*>(kp + 32),
               *reinterpret_cast<const float4*>(kp + 36));
  }
  const int nt = 12 - jr32;
  const int T = nt << 2;
  float gs[16];
#pragma unroll
  for (int r = 0; r < 16; ++r) gs[r] = 0.f;

  for (int tt = w; tt < T; tt += 4) {
    int cq = tt / nt, qrem = tt - cq*nt;
    int qi = jr32 + qrem;
    int i0 = cq*SPP + (qi << 5);
    const bool diag = (qrem == 0);
    const float* qp = Qb + ((size_t)h2*S + i0 + ql)*DQK + (h << 3);
    bf16x8 qf0 = cvt8(*reinterpret_cast<const float4*>(qp),
                      *reinterpret_cast<const float4*>(qp + 4));
    bf16x8 qf1 = cvt8(*reinterpret_cast<const float4*>(qp + 16),
                      *reinterpret_cast<const float4*>(qp + 20));
    bf16x8 qf2 = cvt8(*reinterpret_cast<const float4*>(qp + 32),
                      *reinterpret_cast<const float4*>(qp + 36));
    f32x16 st;
#pragma unroll
    for (int r = 0; r < 16; ++r) st[r] = 0.f;
    st = __builtin_amdgcn_mfma_f32_32x32x16_bf16(kf0, qf0, st, 0, 0, 0);
    st = __builtin_amdgcn_mfma_f32_32x32x16_bf16(kf1, qf1, st, 0, 0, 0);
    st = __builtin_amdgcn_mfma_f32_32x32x16_bf16(kf2, qf2, st, 0, 0, 0);
    float Mq = rowm[h2*S + i0 + ql];
    float Lq = 1.0f / rowl[h2*S + i0 + ql];
    if (diag) {
#pragma unroll
      for (int r = 0; r < 16; ++r) {
        int kl = (r & 3) + ((r >> 2) << 3) + (h << 2);
        if (kl <= ql) gs[r] += __expf(st[r]*SCALING - Mq) * Lq;
      }
    } else {
#pragma unroll
      for (int r = 0; r < 16; ++r) gs[r] += __expf(st[r]*SCALING - Mq) * Lq;
    }
  }
  __shared__ float gw[4][32];
#pragma unroll
  for (int r = 0; r < 16; ++r) {
    float v = gs[r];
#pragma unroll
    for (int mm = 1; mm < 32; mm <<= 1) v += __shfl_xor(v, mm, 32);
    if (ql == 0) gw[w][(r & 3) + ((r >> 2) << 3) + (h << 2)] = v;
  }
  __syncthreads();
  if (tid < 32) {
    float s = gw[0][tid] + gw[1][tid] + gw[2][tid] + gw[3][tid];
    gcol[hh*S + j0 + tid] = s * (1.0f / (float)S);
  }
}

// ---------------- Wpre: masked prefix of g-weighted V ----------------
__global__ __launch_bounds__(256) void build_wpre(const float* __restrict__ gcol,
    const float* __restrict__ kvb, float* __restrict__ Wpre) {
  const int hh = blockIdx.x >> 2;
  const int dq = (blockIdx.x & 3) << 4;
  __shared__ float Wt[SPP][16];
  const int tid = threadIdx.x;
  for (int idx = tid; idx < SPP*16; idx += 256) {
    int r = idx >> 4, dd = idx & 15;
    float val = 0.f;
#pragma unroll
    for (int b2 = 0; b2 < 4; ++b2) {
      int j = b2*SPP + r;
      val = fmaf(gcol[hh*S + j], kvb[(size_t)j*2048 + hh*128 + 64 + dq + dd], val);
    }
    Wt[r][dd] = val;
  }
  __syncthreads();
  if (tid < 16) {
    float run = 0.f;
    for (int r = 0; r < SPP; ++r) { run += Wt[r][tid]; Wt[r][tid] = run; }
  }
  __syncthreads();
  for (int idx = tid; idx < SPP*16; idx += 256) {
    int r = idx >> 4, dd = idx & 15;
    Wpre[((size_t)hh*SPP + r)*HD + dq + dd] = Wt[r][dd];
  }
}

// ---------------- combine (diff-attn) + per-head RMSNorm + scrambled reshape ----
__global__ __launch_bounds__(64) void combine_rms(const float* __restrict__ Ob,
    const float* __restrict__ Wpre, const float* __restrict__ lamp,
    const float* __restrict__ anw, float* __restrict__ attno) {
  const int t = blockIdx.x, h = blockIdx.y, d = threadIdx.x;
  const float lam = lamp[0];
  const float o1 = Ob[((size_t)(2*h)*S + t)*HD + d];
  const float o2 = Ob[((size_t)(2*h+1)*S + t)*HD + d];
  const float w3 = Wpre[((size_t)h*SPP + (t % SPP))*HD + d];
  float val = o1 - lam*o2 + lam*w3;
  float ss = val*val;
#pragma unroll
  for (int mm = 1; mm < 64; mm <<= 1) ss += __shfl_xor(ss, mm, 64);
  float scale = rsqrtf(ss * (1.0f/HD) + ATTN_EPS) * anw[d];
  int tn = h*96 + (t >> 4);
  int cn = ((t & 15) << 6) + d;
  attno[(size_t)tn*DM + cn] = val * scale;
}

// =========================== launch ===========================
extern "C" void kernel_launch(void* const* d_in, const int* in_sizes, int n_in,
                              void* d_out, int out_size, void* d_ws, size_t ws_size,
                              hipStream_t stream) {
  (void)in_sizes; (void)n_in; (void)out_size;
  const float* x    = (const float*)d_in[0];
  const float* fc   = (const float*)d_in[1];
  const float* fs   = (const float*)d_in[2];
  const float* n1w  = (const float*)d_in[3];
  const float* n2w  = (const float*)d_in[4];
  const float* kvdw = (const float*)d_in[5];
  const float* qdw  = (const float*)d_in[6];
  const float* kvnw = (const float*)d_in[7];
  const float* qnw  = (const float*)d_in[8];
  const float* kvuw = (const float*)d_in[9];
  const float* quw  = (const float*)d_in[10];
  const float* lq1  = (const float*)d_in[11];
  const float* lk1  = (const float*)d_in[12];
  const float* lq2  = (const float*)d_in[13];
  const float* lk2  = (const float*)d_in[14];
  const float* anw  = (const float*)d_in[15];
  const float* ow   = (const float*)d_in[16];
  const float* ffiw = (const float*)d_in[17];
  const float* ffow = (const float*)d_in[18];
  float* out = (float*)d_out;
  float* ws  = (float*)d_ws;

  float* xin   = ws;
  float* ckv   = xin   + (size_t)S*DM;
  float* qmid  = ckv   + (size_t)S*288;
  float* kvb   = qmid  + (size_t)S*QC;
  float* qf    = kvb   + (size_t)S*2048;
  float* Qb    = qf    + (size_t)S*1536;
  float* Kb    = Qb    + (size_t)H2N*S*DQK;
  float* Obuf  = Kb    + (size_t)H2N*S*DQK;
  float* rowm  = Obuf  + (size_t)H2N*S*HD;
  float* rowl  = rowm  + (size_t)H2N*S;
  float* gcol  = rowl  + (size_t)H2N*S;
  float* Wpre  = gcol  + (size_t)NH*S;
  float* attno = Wpre  + (size_t)NH*SPP*HD;
  float* lamp  = attno + (size_t)S*DM;
  short* fbufs = (short*)kvb;     // bf16 FFN activation overlays kv region
  // flash z=1 partials (dead windows): xin (h2<16), qf (h2>=16)
  float* Ob1a = xin;
  float* Ob1b = qf;
  float* rm1  = qf + (size_t)16*S*HD;
  float* rl1  = rm1 + (size_t)H2N*S;
  // bf16 weight copies in dead regions:
  short* kvdw_bf = (short*)attno;                 // early weights -> attno (dead till combine)
  short* qdw_bf  = kvdw_bf + 294912;
  short* kvuw_bf = qdw_bf  + 393216;
  short* quw_bf  = kvuw_bf + 524288;
  short* ffiw_bf = (short*)Qb;                    // Qb+Kb dead after colsum_mfma
  short* ow_bf   = ffiw_bf + 8388608;             // ends exactly at Kb end
  short* ffow_bf = (short*)Obuf;                  // Obuf dead after combine_rms
  if (ws_size < (size_t)18063376 * sizeof(float)) return;

  cvt_w4<<<880, 256, 0, stream>>>(kvdw, 294912, qdw, 393216, kvuw, 524288, quw, 589824, kvdw_bf);
  rmsnorm_k<<<S, 256, 0, stream>>>(x, n1w, xin, DM, DM, DM, EPS_RMS);
  { dim3 g(5, 24);  mgemm_nt<0,0><<<g, 256, 0, stream>>>(xin, kvdw_bf, nullptr, ckv, S, 288, DM, DM, DM, 288); }
  { dim3 g(6, 24);  mgemm_nt<0,0><<<g, 256, 0, stream>>>(xin, qdw_bf,  nullptr, qmid, S, QC, DM, DM, DM, QC); }
  rmsnorm_k<<<S, 256, 0, stream>>>(ckv,  kvnw, ckv,  KVC, 288, 288, EPS_RMS);
  rmsnorm_k<<<S, 256, 0, stream>>>(qmid, qnw,  qmid, QC,  QC,  QC,  EPS_RMS);
  { dim3 g(32, 24); mgemm_nt<0,0><<<g, 256, 0, stream>>>(ckv,  kvuw_bf, nullptr, kvb, S, 2048, KVC, 288, KVC, 2048); }
  { dim3 g(24, 24); mgemm_nt<0,0><<<g, 256, 0, stream>>>(qmid, quw_bf,  nullptr, qf,  S, 1536, QC,  QC,  QC,  1536); }
  { dim3 g(6, 32);  build_qk<<<g, 256, 0, stream>>>(qf, kvb, ckv, fc, fs, Qb, Kb); }
  compute_lam<<<1, 32, 0, stream>>>(lq1, lk1, lq2, lk2, lamp);
  { dim3 g(12, 32, 2); flash_mfma<<<g, 256, 0, stream>>>(Qb, Kb, kvb, Obuf, rowm, rowl,
                                                         Ob1a, Ob1b, rm1, rl1); }
  merge_flash<<<(H2N*S)/4, 256, 0, stream>>>(Obuf, rowm, rowl, Ob1a, Ob1b, rm1, rl1);
  { dim3 g(48, 16); colsum_mfma<<<g, 256, 0, stream>>>(Qb, Kb, rowm, rowl, gcol); }
  cvt_w4<<<4608, 256, 0, stream>>>(ffiw, 8388608, ow, 1048576, nullptr, 0, nullptr, 0, ffiw_bf);
  build_wpre<<<64, 256, 0, stream>>>(gcol, kvb, Wpre);
  { dim3 g(S, 16);  combine_rms<<<g, 64, 0, stream>>>(Obuf, Wpre, lamp, anw, attno); }
  cvt_w4<<<2048, 256, 0, stream>>>(ffow, 4194304, nullptr, 0, nullptr, 0, nullptr, 0, ffow_bf);
  { dim3 g(16, 24); mgemm_nt<1,0><<<g, 256, 0, stream>>>(attno, ow_bf, x, out, S, DM, DM, DM, DM, DM); }
  rmsnorm_k<<<S, 256, 0, stream>>>(out, n2w, xin, DM, DM, DM, EPS_RMS);
  { dim3 g(64, 24); mgemm_glu<<<g, 256, 0, stream>>>(xin, ffiw_bf, fbufs, S, DFF, DM, DM, DM, DFF); }
  { dim3 g(16, 24); mgemm_nt<1,1><<<g, 256, 0, stream>>>(fbufs, ffow_bf, out, out, S, DM, DFF, DFF, DFF, DM); }
}

// Round 9
// 283.482 us; speedup vs baseline: 8.3747x; 1.0517x over previous
//
#include <hip/hip_runtime.h>
#include <math.h>

#define S     1536
#define DM    1024
#define NH    16
#define H2N   32
#define HD    64
#define KVC   256
#define QC    384
#define DFF   4096
#define SPP   384
#define DQK   48
#define EPS_RMS  1.1920929e-07f
#define ATTN_EPS 1e-5f
#define SCALING  0.14433756729740643f   /* 48^-0.5 */

typedef float f32x4 __attribute__((ext_vector_type(4)));
typedef float f32x16 __attribute__((ext_vector_type(16)));
typedef short bf16x8 __attribute__((ext_vector_type(8)));

__device__ __forceinline__ short cvt_bf16(float f) {      // scalar fallback (epilogues)
  union { float f; unsigned u; } x; x.f = f;
  unsigned r = x.u + 0x7FFFu + ((x.u >> 16) & 1u);
  return (short)(r >> 16);
}
__device__ __forceinline__ unsigned pk2(float a, float b) { // HW RNE pack
  unsigned r;
  asm("v_cvt_pk_bf16_f32 %0, %1, %2" : "=v"(r) : "v"(a), "v"(b));
  return r;
}
__device__ __forceinline__ bf16x8 cvt8(float4 a, float4 b) {
  union { unsigned u[4]; bf16x8 v; } r;
  r.u[0] = pk2(a.x, a.y); r.u[1] = pk2(a.z, a.w);
  r.u[2] = pk2(b.x, b.y); r.u[3] = pk2(b.z, b.w);
  return r.v;
}

// ---------------- weight fp32 -> bf16 (up to 4 segments, sizes %2048==0) ----
__global__ __launch_bounds__(256) void cvt_w4(const float* __restrict__ s0, int n0,
    const float* __restrict__ s1, int n1, const float* __restrict__ s2, int n2,
    const float* __restrict__ s3, int n3, short* __restrict__ dst) {
  long base = (long)blockIdx.x * 2048 + (long)threadIdx.x * 8;
  const float* src; long off;
  if (base < n0) { src = s0; off = base; }
  else if (base < (long)n0 + n1) { src = s1; off = base - n0; }
  else if (base < (long)n0 + n1 + n2) { src = s2; off = base - n0 - n1; }
  else { src = s3; off = base - n0 - n1 - n2; }
  float4 a = *reinterpret_cast<const float4*>(src + off);
  float4 b = *reinterpret_cast<const float4*>(src + off + 4);
  *reinterpret_cast<bf16x8*>(dst + base) = cvt8(a, b);
}

// ---------------- RMSNorm ----------------
__global__ __launch_bounds__(256) void rmsnorm_k(const float* __restrict__ in,
    const float* __restrict__ w, float* __restrict__ out,
    int cols, int ldin, int ldout, float eps) {
  const int row = blockIdx.x;
  const float* xr = in + (size_t)row * ldin;
  float* yr = out + (size_t)row * ldout;
  const int tid = threadIdx.x;
  float ss = 0.f;
  for (int c = tid << 2; c < cols; c += 1024) {
    float4 v = *reinterpret_cast<const float4*>(xr + c);
    ss += v.x*v.x + v.y*v.y + v.z*v.z + v.w*v.w;
  }
#pragma unroll
  for (int mm = 1; mm < 64; mm <<= 1) ss += __shfl_xor(ss, mm, 64);
  __shared__ float red[4];
  if ((tid & 63) == 0) red[tid >> 6] = ss;
  __syncthreads();
  float tot = red[0] + red[1] + red[2] + red[3];
  float scale = rsqrtf(tot / (float)cols + eps);
  for (int c = tid << 2; c < cols; c += 1024) {
    float4 v = *reinterpret_cast<const float4*>(xr + c);
    float4 wv = *reinterpret_cast<const float4*>(w + c);
    float4 ov = make_float4(v.x*scale*wv.x, v.y*scale*wv.y, v.z*scale*wv.z, v.w*scale*wv.w);
    *reinterpret_cast<float4*>(yr + c) = ov;
  }
}

// ------------- bf16 MFMA GEMM, BK=64, register-prefetch; B is bf16 ----------
template<int ADD, int ABF>
__global__ __launch_bounds__(256) void mgemm_nt(const void* __restrict__ Av,
    const short* __restrict__ B, const float* __restrict__ src, float* __restrict__ C,
    int M, int N, int K, int lda, int ldb, int ldc) {
  __shared__ short As[64][72];
  __shared__ short Bs[64][72];
  const int bm = blockIdx.y * 64, bn = blockIdx.x * 64;
  const int tid = threadIdx.x;
  const int w = tid >> 6, lane = tid & 63;
  const int wr = (w >> 1) << 5, wc = (w & 1) << 5;
  const int srow = tid >> 2, sk = (tid & 3) << 4;
  const int lrow = lane & 15, lk8 = (lane >> 4) << 3;
  const int arow = bm + srow, brow = bn + srow;
  const bool bvalid = brow < N;
  const float* Af = (const float*)Av;
  const short* Ah = (const short*)Av;
  f32x4 acc[2][2];
#pragma unroll
  for (int i = 0; i < 2; ++i)
#pragma unroll
    for (int j = 0; j < 2; ++j) acc[i][j] = (f32x4){0.f, 0.f, 0.f, 0.f};

  float4 ra[4]; bf16x8 rah0, rah1, rbh0, rbh1;
  if (ABF) {
    const short* ap = Ah + (size_t)arow * lda + sk;
    rah0 = *reinterpret_cast<const bf16x8*>(ap);
    rah1 = *reinterpret_cast<const bf16x8*>(ap + 8);
  } else {
    const float* ap = Af + (size_t)arow * lda + sk;
    ra[0] = *reinterpret_cast<const float4*>(ap);
    ra[1] = *reinterpret_cast<const float4*>(ap + 4);
    ra[2] = *reinterpret_cast<const float4*>(ap + 8);
    ra[3] = *reinterpret_cast<const float4*>(ap + 12);
  }
  rbh0 = (bf16x8){0,0,0,0,0,0,0,0}; rbh1 = rbh0;
  if (bvalid) {
    const short* bp = B + (size_t)brow * ldb + sk;
    rbh0 = *reinterpret_cast<const bf16x8*>(bp);
    rbh1 = *reinterpret_cast<const bf16x8*>(bp + 8);
  }

  for (int k0 = 0; k0 < K; k0 += 64) {
    bf16x8 va0, va1;
    if (ABF) { va0 = rah0; va1 = rah1; }
    else     { va0 = cvt8(ra[0], ra[1]); va1 = cvt8(ra[2], ra[3]); }
    bf16x8 vb0 = rbh0, vb1 = rbh1;
    __syncthreads();
    *reinterpret_cast<bf16x8*>(&As[srow][sk])     = va0;
    *reinterpret_cast<bf16x8*>(&As[srow][sk + 8]) = va1;
    *reinterpret_cast<bf16x8*>(&Bs[srow][sk])     = vb0;
    *reinterpret_cast<bf16x8*>(&Bs[srow][sk + 8]) = vb1;
    __syncthreads();
    const int kn = k0 + 64;
    if (kn < K) {
      if (ABF) {
        const short* ap = Ah + (size_t)arow * lda + kn + sk;
        rah0 = *reinterpret_cast<const bf16x8*>(ap);
        rah1 = *reinterpret_cast<const bf16x8*>(ap + 8);
      } else {
        const float* ap = Af + (size_t)arow * lda + kn + sk;
        ra[0] = *reinterpret_cast<const float4*>(ap);
        ra[1] = *reinterpret_cast<const float4*>(ap + 4);
        ra[2] = *reinterpret_cast<const float4*>(ap + 8);
        ra[3] = *reinterpret_cast<const float4*>(ap + 12);
      }
      if (bvalid) {
        const short* bp = B + (size_t)brow * ldb + kn + sk;
        rbh0 = *reinterpret_cast<const bf16x8*>(bp);
        rbh1 = *reinterpret_cast<const bf16x8*>(bp + 8);
      }
    }
#pragma unroll
    for (int kk = 0; kk < 2; ++kk) {
      bf16x8 af0 = *reinterpret_cast<bf16x8*>(&As[wr + lrow][(kk << 5) + lk8]);
      bf16x8 af1 = *reinterpret_cast<bf16x8*>(&As[wr + 16 + lrow][(kk << 5) + lk8]);
      bf16x8 bf0 = *reinterpret_cast<bf16x8*>(&Bs[wc + lrow][(kk << 5) + lk8]);
      bf16x8 bf1 = *reinterpret_cast<bf16x8*>(&Bs[wc + 16 + lrow][(kk << 5) + lk8]);
      acc[0][0] = __builtin_amdgcn_mfma_f32_16x16x32_bf16(af0, bf0, acc[0][0], 0, 0, 0);
      acc[0][1] = __builtin_amdgcn_mfma_f32_16x16x32_bf16(af0, bf1, acc[0][1], 0, 0, 0);
      acc[1][0] = __builtin_amdgcn_mfma_f32_16x16x32_bf16(af1, bf0, acc[1][0], 0, 0, 0);
      acc[1][1] = __builtin_amdgcn_mfma_f32_16x16x32_bf16(af1, bf1, acc[1][1], 0, 0, 0);
    }
  }
  const int crow0 = bm + wr + ((lane >> 4) << 2);
  const int ccol0 = bn + wc + lrow;
#pragma unroll
  for (int mi = 0; mi < 2; ++mi)
#pragma unroll
    for (int ni = 0; ni < 2; ++ni) {
      int colc = ccol0 + (ni << 4);
      if (colc < N) {
#pragma unroll
        for (int r = 0; r < 4; ++r) {
          int rowc = crow0 + (mi << 4) + r;
          float v = acc[mi][ni][r];
          if (ADD) v += src[(size_t)rowc * ldc + colc];
          C[(size_t)rowc * ldc + colc] = v;
        }
      }
    }
}

// ------------- bf16 MFMA SwiGLU GEMM (pipelined), bf16 B + bf16 output ------
__global__ __launch_bounds__(256) void mgemm_glu(const float* __restrict__ A,
    const short* __restrict__ Bw, short* __restrict__ C,
    int M, int N, int K, int lda, int ldb, int ldc) {
  __shared__ short As[64][72];
  __shared__ short Bu[64][72];
  __shared__ short Bv[64][72];
  const int bm = blockIdx.y * 64, bn = blockIdx.x * 64;
  const int tid = threadIdx.x;
  const int w = tid >> 6, lane = tid & 63;
  const int wr = (w >> 1) << 5, wc = (w & 1) << 5;
  const int srow = tid >> 2, sk = (tid & 3) << 4;
  const int lrow = lane & 15, lk8 = (lane >> 4) << 3;
  const int arow = bm + srow, brow = bn + srow;
  f32x4 au[2][2], av[2][2];
#pragma unroll
  for (int i = 0; i < 2; ++i)
#pragma unroll
    for (int j = 0; j < 2; ++j) {
      au[i][j] = (f32x4){0.f, 0.f, 0.f, 0.f};
      av[i][j] = (f32x4){0.f, 0.f, 0.f, 0.f};
    }
  float4 ra[4]; bf16x8 ru0, ru1, rv0, rv1;
  {
    const float* ap = A + (size_t)arow * lda + sk;
    const short* up = Bw + (size_t)brow * ldb + sk;
    const short* vp = Bw + (size_t)(N + brow) * ldb + sk;
#pragma unroll
    for (int e = 0; e < 4; ++e) ra[e] = *reinterpret_cast<const float4*>(ap + (e << 2));
    ru0 = *reinterpret_cast<const bf16x8*>(up);
    ru1 = *reinterpret_cast<const bf16x8*>(up + 8);
    rv0 = *reinterpret_cast<const bf16x8*>(vp);
    rv1 = *reinterpret_cast<const bf16x8*>(vp + 8);
  }
  for (int k0 = 0; k0 < K; k0 += 64) {
    bf16x8 a0 = cvt8(ra[0], ra[1]), a1 = cvt8(ra[2], ra[3]);
    bf16x8 u0 = ru0, u1 = ru1, v0 = rv0, v1 = rv1;
    __syncthreads();
    *reinterpret_cast<bf16x8*>(&As[srow][sk])     = a0;
    *reinterpret_cast<bf16x8*>(&As[srow][sk + 8]) = a1;
    *reinterpret_cast<bf16x8*>(&Bu[srow][sk])     = u0;
    *reinterpret_cast<bf16x8*>(&Bu[srow][sk + 8]) = u1;
    *reinterpret_cast<bf16x8*>(&Bv[srow][sk])     = v0;
    *reinterpret_cast<bf16x8*>(&Bv[srow][sk + 8]) = v1;
    __syncthreads();
    const int kn = k0 + 64;
    if (kn < K) {
      const float* ap = A + (size_t)arow * lda + kn + sk;
      const short* up = Bw + (size_t)brow * ldb + kn + sk;
      const short* vp = Bw + (size_t)(N + brow) * ldb + kn + sk;
#pragma unroll
      for (int e = 0; e < 4; ++e) ra[e] = *reinterpret_cast<const float4*>(ap + (e << 2));
      ru0 = *reinterpret_cast<const bf16x8*>(up);
      ru1 = *reinterpret_cast<const bf16x8*>(up + 8);
      rv0 = *reinterpret_cast<const bf16x8*>(vp);
      rv1 = *reinterpret_cast<const bf16x8*>(vp + 8);
    }
#pragma unroll
    for (int kk = 0; kk < 2; ++kk) {
      bf16x8 af0 = *reinterpret_cast<bf16x8*>(&As[wr + lrow][(kk << 5) + lk8]);
      bf16x8 af1 = *reinterpret_cast<bf16x8*>(&As[wr + 16 + lrow][(kk << 5) + lk8]);
      bf16x8 uf0 = *reinterpret_cast<bf16x8*>(&Bu[wc + lrow][(kk << 5) + lk8]);
      bf16x8 uf1 = *reinterpret_cast<bf16x8*>(&Bu[wc + 16 + lrow][(kk << 5) + lk8]);
      bf16x8 vf0 = *reinterpret_cast<bf16x8*>(&Bv[wc + lrow][(kk << 5) + lk8]);
      bf16x8 vf1 = *reinterpret_cast<bf16x8*>(&Bv[wc + 16 + lrow][(kk << 5) + lk8]);
      au[0][0] = __builtin_amdgcn_mfma_f32_16x16x32_bf16(af0, uf0, au[0][0], 0, 0, 0);
      au[0][1] = __builtin_amdgcn_mfma_f32_16x16x32_bf16(af0, uf1, au[0][1], 0, 0, 0);
      au[1][0] = __builtin_amdgcn_mfma_f32_16x16x32_bf16(af1, uf0, au[1][0], 0, 0, 0);
      au[1][1] = __builtin_amdgcn_mfma_f32_16x16x32_bf16(af1, uf1, au[1][1], 0, 0, 0);
      av[0][0] = __builtin_amdgcn_mfma_f32_16x16x32_bf16(af0, vf0, av[0][0], 0, 0, 0);
      av[0][1] = __builtin_amdgcn_mfma_f32_16x16x32_bf16(af0, vf1, av[0][1], 0, 0, 0);
      av[1][0] = __builtin_amdgcn_mfma_f32_16x16x32_bf16(af1, vf0, av[1][0], 0, 0, 0);
      av[1][1] = __builtin_amdgcn_mfma_f32_16x16x32_bf16(af1, vf1, av[1][1], 0, 0, 0);
    }
  }
  const int crow0 = bm + wr + ((lane >> 4) << 2);
  const int ccol0 = bn + wc + lrow;
#pragma unroll
  for (int mi = 0; mi < 2; ++mi)
#pragma unroll
    for (int ni = 0; ni < 2; ++ni) {
      int colc = ccol0 + (ni << 4);
#pragma unroll
      for (int r = 0; r < 4; ++r) {
        int rowc = crow0 + (mi << 4) + r;
        float uu = au[mi][ni][r], vg = av[mi][ni][r];
        float sig = 1.0f / (1.0f + __expf(-vg));
        C[(size_t)rowc * ldc + colc] = cvt_bf16(uu * vg * sig);
      }
    }
}

// ---------------- Build Q/K (split heads + RoPE) -> bf16 ----------------
__global__ __launch_bounds__(256) void build_qk(const float* __restrict__ qf,
    const float* __restrict__ kvb, const float* __restrict__ ckv,
    const float* __restrict__ fc, const float* __restrict__ fs,
    short* __restrict__ Qb, short* __restrict__ Kb) {
  int t = blockIdx.x * 256 + threadIdx.x;
  int h2 = blockIdx.y;
  if (t >= S) return;
  int hh = h2 >> 1, par = h2 & 1;
  const float* qrow = qf + (size_t)t*1536 + hh*96;
  const float* krow = kvb + (size_t)t*2048 + hh*128;
  unsigned qu[24], ku[24];
#pragma unroll
  for (int xq = 0; xq < 8; ++xq) {
    float4 qv = *reinterpret_cast<const float4*>(qrow + par*32 + (xq<<2));
    float4 kv = *reinterpret_cast<const float4*>(krow + par*32 + (xq<<2));
    qu[xq*2]   = pk2(qv.x, qv.y); qu[xq*2+1] = pk2(qv.z, qv.w);
    ku[xq*2]   = pk2(kv.x, kv.y); ku[xq*2+1] = pk2(kv.z, kv.w);
  }
  int p = t >> 2;
  const float* qr = qrow + 64 + par*16;
  const float* kr = ckv + (size_t)t*288 + 256 + par*16;
#pragma unroll
  for (int mq = 0; mq < 8; ++mq) {
    float c = 1.f, sn = 0.f;
    if (p > 0) { c = fc[(p-1)*8 + mq]; sn = fs[(p-1)*8 + mq]; }
    float q0 = qr[2*mq], q1 = qr[2*mq+1];
    qu[16 + mq] = pk2(q0*c - q1*sn, q0*sn + q1*c);
    float k0 = kr[2*mq], k1 = kr[2*mq+1];
    ku[16 + mq] = pk2(k0*c - k1*sn, k0*sn + k1*c);
  }
  unsigned* qo = (unsigned*)(Qb + ((size_t)h2*S + t)*DQK);
  unsigned* ko = (unsigned*)(Kb + ((size_t)h2*S + t)*DQK);
#pragma unroll
  for (int e = 0; e < 6; ++e) {
    *reinterpret_cast<uint4*>(qo + (e<<2)) = make_uint4(qu[e*4], qu[e*4+1], qu[e*4+2], qu[e*4+3]);
    *reinterpret_cast<uint4*>(ko + (e<<2)) = make_uint4(ku[e*4], ku[e*4+1], ku[e*4+2], ku[e*4+3]);
  }
}

// ---------------- V transpose to bf16: Vt[hh][d][t] ----------------
// grid (16, 12), 256 thr: head hh, 128-t chunk
__global__ __launch_bounds__(256) void vt_build(const float* __restrict__ kvb,
    short* __restrict__ Vt) {
  const int hh = blockIdx.x;
  const int t0 = blockIdx.y << 7;
  __shared__ short Ts[128][74];
  const int tl = threadIdx.x >> 3, dp = (threadIdx.x & 7) << 3;
#pragma unroll
  for (int pass = 0; pass < 4; ++pass) {
    int t = t0 + (pass << 5) + tl;
    const float* vp = kvb + (size_t)t*2048 + hh*128 + 64 + dp;
    float4 a = *reinterpret_cast<const float4*>(vp);
    float4 b = *reinterpret_cast<const float4*>(vp + 4);
    *reinterpret_cast<bf16x8*>(&Ts[(pass << 5) + tl][dp]) = cvt8(a, b);
  }
  __syncthreads();
  for (int idx = threadIdx.x; idx < 1024; idx += 256) {
    int d = idx >> 4, tseg = (idx & 15) << 3;
    bf16x8 v;
#pragma unroll
    for (int e = 0; e < 8; ++e) v[e] = Ts[tseg + e][d];
    *reinterpret_cast<bf16x8*>(Vt + ((size_t)hh*HD + d)*S + t0 + tseg) = v;
  }
}

// ---------------- lambda scalar ----------------
__global__ void compute_lam(const float* __restrict__ lq1, const float* __restrict__ lk1,
                            const float* __restrict__ lq2, const float* __restrict__ lk2,
                            float* __restrict__ lamp) {
  int t = threadIdx.x;
  float a = lq1[t]*lk1[t];
  float b = lq2[t]*lk2[t];
#pragma unroll
  for (int mm = 1; mm < 32; mm <<= 1) { a += __shfl_xor(a, mm, 32); b += __shfl_xor(b, mm, 32); }
  if (t == 0) lamp[0] = expf(a) - expf(b) + 0.2f;
}

// ---------------- MFMA flash attention (bf16 inputs, split-j) ----------
__global__ __launch_bounds__(256) void flash_mfma(const short* __restrict__ Qb,
    const short* __restrict__ Kb, const short* __restrict__ Vg,
    float* __restrict__ Ob, float* __restrict__ rowm, float* __restrict__ rowl,
    float* __restrict__ Ob1a, float* __restrict__ Ob1b,
    float* __restrict__ rm1, float* __restrict__ rl1) {
  const int h2 = blockIdx.y;
  const int hh = h2 >> 1;
  const int i0 = blockIdx.x << 7;
  const int z  = blockIdx.z;
  const int tid = threadIdx.x;
  const int w = tid >> 6, lane = tid & 63;
  const int ql = lane & 31, h = lane >> 5;
  const int qbase = i0 + (w << 5);
  const int rbase = i0 % SPP;
  const int ri0w = rbase + (w << 5);
  const int jmaxb = rbase + 96;

  __shared__ __align__(16) short Ks[32][72];
  __shared__ __align__(16) short Vt[64][40];
  __shared__ __align__(16) float Ot[4][32][36];

  bf16x8 qf0, qf1, qf2;
  {
    const short* qp = Qb + ((size_t)h2*S + qbase + ql)*DQK + (h << 3);
    qf0 = *reinterpret_cast<const bf16x8*>(qp);
    qf1 = *reinterpret_cast<const bf16x8*>(qp + 16);
    qf2 = *reinterpret_cast<const bf16x8*>(qp + 32);
  }

  float m = -1e30f, l = 0.f;
  f32x16 o0, o1;
#pragma unroll
  for (int r = 0; r < 16; ++r) { o0[r] = 0.f; o1[r] = 0.f; }

  for (int c = (z << 1); c < (z << 1) + 2; ++c) {
    for (int jr = 0; jr <= jmaxb; jr += 32) {
      const int j0 = c*SPP + jr;
      __syncthreads();
      if (tid < 192) {
        int r = tid / 6, c8 = (tid % 6) << 3;
        *reinterpret_cast<bf16x8*>(&Ks[r][c8]) =
          *reinterpret_cast<const bf16x8*>(Kb + ((size_t)h2*S + j0 + r)*DQK + c8);
      }
      {
        int d = tid >> 2, part = (tid & 3) << 3;
        *reinterpret_cast<bf16x8*>(&Vt[d][part]) =
          *reinterpret_cast<const bf16x8*>(Vg + ((size_t)hh*HD + d)*S + j0 + part);
      }
      __syncthreads();
      if (jr > ri0w) continue;
      const bool diag = (jr == ri0w);

      bf16x8 kf0 = *reinterpret_cast<bf16x8*>(&Ks[ql][(h << 3)]);
      bf16x8 kf1 = *reinterpret_cast<bf16x8*>(&Ks[ql][16 + (h << 3)]);
      bf16x8 kf2 = *reinterpret_cast<bf16x8*>(&Ks[ql][32 + (h << 3)]);
      f32x16 st;
#pragma unroll
      for (int r = 0; r < 16; ++r) st[r] = 0.f;
      st = __builtin_amdgcn_mfma_f32_32x32x16_bf16(kf0, qf0, st, 0, 0, 0);
      st = __builtin_amdgcn_mfma_f32_32x32x16_bf16(kf1, qf1, st, 0, 0, 0);
      st = __builtin_amdgcn_mfma_f32_32x32x16_bf16(kf2, qf2, st, 0, 0, 0);

      if (diag) {
#pragma unroll
        for (int r = 0; r < 16; ++r) {
          int kl = (r & 3) + ((r >> 2) << 3) + (h << 2);
          st[r] = (kl <= ql) ? st[r] * SCALING : -1e30f;
        }
      } else {
#pragma unroll
        for (int r = 0; r < 16; ++r) st[r] *= SCALING;
      }

      float tm = st[0];
#pragma unroll
      for (int r = 1; r < 16; ++r) tm = fmaxf(tm, st[r]);
      tm = fmaxf(tm, __shfl_xor(tm, 32));
      float mnew = fmaxf(m, tm);
      float sc = __expf(m - mnew);
      m = mnew;
      float ps = 0.f;
#pragma unroll
      for (int r = 0; r < 16; ++r) { float p = __expf(st[r] - mnew); st[r] = p; ps += p; }
      ps += __shfl_xor(ps, 32);
      l = l * sc + ps;
#pragma unroll
      for (int r = 0; r < 16; ++r) { o0[r] *= sc; o1[r] *= sc; }

      unsigned A0 = pk2(st[0],  st[1]),  B0 = pk2(st[2],  st[3]);
      unsigned C0 = pk2(st[4],  st[5]),  D0 = pk2(st[6],  st[7]);
      unsigned A1 = pk2(st[8],  st[9]),  B1 = pk2(st[10], st[11]);
      unsigned C1 = pk2(st[12], st[13]), D1 = pk2(st[14], st[15]);
      unsigned xA0 = (unsigned)__shfl_xor((int)A0, 32), xB0 = (unsigned)__shfl_xor((int)B0, 32);
      unsigned xC0 = (unsigned)__shfl_xor((int)C0, 32), xD0 = (unsigned)__shfl_xor((int)D0, 32);
      unsigned xA1 = (unsigned)__shfl_xor((int)A1, 32), xB1 = (unsigned)__shfl_xor((int)B1, 32);
      unsigned xC1 = (unsigned)__shfl_xor((int)C1, 32), xD1 = (unsigned)__shfl_xor((int)D1, 32);
      union { unsigned u[4]; bf16x8 v; } P0, P1;
      P0.u[0] = h ? xC0 : A0;  P0.u[1] = h ? xD0 : B0;
      P0.u[2] = h ? C0 : xA0;  P0.u[3] = h ? D0 : xB0;
      P1.u[0] = h ? xC1 : A1;  P1.u[1] = h ? xD1 : B1;
      P1.u[2] = h ? C1 : xA1;  P1.u[3] = h ? D1 : xB1;

      bf16x8 v00 = *reinterpret_cast<bf16x8*>(&Vt[ql][(h << 3)]);
      bf16x8 v01 = *reinterpret_cast<bf16x8*>(&Vt[ql][16 + (h << 3)]);
      bf16x8 v10 = *reinterpret_cast<bf16x8*>(&Vt[32 + ql][(h << 3)]);
      bf16x8 v11 = *reinterpret_cast<bf16x8*>(&Vt[32 + ql][16 + (h << 3)]);
      o0 = __builtin_amdgcn_mfma_f32_32x32x16_bf16(v00, P0.v, o0, 0, 0, 0);
      o0 = __builtin_amdgcn_mfma_f32_32x32x16_bf16(v01, P1.v, o0, 0, 0, 0);
      o1 = __builtin_amdgcn_mfma_f32_32x32x16_bf16(v10, P0.v, o1, 0, 0, 0);
      o1 = __builtin_amdgcn_mfma_f32_32x32x16_bf16(v11, P1.v, o1, 0, 0, 0);
    }
  }

  // epilogue: two-pass transpose through half-size wave-private LDS
  float* ot = &Ot[w][0][0];
  float* orow;
  if (z == 0) orow = Ob + ((size_t)h2*S + qbase)*HD;
  else orow = (h2 < 16) ? Ob1a + ((size_t)h2*S + qbase)*HD
                        : Ob1b + ((size_t)(h2 - 16)*S + qbase)*HD;
#pragma unroll
  for (int r = 0; r < 16; ++r) {
    int dl = (r & 3) + ((r >> 2) << 3) + (h << 2);
    ot[ql*36 + dl] = o0[r];
  }
#pragma unroll
  for (int it = 0; it < 4; ++it) {   // same-wave LDS: in-order, no barrier
    int idx = lane + (it << 6);
    int row = idx >> 3, c4 = (idx & 7) << 2;
    float4 v = *reinterpret_cast<float4*>(&ot[row*36 + c4]);
    *reinterpret_cast<float4*>(&orow[(size_t)row*HD + c4]) = v;
  }
#pragma unroll
  for (int r = 0; r < 16; ++r) {
    int dl = (r & 3) + ((r >> 2) << 3) + (h << 2);
    ot[ql*36 + dl] = o1[r];
  }
#pragma unroll
  for (int it = 0; it < 4; ++it) {
    int idx = lane + (it << 6);
    int row = idx >> 3, c4 = (idx & 7) << 2;
    float4 v = *reinterpret_cast<float4*>(&ot[row*36 + c4]);
    *reinterpret_cast<float4*>(&orow[(size_t)row*HD + 32 + c4]) = v;
  }
  if (lane < 32) {
    if (z == 0) { rowm[h2*S + qbase + lane] = m; rowl[h2*S + qbase + lane] = l; }
    else        { rm1[h2*S + qbase + lane] = m;  rl1[h2*S + qbase + lane] = l; }
  }
}

// ---------------- merge the two flash partials, normalize ----------------
__global__ __launch_bounds__(256) void merge_flash(float* __restrict__ Ob,
    float* __restrict__ rowm, float* __restrict__ rowl,
    const float* __restrict__ Ob1a, const float* __restrict__ Ob1b,
    const float* __restrict__ rm1, const float* __restrict__ rl1) {
  const int gid = blockIdx.x * 4 + (threadIdx.x >> 6);
  const int d = threadIdx.x & 63;
  const int h2 = gid / S;
  float m0 = rowm[gid], l0 = rowl[gid], m1 = rm1[gid], l1 = rl1[gid];
  float m = fmaxf(m0, m1);
  float w0 = __expf(m0 - m), w1 = __expf(m1 - m);
  float linv = 1.0f / (l0*w0 + l1*w1);
  const float* o1 = (h2 < 16) ? (Ob1a + (size_t)gid*HD)
                              : (Ob1b + ((size_t)gid - (size_t)16*S)*HD);
  float v0 = Ob[(size_t)gid*HD + d];
  float v1 = o1[d];
  Ob[(size_t)gid*HD + d] = (v0*w0 + v1*w1) * linv;
  if (d == 0) { rowm[gid] = m; rowl[gid] = l0*w0 + l1*w1; }
}

// ---------------- colsum via MFMA (bf16 inputs) ----------------
__global__ __launch_bounds__(256) void colsum_mfma(const short* __restrict__ Qb,
    const short* __restrict__ Kb, const float* __restrict__ rowm,
    const float* __restrict__ rowl, float* __restrict__ gcol) {
  const int jt = blockIdx.x;
  const int hh = blockIdx.y, h2 = hh << 1;
  const int cK = jt / 12, jr32 = jt % 12;
  const int jr = jr32 << 5;
  const int j0 = cK*SPP + jr;
  const int tid = threadIdx.x;
  const int w = tid >> 6, lane = tid & 63;
  const int ql = lane & 31, h = lane >> 5;

  bf16x8 kf0, kf1, kf2;
  {
    const short* kp = Kb + ((size_t)h2*S + j0 + ql)*DQK + (h << 3);
    kf0 = *reinterpret_cast<const bf16x8*>(kp);
    kf1 = *reinterpret_cast<const bf16x8*>(kp + 16);
    kf2 = *reinterpret_cast<const bf16x8*>(kp + 32);
  }
  const int nt = 12 - jr32;
  const int T = nt << 2;
  float gs[16];
#pragma unroll
  for (int r = 0; r < 16; ++r) gs[r] = 0.f;

  for (int tt = w; tt < T; tt += 4) {
    int cq = tt / nt, qrem = tt - cq*nt;
    int qi = jr32 + qrem;
    int i0 = cq*SPP + (qi << 5);
    const bool diag = (qrem == 0);
    const short* qp = Qb + ((size_t)h2*S + i0 + ql)*DQK + (h << 3);
    bf16x8 qf0 = *reinterpret_cast<const bf16x8*>(qp);
    bf16x8 qf1 = *reinterpret_cast<const bf16x8*>(qp + 16);
    bf16x8 qf2 = *reinterpret_cast<const bf16x8*>(qp + 32);
    f32x16 st;
#pragma unroll
    for (int r = 0; r < 16; ++r) st[r] = 0.f;
    st = __builtin_amdgcn_mfma_f32_32x32x16_bf16(kf0, qf0, st, 0, 0, 0);
    st = __builtin_amdgcn_mfma_f32_32x32x16_bf16(kf1, qf1, st, 0, 0, 0);
    st = __builtin_amdgcn_mfma_f32_32x32x16_bf16(kf2, qf2, st, 0, 0, 0);
    float Mq = rowm[h2*S + i0 + ql];
    float Lq = 1.0f / rowl[h2*S + i0 + ql];
    if (diag) {
#pragma unroll
      for (int r = 0; r < 16; ++r) {
        int kl = (r & 3) + ((r >> 2) << 3) + (h << 2);
        if (kl <= ql) gs[r] += __expf(st[r]*SCALING - Mq) * Lq;
      }
    } else {
#pragma unroll
      for (int r = 0; r < 16; ++r) gs[r] += __expf(st[r]*SCALING - Mq) * Lq;
    }
  }
  __shared__ float gw[4][32];
#pragma unroll
  for (int r = 0; r < 16; ++r) {
    float v = gs[r];
#pragma unroll
    for (int mm = 1; mm < 32; mm <<= 1) v += __shfl_xor(v, mm, 32);
    if (ql == 0) gw[w][(r & 3) + ((r >> 2) << 3) + (h << 2)] = v;
  }
  __syncthreads();
  if (tid < 32) {
    float s = gw[0][tid] + gw[1][tid] + gw[2][tid] + gw[3][tid];
    gcol[hh*S + j0 + tid] = s * (1.0f / (float)S);
  }
}

// ---------------- Wpre: masked prefix of g-weighted V ----------------
__global__ __launch_bounds__(256) void build_wpre(const float* __restrict__ gcol,
    const float* __restrict__ kvb, float* __restrict__ Wpre) {
  const int hh = blockIdx.x >> 2;
  const int dq = (blockIdx.x & 3) << 4;
  __shared__ float Wt[SPP][16];
  const int tid = threadIdx.x;
  for (int idx = tid; idx < SPP*16; idx += 256) {
    int r = idx >> 4, dd = idx & 15;
    float val = 0.f;
#pragma unroll
    for (int b2 = 0; b2 < 4; ++b2) {
      int j = b2*SPP + r;
      val = fmaf(gcol[hh*S + j], kvb[(size_t)j*2048 + hh*128 + 64 + dq + dd], val);
    }
    Wt[r][dd] = val;
  }
  __syncthreads();
  if (tid < 16) {
    float run = 0.f;
    for (int r = 0; r < SPP; ++r) { run += Wt[r][tid]; Wt[r][tid] = run; }
  }
  __syncthreads();
  for (int idx = tid; idx < SPP*16; idx += 256) {
    int r = idx >> 4, dd = idx & 15;
    Wpre[((size_t)hh*SPP + r)*HD + dq + dd] = Wt[r][dd];
  }
}

// ---------------- combine (diff-attn) + per-head RMSNorm + scrambled reshape ----
__global__ __launch_bounds__(64) void combine_rms(const float* __restrict__ Ob,
    const float* __restrict__ Wpre, const float* __restrict__ lamp,
    const float* __restrict__ anw, float* __restrict__ attno) {
  const int t = blockIdx.x, h = blockIdx.y, d = threadIdx.x;
  const float lam = lamp[0];
  const float o1 = Ob[((size_t)(2*h)*S + t)*HD + d];
  const float o2 = Ob[((size_t)(2*h+1)*S + t)*HD + d];
  const float w3 = Wpre[((size_t)h*SPP + (t % SPP))*HD + d];
  float val = o1 - lam*o2 + lam*w3;
  float ss = val*val;
#pragma unroll
  for (int mm = 1; mm < 64; mm <<= 1) ss += __shfl_xor(ss, mm, 64);
  float scale = rsqrtf(ss * (1.0f/HD) + ATTN_EPS) * anw[d];
  int tn = h*96 + (t >> 4);
  int cn = ((t & 15) << 6) + d;
  attno[(size_t)tn*DM + cn] = val * scale;
}

// =========================== launch ===========================
extern "C" void kernel_launch(void* const* d_in, const int* in_sizes, int n_in,
                              void* d_out, int out_size, void* d_ws, size_t ws_size,
                              hipStream_t stream) {
  (void)in_sizes; (void)n_in; (void)out_size;
  const float* x    = (const float*)d_in[0];
  const float* fc   = (const float*)d_in[1];
  const float* fs   = (const float*)d_in[2];
  const float* n1w  = (const float*)d_in[3];
  const float* n2w  = (const float*)d_in[4];
  const float* kvdw = (const float*)d_in[5];
  const float* qdw  = (const float*)d_in[6];
  const float* kvnw = (const float*)d_in[7];
  const float* qnw  = (const float*)d_in[8];
  const float* kvuw = (const float*)d_in[9];
  const float* quw  = (const float*)d_in[10];
  const float* lq1  = (const float*)d_in[11];
  const float* lk1  = (const float*)d_in[12];
  const float* lq2  = (const float*)d_in[13];
  const float* lk2  = (const float*)d_in[14];
  const float* anw  = (const float*)d_in[15];
  const float* ow   = (const float*)d_in[16];
  const float* ffiw = (const float*)d_in[17];
  const float* ffow = (const float*)d_in[18];
  float* out = (float*)d_out;
  float* ws  = (float*)d_ws;

  float* xin   = ws;
  float* ckv   = xin   + (size_t)S*DM;
  float* qmid  = ckv   + (size_t)S*288;
  float* kvb   = qmid  + (size_t)S*QC;
  float* qf    = kvb   + (size_t)S*2048;
  float* Qb    = qf    + (size_t)S*1536;
  float* Kb    = Qb    + (size_t)H2N*S*DQK;
  float* Obuf  = Kb    + (size_t)H2N*S*DQK;
  float* rowm  = Obuf  + (size_t)H2N*S*HD;
  float* rowl  = rowm  + (size_t)H2N*S;
  float* gcol  = rowl  + (size_t)H2N*S;
  float* Wpre  = gcol  + (size_t)NH*S;
  float* attno = Wpre  + (size_t)NH*SPP*HD;
  float* lamp  = attno + (size_t)S*DM;
  short* fbufs = (short*)kvb;     // bf16 FFN activation overlays kv region
  // flash z=1 partials (dead windows): xin (h2<16), qf (h2>=16)
  float* Ob1a = xin;
  float* Ob1b = qf;
  float* rm1  = qf + (size_t)16*S*HD;
  float* rl1  = rm1 + (size_t)H2N*S;
  // bf16 attention operand views (halves of the old fp32 Qb/Kb regions):
  short* Qb_bf = (short*)Qb;                      // 2359296 shorts
  short* Kb_bf = (short*)Kb;
  short* Vt_bf = (short*)Qb + 2359296;            // upper half of Qb region
  // bf16 weight copies in dead regions:
  short* kvdw_bf = (short*)attno;                 // early weights -> attno (dead till combine)
  short* qdw_bf  = kvdw_bf + 294912;
  short* kvuw_bf = qdw_bf  + 393216;
  short* quw_bf  = kvuw_bf + 524288;
  short* ffiw_bf = (short*)Qb;                    // Qb+Kb dead after colsum_mfma
  short* ow_bf   = ffiw_bf + 8388608;
  short* ffow_bf = (short*)Obuf;                  // Obuf dead after combine_rms
  if (ws_size < (size_t)18063376 * sizeof(float)) return;

  cvt_w4<<<880, 256, 0, stream>>>(kvdw, 294912, qdw, 393216, kvuw, 524288, quw, 589824, kvdw_bf);
  rmsnorm_k<<<S, 256, 0, stream>>>(x, n1w, xin, DM, DM, DM, EPS_RMS);
  { dim3 g(5, 24);  mgemm_nt<0,0><<<g, 256, 0, stream>>>(xin, kvdw_bf, nullptr, ckv, S, 288, DM, DM, DM, 288); }
  { dim3 g(6, 24);  mgemm_nt<0,0><<<g, 256, 0, stream>>>(xin, qdw_bf,  nullptr, qmid, S, QC, DM, DM, DM, QC); }
  rmsnorm_k<<<S, 256, 0, stream>>>(ckv,  kvnw, ckv,  KVC, 288, 288, EPS_RMS);
  rmsnorm_k<<<S, 256, 0, stream>>>(qmid, qnw,  qmid, QC,  QC,  QC,  EPS_RMS);
  { dim3 g(32, 24); mgemm_nt<0,0><<<g, 256, 0, stream>>>(ckv,  kvuw_bf, nullptr, kvb, S, 2048, KVC, 288, KVC, 2048); }
  { dim3 g(24, 24); mgemm_nt<0,0><<<g, 256, 0, stream>>>(qmid, quw_bf,  nullptr, qf,  S, 1536, QC,  QC,  QC,  1536); }
  { dim3 g(6, 32);  build_qk<<<g, 256, 0, stream>>>(qf, kvb, ckv, fc, fs, Qb_bf, Kb_bf); }
  { dim3 g(16, 12); vt_build<<<g, 256, 0, stream>>>(kvb, Vt_bf); }
  compute_lam<<<1, 32, 0, stream>>>(lq1, lk1, lq2, lk2, lamp);
  { dim3 g(12, 32, 2); flash_mfma<<<g, 256, 0, stream>>>(Qb_bf, Kb_bf, Vt_bf, Obuf, rowm, rowl,
                                                         Ob1a, Ob1b, rm1, rl1); }
  merge_flash<<<(H2N*S)/4, 256, 0, stream>>>(Obuf, rowm, rowl, Ob1a, Ob1b, rm1, rl1);
  { dim3 g(48, 16); colsum_mfma<<<g, 256, 0, stream>>>(Qb_bf, Kb_bf, rowm, rowl, gcol); }
  cvt_w4<<<4608, 256, 0, stream>>>(ffiw, 8388608, ow, 1048576, nullptr, 0, nullptr, 0, ffiw_bf);
  build_wpre<<<64, 256, 0, stream>>>(gcol, kvb, Wpre);
  { dim3 g(S, 16);  combine_rms<<<g, 64, 0, stream>>>(Obuf, Wpre, lamp, anw, attno); }
  cvt_w4<<<2048, 256, 0, stream>>>(ffow, 4194304, nullptr, 0, nullptr, 0, nullptr, 0, ffow_bf);
  { dim3 g(16, 24); mgemm_nt<1,0><<<g, 256, 0, stream>>>(attno, ow_bf, x, out, S, DM, DM, DM, DM, DM); }
  rmsnorm_k<<<S, 256, 0, stream>>>(out, n2w, xin, DM, DM, DM, EPS_RMS);
  { dim3 g(64, 24); mgemm_glu<<<g, 256, 0, stream>>>(xin, ffiw_bf, fbufs, S, DFF, DM, DM, DM, DFF); }
  { dim3 g(16, 24); mgemm_nt<1,1><<<g, 256, 0, stream>>>(fbufs, ffow_bf, out, out, S, DM, DFF, DFF, DFF, DM); }
}

// Round 10
// 276.726 us; speedup vs baseline: 8.5791x; 1.0244x over previous
//
#include <hip/hip_runtime.h>
#include <math.h>

#define S     1536
#define DM    1024
#define NH    16
#define H2N   32
#define HD    64
#define KVC   256
#define QC    384
#define DFF   4096
#define SPP   384
#define DQK   48
#define EPS_RMS  1.1920929e-07f
#define ATTN_EPS 1e-5f
#define SCALING  0.14433756729740643f   /* 48^-0.5 */

typedef float f32x4 __attribute__((ext_vector_type(4)));
typedef float f32x16 __attribute__((ext_vector_type(16)));
typedef short bf16x8 __attribute__((ext_vector_type(8)));

__device__ __forceinline__ short cvt_bf16(float f) {      // scalar fallback (epilogues)
  union { float f; unsigned u; } x; x.f = f;
  unsigned r = x.u + 0x7FFFu + ((x.u >> 16) & 1u);
  return (short)(r >> 16);
}
__device__ __forceinline__ unsigned pk2(float a, float b) { // HW RNE pack
  unsigned r;
  asm("v_cvt_pk_bf16_f32 %0, %1, %2" : "=v"(r) : "v"(a), "v"(b));
  return r;
}
__device__ __forceinline__ bf16x8 cvt8(float4 a, float4 b) {
  union { unsigned u[4]; bf16x8 v; } r;
  r.u[0] = pk2(a.x, a.y); r.u[1] = pk2(a.z, a.w);
  r.u[2] = pk2(b.x, b.y); r.u[3] = pk2(b.z, b.w);
  return r.v;
}

// ---------------- weight fp32 -> bf16 (up to 4 segments, sizes %2048==0) ----
__global__ __launch_bounds__(256) void cvt_w4(const float* __restrict__ s0, int n0,
    const float* __restrict__ s1, int n1, const float* __restrict__ s2, int n2,
    const float* __restrict__ s3, int n3, short* __restrict__ dst) {
  long base = (long)blockIdx.x * 2048 + (long)threadIdx.x * 8;
  const float* src; long off;
  if (base < n0) { src = s0; off = base; }
  else if (base < (long)n0 + n1) { src = s1; off = base - n0; }
  else if (base < (long)n0 + n1 + n2) { src = s2; off = base - n0 - n1; }
  else { src = s3; off = base - n0 - n1 - n2; }
  float4 a = *reinterpret_cast<const float4*>(src + off);
  float4 b = *reinterpret_cast<const float4*>(src + off + 4);
  *reinterpret_cast<bf16x8*>(dst + base) = cvt8(a, b);
}

// ---------------- RMSNorm -> fp32 out ----------------
__global__ __launch_bounds__(256) void rmsnorm_k(const float* __restrict__ in,
    const float* __restrict__ w, float* __restrict__ out,
    int cols, int ldin, int ldout, float eps) {
  const int row = blockIdx.x;
  const float* xr = in + (size_t)row * ldin;
  float* yr = out + (size_t)row * ldout;
  const int tid = threadIdx.x;
  float ss = 0.f;
  for (int c = tid << 2; c < cols; c += 1024) {
    float4 v = *reinterpret_cast<const float4*>(xr + c);
    ss += v.x*v.x + v.y*v.y + v.z*v.z + v.w*v.w;
  }
#pragma unroll
  for (int mm = 1; mm < 64; mm <<= 1) ss += __shfl_xor(ss, mm, 64);
  __shared__ float red[4];
  if ((tid & 63) == 0) red[tid >> 6] = ss;
  __syncthreads();
  float tot = red[0] + red[1] + red[2] + red[3];
  float scale = rsqrtf(tot / (float)cols + eps);
  for (int c = tid << 2; c < cols; c += 1024) {
    float4 v = *reinterpret_cast<const float4*>(xr + c);
    float4 wv = *reinterpret_cast<const float4*>(w + c);
    float4 ov = make_float4(v.x*scale*wv.x, v.y*scale*wv.y, v.z*scale*wv.z, v.w*scale*wv.w);
    *reinterpret_cast<float4*>(yr + c) = ov;
  }
}

// ---------------- RMSNorm -> bf16 out ----------------
__global__ __launch_bounds__(256) void rmsnorm_bf(const float* __restrict__ in,
    const float* __restrict__ w, short* __restrict__ out,
    int cols, int ldin, int ldout, float eps) {
  const int row = blockIdx.x;
  const float* xr = in + (size_t)row * ldin;
  short* yr = out + (size_t)row * ldout;
  const int tid = threadIdx.x;
  float ss = 0.f;
  for (int c = tid << 2; c < cols; c += 1024) {
    float4 v = *reinterpret_cast<const float4*>(xr + c);
    ss += v.x*v.x + v.y*v.y + v.z*v.z + v.w*v.w;
  }
#pragma unroll
  for (int mm = 1; mm < 64; mm <<= 1) ss += __shfl_xor(ss, mm, 64);
  __shared__ float red[4];
  if ((tid & 63) == 0) red[tid >> 6] = ss;
  __syncthreads();
  float tot = red[0] + red[1] + red[2] + red[3];
  float scale = rsqrtf(tot / (float)cols + eps);
  for (int c = tid << 2; c < cols; c += 1024) {
    float4 v = *reinterpret_cast<const float4*>(xr + c);
    float4 wv = *reinterpret_cast<const float4*>(w + c);
    uint2 p;
    p.x = pk2(v.x*scale*wv.x, v.y*scale*wv.y);
    p.y = pk2(v.z*scale*wv.z, v.w*scale*wv.w);
    *reinterpret_cast<uint2*>(yr + c) = p;
  }
}

// ------------- bf16 MFMA GEMM, BK=64, register-prefetch; A,B bf16 ----------
template<int ADD>
__global__ __launch_bounds__(256) void mgemm_nt(const short* __restrict__ A,
    const short* __restrict__ B, const float* __restrict__ src, float* __restrict__ C,
    int M, int N, int K, int lda, int ldb, int ldc) {
  __shared__ short As[64][72];
  __shared__ short Bs[64][72];
  const int bm = blockIdx.y * 64, bn = blockIdx.x * 64;
  const int tid = threadIdx.x;
  const int w = tid >> 6, lane = tid & 63;
  const int wr = (w >> 1) << 5, wc = (w & 1) << 5;
  const int srow = tid >> 2, sk = (tid & 3) << 4;
  const int lrow = lane & 15, lk8 = (lane >> 4) << 3;
  const int arow = bm + srow, brow = bn + srow;
  const bool bvalid = brow < N;
  f32x4 acc[2][2];
#pragma unroll
  for (int i = 0; i < 2; ++i)
#pragma unroll
    for (int j = 0; j < 2; ++j) acc[i][j] = (f32x4){0.f, 0.f, 0.f, 0.f};

  bf16x8 rah0, rah1, rbh0, rbh1;
  {
    const short* ap = A + (size_t)arow * lda + sk;
    rah0 = *reinterpret_cast<const bf16x8*>(ap);
    rah1 = *reinterpret_cast<const bf16x8*>(ap + 8);
  }
  rbh0 = (bf16x8){0,0,0,0,0,0,0,0}; rbh1 = rbh0;
  if (bvalid) {
    const short* bp = B + (size_t)brow * ldb + sk;
    rbh0 = *reinterpret_cast<const bf16x8*>(bp);
    rbh1 = *reinterpret_cast<const bf16x8*>(bp + 8);
  }

  for (int k0 = 0; k0 < K; k0 += 64) {
    bf16x8 va0 = rah0, va1 = rah1, vb0 = rbh0, vb1 = rbh1;
    __syncthreads();
    *reinterpret_cast<bf16x8*>(&As[srow][sk])     = va0;
    *reinterpret_cast<bf16x8*>(&As[srow][sk + 8]) = va1;
    *reinterpret_cast<bf16x8*>(&Bs[srow][sk])     = vb0;
    *reinterpret_cast<bf16x8*>(&Bs[srow][sk + 8]) = vb1;
    __syncthreads();
    const int kn = k0 + 64;
    if (kn < K) {
      const short* ap = A + (size_t)arow * lda + kn + sk;
      rah0 = *reinterpret_cast<const bf16x8*>(ap);
      rah1 = *reinterpret_cast<const bf16x8*>(ap + 8);
      if (bvalid) {
        const short* bp = B + (size_t)brow * ldb + kn + sk;
        rbh0 = *reinterpret_cast<const bf16x8*>(bp);
        rbh1 = *reinterpret_cast<const bf16x8*>(bp + 8);
      }
    }
#pragma unroll
    for (int kk = 0; kk < 2; ++kk) {
      bf16x8 af0 = *reinterpret_cast<bf16x8*>(&As[wr + lrow][(kk << 5) + lk8]);
      bf16x8 af1 = *reinterpret_cast<bf16x8*>(&As[wr + 16 + lrow][(kk << 5) + lk8]);
      bf16x8 bf0 = *reinterpret_cast<bf16x8*>(&Bs[wc + lrow][(kk << 5) + lk8]);
      bf16x8 bf1 = *reinterpret_cast<bf16x8*>(&Bs[wc + 16 + lrow][(kk << 5) + lk8]);
      acc[0][0] = __builtin_amdgcn_mfma_f32_16x16x32_bf16(af0, bf0, acc[0][0], 0, 0, 0);
      acc[0][1] = __builtin_amdgcn_mfma_f32_16x16x32_bf16(af0, bf1, acc[0][1], 0, 0, 0);
      acc[1][0] = __builtin_amdgcn_mfma_f32_16x16x32_bf16(af1, bf0, acc[1][0], 0, 0, 0);
      acc[1][1] = __builtin_amdgcn_mfma_f32_16x16x32_bf16(af1, bf1, acc[1][1], 0, 0, 0);
    }
  }
  const int crow0 = bm + wr + ((lane >> 4) << 2);
  const int ccol0 = bn + wc + lrow;
#pragma unroll
  for (int mi = 0; mi < 2; ++mi)
#pragma unroll
    for (int ni = 0; ni < 2; ++ni) {
      int colc = ccol0 + (ni << 4);
      if (colc < N) {
#pragma unroll
        for (int r = 0; r < 4; ++r) {
          int rowc = crow0 + (mi << 4) + r;
          float v = acc[mi][ni][r];
          if (ADD) v += src[(size_t)rowc * ldc + colc];
          C[(size_t)rowc * ldc + colc] = v;
        }
      }
    }
}

// ------------- 128x128 bf16 SwiGLU GEMM: per-wave 64x64 u AND v -------------
// C = (A@Bu^T) * silu(A@Bv^T), all bf16 in, bf16 out. M%128==0, N%128==0.
__global__ __launch_bounds__(256) void mgemm_glu(const short* __restrict__ A,
    const short* __restrict__ Bw, short* __restrict__ C,
    int M, int N, int K, int lda, int ldb, int ldc) {
  __shared__ short As[128][72];
  __shared__ short Bu[128][72];
  __shared__ short Bv[128][72];
  const int bm = blockIdx.y * 128, bn = blockIdx.x * 128;
  const int tid = threadIdx.x;
  const int w = tid >> 6, lane = tid & 63;
  const int wr = (w >> 1) << 6, wc = (w & 1) << 6;
  const int srow = tid >> 1, sc = (tid & 1) << 5;
  const int lrow = lane & 15, lk8 = (lane >> 4) << 3;
  const int arow = bm + srow, brow = bn + srow;
  f32x4 au[4][4], av[4][4];
#pragma unroll
  for (int i = 0; i < 4; ++i)
#pragma unroll
    for (int j = 0; j < 4; ++j) {
      au[i][j] = (f32x4){0.f, 0.f, 0.f, 0.f};
      av[i][j] = (f32x4){0.f, 0.f, 0.f, 0.f};
    }
  bf16x8 ra[4], ru[4], rv[4];
  {
    const short* ap = A + (size_t)arow * lda + sc;
    const short* up = Bw + (size_t)brow * ldb + sc;
    const short* vp = Bw + (size_t)(N + brow) * ldb + sc;
#pragma unroll
    for (int e = 0; e < 4; ++e) {
      ra[e] = *reinterpret_cast<const bf16x8*>(ap + (e << 3));
      ru[e] = *reinterpret_cast<const bf16x8*>(up + (e << 3));
      rv[e] = *reinterpret_cast<const bf16x8*>(vp + (e << 3));
    }
  }
  for (int k0 = 0; k0 < K; k0 += 64) {
    __syncthreads();
#pragma unroll
    for (int e = 0; e < 4; ++e) {
      *reinterpret_cast<bf16x8*>(&As[srow][sc + (e << 3)]) = ra[e];
      *reinterpret_cast<bf16x8*>(&Bu[srow][sc + (e << 3)]) = ru[e];
      *reinterpret_cast<bf16x8*>(&Bv[srow][sc + (e << 3)]) = rv[e];
    }
    __syncthreads();
    const int kn = k0 + 64;
    if (kn < K) {
      const short* ap = A + (size_t)arow * lda + kn + sc;
      const short* up = Bw + (size_t)brow * ldb + kn + sc;
      const short* vp = Bw + (size_t)(N + brow) * ldb + kn + sc;
#pragma unroll
      for (int e = 0; e < 4; ++e) {
        ra[e] = *reinterpret_cast<const bf16x8*>(ap + (e << 3));
        ru[e] = *reinterpret_cast<const bf16x8*>(up + (e << 3));
        rv[e] = *reinterpret_cast<const bf16x8*>(vp + (e << 3));
      }
    }
#pragma unroll
    for (int kk = 0; kk < 2; ++kk) {
      bf16x8 af[4], bfr[4];
#pragma unroll
      for (int i = 0; i < 4; ++i)
        af[i] = *reinterpret_cast<bf16x8*>(&As[wr + (i << 4) + lrow][(kk << 5) + lk8]);
#pragma unroll
      for (int j = 0; j < 4; ++j)
        bfr[j] = *reinterpret_cast<bf16x8*>(&Bu[wc + (j << 4) + lrow][(kk << 5) + lk8]);
#pragma unroll
      for (int i = 0; i < 4; ++i)
#pragma unroll
        for (int j = 0; j < 4; ++j)
          au[i][j] = __builtin_amdgcn_mfma_f32_16x16x32_bf16(af[i], bfr[j], au[i][j], 0, 0, 0);
#pragma unroll
      for (int j = 0; j < 4; ++j)
        bfr[j] = *reinterpret_cast<bf16x8*>(&Bv[wc + (j << 4) + lrow][(kk << 5) + lk8]);
#pragma unroll
      for (int i = 0; i < 4; ++i)
#pragma unroll
        for (int j = 0; j < 4; ++j)
          av[i][j] = __builtin_amdgcn_mfma_f32_16x16x32_bf16(af[i], bfr[j], av[i][j], 0, 0, 0);
    }
  }
  const int crow0 = bm + wr + ((lane >> 4) << 2);
  const int ccol0 = bn + wc + lrow;
#pragma unroll
  for (int mi = 0; mi < 4; ++mi)
#pragma unroll
    for (int ni = 0; ni < 4; ++ni) {
      int colc = ccol0 + (ni << 4);
#pragma unroll
      for (int r = 0; r < 4; ++r) {
        int rowc = crow0 + (mi << 4) + r;
        float uu = au[mi][ni][r], vg = av[mi][ni][r];
        float sig = 1.0f / (1.0f + __expf(-vg));
        C[(size_t)rowc * ldc + colc] = cvt_bf16(uu * vg * sig);
      }
    }
}

// ---------------- Build Q/K (split heads + RoPE) -> bf16 ----------------
__global__ __launch_bounds__(256) void build_qk(const float* __restrict__ qf,
    const float* __restrict__ kvb, const float* __restrict__ ckv,
    const float* __restrict__ fc, const float* __restrict__ fs,
    short* __restrict__ Qb, short* __restrict__ Kb) {
  int t = blockIdx.x * 256 + threadIdx.x;
  int h2 = blockIdx.y;
  if (t >= S) return;
  int hh = h2 >> 1, par = h2 & 1;
  const float* qrow = qf + (size_t)t*1536 + hh*96;
  const float* krow = kvb + (size_t)t*2048 + hh*128;
  unsigned qu[24], ku[24];
#pragma unroll
  for (int xq = 0; xq < 8; ++xq) {
    float4 qv = *reinterpret_cast<const float4*>(qrow + par*32 + (xq<<2));
    float4 kv = *reinterpret_cast<const float4*>(krow + par*32 + (xq<<2));
    qu[xq*2]   = pk2(qv.x, qv.y); qu[xq*2+1] = pk2(qv.z, qv.w);
    ku[xq*2]   = pk2(kv.x, kv.y); ku[xq*2+1] = pk2(kv.z, kv.w);
  }
  int p = t >> 2;
  const float* qr = qrow + 64 + par*16;
  const float* kr = ckv + (size_t)t*288 + 256 + par*16;
#pragma unroll
  for (int mq = 0; mq < 8; ++mq) {
    float c = 1.f, sn = 0.f;
    if (p > 0) { c = fc[(p-1)*8 + mq]; sn = fs[(p-1)*8 + mq]; }
    float q0 = qr[2*mq], q1 = qr[2*mq+1];
    qu[16 + mq] = pk2(q0*c - q1*sn, q0*sn + q1*c);
    float k0 = kr[2*mq], k1 = kr[2*mq+1];
    ku[16 + mq] = pk2(k0*c - k1*sn, k0*sn + k1*c);
  }
  unsigned* qo = (unsigned*)(Qb + ((size_t)h2*S + t)*DQK);
  unsigned* ko = (unsigned*)(Kb + ((size_t)h2*S + t)*DQK);
#pragma unroll
  for (int e = 0; e < 6; ++e) {
    *reinterpret_cast<uint4*>(qo + (e<<2)) = make_uint4(qu[e*4], qu[e*4+1], qu[e*4+2], qu[e*4+3]);
    *reinterpret_cast<uint4*>(ko + (e<<2)) = make_uint4(ku[e*4], ku[e*4+1], ku[e*4+2], ku[e*4+3]);
  }
}

// ---------------- V transpose to bf16: Vt[hh][d][t] ----------------
__global__ __launch_bounds__(256) void vt_build(const float* __restrict__ kvb,
    short* __restrict__ Vt) {
  const int hh = blockIdx.x;
  const int t0 = blockIdx.y << 7;
  __shared__ short Ts[128][74];
  const int tl = threadIdx.x >> 3, dp = (threadIdx.x & 7) << 3;
#pragma unroll
  for (int pass = 0; pass < 4; ++pass) {
    int t = t0 + (pass << 5) + tl;
    const float* vp = kvb + (size_t)t*2048 + hh*128 + 64 + dp;
    float4 a = *reinterpret_cast<const float4*>(vp);
    float4 b = *reinterpret_cast<const float4*>(vp + 4);
    *reinterpret_cast<bf16x8*>(&Ts[(pass << 5) + tl][dp]) = cvt8(a, b);
  }
  __syncthreads();
  for (int idx = threadIdx.x; idx < 1024; idx += 256) {
    int d = idx >> 4, tseg = (idx & 15) << 3;
    bf16x8 v;
#pragma unroll
    for (int e = 0; e < 8; ++e) v[e] = Ts[tseg + e][d];
    *reinterpret_cast<bf16x8*>(Vt + ((size_t)hh*HD + d)*S + t0 + tseg) = v;
  }
}

// ---------------- lambda scalar ----------------
__global__ void compute_lam(const float* __restrict__ lq1, const float* __restrict__ lk1,
                            const float* __restrict__ lq2, const float* __restrict__ lk2,
                            float* __restrict__ lamp) {
  int t = threadIdx.x;
  float a = lq1[t]*lk1[t];
  float b = lq2[t]*lk2[t];
#pragma unroll
  for (int mm = 1; mm < 32; mm <<= 1) { a += __shfl_xor(a, mm, 32); b += __shfl_xor(b, mm, 32); }
  if (t == 0) lamp[0] = expf(a) - expf(b) + 0.2f;
}

// ---------------- MFMA flash attention (bf16 inputs, split-j) ----------
__global__ __launch_bounds__(256) void flash_mfma(const short* __restrict__ Qb,
    const short* __restrict__ Kb, const short* __restrict__ Vg,
    float* __restrict__ Ob, float* __restrict__ rowm, float* __restrict__ rowl,
    float* __restrict__ Ob1a, float* __restrict__ Ob1b,
    float* __restrict__ rm1, float* __restrict__ rl1) {
  const int h2 = blockIdx.y;
  const int hh = h2 >> 1;
  const int i0 = blockIdx.x << 7;
  const int z  = blockIdx.z;
  const int tid = threadIdx.x;
  const int w = tid >> 6, lane = tid & 63;
  const int ql = lane & 31, h = lane >> 5;
  const int qbase = i0 + (w << 5);
  const int rbase = i0 % SPP;
  const int ri0w = rbase + (w << 5);
  const int jmaxb = rbase + 96;

  __shared__ __align__(16) short Ks[32][72];
  __shared__ __align__(16) short Vt[64][40];
  __shared__ __align__(16) float Ot[4][32][36];

  bf16x8 qf0, qf1, qf2;
  {
    const short* qp = Qb + ((size_t)h2*S + qbase + ql)*DQK + (h << 3);
    qf0 = *reinterpret_cast<const bf16x8*>(qp);
    qf1 = *reinterpret_cast<const bf16x8*>(qp + 16);
    qf2 = *reinterpret_cast<const bf16x8*>(qp + 32);
  }

  float m = -1e30f, l = 0.f;
  f32x16 o0, o1;
#pragma unroll
  for (int r = 0; r < 16; ++r) { o0[r] = 0.f; o1[r] = 0.f; }

  for (int c = (z << 1); c < (z << 1) + 2; ++c) {
    for (int jr = 0; jr <= jmaxb; jr += 32) {
      const int j0 = c*SPP + jr;
      __syncthreads();
      if (tid < 192) {
        int r = tid / 6, c8 = (tid % 6) << 3;
        *reinterpret_cast<bf16x8*>(&Ks[r][c8]) =
          *reinterpret_cast<const bf16x8*>(Kb + ((size_t)h2*S + j0 + r)*DQK + c8);
      }
      {
        int d = tid >> 2, part = (tid & 3) << 3;
        *reinterpret_cast<bf16x8*>(&Vt[d][part]) =
          *reinterpret_cast<const bf16x8*>(Vg + ((size_t)hh*HD + d)*S + j0 + part);
      }
      __syncthreads();
      if (jr > ri0w) continue;
      const bool diag = (jr == ri0w);

      bf16x8 kf0 = *reinterpret_cast<bf16x8*>(&Ks[ql][(h << 3)]);
      bf16x8 kf1 = *reinterpret_cast<bf16x8*>(&Ks[ql][16 + (h << 3)]);
      bf16x8 kf2 = *reinterpret_cast<bf16x8*>(&Ks[ql][32 + (h << 3)]);
      f32x16 st;
#pragma unroll
      for (int r = 0; r < 16; ++r) st[r] = 0.f;
      st = __builtin_amdgcn_mfma_f32_32x32x16_bf16(kf0, qf0, st, 0, 0, 0);
      st = __builtin_amdgcn_mfma_f32_32x32x16_bf16(kf1, qf1, st, 0, 0, 0);
      st = __builtin_amdgcn_mfma_f32_32x32x16_bf16(kf2, qf2, st, 0, 0, 0);

      if (diag) {
#pragma unroll
        for (int r = 0; r < 16; ++r) {
          int kl = (r & 3) + ((r >> 2) << 3) + (h << 2);
          st[r] = (kl <= ql) ? st[r] * SCALING : -1e30f;
        }
      } else {
#pragma unroll
        for (int r = 0; r < 16; ++r) st[r] *= SCALING;
      }

      float tm = st[0];
#pragma unroll
      for (int r = 1; r < 16; ++r) tm = fmaxf(tm, st[r]);
      tm = fmaxf(tm, __shfl_xor(tm, 32));
      float mnew = fmaxf(m, tm);
      float sc = __expf(m - mnew);
      m = mnew;
      float ps = 0.f;
#pragma unroll
      for (int r = 0; r < 16; ++r) { float p = __expf(st[r] - mnew); st[r] = p; ps += p; }
      ps += __shfl_xor(ps, 32);
      l = l * sc + ps;
#pragma unroll
      for (int r = 0; r < 16; ++r) { o0[r] *= sc; o1[r] *= sc; }

      unsigned A0 = pk2(st[0],  st[1]),  B0 = pk2(st[2],  st[3]);
      unsigned C0 = pk2(st[4],  st[5]),  D0 = pk2(st[6],  st[7]);
      unsigned A1 = pk2(st[8],  st[9]),  B1 = pk2(st[10], st[11]);
      unsigned C1 = pk2(st[12], st[13]), D1 = pk2(st[14], st[15]);
      unsigned xA0 = (unsigned)__shfl_xor((int)A0, 32), xB0 = (unsigned)__shfl_xor((int)B0, 32);
      unsigned xC0 = (unsigned)__shfl_xor((int)C0, 32), xD0 = (unsigned)__shfl_xor((int)D0, 32);
      unsigned xA1 = (unsigned)__shfl_xor((int)A1, 32), xB1 = (unsigned)__shfl_xor((int)B1, 32);
      unsigned xC1 = (unsigned)__shfl_xor((int)C1, 32), xD1 = (unsigned)__shfl_xor((int)D1, 32);
      union { unsigned u[4]; bf16x8 v; } P0, P1;
      P0.u[0] = h ? xC0 : A0;  P0.u[1] = h ? xD0 : B0;
      P0.u[2] = h ? C0 : xA0;  P0.u[3] = h ? D0 : xB0;
      P1.u[0] = h ? xC1 : A1;  P1.u[1] = h ? xD1 : B1;
      P1.u[2] = h ? C1 : xA1;  P1.u[3] = h ? D1 : xB1;

      bf16x8 v00 = *reinterpret_cast<bf16x8*>(&Vt[ql][(h << 3)]);
      bf16x8 v01 = *reinterpret_cast<bf16x8*>(&Vt[ql][16 + (h << 3)]);
      bf16x8 v10 = *reinterpret_cast<bf16x8*>(&Vt[32 + ql][(h << 3)]);
      bf16x8 v11 = *reinterpret_cast<bf16x8*>(&Vt[32 + ql][16 + (h << 3)]);
      o0 = __builtin_amdgcn_mfma_f32_32x32x16_bf16(v00, P0.v, o0, 0, 0, 0);
      o0 = __builtin_amdgcn_mfma_f32_32x32x16_bf16(v01, P1.v, o0, 0, 0, 0);
      o1 = __builtin_amdgcn_mfma_f32_32x32x16_bf16(v10, P0.v, o1, 0, 0, 0);
      o1 = __builtin_amdgcn_mfma_f32_32x32x16_bf16(v11, P1.v, o1, 0, 0, 0);
    }
  }

  // epilogue: two-pass transpose through half-size wave-private LDS
  float* ot = &Ot[w][0][0];
  float* orow;
  if (z == 0) orow = Ob + ((size_t)h2*S + qbase)*HD;
  else orow = (h2 < 16) ? Ob1a + ((size_t)h2*S + qbase)*HD
                        : Ob1b + ((size_t)(h2 - 16)*S + qbase)*HD;
#pragma unroll
  for (int r = 0; r < 16; ++r) {
    int dl = (r & 3) + ((r >> 2) << 3) + (h << 2);
    ot[ql*36 + dl] = o0[r];
  }
#pragma unroll
  for (int it = 0; it < 4; ++it) {   // same-wave LDS: in-order, no barrier
    int idx = lane + (it << 6);
    int row = idx >> 3, c4 = (idx & 7) << 2;
    float4 v = *reinterpret_cast<float4*>(&ot[row*36 + c4]);
    *reinterpret_cast<float4*>(&orow[(size_t)row*HD + c4]) = v;
  }
#pragma unroll
  for (int r = 0; r < 16; ++r) {
    int dl = (r & 3) + ((r >> 2) << 3) + (h << 2);
    ot[ql*36 + dl] = o1[r];
  }
#pragma unroll
  for (int it = 0; it < 4; ++it) {
    int idx = lane + (it << 6);
    int row = idx >> 3, c4 = (idx & 7) << 2;
    float4 v = *reinterpret_cast<float4*>(&ot[row*36 + c4]);
    *reinterpret_cast<float4*>(&orow[(size_t)row*HD + 32 + c4]) = v;
  }
  if (lane < 32) {
    if (z == 0) { rowm[h2*S + qbase + lane] = m; rowl[h2*S + qbase + lane] = l; }
    else        { rm1[h2*S + qbase + lane] = m;  rl1[h2*S + qbase + lane] = l; }
  }
}

// ---------------- merge the two flash partials, normalize ----------------
__global__ __launch_bounds__(256) void merge_flash(float* __restrict__ Ob,
    float* __restrict__ rowm, float* __restrict__ rowl,
    const float* __restrict__ Ob1a, const float* __restrict__ Ob1b,
    const float* __restrict__ rm1, const float* __restrict__ rl1) {
  const int gid = blockIdx.x * 4 + (threadIdx.x >> 6);
  const int d = threadIdx.x & 63;
  const int h2 = gid / S;
  float m0 = rowm[gid], l0 = rowl[gid], m1 = rm1[gid], l1 = rl1[gid];
  float m = fmaxf(m0, m1);
  float w0 = __expf(m0 - m), w1 = __expf(m1 - m);
  float linv = 1.0f / (l0*w0 + l1*w1);
  const float* o1 = (h2 < 16) ? (Ob1a + (size_t)gid*HD)
                              : (Ob1b + ((size_t)gid - (size_t)16*S)*HD);
  float v0 = Ob[(size_t)gid*HD + d];
  float v1 = o1[d];
  Ob[(size_t)gid*HD + d] = (v0*w0 + v1*w1) * linv;
  if (d == 0) { rowm[gid] = m; rowl[gid] = l0*w0 + l1*w1; }
}

// ---------------- colsum via MFMA (bf16 inputs) ----------------
__global__ __launch_bounds__(256) void colsum_mfma(const short* __restrict__ Qb,
    const short* __restrict__ Kb, const float* __restrict__ rowm,
    const float* __restrict__ rowl, float* __restrict__ gcol) {
  const int jt = blockIdx.x;
  const int hh = blockIdx.y, h2 = hh << 1;
  const int cK = jt / 12, jr32 = jt % 12;
  const int jr = jr32 << 5;
  const int j0 = cK*SPP + jr;
  const int tid = threadIdx.x;
  const int w = tid >> 6, lane = tid & 63;
  const int ql = lane & 31, h = lane >> 5;

  bf16x8 kf0, kf1, kf2;
  {
    const short* kp = Kb + ((size_t)h2*S + j0 + ql)*DQK + (h << 3);
    kf0 = *reinterpret_cast<const bf16x8*>(kp);
    kf1 = *reinterpret_cast<const bf16x8*>(kp + 16);
    kf2 = *reinterpret_cast<const bf16x8*>(kp + 32);
  }
  const int nt = 12 - jr32;
  const int T = nt << 2;
  float gs[16];
#pragma unroll
  for (int r = 0; r < 16; ++r) gs[r] = 0.f;

  for (int tt = w; tt < T; tt += 4) {
    int cq = tt / nt, qrem = tt - cq*nt;
    int qi = jr32 + qrem;
    int i0 = cq*SPP + (qi << 5);
    const bool diag = (qrem == 0);
    const short* qp = Qb + ((size_t)h2*S + i0 + ql)*DQK + (h << 3);
    bf16x8 qf0 = *reinterpret_cast<const bf16x8*>(qp);
    bf16x8 qf1 = *reinterpret_cast<const bf16x8*>(qp + 16);
    bf16x8 qf2 = *reinterpret_cast<const bf16x8*>(qp + 32);
    f32x16 st;
#pragma unroll
    for (int r = 0; r < 16; ++r) st[r] = 0.f;
    st = __builtin_amdgcn_mfma_f32_32x32x16_bf16(kf0, qf0, st, 0, 0, 0);
    st = __builtin_amdgcn_mfma_f32_32x32x16_bf16(kf1, qf1, st, 0, 0, 0);
    st = __builtin_amdgcn_mfma_f32_32x32x16_bf16(kf2, qf2, st, 0, 0, 0);
    float Mq = rowm[h2*S + i0 + ql];
    float Lq = 1.0f / rowl[h2*S + i0 + ql];
    if (diag) {
#pragma unroll
      for (int r = 0; r < 16; ++r) {
        int kl = (r & 3) + ((r >> 2) << 3) + (h << 2);
        if (kl <= ql) gs[r] += __expf(st[r]*SCALING - Mq) * Lq;
      }
    } else {
#pragma unroll
      for (int r = 0; r < 16; ++r) gs[r] += __expf(st[r]*SCALING - Mq) * Lq;
    }
  }
  __shared__ float gw[4][32];
#pragma unroll
  for (int r = 0; r < 16; ++r) {
    float v = gs[r];
#pragma unroll
    for (int mm = 1; mm < 32; mm <<= 1) v += __shfl_xor(v, mm, 32);
    if (ql == 0) gw[w][(r & 3) + ((r >> 2) << 3) + (h << 2)] = v;
  }
  __syncthreads();
  if (tid < 32) {
    float s = gw[0][tid] + gw[1][tid] + gw[2][tid] + gw[3][tid];
    gcol[hh*S + j0 + tid] = s * (1.0f / (float)S);
  }
}

// ---------------- Wpre: masked prefix of g-weighted V ----------------
__global__ __launch_bounds__(256) void build_wpre(const float* __restrict__ gcol,
    const float* __restrict__ kvb, float* __restrict__ Wpre) {
  const int hh = blockIdx.x >> 2;
  const int dq = (blockIdx.x & 3) << 4;
  __shared__ float Wt[SPP][16];
  const int tid = threadIdx.x;
  for (int idx = tid; idx < SPP*16; idx += 256) {
    int r = idx >> 4, dd = idx & 15;
    float val = 0.f;
#pragma unroll
    for (int b2 = 0; b2 < 4; ++b2) {
      int j = b2*SPP + r;
      val = fmaf(gcol[hh*S + j], kvb[(size_t)j*2048 + hh*128 + 64 + dq + dd], val);
    }
    Wt[r][dd] = val;
  }
  __syncthreads();
  if (tid < 16) {
    float run = 0.f;
    for (int r = 0; r < SPP; ++r) { run += Wt[r][tid]; Wt[r][tid] = run; }
  }
  __syncthreads();
  for (int idx = tid; idx < SPP*16; idx += 256) {
    int r = idx >> 4, dd = idx & 15;
    Wpre[((size_t)hh*SPP + r)*HD + dq + dd] = Wt[r][dd];
  }
}

// ------- combine (diff-attn) + per-head RMSNorm + scrambled reshape -> bf16 ---
__global__ __launch_bounds__(64) void combine_rms(const float* __restrict__ Ob,
    const float* __restrict__ Wpre, const float* __restrict__ lamp,
    const float* __restrict__ anw, short* __restrict__ attno) {
  const int t = blockIdx.x, h = blockIdx.y, d = threadIdx.x;
  const float lam = lamp[0];
  const float o1 = Ob[((size_t)(2*h)*S + t)*HD + d];
  const float o2 = Ob[((size_t)(2*h+1)*S + t)*HD + d];
  const float w3 = Wpre[((size_t)h*SPP + (t % SPP))*HD + d];
  float val = o1 - lam*o2 + lam*w3;
  float ss = val*val;
#pragma unroll
  for (int mm = 1; mm < 64; mm <<= 1) ss += __shfl_xor(ss, mm, 64);
  float scale = rsqrtf(ss * (1.0f/HD) + ATTN_EPS) * anw[d];
  int tn = h*96 + (t >> 4);
  int cn = ((t & 15) << 6) + d;
  attno[(size_t)tn*DM + cn] = cvt_bf16(val * scale);
}

// =========================== launch ===========================
extern "C" void kernel_launch(void* const* d_in, const int* in_sizes, int n_in,
                              void* d_out, int out_size, void* d_ws, size_t ws_size,
                              hipStream_t stream) {
  (void)in_sizes; (void)n_in; (void)out_size;
  const float* x    = (const float*)d_in[0];
  const float* fc   = (const float*)d_in[1];
  const float* fs   = (const float*)d_in[2];
  const float* n1w  = (const float*)d_in[3];
  const float* n2w  = (const float*)d_in[4];
  const float* kvdw = (const float*)d_in[5];
  const float* qdw  = (const float*)d_in[6];
  const float* kvnw = (const float*)d_in[7];
  const float* qnw  = (const float*)d_in[8];
  const float* kvuw = (const float*)d_in[9];
  const float* quw  = (const float*)d_in[10];
  const float* lq1  = (const float*)d_in[11];
  const float* lk1  = (const float*)d_in[12];
  const float* lq2  = (const float*)d_in[13];
  const float* lk2  = (const float*)d_in[14];
  const float* anw  = (const float*)d_in[15];
  const float* ow   = (const float*)d_in[16];
  const float* ffiw = (const float*)d_in[17];
  const float* ffow = (const float*)d_in[18];
  float* out = (float*)d_out;
  float* ws  = (float*)d_ws;

  float* xin   = ws;
  float* ckv   = xin   + (size_t)S*DM;
  float* qmid  = ckv   + (size_t)S*288;
  float* kvb   = qmid  + (size_t)S*QC;
  float* qf    = kvb   + (size_t)S*2048;
  float* Qb    = qf    + (size_t)S*1536;
  float* Kb    = Qb    + (size_t)H2N*S*DQK;
  float* Obuf  = Kb    + (size_t)H2N*S*DQK;
  float* rowm  = Obuf  + (size_t)H2N*S*HD;
  float* rowl  = rowm  + (size_t)H2N*S;
  float* gcol  = rowl  + (size_t)H2N*S;
  float* Wpre  = gcol  + (size_t)NH*S;
  float* attno = Wpre  + (size_t)NH*SPP*HD;
  float* lamp  = attno + (size_t)S*DM;
  short* fbufs = (short*)kvb;     // bf16 FFN activation overlays kv region
  // flash z=1 partials (dead windows): xin (h2<16), qf (h2>=16)
  float* Ob1a = xin;
  float* Ob1b = qf;
  float* rm1  = qf + (size_t)16*S*HD;
  float* rl1  = rm1 + (size_t)H2N*S;
  // bf16 attention operand views (halves of old fp32 Qb/Kb regions):
  short* Qb_bf = (short*)Qb;
  short* Kb_bf = (short*)Kb;
  short* Vt_bf = (short*)Qb + 2359296;
  // bf16 activations (A operands):
  short* xin_bf  = (short*)xin;                   // rmsnorm1 out; dead before flash
  short* ckv_bf  = (short*)Obuf;                  // Obuf dead until flash
  short* qmid_bf = ckv_bf + (size_t)S*KVC;
  short* h_bf    = (short*)xin;                   // rmsnorm2 out (xin dead by then)
  short* attno_bf = (short*)attno;
  // bf16 weight copies in dead regions:
  short* kvdw_bf = (short*)attno;                 // dead until combine_rms
  short* qdw_bf  = kvdw_bf + 294912;
  short* kvuw_bf = qdw_bf  + 393216;
  short* quw_bf  = kvuw_bf + 524288;
  short* ffiw_bf = (short*)Qb;                    // Qb+Kb dead after colsum_mfma
  short* ow_bf   = ffiw_bf + 8388608;
  short* ffow_bf = (short*)Obuf;                  // Obuf dead after combine_rms
  if (ws_size < (size_t)18063376 * sizeof(float)) return;

  cvt_w4<<<880, 256, 0, stream>>>(kvdw, 294912, qdw, 393216, kvuw, 524288, quw, 589824, kvdw_bf);
  rmsnorm_bf<<<S, 256, 0, stream>>>(x, n1w, xin_bf, DM, DM, DM, EPS_RMS);
  { dim3 g(5, 24);  mgemm_nt<0><<<g, 256, 0, stream>>>(xin_bf, kvdw_bf, nullptr, ckv, S, 288, DM, DM, DM, 288); }
  { dim3 g(6, 24);  mgemm_nt<0><<<g, 256, 0, stream>>>(xin_bf, qdw_bf,  nullptr, qmid, S, QC, DM, DM, DM, QC); }
  rmsnorm_bf<<<S, 256, 0, stream>>>(ckv,  kvnw, ckv_bf,  KVC, 288, KVC, EPS_RMS);
  rmsnorm_bf<<<S, 256, 0, stream>>>(qmid, qnw,  qmid_bf, QC,  QC,  QC,  EPS_RMS);
  { dim3 g(32, 24); mgemm_nt<0><<<g, 256, 0, stream>>>(ckv_bf,  kvuw_bf, nullptr, kvb, S, 2048, KVC, KVC, KVC, 2048); }
  { dim3 g(24, 24); mgemm_nt<0><<<g, 256, 0, stream>>>(qmid_bf, quw_bf,  nullptr, qf,  S, 1536, QC,  QC,  QC,  1536); }
  { dim3 g(6, 32);  build_qk<<<g, 256, 0, stream>>>(qf, kvb, ckv, fc, fs, Qb_bf, Kb_bf); }
  { dim3 g(16, 12); vt_build<<<g, 256, 0, stream>>>(kvb, Vt_bf); }
  compute_lam<<<1, 32, 0, stream>>>(lq1, lk1, lq2, lk2, lamp);
  { dim3 g(12, 32, 2); flash_mfma<<<g, 256, 0, stream>>>(Qb_bf, Kb_bf, Vt_bf, Obuf, rowm, rowl,
                                                         Ob1a, Ob1b, rm1, rl1); }
  merge_flash<<<(H2N*S)/4, 256, 0, stream>>>(Obuf, rowm, rowl, Ob1a, Ob1b, rm1, rl1);
  { dim3 g(48, 16); colsum_mfma<<<g, 256, 0, stream>>>(Qb_bf, Kb_bf, rowm, rowl, gcol); }
  cvt_w4<<<4608, 256, 0, stream>>>(ffiw, 8388608, ow, 1048576, nullptr, 0, nullptr, 0, ffiw_bf);
  build_wpre<<<64, 256, 0, stream>>>(gcol, kvb, Wpre);
  { dim3 g(S, 16);  combine_rms<<<g, 64, 0, stream>>>(Obuf, Wpre, lamp, anw, attno_bf); }
  cvt_w4<<<2048, 256, 0, stream>>>(ffow, 4194304, nullptr, 0, nullptr, 0, nullptr, 0, ffow_bf);
  { dim3 g(16, 24); mgemm_nt<1><<<g, 256, 0, stream>>>(attno_bf, ow_bf, x, out, S, DM, DM, DM, DM, DM); }
  rmsnorm_bf<<<S, 256, 0, stream>>>(out, n2w, h_bf, DM, DM, DM, EPS_RMS);
  { dim3 g(32, 12); mgemm_glu<<<g, 256, 0, stream>>>(h_bf, ffiw_bf, fbufs, S, DFF, DM, DM, DM, DFF); }
  { dim3 g(16, 24); mgemm_nt<1><<<g, 256, 0, stream>>>(fbufs, ffow_bf, out, out, S, DM, DFF, DFF, DFF, DM); }
}

// Round 11
// 255.170 us; speedup vs baseline: 9.3039x; 1.0845x over previous
//
#include <hip/hip_runtime.h>
#include <math.h>

#define S     1536
#define DM    1024
#define NH    16
#define H2N   32
#define HD    64
#define KVC   256
#define QC    384
#define DFF   4096
#define SPP   384
#define DQK   48
#define EPS_RMS  1.1920929e-07f
#define ATTN_EPS 1e-5f
#define SCALING  0.14433756729740643f   /* 48^-0.5 */

typedef float f32x4 __attribute__((ext_vector_type(4)));
typedef float f32x16 __attribute__((ext_vector_type(16)));
typedef short bf16x8 __attribute__((ext_vector_type(8)));

__device__ __forceinline__ short cvt_bf16(float f) {      // scalar fallback (epilogues)
  union { float f; unsigned u; } x; x.f = f;
  unsigned r = x.u + 0x7FFFu + ((x.u >> 16) & 1u);
  return (short)(r >> 16);
}
__device__ __forceinline__ unsigned pk2(float a, float b) { // HW RNE pack
  unsigned r;
  asm("v_cvt_pk_bf16_f32 %0, %1, %2" : "=v"(r) : "v"(a), "v"(b));
  return r;
}
__device__ __forceinline__ bf16x8 cvt8(float4 a, float4 b) {
  union { unsigned u[4]; bf16x8 v; } r;
  r.u[0] = pk2(a.x, a.y); r.u[1] = pk2(a.z, a.w);
  r.u[2] = pk2(b.x, b.y); r.u[3] = pk2(b.z, b.w);
  return r.v;
}

// ---------------- weight fp32 -> bf16 (up to 4 segments, sizes %2048==0) ----
__global__ __launch_bounds__(256) void cvt_w4(const float* __restrict__ s0, int n0,
    const float* __restrict__ s1, int n1, const float* __restrict__ s2, int n2,
    const float* __restrict__ s3, int n3, short* __restrict__ dst) {
  long base = (long)blockIdx.x * 2048 + (long)threadIdx.x * 8;
  const float* src; long off;
  if (base < n0) { src = s0; off = base; }
  else if (base < (long)n0 + n1) { src = s1; off = base - n0; }
  else if (base < (long)n0 + n1 + n2) { src = s2; off = base - n0 - n1; }
  else { src = s3; off = base - n0 - n1 - n2; }
  float4 a = *reinterpret_cast<const float4*>(src + off);
  float4 b = *reinterpret_cast<const float4*>(src + off + 4);
  *reinterpret_cast<bf16x8*>(dst + base) = cvt8(a, b);
}

// ---------------- RMSNorm -> bf16 out ----------------
__global__ __launch_bounds__(256) void rmsnorm_bf(const float* __restrict__ in,
    const float* __restrict__ w, short* __restrict__ out,
    int cols, int ldin, int ldout, float eps) {
  const int row = blockIdx.x;
  const float* xr = in + (size_t)row * ldin;
  short* yr = out + (size_t)row * ldout;
  const int tid = threadIdx.x;
  float ss = 0.f;
  for (int c = tid << 2; c < cols; c += 1024) {
    float4 v = *reinterpret_cast<const float4*>(xr + c);
    ss += v.x*v.x + v.y*v.y + v.z*v.z + v.w*v.w;
  }
#pragma unroll
  for (int mm = 1; mm < 64; mm <<= 1) ss += __shfl_xor(ss, mm, 64);
  __shared__ float red[4];
  if ((tid & 63) == 0) red[tid >> 6] = ss;
  __syncthreads();
  float tot = red[0] + red[1] + red[2] + red[3];
  float scale = rsqrtf(tot / (float)cols + eps);
  for (int c = tid << 2; c < cols; c += 1024) {
    float4 v = *reinterpret_cast<const float4*>(xr + c);
    float4 wv = *reinterpret_cast<const float4*>(w + c);
    uint2 p;
    p.x = pk2(v.x*scale*wv.x, v.y*scale*wv.y);
    p.y = pk2(v.z*scale*wv.z, v.w*scale*wv.w);
    *reinterpret_cast<uint2*>(yr + c) = p;
  }
}

// ------------- bf16 MFMA GEMM, BK=64, register-prefetch; A,B bf16 ----------
template<int ADD>
__global__ __launch_bounds__(256) void mgemm_nt(const short* __restrict__ A,
    const short* __restrict__ B, const float* __restrict__ src, float* __restrict__ C,
    int M, int N, int K, int lda, int ldb, int ldc) {
  __shared__ short As[64][72];
  __shared__ short Bs[64][72];
  const int bm = blockIdx.y * 64, bn = blockIdx.x * 64;
  const int tid = threadIdx.x;
  const int w = tid >> 6, lane = tid & 63;
  const int wr = (w >> 1) << 5, wc = (w & 1) << 5;
  const int srow = tid >> 2, sk = (tid & 3) << 4;
  const int lrow = lane & 15, lk8 = (lane >> 4) << 3;
  const int arow = bm + srow, brow = bn + srow;
  const bool bvalid = brow < N;
  f32x4 acc[2][2];
#pragma unroll
  for (int i = 0; i < 2; ++i)
#pragma unroll
    for (int j = 0; j < 2; ++j) acc[i][j] = (f32x4){0.f, 0.f, 0.f, 0.f};

  bf16x8 rah0, rah1, rbh0, rbh1;
  {
    const short* ap = A + (size_t)arow * lda + sk;
    rah0 = *reinterpret_cast<const bf16x8*>(ap);
    rah1 = *reinterpret_cast<const bf16x8*>(ap + 8);
  }
  rbh0 = (bf16x8){0,0,0,0,0,0,0,0}; rbh1 = rbh0;
  if (bvalid) {
    const short* bp = B + (size_t)brow * ldb + sk;
    rbh0 = *reinterpret_cast<const bf16x8*>(bp);
    rbh1 = *reinterpret_cast<const bf16x8*>(bp + 8);
  }

  for (int k0 = 0; k0 < K; k0 += 64) {
    bf16x8 va0 = rah0, va1 = rah1, vb0 = rbh0, vb1 = rbh1;
    __syncthreads();
    *reinterpret_cast<bf16x8*>(&As[srow][sk])     = va0;
    *reinterpret_cast<bf16x8*>(&As[srow][sk + 8]) = va1;
    *reinterpret_cast<bf16x8*>(&Bs[srow][sk])     = vb0;
    *reinterpret_cast<bf16x8*>(&Bs[srow][sk + 8]) = vb1;
    __syncthreads();
    const int kn = k0 + 64;
    if (kn < K) {
      const short* ap = A + (size_t)arow * lda + kn + sk;
      rah0 = *reinterpret_cast<const bf16x8*>(ap);
      rah1 = *reinterpret_cast<const bf16x8*>(ap + 8);
      if (bvalid) {
        const short* bp = B + (size_t)brow * ldb + kn + sk;
        rbh0 = *reinterpret_cast<const bf16x8*>(bp);
        rbh1 = *reinterpret_cast<const bf16x8*>(bp + 8);
      }
    }
#pragma unroll
    for (int kk = 0; kk < 2; ++kk) {
      bf16x8 af0 = *reinterpret_cast<bf16x8*>(&As[wr + lrow][(kk << 5) + lk8]);
      bf16x8 af1 = *reinterpret_cast<bf16x8*>(&As[wr + 16 + lrow][(kk << 5) + lk8]);
      bf16x8 bf0 = *reinterpret_cast<bf16x8*>(&Bs[wc + lrow][(kk << 5) + lk8]);
      bf16x8 bf1 = *reinterpret_cast<bf16x8*>(&Bs[wc + 16 + lrow][(kk << 5) + lk8]);
      acc[0][0] = __builtin_amdgcn_mfma_f32_16x16x32_bf16(af0, bf0, acc[0][0], 0, 0, 0);
      acc[0][1] = __builtin_amdgcn_mfma_f32_16x16x32_bf16(af0, bf1, acc[0][1], 0, 0, 0);
      acc[1][0] = __builtin_amdgcn_mfma_f32_16x16x32_bf16(af1, bf0, acc[1][0], 0, 0, 0);
      acc[1][1] = __builtin_amdgcn_mfma_f32_16x16x32_bf16(af1, bf1, acc[1][1], 0, 0, 0);
    }
  }
  const int crow0 = bm + wr + ((lane >> 4) << 2);
  const int ccol0 = bn + wc + lrow;
#pragma unroll
  for (int mi = 0; mi < 2; ++mi)
#pragma unroll
    for (int ni = 0; ni < 2; ++ni) {
      int colc = ccol0 + (ni << 4);
      if (colc < N) {
#pragma unroll
        for (int r = 0; r < 4; ++r) {
          int rowc = crow0 + (mi << 4) + r;
          float v = acc[mi][ni][r];
          if (ADD) v += src[(size_t)rowc * ldc + colc];
          C[(size_t)rowc * ldc + colc] = v;
        }
      }
    }
}

// ------- 128(M)x64(N) bf16 SwiGLU GEMM: 4 waves, per-wave 64x32 u AND v -----
// C = (A@Bu^T) * silu(A@Bv^T), all bf16. M%128==0, N%64==0.
__global__ __launch_bounds__(256) void mgemm_glu(const short* __restrict__ A,
    const short* __restrict__ Bw, short* __restrict__ C,
    int M, int N, int K, int lda, int ldb, int ldc) {
  __shared__ short As[128][72];
  __shared__ short Bu[64][72];
  __shared__ short Bv[64][72];
  const int bm = blockIdx.y * 128, bn = blockIdx.x * 64;
  const int tid = threadIdx.x;
  const int w = tid >> 6, lane = tid & 63;
  const int wr = (w >> 1) << 6, wc = (w & 1) << 5;
  const int arow = bm + (tid >> 1), ac = (tid & 1) << 5;   // A: 32 elems/thread
  const int brow = bn + (tid >> 2), bc = (tid & 3) << 4;   // Bu/Bv: 16 elems/thread
  const int lrow = lane & 15, lk8 = (lane >> 4) << 3;
  f32x4 au[4][2], av[4][2];
#pragma unroll
  for (int i = 0; i < 4; ++i)
#pragma unroll
    for (int j = 0; j < 2; ++j) {
      au[i][j] = (f32x4){0.f, 0.f, 0.f, 0.f};
      av[i][j] = (f32x4){0.f, 0.f, 0.f, 0.f};
    }
  bf16x8 ra[4], ru[2], rv[2];
  {
    const short* ap = A + (size_t)arow * lda + ac;
    const short* up = Bw + (size_t)brow * ldb + bc;
    const short* vp = Bw + (size_t)(N + brow) * ldb + bc;
#pragma unroll
    for (int e = 0; e < 4; ++e) ra[e] = *reinterpret_cast<const bf16x8*>(ap + (e << 3));
    ru[0] = *reinterpret_cast<const bf16x8*>(up);
    ru[1] = *reinterpret_cast<const bf16x8*>(up + 8);
    rv[0] = *reinterpret_cast<const bf16x8*>(vp);
    rv[1] = *reinterpret_cast<const bf16x8*>(vp + 8);
  }
  for (int k0 = 0; k0 < K; k0 += 64) {
    __syncthreads();
#pragma unroll
    for (int e = 0; e < 4; ++e)
      *reinterpret_cast<bf16x8*>(&As[tid >> 1][ac + (e << 3)]) = ra[e];
    *reinterpret_cast<bf16x8*>(&Bu[tid >> 2][bc])     = ru[0];
    *reinterpret_cast<bf16x8*>(&Bu[tid >> 2][bc + 8]) = ru[1];
    *reinterpret_cast<bf16x8*>(&Bv[tid >> 2][bc])     = rv[0];
    *reinterpret_cast<bf16x8*>(&Bv[tid >> 2][bc + 8]) = rv[1];
    __syncthreads();
    const int kn = k0 + 64;
    if (kn < K) {
      const short* ap = A + (size_t)arow * lda + kn + ac;
      const short* up = Bw + (size_t)brow * ldb + kn + bc;
      const short* vp = Bw + (size_t)(N + brow) * ldb + kn + bc;
#pragma unroll
      for (int e = 0; e < 4; ++e) ra[e] = *reinterpret_cast<const bf16x8*>(ap + (e << 3));
      ru[0] = *reinterpret_cast<const bf16x8*>(up);
      ru[1] = *reinterpret_cast<const bf16x8*>(up + 8);
      rv[0] = *reinterpret_cast<const bf16x8*>(vp);
      rv[1] = *reinterpret_cast<const bf16x8*>(vp + 8);
    }
#pragma unroll
    for (int kk = 0; kk < 2; ++kk) {
      bf16x8 af[4], uf[2], vf[2];
#pragma unroll
      for (int i = 0; i < 4; ++i)
        af[i] = *reinterpret_cast<bf16x8*>(&As[wr + (i << 4) + lrow][(kk << 5) + lk8]);
#pragma unroll
      for (int j = 0; j < 2; ++j) {
        uf[j] = *reinterpret_cast<bf16x8*>(&Bu[wc + (j << 4) + lrow][(kk << 5) + lk8]);
        vf[j] = *reinterpret_cast<bf16x8*>(&Bv[wc + (j << 4) + lrow][(kk << 5) + lk8]);
      }
#pragma unroll
      for (int i = 0; i < 4; ++i)
#pragma unroll
        for (int j = 0; j < 2; ++j) {
          au[i][j] = __builtin_amdgcn_mfma_f32_16x16x32_bf16(af[i], uf[j], au[i][j], 0, 0, 0);
          av[i][j] = __builtin_amdgcn_mfma_f32_16x16x32_bf16(af[i], vf[j], av[i][j], 0, 0, 0);
        }
    }
  }
  const int crow0 = bm + wr + ((lane >> 4) << 2);
  const int ccol0 = bn + wc + lrow;
#pragma unroll
  for (int mi = 0; mi < 4; ++mi)
#pragma unroll
    for (int ni = 0; ni < 2; ++ni) {
      int colc = ccol0 + (ni << 4);
#pragma unroll
      for (int r = 0; r < 4; ++r) {
        int rowc = crow0 + (mi << 4) + r;
        float uu = au[mi][ni][r], vg = av[mi][ni][r];
        float sig = 1.0f / (1.0f + __expf(-vg));
        C[(size_t)rowc * ldc + colc] = cvt_bf16(uu * vg * sig);
      }
    }
}

// ---------------- Build Q/K (split heads + RoPE) -> bf16 ----------------
__global__ __launch_bounds__(256) void build_qk(const float* __restrict__ qf,
    const float* __restrict__ kvb, const float* __restrict__ ckv,
    const float* __restrict__ fc, const float* __restrict__ fs,
    short* __restrict__ Qb, short* __restrict__ Kb) {
  int t = blockIdx.x * 256 + threadIdx.x;
  int h2 = blockIdx.y;
  if (t >= S) return;
  int hh = h2 >> 1, par = h2 & 1;
  const float* qrow = qf + (size_t)t*1536 + hh*96;
  const float* krow = kvb + (size_t)t*2048 + hh*128;
  unsigned qu[24], ku[24];
#pragma unroll
  for (int xq = 0; xq < 8; ++xq) {
    float4 qv = *reinterpret_cast<const float4*>(qrow + par*32 + (xq<<2));
    float4 kv = *reinterpret_cast<const float4*>(krow + par*32 + (xq<<2));
    qu[xq*2]   = pk2(qv.x, qv.y); qu[xq*2+1] = pk2(qv.z, qv.w);
    ku[xq*2]   = pk2(kv.x, kv.y); ku[xq*2+1] = pk2(kv.z, kv.w);
  }
  int p = t >> 2;
  const float* qr = qrow + 64 + par*16;
  const float* kr = ckv + (size_t)t*288 + 256 + par*16;
#pragma unroll
  for (int mq = 0; mq < 8; ++mq) {
    float c = 1.f, sn = 0.f;
    if (p > 0) { c = fc[(p-1)*8 + mq]; sn = fs[(p-1)*8 + mq]; }
    float q0 = qr[2*mq], q1 = qr[2*mq+1];
    qu[16 + mq] = pk2(q0*c - q1*sn, q0*sn + q1*c);
    float k0 = kr[2*mq], k1 = kr[2*mq+1];
    ku[16 + mq] = pk2(k0*c - k1*sn, k0*sn + k1*c);
  }
  unsigned* qo = (unsigned*)(Qb + ((size_t)h2*S + t)*DQK);
  unsigned* ko = (unsigned*)(Kb + ((size_t)h2*S + t)*DQK);
#pragma unroll
  for (int e = 0; e < 6; ++e) {
    *reinterpret_cast<uint4*>(qo + (e<<2)) = make_uint4(qu[e*4], qu[e*4+1], qu[e*4+2], qu[e*4+3]);
    *reinterpret_cast<uint4*>(ko + (e<<2)) = make_uint4(ku[e*4], ku[e*4+1], ku[e*4+2], ku[e*4+3]);
  }
}

// ---------------- V transpose to bf16: Vt[hh][d][t] ----------------
__global__ __launch_bounds__(256) void vt_build(const float* __restrict__ kvb,
    short* __restrict__ Vt) {
  const int hh = blockIdx.x;
  const int t0 = blockIdx.y << 7;
  __shared__ short Ts[128][74];
  const int tl = threadIdx.x >> 3, dp = (threadIdx.x & 7) << 3;
#pragma unroll
  for (int pass = 0; pass < 4; ++pass) {
    int t = t0 + (pass << 5) + tl;
    const float* vp = kvb + (size_t)t*2048 + hh*128 + 64 + dp;
    float4 a = *reinterpret_cast<const float4*>(vp);
    float4 b = *reinterpret_cast<const float4*>(vp + 4);
    *reinterpret_cast<bf16x8*>(&Ts[(pass << 5) + tl][dp]) = cvt8(a, b);
  }
  __syncthreads();
  for (int idx = threadIdx.x; idx < 1024; idx += 256) {
    int d = idx >> 4, tseg = (idx & 15) << 3;
    bf16x8 v;
#pragma unroll
    for (int e = 0; e < 8; ++e) v[e] = Ts[tseg + e][d];
    *reinterpret_cast<bf16x8*>(Vt + ((size_t)hh*HD + d)*S + t0 + tseg) = v;
  }
}

// ---------------- lambda scalar ----------------
__global__ void compute_lam(const float* __restrict__ lq1, const float* __restrict__ lk1,
                            const float* __restrict__ lq2, const float* __restrict__ lk2,
                            float* __restrict__ lamp) {
  int t = threadIdx.x;
  float a = lq1[t]*lk1[t];
  float b = lq2[t]*lk2[t];
#pragma unroll
  for (int mm = 1; mm < 32; mm <<= 1) { a += __shfl_xor(a, mm, 32); b += __shfl_xor(b, mm, 32); }
  if (t == 0) lamp[0] = expf(a) - expf(b) + 0.2f;
}

// ---------------- MFMA flash attention (bf16 inputs, split-j) ----------
__global__ __launch_bounds__(256) void flash_mfma(const short* __restrict__ Qb,
    const short* __restrict__ Kb, const short* __restrict__ Vg,
    float* __restrict__ Ob, float* __restrict__ rowm, float* __restrict__ rowl,
    float* __restrict__ Ob1a, float* __restrict__ Ob1b,
    float* __restrict__ rm1, float* __restrict__ rl1) {
  const int h2 = blockIdx.y;
  const int hh = h2 >> 1;
  const int i0 = blockIdx.x << 7;
  const int z  = blockIdx.z;
  const int tid = threadIdx.x;
  const int w = tid >> 6, lane = tid & 63;
  const int ql = lane & 31, h = lane >> 5;
  const int qbase = i0 + (w << 5);
  const int rbase = i0 % SPP;
  const int ri0w = rbase + (w << 5);
  const int jmaxb = rbase + 96;

  __shared__ __align__(16) short Ks[32][72];
  __shared__ __align__(16) short Vt[64][40];
  __shared__ __align__(16) float Ot[4][32][36];

  bf16x8 qf0, qf1, qf2;
  {
    const short* qp = Qb + ((size_t)h2*S + qbase + ql)*DQK + (h << 3);
    qf0 = *reinterpret_cast<const bf16x8*>(qp);
    qf1 = *reinterpret_cast<const bf16x8*>(qp + 16);
    qf2 = *reinterpret_cast<const bf16x8*>(qp + 32);
  }

  float m = -1e30f, l = 0.f;
  f32x16 o0, o1;
#pragma unroll
  for (int r = 0; r < 16; ++r) { o0[r] = 0.f; o1[r] = 0.f; }

  for (int c = (z << 1); c < (z << 1) + 2; ++c) {
    for (int jr = 0; jr <= jmaxb; jr += 32) {
      const int j0 = c*SPP + jr;
      __syncthreads();
      if (tid < 192) {
        int r = tid / 6, c8 = (tid % 6) << 3;
        *reinterpret_cast<bf16x8*>(&Ks[r][c8]) =
          *reinterpret_cast<const bf16x8*>(Kb + ((size_t)h2*S + j0 + r)*DQK + c8);
      }
      {
        int d = tid >> 2, part = (tid & 3) << 3;
        *reinterpret_cast<bf16x8*>(&Vt[d][part]) =
          *reinterpret_cast<const bf16x8*>(Vg + ((size_t)hh*HD + d)*S + j0 + part);
      }
      __syncthreads();
      if (jr > ri0w) continue;
      const bool diag = (jr == ri0w);

      bf16x8 kf0 = *reinterpret_cast<bf16x8*>(&Ks[ql][(h << 3)]);
      bf16x8 kf1 = *reinterpret_cast<bf16x8*>(&Ks[ql][16 + (h << 3)]);
      bf16x8 kf2 = *reinterpret_cast<bf16x8*>(&Ks[ql][32 + (h << 3)]);
      f32x16 st;
#pragma unroll
      for (int r = 0; r < 16; ++r) st[r] = 0.f;
      st = __builtin_amdgcn_mfma_f32_32x32x16_bf16(kf0, qf0, st, 0, 0, 0);
      st = __builtin_amdgcn_mfma_f32_32x32x16_bf16(kf1, qf1, st, 0, 0, 0);
      st = __builtin_amdgcn_mfma_f32_32x32x16_bf16(kf2, qf2, st, 0, 0, 0);

      if (diag) {
#pragma unroll
        for (int r = 0; r < 16; ++r) {
          int kl = (r & 3) + ((r >> 2) << 3) + (h << 2);
          st[r] = (kl <= ql) ? st[r] * SCALING : -1e30f;
        }
      } else {
#pragma unroll
        for (int r = 0; r < 16; ++r) st[r] *= SCALING;
      }

      float tm = st[0];
#pragma unroll
      for (int r = 1; r < 16; ++r) tm = fmaxf(tm, st[r]);
      tm = fmaxf(tm, __shfl_xor(tm, 32));
      float mnew = fmaxf(m, tm);
      float sc = __expf(m - mnew);
      m = mnew;
      float ps = 0.f;
#pragma unroll
      for (int r = 0; r < 16; ++r) { float p = __expf(st[r] - mnew); st[r] = p; ps += p; }
      ps += __shfl_xor(ps, 32);
      l = l * sc + ps;
#pragma unroll
      for (int r = 0; r < 16; ++r) { o0[r] *= sc; o1[r] *= sc; }

      unsigned A0 = pk2(st[0],  st[1]),  B0 = pk2(st[2],  st[3]);
      unsigned C0 = pk2(st[4],  st[5]),  D0 = pk2(st[6],  st[7]);
      unsigned A1 = pk2(st[8],  st[9]),  B1 = pk2(st[10], st[11]);
      unsigned C1 = pk2(st[12], st[13]), D1 = pk2(st[14], st[15]);
      unsigned xA0 = (unsigned)__shfl_xor((int)A0, 32), xB0 = (unsigned)__shfl_xor((int)B0, 32);
      unsigned xC0 = (unsigned)__shfl_xor((int)C0, 32), xD0 = (unsigned)__shfl_xor((int)D0, 32);
      unsigned xA1 = (unsigned)__shfl_xor((int)A1, 32), xB1 = (unsigned)__shfl_xor((int)B1, 32);
      unsigned xC1 = (unsigned)__shfl_xor((int)C1, 32), xD1 = (unsigned)__shfl_xor((int)D1, 32);
      union { unsigned u[4]; bf16x8 v; } P0, P1;
      P0.u[0] = h ? xC0 : A0;  P0.u[1] = h ? xD0 : B0;
      P0.u[2] = h ? C0 : xA0;  P0.u[3] = h ? D0 : xB0;
      P1.u[0] = h ? xC1 : A1;  P1.u[1] = h ? xD1 : B1;
      P1.u[2] = h ? C1 : xA1;  P1.u[3] = h ? D1 : xB1;

      bf16x8 v00 = *reinterpret_cast<bf16x8*>(&Vt[ql][(h << 3)]);
      bf16x8 v01 = *reinterpret_cast<bf16x8*>(&Vt[ql][16 + (h << 3)]);
      bf16x8 v10 = *reinterpret_cast<bf16x8*>(&Vt[32 + ql][(h << 3)]);
      bf16x8 v11 = *reinterpret_cast<bf16x8*>(&Vt[32 + ql][16 + (h << 3)]);
      o0 = __builtin_amdgcn_mfma_f32_32x32x16_bf16(v00, P0.v, o0, 0, 0, 0);
      o0 = __builtin_amdgcn_mfma_f32_32x32x16_bf16(v01, P1.v, o0, 0, 0, 0);
      o1 = __builtin_amdgcn_mfma_f32_32x32x16_bf16(v10, P0.v, o1, 0, 0, 0);
      o1 = __builtin_amdgcn_mfma_f32_32x32x16_bf16(v11, P1.v, o1, 0, 0, 0);
    }
  }

  // epilogue: two-pass transpose through half-size wave-private LDS
  float* ot = &Ot[w][0][0];
  float* orow;
  if (z == 0) orow = Ob + ((size_t)h2*S + qbase)*HD;
  else orow = (h2 < 16) ? Ob1a + ((size_t)h2*S + qbase)*HD
                        : Ob1b + ((size_t)(h2 - 16)*S + qbase)*HD;
#pragma unroll
  for (int r = 0; r < 16; ++r) {
    int dl = (r & 3) + ((r >> 2) << 3) + (h << 2);
    ot[ql*36 + dl] = o0[r];
  }
#pragma unroll
  for (int it = 0; it < 4; ++it) {   // same-wave LDS: in-order, no barrier
    int idx = lane + (it << 6);
    int row = idx >> 3, c4 = (idx & 7) << 2;
    float4 v = *reinterpret_cast<float4*>(&ot[row*36 + c4]);
    *reinterpret_cast<float4*>(&orow[(size_t)row*HD + c4]) = v;
  }
#pragma unroll
  for (int r = 0; r < 16; ++r) {
    int dl = (r & 3) + ((r >> 2) << 3) + (h << 2);
    ot[ql*36 + dl] = o1[r];
  }
#pragma unroll
  for (int it = 0; it < 4; ++it) {
    int idx = lane + (it << 6);
    int row = idx >> 3, c4 = (idx & 7) << 2;
    float4 v = *reinterpret_cast<float4*>(&ot[row*36 + c4]);
    *reinterpret_cast<float4*>(&orow[(size_t)row*HD + 32 + c4]) = v;
  }
  if (lane < 32) {
    if (z == 0) { rowm[h2*S + qbase + lane] = m; rowl[h2*S + qbase + lane] = l; }
    else        { rm1[h2*S + qbase + lane] = m;  rl1[h2*S + qbase + lane] = l; }
  }
}

// ---------------- merge the two flash partials, normalize ----------------
__global__ __launch_bounds__(256) void merge_flash(float* __restrict__ Ob,
    float* __restrict__ rowm, float* __restrict__ rowl,
    const float* __restrict__ Ob1a, const float* __restrict__ Ob1b,
    const float* __restrict__ rm1, const float* __restrict__ rl1) {
  const int gid = blockIdx.x * 4 + (threadIdx.x >> 6);
  const int d = threadIdx.x & 63;
  const int h2 = gid / S;
  float m0 = rowm[gid], l0 = rowl[gid], m1 = rm1[gid], l1 = rl1[gid];
  float m = fmaxf(m0, m1);
  float w0 = __expf(m0 - m), w1 = __expf(m1 - m);
  float linv = 1.0f / (l0*w0 + l1*w1);
  const float* o1 = (h2 < 16) ? (Ob1a + (size_t)gid*HD)
                              : (Ob1b + ((size_t)gid - (size_t)16*S)*HD);
  float v0 = Ob[(size_t)gid*HD + d];
  float v1 = o1[d];
  Ob[(size_t)gid*HD + d] = (v0*w0 + v1*w1) * linv;
  if (d == 0) { rowm[gid] = m; rowl[gid] = l0*w0 + l1*w1; }
}

// ---------------- colsum via MFMA (bf16 inputs) ----------------
__global__ __launch_bounds__(256) void colsum_mfma(const short* __restrict__ Qb,
    const short* __restrict__ Kb, const float* __restrict__ rowm,
    const float* __restrict__ rowl, float* __restrict__ gcol) {
  const int jt = blockIdx.x;
  const int hh = blockIdx.y, h2 = hh << 1;
  const int cK = jt / 12, jr32 = jt % 12;
  const int jr = jr32 << 5;
  const int j0 = cK*SPP + jr;
  const int tid = threadIdx.x;
  const int w = tid >> 6, lane = tid & 63;
  const int ql = lane & 31, h = lane >> 5;

  bf16x8 kf0, kf1, kf2;
  {
    const short* kp = Kb + ((size_t)h2*S + j0 + ql)*DQK + (h << 3);
    kf0 = *reinterpret_cast<const bf16x8*>(kp);
    kf1 = *reinterpret_cast<const bf16x8*>(kp + 16);
    kf2 = *reinterpret_cast<const bf16x8*>(kp + 32);
  }
  const int nt = 12 - jr32;
  const int T = nt << 2;
  float gs[16];
#pragma unroll
  for (int r = 0; r < 16; ++r) gs[r] = 0.f;

  for (int tt = w; tt < T; tt += 4) {
    int cq = tt / nt, qrem = tt - cq*nt;
    int qi = jr32 + qrem;
    int i0 = cq*SPP + (qi << 5);
    const bool diag = (qrem == 0);
    const short* qp = Qb + ((size_t)h2*S + i0 + ql)*DQK + (h << 3);
    bf16x8 qf0 = *reinterpret_cast<const bf16x8*>(qp);
    bf16x8 qf1 = *reinterpret_cast<const bf16x8*>(qp + 16);
    bf16x8 qf2 = *reinterpret_cast<const bf16x8*>(qp + 32);
    f32x16 st;
#pragma unroll
    for (int r = 0; r < 16; ++r) st[r] = 0.f;
    st = __builtin_amdgcn_mfma_f32_32x32x16_bf16(kf0, qf0, st, 0, 0, 0);
    st = __builtin_amdgcn_mfma_f32_32x32x16_bf16(kf1, qf1, st, 0, 0, 0);
    st = __builtin_amdgcn_mfma_f32_32x32x16_bf16(kf2, qf2, st, 0, 0, 0);
    float Mq = rowm[h2*S + i0 + ql];
    float Lq = 1.0f / rowl[h2*S + i0 + ql];
    if (diag) {
#pragma unroll
      for (int r = 0; r < 16; ++r) {
        int kl = (r & 3) + ((r >> 2) << 3) + (h << 2);
        if (kl <= ql) gs[r] += __expf(st[r]*SCALING - Mq) * Lq;
      }
    } else {
#pragma unroll
      for (int r = 0; r < 16; ++r) gs[r] += __expf(st[r]*SCALING - Mq) * Lq;
    }
  }
  __shared__ float gw[4][32];
#pragma unroll
  for (int r = 0; r < 16; ++r) {
    float v = gs[r];
#pragma unroll
    for (int mm = 1; mm < 32; mm <<= 1) v += __shfl_xor(v, mm, 32);
    if (ql == 0) gw[w][(r & 3) + ((r >> 2) << 3) + (h << 2)] = v;
  }
  __syncthreads();
  if (tid < 32) {
    float s = gw[0][tid] + gw[1][tid] + gw[2][tid] + gw[3][tid];
    gcol[hh*S + j0 + tid] = s * (1.0f / (float)S);
  }
}

// ---------------- Wpre: masked prefix of g-weighted V ----------------
__global__ __launch_bounds__(256) void build_wpre(const float* __restrict__ gcol,
    const float* __restrict__ kvb, float* __restrict__ Wpre) {
  const int hh = blockIdx.x >> 2;
  const int dq = (blockIdx.x & 3) << 4;
  __shared__ float Wt[SPP][16];
  const int tid = threadIdx.x;
  for (int idx = tid; idx < SPP*16; idx += 256) {
    int r = idx >> 4, dd = idx & 15;
    float val = 0.f;
#pragma unroll
    for (int b2 = 0; b2 < 4; ++b2) {
      int j = b2*SPP + r;
      val = fmaf(gcol[hh*S + j], kvb[(size_t)j*2048 + hh*128 + 64 + dq + dd], val);
    }
    Wt[r][dd] = val;
  }
  __syncthreads();
  if (tid < 16) {
    float run = 0.f;
    for (int r = 0; r < SPP; ++r) { run += Wt[r][tid]; Wt[r][tid] = run; }
  }
  __syncthreads();
  for (int idx = tid; idx < SPP*16; idx += 256) {
    int r = idx >> 4, dd = idx & 15;
    Wpre[((size_t)hh*SPP + r)*HD + dq + dd] = Wt[r][dd];
  }
}

// ------- combine (diff-attn) + per-head RMSNorm + scrambled reshape -> bf16 ---
__global__ __launch_bounds__(64) void combine_rms(const float* __restrict__ Ob,
    const float* __restrict__ Wpre, const float* __restrict__ lamp,
    const float* __restrict__ anw, short* __restrict__ attno) {
  const int t = blockIdx.x, h = blockIdx.y, d = threadIdx.x;
  const float lam = lamp[0];
  const float o1 = Ob[((size_t)(2*h)*S + t)*HD + d];
  const float o2 = Ob[((size_t)(2*h+1)*S + t)*HD + d];
  const float w3 = Wpre[((size_t)h*SPP + (t % SPP))*HD + d];
  float val = o1 - lam*o2 + lam*w3;
  float ss = val*val;
#pragma unroll
  for (int mm = 1; mm < 64; mm <<= 1) ss += __shfl_xor(ss, mm, 64);
  float scale = rsqrtf(ss * (1.0f/HD) + ATTN_EPS) * anw[d];
  int tn = h*96 + (t >> 4);
  int cn = ((t & 15) << 6) + d;
  attno[(size_t)tn*DM + cn] = cvt_bf16(val * scale);
}

// =========================== launch ===========================
extern "C" void kernel_launch(void* const* d_in, const int* in_sizes, int n_in,
                              void* d_out, int out_size, void* d_ws, size_t ws_size,
                              hipStream_t stream) {
  (void)in_sizes; (void)n_in; (void)out_size;
  const float* x    = (const float*)d_in[0];
  const float* fc   = (const float*)d_in[1];
  const float* fs   = (const float*)d_in[2];
  const float* n1w  = (const float*)d_in[3];
  const float* n2w  = (const float*)d_in[4];
  const float* kvdw = (const float*)d_in[5];
  const float* qdw  = (const float*)d_in[6];
  const float* kvnw = (const float*)d_in[7];
  const float* qnw  = (const float*)d_in[8];
  const float* kvuw = (const float*)d_in[9];
  const float* quw  = (const float*)d_in[10];
  const float* lq1  = (const float*)d_in[11];
  const float* lk1  = (const float*)d_in[12];
  const float* lq2  = (const float*)d_in[13];
  const float* lk2  = (const float*)d_in[14];
  const float* anw  = (const float*)d_in[15];
  const float* ow   = (const float*)d_in[16];
  const float* ffiw = (const float*)d_in[17];
  const float* ffow = (const float*)d_in[18];
  float* out = (float*)d_out;
  float* ws  = (float*)d_ws;

  float* xin   = ws;
  float* ckv   = xin   + (size_t)S*DM;
  float* qmid  = ckv   + (size_t)S*288;
  float* kvb   = qmid  + (size_t)S*QC;
  float* qf    = kvb   + (size_t)S*2048;
  float* Qb    = qf    + (size_t)S*1536;
  float* Kb    = Qb    + (size_t)H2N*S*DQK;
  float* Obuf  = Kb    + (size_t)H2N*S*DQK;
  float* rowm  = Obuf  + (size_t)H2N*S*HD;
  float* rowl  = rowm  + (size_t)H2N*S;
  float* gcol  = rowl  + (size_t)H2N*S;
  float* Wpre  = gcol  + (size_t)NH*S;
  float* attno = Wpre  + (size_t)NH*SPP*HD;
  float* lamp  = attno + (size_t)S*DM;
  short* fbufs = (short*)kvb;     // bf16 FFN activation overlays kv region
  // flash z=1 partials (dead windows): xin (h2<16), qf (h2>=16)
  float* Ob1a = xin;
  float* Ob1b = qf;
  float* rm1  = qf + (size_t)16*S*HD;
  float* rl1  = rm1 + (size_t)H2N*S;
  // bf16 attention operand views (halves of old fp32 Qb/Kb regions):
  short* Qb_bf = (short*)Qb;
  short* Kb_bf = (short*)Kb;
  short* Vt_bf = (short*)Qb + 2359296;
  // bf16 activations (A operands):
  short* xin_bf  = (short*)xin;                   // rmsnorm1 out; dead before flash
  short* ckv_bf  = (short*)Obuf;                  // Obuf dead until flash
  short* qmid_bf = ckv_bf + (size_t)S*KVC;
  short* h_bf    = (short*)xin;                   // rmsnorm2 out (xin dead by then)
  short* attno_bf = (short*)attno;
  // bf16 weight copies in dead regions:
  short* kvdw_bf = (short*)attno;                 // dead until combine_rms
  short* qdw_bf  = kvdw_bf + 294912;
  short* kvuw_bf = qdw_bf  + 393216;
  short* quw_bf  = kvuw_bf + 524288;
  short* ffiw_bf = (short*)Qb;                    // Qb+Kb dead after colsum_mfma
  short* ow_bf   = ffiw_bf + 8388608;
  short* ffow_bf = (short*)Obuf;                  // Obuf dead after combine_rms
  if (ws_size < (size_t)18063376 * sizeof(float)) return;

  cvt_w4<<<880, 256, 0, stream>>>(kvdw, 294912, qdw, 393216, kvuw, 524288, quw, 589824, kvdw_bf);
  rmsnorm_bf<<<S, 256, 0, stream>>>(x, n1w, xin_bf, DM, DM, DM, EPS_RMS);
  { dim3 g(5, 24);  mgemm_nt<0><<<g, 256, 0, stream>>>(xin_bf, kvdw_bf, nullptr, ckv, S, 288, DM, DM, DM, 288); }
  { dim3 g(6, 24);  mgemm_nt<0><<<g, 256, 0, stream>>>(xin_bf, qdw_bf,  nullptr, qmid, S, QC, DM, DM, DM, QC); }
  rmsnorm_bf<<<S, 256, 0, stream>>>(ckv,  kvnw, ckv_bf,  KVC, 288, KVC, EPS_RMS);
  rmsnorm_bf<<<S, 256, 0, stream>>>(qmid, qnw,  qmid_bf, QC,  QC,  QC,  EPS_RMS);
  { dim3 g(32, 24); mgemm_nt<0><<<g, 256, 0, stream>>>(ckv_bf,  kvuw_bf, nullptr, kvb, S, 2048, KVC, KVC, KVC, 2048); }
  { dim3 g(24, 24); mgemm_nt<0><<<g, 256, 0, stream>>>(qmid_bf, quw_bf,  nullptr, qf,  S, 1536, QC,  QC,  QC,  1536); }
  { dim3 g(6, 32);  build_qk<<<g, 256, 0, stream>>>(qf, kvb, ckv, fc, fs, Qb_bf, Kb_bf); }
  { dim3 g(16, 12); vt_build<<<g, 256, 0, stream>>>(kvb, Vt_bf); }
  compute_lam<<<1, 32, 0, stream>>>(lq1, lk1, lq2, lk2, lamp);
  { dim3 g(12, 32, 2); flash_mfma<<<g, 256, 0, stream>>>(Qb_bf, Kb_bf, Vt_bf, Obuf, rowm, rowl,
                                                         Ob1a, Ob1b, rm1, rl1); }
  merge_flash<<<(H2N*S)/4, 256, 0, stream>>>(Obuf, rowm, rowl, Ob1a, Ob1b, rm1, rl1);
  { dim3 g(48, 16); colsum_mfma<<<g, 256, 0, stream>>>(Qb_bf, Kb_bf, rowm, rowl, gcol); }
  cvt_w4<<<4608, 256, 0, stream>>>(ffiw, 8388608, ow, 1048576, nullptr, 0, nullptr, 0, ffiw_bf);
  build_wpre<<<64, 256, 0, stream>>>(gcol, kvb, Wpre);
  { dim3 g(S, 16);  combine_rms<<<g, 64, 0, stream>>>(Obuf, Wpre, lamp, anw, attno_bf); }
  cvt_w4<<<2048, 256, 0, stream>>>(ffow, 4194304, nullptr, 0, nullptr, 0, nullptr, 0, ffow_bf);
  { dim3 g(16, 24); mgemm_nt<1><<<g, 256, 0, stream>>>(attno_bf, ow_bf, x, out, S, DM, DM, DM, DM, DM); }
  rmsnorm_bf<<<S, 256, 0, stream>>>(out, n2w, h_bf, DM, DM, DM, EPS_RMS);
  { dim3 g(64, 12); mgemm_glu<<<g, 256, 0, stream>>>(h_bf, ffiw_bf, fbufs, S, DFF, DM, DM, DM, DFF); }
  { dim3 g(16, 24); mgemm_nt<1><<<g, 256, 0, stream>>>(fbufs, ffow_bf, out, out, S, DM, DFF, DFF, DFF, DM); }
}

// Round 12
// 253.918 us; speedup vs baseline: 9.3497x; 1.0049x over previous
//
#include <hip/hip_runtime.h>
#include <math.h>

#define S     1536
#define DM    1024
#define NH    16
#define H2N   32
#define HD    64
#define KVC   256
#define QC    384
#define DFF   4096
#define SPP   384
#define DQK   48
#define EPS_RMS  1.1920929e-07f
#define ATTN_EPS 1e-5f
#define SCALING  0.14433756729740643f   /* 48^-0.5 */

typedef float f32x4 __attribute__((ext_vector_type(4)));
typedef float f32x16 __attribute__((ext_vector_type(16)));
typedef short bf16x8 __attribute__((ext_vector_type(8)));

__device__ __forceinline__ short cvt_bf16(float f) {      // scalar fallback (epilogues)
  union { float f; unsigned u; } x; x.f = f;
  unsigned r = x.u + 0x7FFFu + ((x.u >> 16) & 1u);
  return (short)(r >> 16);
}
__device__ __forceinline__ unsigned pk2(float a, float b) { // HW RNE pack
  unsigned r;
  asm("v_cvt_pk_bf16_f32 %0, %1, %2" : "=v"(r) : "v"(a), "v"(b));
  return r;
}
__device__ __forceinline__ bf16x8 cvt8(float4 a, float4 b) {
  union { unsigned u[4]; bf16x8 v; } r;
  r.u[0] = pk2(a.x, a.y); r.u[1] = pk2(a.z, a.w);
  r.u[2] = pk2(b.x, b.y); r.u[3] = pk2(b.z, b.w);
  return r.v;
}

// ---------------- weight fp32 -> bf16 (up to 4 segments, sizes %2048==0) ----
__global__ __launch_bounds__(256) void cvt_w4(const float* __restrict__ s0, int n0,
    const float* __restrict__ s1, int n1, const float* __restrict__ s2, int n2,
    const float* __restrict__ s3, int n3, short* __restrict__ dst) {
  long base = (long)blockIdx.x * 2048 + (long)threadIdx.x * 8;
  const float* src; long off;
  if (base < n0) { src = s0; off = base; }
  else if (base < (long)n0 + n1) { src = s1; off = base - n0; }
  else if (base < (long)n0 + n1 + n2) { src = s2; off = base - n0 - n1; }
  else { src = s3; off = base - n0 - n1 - n2; }
  float4 a = *reinterpret_cast<const float4*>(src + off);
  float4 b = *reinterpret_cast<const float4*>(src + off + 4);
  *reinterpret_cast<bf16x8*>(dst + base) = cvt8(a, b);
}

// ---------------- RMSNorm -> bf16 out ----------------
__global__ __launch_bounds__(256) void rmsnorm_bf(const float* __restrict__ in,
    const float* __restrict__ w, short* __restrict__ out,
    int cols, int ldin, int ldout, float eps) {
  const int row = blockIdx.x;
  const float* xr = in + (size_t)row * ldin;
  short* yr = out + (size_t)row * ldout;
  const int tid = threadIdx.x;
  float ss = 0.f;
  for (int c = tid << 2; c < cols; c += 1024) {
    float4 v = *reinterpret_cast<const float4*>(xr + c);
    ss += v.x*v.x + v.y*v.y + v.z*v.z + v.w*v.w;
  }
#pragma unroll
  for (int mm = 1; mm < 64; mm <<= 1) ss += __shfl_xor(ss, mm, 64);
  __shared__ float red[4];
  if ((tid & 63) == 0) red[tid >> 6] = ss;
  __syncthreads();
  float tot = red[0] + red[1] + red[2] + red[3];
  float scale = rsqrtf(tot / (float)cols + eps);
  for (int c = tid << 2; c < cols; c += 1024) {
    float4 v = *reinterpret_cast<const float4*>(xr + c);
    float4 wv = *reinterpret_cast<const float4*>(w + c);
    uint2 p;
    p.x = pk2(v.x*scale*wv.x, v.y*scale*wv.y);
    p.y = pk2(v.z*scale*wv.z, v.w*scale*wv.w);
    *reinterpret_cast<uint2*>(yr + c) = p;
  }
}

// ------------- bf16 MFMA GEMM, BK=64, register-prefetch; A,B bf16 ----------
template<int ADD>
__global__ __launch_bounds__(256) void mgemm_nt(const short* __restrict__ A,
    const short* __restrict__ B, const float* __restrict__ src, float* __restrict__ C,
    int M, int N, int K, int lda, int ldb, int ldc) {
  __shared__ short As[64][72];
  __shared__ short Bs[64][72];
  const int bm = blockIdx.y * 64, bn = blockIdx.x * 64;
  const int tid = threadIdx.x;
  const int w = tid >> 6, lane = tid & 63;
  const int wr = (w >> 1) << 5, wc = (w & 1) << 5;
  const int srow = tid >> 2, sk = (tid & 3) << 4;
  const int lrow = lane & 15, lk8 = (lane >> 4) << 3;
  const int arow = bm + srow, brow = bn + srow;
  const bool bvalid = brow < N;
  f32x4 acc[2][2];
#pragma unroll
  for (int i = 0; i < 2; ++i)
#pragma unroll
    for (int j = 0; j < 2; ++j) acc[i][j] = (f32x4){0.f, 0.f, 0.f, 0.f};

  bf16x8 rah0, rah1, rbh0, rbh1;
  {
    const short* ap = A + (size_t)arow * lda + sk;
    rah0 = *reinterpret_cast<const bf16x8*>(ap);
    rah1 = *reinterpret_cast<const bf16x8*>(ap + 8);
  }
  rbh0 = (bf16x8){0,0,0,0,0,0,0,0}; rbh1 = rbh0;
  if (bvalid) {
    const short* bp = B + (size_t)brow * ldb + sk;
    rbh0 = *reinterpret_cast<const bf16x8*>(bp);
    rbh1 = *reinterpret_cast<const bf16x8*>(bp + 8);
  }

  for (int k0 = 0; k0 < K; k0 += 64) {
    bf16x8 va0 = rah0, va1 = rah1, vb0 = rbh0, vb1 = rbh1;
    __syncthreads();
    *reinterpret_cast<bf16x8*>(&As[srow][sk])     = va0;
    *reinterpret_cast<bf16x8*>(&As[srow][sk + 8]) = va1;
    *reinterpret_cast<bf16x8*>(&Bs[srow][sk])     = vb0;
    *reinterpret_cast<bf16x8*>(&Bs[srow][sk + 8]) = vb1;
    __syncthreads();
    const int kn = k0 + 64;
    if (kn < K) {
      const short* ap = A + (size_t)arow * lda + kn + sk;
      rah0 = *reinterpret_cast<const bf16x8*>(ap);
      rah1 = *reinterpret_cast<const bf16x8*>(ap + 8);
      if (bvalid) {
        const short* bp = B + (size_t)brow * ldb + kn + sk;
        rbh0 = *reinterpret_cast<const bf16x8*>(bp);
        rbh1 = *reinterpret_cast<const bf16x8*>(bp + 8);
      }
    }
#pragma unroll
    for (int kk = 0; kk < 2; ++kk) {
      bf16x8 af0 = *reinterpret_cast<bf16x8*>(&As[wr + lrow][(kk << 5) + lk8]);
      bf16x8 af1 = *reinterpret_cast<bf16x8*>(&As[wr + 16 + lrow][(kk << 5) + lk8]);
      bf16x8 bf0 = *reinterpret_cast<bf16x8*>(&Bs[wc + lrow][(kk << 5) + lk8]);
      bf16x8 bf1 = *reinterpret_cast<bf16x8*>(&Bs[wc + 16 + lrow][(kk << 5) + lk8]);
      acc[0][0] = __builtin_amdgcn_mfma_f32_16x16x32_bf16(af0, bf0, acc[0][0], 0, 0, 0);
      acc[0][1] = __builtin_amdgcn_mfma_f32_16x16x32_bf16(af0, bf1, acc[0][1], 0, 0, 0);
      acc[1][0] = __builtin_amdgcn_mfma_f32_16x16x32_bf16(af1, bf0, acc[1][0], 0, 0, 0);
      acc[1][1] = __builtin_amdgcn_mfma_f32_16x16x32_bf16(af1, bf1, acc[1][1], 0, 0, 0);
    }
  }
  const int crow0 = bm + wr + ((lane >> 4) << 2);
  const int ccol0 = bn + wc + lrow;
#pragma unroll
  for (int mi = 0; mi < 2; ++mi)
#pragma unroll
    for (int ni = 0; ni < 2; ++ni) {
      int colc = ccol0 + (ni << 4);
      if (colc < N) {
#pragma unroll
        for (int r = 0; r < 4; ++r) {
          int rowc = crow0 + (mi << 4) + r;
          float v = acc[mi][ni][r];
          if (ADD) v += src[(size_t)rowc * ldc + colc];
          C[(size_t)rowc * ldc + colc] = v;
        }
      }
    }
}

// ------- 128(M)x64(N) bf16 SwiGLU GEMM: 4 waves, per-wave 64x32 u AND v -----
__global__ __launch_bounds__(256) void mgemm_glu(const short* __restrict__ A,
    const short* __restrict__ Bw, short* __restrict__ C,
    int M, int N, int K, int lda, int ldb, int ldc) {
  __shared__ short As[128][72];
  __shared__ short Bu[64][72];
  __shared__ short Bv[64][72];
  const int bm = blockIdx.y * 128, bn = blockIdx.x * 64;
  const int tid = threadIdx.x;
  const int w = tid >> 6, lane = tid & 63;
  const int wr = (w >> 1) << 6, wc = (w & 1) << 5;
  const int arow = bm + (tid >> 1), ac = (tid & 1) << 5;
  const int brow = bn + (tid >> 2), bc = (tid & 3) << 4;
  const int lrow = lane & 15, lk8 = (lane >> 4) << 3;
  f32x4 au[4][2], av[4][2];
#pragma unroll
  for (int i = 0; i < 4; ++i)
#pragma unroll
    for (int j = 0; j < 2; ++j) {
      au[i][j] = (f32x4){0.f, 0.f, 0.f, 0.f};
      av[i][j] = (f32x4){0.f, 0.f, 0.f, 0.f};
    }
  bf16x8 ra[4], ru[2], rv[2];
  {
    const short* ap = A + (size_t)arow * lda + ac;
    const short* up = Bw + (size_t)brow * ldb + bc;
    const short* vp = Bw + (size_t)(N + brow) * ldb + bc;
#pragma unroll
    for (int e = 0; e < 4; ++e) ra[e] = *reinterpret_cast<const bf16x8*>(ap + (e << 3));
    ru[0] = *reinterpret_cast<const bf16x8*>(up);
    ru[1] = *reinterpret_cast<const bf16x8*>(up + 8);
    rv[0] = *reinterpret_cast<const bf16x8*>(vp);
    rv[1] = *reinterpret_cast<const bf16x8*>(vp + 8);
  }
  for (int k0 = 0; k0 < K; k0 += 64) {
    __syncthreads();
#pragma unroll
    for (int e = 0; e < 4; ++e)
      *reinterpret_cast<bf16x8*>(&As[tid >> 1][ac + (e << 3)]) = ra[e];
    *reinterpret_cast<bf16x8*>(&Bu[tid >> 2][bc])     = ru[0];
    *reinterpret_cast<bf16x8*>(&Bu[tid >> 2][bc + 8]) = ru[1];
    *reinterpret_cast<bf16x8*>(&Bv[tid >> 2][bc])     = rv[0];
    *reinterpret_cast<bf16x8*>(&Bv[tid >> 2][bc + 8]) = rv[1];
    __syncthreads();
    const int kn = k0 + 64;
    if (kn < K) {
      const short* ap = A + (size_t)arow * lda + kn + ac;
      const short* up = Bw + (size_t)brow * ldb + kn + bc;
      const short* vp = Bw + (size_t)(N + brow) * ldb + kn + bc;
#pragma unroll
      for (int e = 0; e < 4; ++e) ra[e] = *reinterpret_cast<const bf16x8*>(ap + (e << 3));
      ru[0] = *reinterpret_cast<const bf16x8*>(up);
      ru[1] = *reinterpret_cast<const bf16x8*>(up + 8);
      rv[0] = *reinterpret_cast<const bf16x8*>(vp);
      rv[1] = *reinterpret_cast<const bf16x8*>(vp + 8);
    }
#pragma unroll
    for (int kk = 0; kk < 2; ++kk) {
      bf16x8 af[4], uf[2], vf[2];
#pragma unroll
      for (int i = 0; i < 4; ++i)
        af[i] = *reinterpret_cast<bf16x8*>(&As[wr + (i << 4) + lrow][(kk << 5) + lk8]);
#pragma unroll
      for (int j = 0; j < 2; ++j) {
        uf[j] = *reinterpret_cast<bf16x8*>(&Bu[wc + (j << 4) + lrow][(kk << 5) + lk8]);
        vf[j] = *reinterpret_cast<bf16x8*>(&Bv[wc + (j << 4) + lrow][(kk << 5) + lk8]);
      }
#pragma unroll
      for (int i = 0; i < 4; ++i)
#pragma unroll
        for (int j = 0; j < 2; ++j) {
          au[i][j] = __builtin_amdgcn_mfma_f32_16x16x32_bf16(af[i], uf[j], au[i][j], 0, 0, 0);
          av[i][j] = __builtin_amdgcn_mfma_f32_16x16x32_bf16(af[i], vf[j], av[i][j], 0, 0, 0);
        }
    }
  }
  const int crow0 = bm + wr + ((lane >> 4) << 2);
  const int ccol0 = bn + wc + lrow;
#pragma unroll
  for (int mi = 0; mi < 4; ++mi)
#pragma unroll
    for (int ni = 0; ni < 2; ++ni) {
      int colc = ccol0 + (ni << 4);
#pragma unroll
      for (int r = 0; r < 4; ++r) {
        int rowc = crow0 + (mi << 4) + r;
        float uu = au[mi][ni][r], vg = av[mi][ni][r];
        float sig = 1.0f / (1.0f + __expf(-vg));
        C[(size_t)rowc * ldc + colc] = cvt_bf16(uu * vg * sig);
      }
    }
}

// ---------------- Build Q/K (split heads + RoPE) -> bf16 ----------------
__global__ __launch_bounds__(256) void build_qk(const float* __restrict__ qf,
    const float* __restrict__ kvb, const float* __restrict__ ckv,
    const float* __restrict__ fc, const float* __restrict__ fs,
    short* __restrict__ Qb, short* __restrict__ Kb) {
  int t = blockIdx.x * 256 + threadIdx.x;
  int h2 = blockIdx.y;
  if (t >= S) return;
  int hh = h2 >> 1, par = h2 & 1;
  const float* qrow = qf + (size_t)t*1536 + hh*96;
  const float* krow = kvb + (size_t)t*2048 + hh*128;
  unsigned qu[24], ku[24];
#pragma unroll
  for (int xq = 0; xq < 8; ++xq) {
    float4 qv = *reinterpret_cast<const float4*>(qrow + par*32 + (xq<<2));
    float4 kv = *reinterpret_cast<const float4*>(krow + par*32 + (xq<<2));
    qu[xq*2]   = pk2(qv.x, qv.y); qu[xq*2+1] = pk2(qv.z, qv.w);
    ku[xq*2]   = pk2(kv.x, kv.y); ku[xq*2+1] = pk2(kv.z, kv.w);
  }
  int p = t >> 2;
  const float* qr = qrow + 64 + par*16;
  const float* kr = ckv + (size_t)t*288 + 256 + par*16;
#pragma unroll
  for (int mq = 0; mq < 8; ++mq) {
    float c = 1.f, sn = 0.f;
    if (p > 0) { c = fc[(p-1)*8 + mq]; sn = fs[(p-1)*8 + mq]; }
    float q0 = qr[2*mq], q1 = qr[2*mq+1];
    qu[16 + mq] = pk2(q0*c - q1*sn, q0*sn + q1*c);
    float k0 = kr[2*mq], k1 = kr[2*mq+1];
    ku[16 + mq] = pk2(k0*c - k1*sn, k0*sn + k1*c);
  }
  unsigned* qo = (unsigned*)(Qb + ((size_t)h2*S + t)*DQK);
  unsigned* ko = (unsigned*)(Kb + ((size_t)h2*S + t)*DQK);
#pragma unroll
  for (int e = 0; e < 6; ++e) {
    *reinterpret_cast<uint4*>(qo + (e<<2)) = make_uint4(qu[e*4], qu[e*4+1], qu[e*4+2], qu[e*4+3]);
    *reinterpret_cast<uint4*>(ko + (e<<2)) = make_uint4(ku[e*4], ku[e*4+1], ku[e*4+2], ku[e*4+3]);
  }
}

// ---------------- V transpose to bf16: Vt[hh][d][t] ----------------
__global__ __launch_bounds__(256) void vt_build(const float* __restrict__ kvb,
    short* __restrict__ Vt) {
  const int hh = blockIdx.x;
  const int t0 = blockIdx.y << 7;
  __shared__ short Ts[128][74];
  const int tl = threadIdx.x >> 3, dp = (threadIdx.x & 7) << 3;
#pragma unroll
  for (int pass = 0; pass < 4; ++pass) {
    int t = t0 + (pass << 5) + tl;
    const float* vp = kvb + (size_t)t*2048 + hh*128 + 64 + dp;
    float4 a = *reinterpret_cast<const float4*>(vp);
    float4 b = *reinterpret_cast<const float4*>(vp + 4);
    *reinterpret_cast<bf16x8*>(&Ts[(pass << 5) + tl][dp]) = cvt8(a, b);
  }
  __syncthreads();
  for (int idx = threadIdx.x; idx < 1024; idx += 256) {
    int d = idx >> 4, tseg = (idx & 15) << 3;
    bf16x8 v;
#pragma unroll
    for (int e = 0; e < 8; ++e) v[e] = Ts[tseg + e][d];
    *reinterpret_cast<bf16x8*>(Vt + ((size_t)hh*HD + d)*S + t0 + tseg) = v;
  }
}

// ---------------- lambda scalar ----------------
__global__ void compute_lam(const float* __restrict__ lq1, const float* __restrict__ lk1,
                            const float* __restrict__ lq2, const float* __restrict__ lk2,
                            float* __restrict__ lamp) {
  int t = threadIdx.x;
  float a = lq1[t]*lk1[t];
  float b = lq2[t]*lk2[t];
#pragma unroll
  for (int mm = 1; mm < 32; mm <<= 1) { a += __shfl_xor(a, mm, 32); b += __shfl_xor(b, mm, 32); }
  if (t == 0) lamp[0] = expf(a) - expf(b) + 0.2f;
}

// ------- MFMA flash attention (bf16, split-j, balanced q-tiles, defer-max) ---
// grid (12, 32, 2); block bx = cq*3 + k; wave w owns residue q-tile qi=k+3w.
__global__ __launch_bounds__(256) void flash_mfma(const short* __restrict__ Qb,
    const short* __restrict__ Kb, const short* __restrict__ Vg,
    float* __restrict__ Ob, float* __restrict__ rowm, float* __restrict__ rowl,
    float* __restrict__ Ob1a, float* __restrict__ Ob1b,
    float* __restrict__ rm1, float* __restrict__ rl1) {
  const int h2 = blockIdx.y;
  const int hh = h2 >> 1;
  const int z  = blockIdx.z;
  const int tid = threadIdx.x;
  const int w = tid >> 6, lane = tid & 63;
  const int ql = lane & 31, h = lane >> 5;
  const int cq = blockIdx.x / 3, k = blockIdx.x % 3;
  const int qi = k + 3*w;                 // residue q-tile of this wave
  const int qbase = cq*SPP + (qi << 5);   // global q-row base
  const int ri0w = qi << 5;
  const int jmaxb = (k + 9) << 5;         // block staging bound (max wave)

  __shared__ __align__(16) short Ks[32][72];
  __shared__ __align__(16) short Vt[64][40];
  __shared__ __align__(16) float Ot[4][32][36];

  bf16x8 qf0, qf1, qf2;
  {
    const short* qp = Qb + ((size_t)h2*S + qbase + ql)*DQK + (h << 3);
    qf0 = *reinterpret_cast<const bf16x8*>(qp);
    qf1 = *reinterpret_cast<const bf16x8*>(qp + 16);
    qf2 = *reinterpret_cast<const bf16x8*>(qp + 32);
  }

  float m = -1e30f, l = 0.f;
  f32x16 o0, o1;
#pragma unroll
  for (int r = 0; r < 16; ++r) { o0[r] = 0.f; o1[r] = 0.f; }

  for (int c = (z << 1); c < (z << 1) + 2; ++c) {
    for (int jr = 0; jr <= jmaxb; jr += 32) {
      const int j0 = c*SPP + jr;
      __syncthreads();
      if (tid < 192) {
        int r = tid / 6, c8 = (tid % 6) << 3;
        *reinterpret_cast<bf16x8*>(&Ks[r][c8]) =
          *reinterpret_cast<const bf16x8*>(Kb + ((size_t)h2*S + j0 + r)*DQK + c8);
      }
      {
        int d = tid >> 2, part = (tid & 3) << 3;
        *reinterpret_cast<bf16x8*>(&Vt[d][part]) =
          *reinterpret_cast<const bf16x8*>(Vg + ((size_t)hh*HD + d)*S + j0 + part);
      }
      __syncthreads();
      if (jr > ri0w) continue;
      const bool diag = (jr == ri0w);

      bf16x8 kf0 = *reinterpret_cast<bf16x8*>(&Ks[ql][(h << 3)]);
      bf16x8 kf1 = *reinterpret_cast<bf16x8*>(&Ks[ql][16 + (h << 3)]);
      bf16x8 kf2 = *reinterpret_cast<bf16x8*>(&Ks[ql][32 + (h << 3)]);
      f32x16 st;
#pragma unroll
      for (int r = 0; r < 16; ++r) st[r] = 0.f;
      st = __builtin_amdgcn_mfma_f32_32x32x16_bf16(kf0, qf0, st, 0, 0, 0);
      st = __builtin_amdgcn_mfma_f32_32x32x16_bf16(kf1, qf1, st, 0, 0, 0);
      st = __builtin_amdgcn_mfma_f32_32x32x16_bf16(kf2, qf2, st, 0, 0, 0);

      if (diag) {
#pragma unroll
        for (int r = 0; r < 16; ++r) {
          int kl = (r & 3) + ((r >> 2) << 3) + (h << 2);
          st[r] = (kl <= ql) ? st[r] * SCALING : -1e30f;
        }
      } else {
#pragma unroll
        for (int r = 0; r < 16; ++r) st[r] *= SCALING;
      }

      // defer-max (T13): only rescale when max grows by > 8
      float tm = st[0];
#pragma unroll
      for (int r = 1; r < 16; ++r) tm = fmaxf(tm, st[r]);
      tm = fmaxf(tm, __shfl_xor(tm, 32));
      if (__any(tm > m + 8.0f)) {
        float mnew = fmaxf(m, tm);
        float sc = __expf(m - mnew);
        m = mnew;
        l *= sc;
#pragma unroll
        for (int r = 0; r < 16; ++r) { o0[r] *= sc; o1[r] *= sc; }
      }
      float ps = 0.f;
#pragma unroll
      for (int r = 0; r < 16; ++r) { float p = __expf(st[r] - m); st[r] = p; ps += p; }
      ps += __shfl_xor(ps, 32);
      l += ps;

      unsigned A0 = pk2(st[0],  st[1]),  B0 = pk2(st[2],  st[3]);
      unsigned C0 = pk2(st[4],  st[5]),  D0 = pk2(st[6],  st[7]);
      unsigned A1 = pk2(st[8],  st[9]),  B1 = pk2(st[10], st[11]);
      unsigned C1 = pk2(st[12], st[13]), D1 = pk2(st[14], st[15]);
      unsigned xA0 = (unsigned)__shfl_xor((int)A0, 32), xB0 = (unsigned)__shfl_xor((int)B0, 32);
      unsigned xC0 = (unsigned)__shfl_xor((int)C0, 32), xD0 = (unsigned)__shfl_xor((int)D0, 32);
      unsigned xA1 = (unsigned)__shfl_xor((int)A1, 32), xB1 = (unsigned)__shfl_xor((int)B1, 32);
      unsigned xC1 = (unsigned)__shfl_xor((int)C1, 32), xD1 = (unsigned)__shfl_xor((int)D1, 32);
      union { unsigned u[4]; bf16x8 v; } P0, P1;
      P0.u[0] = h ? xC0 : A0;  P0.u[1] = h ? xD0 : B0;
      P0.u[2] = h ? C0 : xA0;  P0.u[3] = h ? D0 : xB0;
      P1.u[0] = h ? xC1 : A1;  P1.u[1] = h ? xD1 : B1;
      P1.u[2] = h ? C1 : xA1;  P1.u[3] = h ? D1 : xB1;

      bf16x8 v00 = *reinterpret_cast<bf16x8*>(&Vt[ql][(h << 3)]);
      bf16x8 v01 = *reinterpret_cast<bf16x8*>(&Vt[ql][16 + (h << 3)]);
      bf16x8 v10 = *reinterpret_cast<bf16x8*>(&Vt[32 + ql][(h << 3)]);
      bf16x8 v11 = *reinterpret_cast<bf16x8*>(&Vt[32 + ql][16 + (h << 3)]);
      o0 = __builtin_amdgcn_mfma_f32_32x32x16_bf16(v00, P0.v, o0, 0, 0, 0);
      o0 = __builtin_amdgcn_mfma_f32_32x32x16_bf16(v01, P1.v, o0, 0, 0, 0);
      o1 = __builtin_amdgcn_mfma_f32_32x32x16_bf16(v10, P0.v, o1, 0, 0, 0);
      o1 = __builtin_amdgcn_mfma_f32_32x32x16_bf16(v11, P1.v, o1, 0, 0, 0);
    }
  }

  // epilogue: two-pass transpose through half-size wave-private LDS
  float* ot = &Ot[w][0][0];
  float* orow;
  if (z == 0) orow = Ob + ((size_t)h2*S + qbase)*HD;
  else orow = (h2 < 16) ? Ob1a + ((size_t)h2*S + qbase)*HD
                        : Ob1b + ((size_t)(h2 - 16)*S + qbase)*HD;
#pragma unroll
  for (int r = 0; r < 16; ++r) {
    int dl = (r & 3) + ((r >> 2) << 3) + (h << 2);
    ot[ql*36 + dl] = o0[r];
  }
#pragma unroll
  for (int it = 0; it < 4; ++it) {   // same-wave LDS: in-order, no barrier
    int idx = lane + (it << 6);
    int row = idx >> 3, c4 = (idx & 7) << 2;
    float4 v = *reinterpret_cast<float4*>(&ot[row*36 + c4]);
    *reinterpret_cast<float4*>(&orow[(size_t)row*HD + c4]) = v;
  }
#pragma unroll
  for (int r = 0; r < 16; ++r) {
    int dl = (r & 3) + ((r >> 2) << 3) + (h << 2);
    ot[ql*36 + dl] = o1[r];
  }
#pragma unroll
  for (int it = 0; it < 4; ++it) {
    int idx = lane + (it << 6);
    int row = idx >> 3, c4 = (idx & 7) << 2;
    float4 v = *reinterpret_cast<float4*>(&ot[row*36 + c4]);
    *reinterpret_cast<float4*>(&orow[(size_t)row*HD + 32 + c4]) = v;
  }
  if (lane < 32) {
    if (z == 0) { rowm[h2*S + qbase + lane] = m; rowl[h2*S + qbase + lane] = l; }
    else        { rm1[h2*S + qbase + lane] = m;  rl1[h2*S + qbase + lane] = l; }
  }
}

// ---------------- merge the two flash partials, normalize ----------------
__global__ __launch_bounds__(256) void merge_flash(float* __restrict__ Ob,
    float* __restrict__ rowm, float* __restrict__ rowl,
    const float* __restrict__ Ob1a, const float* __restrict__ Ob1b,
    const float* __restrict__ rm1, const float* __restrict__ rl1) {
  const int gid = blockIdx.x * 4 + (threadIdx.x >> 6);
  const int d = threadIdx.x & 63;
  const int h2 = gid / S;
  float m0 = rowm[gid], l0 = rowl[gid], m1 = rm1[gid], l1 = rl1[gid];
  float m = fmaxf(m0, m1);
  float w0 = __expf(m0 - m), w1 = __expf(m1 - m);
  float linv = 1.0f / (l0*w0 + l1*w1);
  const float* o1 = (h2 < 16) ? (Ob1a + (size_t)gid*HD)
                              : (Ob1b + ((size_t)gid - (size_t)16*S)*HD);
  float v0 = Ob[(size_t)gid*HD + d];
  float v1 = o1[d];
  Ob[(size_t)gid*HD + d] = (v0*w0 + v1*w1) * linv;
  if (d == 0) { rowm[gid] = m; rowl[gid] = l0*w0 + l1*w1; }
}

// ---------------- colsum via MFMA (bf16 inputs) ----------------
__global__ __launch_bounds__(256) void colsum_mfma(const short* __restrict__ Qb,
    const short* __restrict__ Kb, const float* __restrict__ rowm,
    const float* __restrict__ rowl, float* __restrict__ gcol) {
  const int jt = blockIdx.x;
  const int hh = blockIdx.y, h2 = hh << 1;
  const int cK = jt / 12, jr32 = jt % 12;
  const int jr = jr32 << 5;
  const int j0 = cK*SPP + jr;
  const int tid = threadIdx.x;
  const int w = tid >> 6, lane = tid & 63;
  const int ql = lane & 31, h = lane >> 5;

  bf16x8 kf0, kf1, kf2;
  {
    const short* kp = Kb + ((size_t)h2*S + j0 + ql)*DQK + (h << 3);
    kf0 = *reinterpret_cast<const bf16x8*>(kp);
    kf1 = *reinterpret_cast<const bf16x8*>(kp + 16);
    kf2 = *reinterpret_cast<const bf16x8*>(kp + 32);
  }
  const int nt = 12 - jr32;
  const int T = nt << 2;
  float gs[16];
#pragma unroll
  for (int r = 0; r < 16; ++r) gs[r] = 0.f;

  for (int tt = w; tt < T; tt += 4) {
    int cq = tt / nt, qrem = tt - cq*nt;
    int qi = jr32 + qrem;
    int i0 = cq*SPP + (qi << 5);
    const bool diag = (qrem == 0);
    const short* qp = Qb + ((size_t)h2*S + i0 + ql)*DQK + (h << 3);
    bf16x8 qf0 = *reinterpret_cast<const bf16x8*>(qp);
    bf16x8 qf1 = *reinterpret_cast<const bf16x8*>(qp + 16);
    bf16x8 qf2 = *reinterpret_cast<const bf16x8*>(qp + 32);
    f32x16 st;
#pragma unroll
    for (int r = 0; r < 16; ++r) st[r] = 0.f;
    st = __builtin_amdgcn_mfma_f32_32x32x16_bf16(kf0, qf0, st, 0, 0, 0);
    st = __builtin_amdgcn_mfma_f32_32x32x16_bf16(kf1, qf1, st, 0, 0, 0);
    st = __builtin_amdgcn_mfma_f32_32x32x16_bf16(kf2, qf2, st, 0, 0, 0);
    float Mq = rowm[h2*S + i0 + ql];
    float Lq = 1.0f / rowl[h2*S + i0 + ql];
    if (diag) {
#pragma unroll
      for (int r = 0; r < 16; ++r) {
        int kl = (r & 3) + ((r >> 2) << 3) + (h << 2);
        if (kl <= ql) gs[r] += __expf(st[r]*SCALING - Mq) * Lq;
      }
    } else {
#pragma unroll
      for (int r = 0; r < 16; ++r) gs[r] += __expf(st[r]*SCALING - Mq) * Lq;
    }
  }
  __shared__ float gw[4][32];
#pragma unroll
  for (int r = 0; r < 16; ++r) {
    float v = gs[r];
#pragma unroll
    for (int mm = 1; mm < 32; mm <<= 1) v += __shfl_xor(v, mm, 32);
    if (ql == 0) gw[w][(r & 3) + ((r >> 2) << 3) + (h << 2)] = v;
  }
  __syncthreads();
  if (tid < 32) {
    float s = gw[0][tid] + gw[1][tid] + gw[2][tid] + gw[3][tid];
    gcol[hh*S + j0 + tid] = s * (1.0f / (float)S);
  }
}

// ---------------- Wpre: masked prefix of g-weighted V ----------------
__global__ __launch_bounds__(256) void build_wpre(const float* __restrict__ gcol,
    const float* __restrict__ kvb, float* __restrict__ Wpre) {
  const int hh = blockIdx.x >> 2;
  const int dq = (blockIdx.x & 3) << 4;
  __shared__ float Wt[SPP][16];
  const int tid = threadIdx.x;
  for (int idx = tid; idx < SPP*16; idx += 256) {
    int r = idx >> 4, dd = idx & 15;
    float val = 0.f;
#pragma unroll
    for (int b2 = 0; b2 < 4; ++b2) {
      int j = b2*SPP + r;
      val = fmaf(gcol[hh*S + j], kvb[(size_t)j*2048 + hh*128 + 64 + dq + dd], val);
    }
    Wt[r][dd] = val;
  }
  __syncthreads();
  if (tid < 16) {
    float run = 0.f;
    for (int r = 0; r < SPP; ++r) { run += Wt[r][tid]; Wt[r][tid] = run; }
  }
  __syncthreads();
  for (int idx = tid; idx < SPP*16; idx += 256) {
    int r = idx >> 4, dd = idx & 15;
    Wpre[((size_t)hh*SPP + r)*HD + dq + dd] = Wt[r][dd];
  }
}

// ------- combine (diff-attn) + per-head RMSNorm + scrambled reshape -> bf16 ---
__global__ __launch_bounds__(64) void combine_rms(const float* __restrict__ Ob,
    const float* __restrict__ Wpre, const float* __restrict__ lamp,
    const float* __restrict__ anw, short* __restrict__ attno) {
  const int t = blockIdx.x, h = blockIdx.y, d = threadIdx.x;
  const float lam = lamp[0];
  const float o1 = Ob[((size_t)(2*h)*S + t)*HD + d];
  const float o2 = Ob[((size_t)(2*h+1)*S + t)*HD + d];
  const float w3 = Wpre[((size_t)h*SPP + (t % SPP))*HD + d];
  float val = o1 - lam*o2 + lam*w3;
  float ss = val*val;
#pragma unroll
  for (int mm = 1; mm < 64; mm <<= 1) ss += __shfl_xor(ss, mm, 64);
  float scale = rsqrtf(ss * (1.0f/HD) + ATTN_EPS) * anw[d];
  int tn = h*96 + (t >> 4);
  int cn = ((t & 15) << 6) + d;
  attno[(size_t)tn*DM + cn] = cvt_bf16(val * scale);
}

// =========================== launch ===========================
extern "C" void kernel_launch(void* const* d_in, const int* in_sizes, int n_in,
                              void* d_out, int out_size, void* d_ws, size_t ws_size,
                              hipStream_t stream) {
  (void)in_sizes; (void)n_in; (void)out_size;
  const float* x    = (const float*)d_in[0];
  const float* fc   = (const float*)d_in[1];
  const float* fs   = (const float*)d_in[2];
  const float* n1w  = (const float*)d_in[3];
  const float* n2w  = (const float*)d_in[4];
  const float* kvdw = (const float*)d_in[5];
  const float* qdw  = (const float*)d_in[6];
  const float* kvnw = (const float*)d_in[7];
  const float* qnw  = (const float*)d_in[8];
  const float* kvuw = (const float*)d_in[9];
  const float* quw  = (const float*)d_in[10];
  const float* lq1  = (const float*)d_in[11];
  const float* lk1  = (const float*)d_in[12];
  const float* lq2  = (const float*)d_in[13];
  const float* lk2  = (const float*)d_in[14];
  const float* anw  = (const float*)d_in[15];
  const float* ow   = (const float*)d_in[16];
  const float* ffiw = (const float*)d_in[17];
  const float* ffow = (const float*)d_in[18];
  float* out = (float*)d_out;
  float* ws  = (float*)d_ws;

  float* xin   = ws;
  float* ckv   = xin   + (size_t)S*DM;
  float* qmid  = ckv   + (size_t)S*288;
  float* kvb   = qmid  + (size_t)S*QC;
  float* qf    = kvb   + (size_t)S*2048;
  float* Qb    = qf    + (size_t)S*1536;
  float* Kb    = Qb    + (size_t)H2N*S*DQK;
  float* Obuf  = Kb    + (size_t)H2N*S*DQK;
  float* rowm  = Obuf  + (size_t)H2N*S*HD;
  float* rowl  = rowm  + (size_t)H2N*S;
  float* gcol  = rowl  + (size_t)H2N*S;
  float* Wpre  = gcol  + (size_t)NH*S;
  float* attno = Wpre  + (size_t)NH*SPP*HD;
  float* lamp  = attno + (size_t)S*DM;
  short* fbufs = (short*)kvb;     // bf16 FFN activation overlays kv region
  float* Ob1a = xin;
  float* Ob1b = qf;
  float* rm1  = qf + (size_t)16*S*HD;
  float* rl1  = rm1 + (size_t)H2N*S;
  short* Qb_bf = (short*)Qb;
  short* Kb_bf = (short*)Kb;
  short* Vt_bf = (short*)Qb + 2359296;
  short* xin_bf  = (short*)xin;
  short* ckv_bf  = (short*)Obuf;
  short* qmid_bf = ckv_bf + (size_t)S*KVC;
  short* h_bf    = (short*)xin;
  short* attno_bf = (short*)attno;
  short* kvdw_bf = (short*)attno;
  short* qdw_bf  = kvdw_bf + 294912;
  short* kvuw_bf = qdw_bf  + 393216;
  short* quw_bf  = kvuw_bf + 524288;
  short* ffiw_bf = (short*)Qb;
  short* ow_bf   = ffiw_bf + 8388608;
  short* ffow_bf = (short*)Obuf;
  if (ws_size < (size_t)18063376 * sizeof(float)) return;

  cvt_w4<<<880, 256, 0, stream>>>(kvdw, 294912, qdw, 393216, kvuw, 524288, quw, 589824, kvdw_bf);
  rmsnorm_bf<<<S, 256, 0, stream>>>(x, n1w, xin_bf, DM, DM, DM, EPS_RMS);
  { dim3 g(5, 24);  mgemm_nt<0><<<g, 256, 0, stream>>>(xin_bf, kvdw_bf, nullptr, ckv, S, 288, DM, DM, DM, 288); }
  { dim3 g(6, 24);  mgemm_nt<0><<<g, 256, 0, stream>>>(xin_bf, qdw_bf,  nullptr, qmid, S, QC, DM, DM, DM, QC); }
  rmsnorm_bf<<<S, 256, 0, stream>>>(ckv,  kvnw, ckv_bf,  KVC, 288, KVC, EPS_RMS);
  rmsnorm_bf<<<S, 256, 0, stream>>>(qmid, qnw,  qmid_bf, QC,  QC,  QC,  EPS_RMS);
  { dim3 g(32, 24); mgemm_nt<0><<<g, 256, 0, stream>>>(ckv_bf,  kvuw_bf, nullptr, kvb, S, 2048, KVC, KVC, KVC, 2048); }
  { dim3 g(24, 24); mgemm_nt<0><<<g, 256, 0, stream>>>(qmid_bf, quw_bf,  nullptr, qf,  S, 1536, QC,  QC,  QC,  1536); }
  { dim3 g(6, 32);  build_qk<<<g, 256, 0, stream>>>(qf, kvb, ckv, fc, fs, Qb_bf, Kb_bf); }
  { dim3 g(16, 12); vt_build<<<g, 256, 0, stream>>>(kvb, Vt_bf); }
  compute_lam<<<1, 32, 0, stream>>>(lq1, lk1, lq2, lk2, lamp);
  { dim3 g(12, 32, 2); flash_mfma<<<g, 256, 0, stream>>>(Qb_bf, Kb_bf, Vt_bf, Obuf, rowm, rowl,
                                                         Ob1a, Ob1b, rm1, rl1); }
  merge_flash<<<(H2N*S)/4, 256, 0, stream>>>(Obuf, rowm, rowl, Ob1a, Ob1b, rm1, rl1);
  { dim3 g(48, 16); colsum_mfma<<<g, 256, 0, stream>>>(Qb_bf, Kb_bf, rowm, rowl, gcol); }
  cvt_w4<<<4608, 256, 0, stream>>>(ffiw, 8388608, ow, 1048576, nullptr, 0, nullptr, 0, ffiw_bf);
  build_wpre<<<64, 256, 0, stream>>>(gcol, kvb, Wpre);
  { dim3 g(S, 16);  combine_rms<<<g, 64, 0, stream>>>(Obuf, Wpre, lamp, anw, attno_bf); }
  cvt_w4<<<2048, 256, 0, stream>>>(ffow, 4194304, nullptr, 0, nullptr, 0, nullptr, 0, ffow_bf);
  { dim3 g(16, 24); mgemm_nt<1><<<g, 256, 0, stream>>>(attno_bf, ow_bf, x, out, S, DM, DM, DM, DM, DM); }
  rmsnorm_bf<<<S, 256, 0, stream>>>(out, n2w, h_bf, DM, DM, DM, EPS_RMS);
  { dim3 g(64, 12); mgemm_glu<<<g, 256, 0, stream>>>(h_bf, ffiw_bf, fbufs, S, DFF, DM, DM, DM, DFF); }
  { dim3 g(16, 24); mgemm_nt<1><<<g, 256, 0, stream>>>(fbufs, ffow_bf, out, out, S, DM, DFF, DFF, DFF, DM); }
}

// Round 13
// 243.825 us; speedup vs baseline: 9.7368x; 1.0414x over previous
//
#include <hip/hip_runtime.h>
#include <math.h>

#define S     1536
#define DM    1024
#define NH    16
#define H2N   32
#define HD    64
#define KVC   256
#define QC    384
#define DFF   4096
#define SPP   384
#define DQK   48
#define EPS_RMS  1.1920929e-07f
#define ATTN_EPS 1e-5f
#define SCALING  0.14433756729740643f   /* 48^-0.5 */

typedef float f32x4 __attribute__((ext_vector_type(4)));
typedef float f32x16 __attribute__((ext_vector_type(16)));
typedef short bf16x8 __attribute__((ext_vector_type(8)));

__device__ __forceinline__ short cvt_bf16(float f) {      // scalar fallback (epilogues)
  union { float f; unsigned u; } x; x.f = f;
  unsigned r = x.u + 0x7FFFu + ((x.u >> 16) & 1u);
  return (short)(r >> 16);
}
__device__ __forceinline__ unsigned pk2(float a, float b) { // HW RNE pack
  unsigned r;
  asm("v_cvt_pk_bf16_f32 %0, %1, %2" : "=v"(r) : "v"(a), "v"(b));
  return r;
}
__device__ __forceinline__ bf16x8 cvt8(float4 a, float4 b) {
  union { unsigned u[4]; bf16x8 v; } r;
  r.u[0] = pk2(a.x, a.y); r.u[1] = pk2(a.z, a.w);
  r.u[2] = pk2(b.x, b.y); r.u[3] = pk2(b.z, b.w);
  return r.v;
}

// ---------------- weight fp32 -> bf16 (up to 4 segments, sizes %2048==0) ----
__global__ __launch_bounds__(256) void cvt_w4(const float* __restrict__ s0, int n0,
    const float* __restrict__ s1, int n1, const float* __restrict__ s2, int n2,
    const float* __restrict__ s3, int n3, short* __restrict__ dst) {
  long base = (long)blockIdx.x * 2048 + (long)threadIdx.x * 8;
  const float* src; long off;
  if (base < n0) { src = s0; off = base; }
  else if (base < (long)n0 + n1) { src = s1; off = base - n0; }
  else if (base < (long)n0 + n1 + n2) { src = s2; off = base - n0 - n1; }
  else { src = s3; off = base - n0 - n1 - n2; }
  float4 a = *reinterpret_cast<const float4*>(src + off);
  float4 b = *reinterpret_cast<const float4*>(src + off + 4);
  *reinterpret_cast<bf16x8*>(dst + base) = cvt8(a, b);
}

// ---------------- RMSNorm -> bf16 out ----------------
__global__ __launch_bounds__(256) void rmsnorm_bf(const float* __restrict__ in,
    const float* __restrict__ w, short* __restrict__ out,
    int cols, int ldin, int ldout, float eps) {
  const int row = blockIdx.x;
  const float* xr = in + (size_t)row * ldin;
  short* yr = out + (size_t)row * ldout;
  const int tid = threadIdx.x;
  float ss = 0.f;
  for (int c = tid << 2; c < cols; c += 1024) {
    float4 v = *reinterpret_cast<const float4*>(xr + c);
    ss += v.x*v.x + v.y*v.y + v.z*v.z + v.w*v.w;
  }
#pragma unroll
  for (int mm = 1; mm < 64; mm <<= 1) ss += __shfl_xor(ss, mm, 64);
  __shared__ float red[4];
  if ((tid & 63) == 0) red[tid >> 6] = ss;
  __syncthreads();
  float tot = red[0] + red[1] + red[2] + red[3];
  float scale = rsqrtf(tot / (float)cols + eps);
  for (int c = tid << 2; c < cols; c += 1024) {
    float4 v = *reinterpret_cast<const float4*>(xr + c);
    float4 wv = *reinterpret_cast<const float4*>(w + c);
    uint2 p;
    p.x = pk2(v.x*scale*wv.x, v.y*scale*wv.y);
    p.y = pk2(v.z*scale*wv.z, v.w*scale*wv.w);
    *reinterpret_cast<uint2*>(yr + c) = p;
  }
}

// ------------- bf16 MFMA GEMM, BK=64, register-prefetch; A,B bf16 ----------
template<int ADD>
__global__ __launch_bounds__(256) void mgemm_nt(const short* __restrict__ A,
    const short* __restrict__ B, const float* __restrict__ src, float* __restrict__ C,
    int M, int N, int K, int lda, int ldb, int ldc) {
  __shared__ short As[64][72];
  __shared__ short Bs[64][72];
  const int bm = blockIdx.y * 64, bn = blockIdx.x * 64;
  const int tid = threadIdx.x;
  const int w = tid >> 6, lane = tid & 63;
  const int wr = (w >> 1) << 5, wc = (w & 1) << 5;
  const int srow = tid >> 2, sk = (tid & 3) << 4;
  const int lrow = lane & 15, lk8 = (lane >> 4) << 3;
  const int arow = bm + srow, brow = bn + srow;
  const bool bvalid = brow < N;
  f32x4 acc[2][2];
#pragma unroll
  for (int i = 0; i < 2; ++i)
#pragma unroll
    for (int j = 0; j < 2; ++j) acc[i][j] = (f32x4){0.f, 0.f, 0.f, 0.f};

  bf16x8 rah0, rah1, rbh0, rbh1;
  {
    const short* ap = A + (size_t)arow * lda + sk;
    rah0 = *reinterpret_cast<const bf16x8*>(ap);
    rah1 = *reinterpret_cast<const bf16x8*>(ap + 8);
  }
  rbh0 = (bf16x8){0,0,0,0,0,0,0,0}; rbh1 = rbh0;
  if (bvalid) {
    const short* bp = B + (size_t)brow * ldb + sk;
    rbh0 = *reinterpret_cast<const bf16x8*>(bp);
    rbh1 = *reinterpret_cast<const bf16x8*>(bp + 8);
  }

  for (int k0 = 0; k0 < K; k0 += 64) {
    bf16x8 va0 = rah0, va1 = rah1, vb0 = rbh0, vb1 = rbh1;
    __syncthreads();
    *reinterpret_cast<bf16x8*>(&As[srow][sk])     = va0;
    *reinterpret_cast<bf16x8*>(&As[srow][sk + 8]) = va1;
    *reinterpret_cast<bf16x8*>(&Bs[srow][sk])     = vb0;
    *reinterpret_cast<bf16x8*>(&Bs[srow][sk + 8]) = vb1;
    __syncthreads();
    const int kn = k0 + 64;
    if (kn < K) {
      const short* ap = A + (size_t)arow * lda + kn + sk;
      rah0 = *reinterpret_cast<const bf16x8*>(ap);
      rah1 = *reinterpret_cast<const bf16x8*>(ap + 8);
      if (bvalid) {
        const short* bp = B + (size_t)brow * ldb + kn + sk;
        rbh0 = *reinterpret_cast<const bf16x8*>(bp);
        rbh1 = *reinterpret_cast<const bf16x8*>(bp + 8);
      }
    }
#pragma unroll
    for (int kk = 0; kk < 2; ++kk) {
      bf16x8 af0 = *reinterpret_cast<bf16x8*>(&As[wr + lrow][(kk << 5) + lk8]);
      bf16x8 af1 = *reinterpret_cast<bf16x8*>(&As[wr + 16 + lrow][(kk << 5) + lk8]);
      bf16x8 bf0 = *reinterpret_cast<bf16x8*>(&Bs[wc + lrow][(kk << 5) + lk8]);
      bf16x8 bf1 = *reinterpret_cast<bf16x8*>(&Bs[wc + 16 + lrow][(kk << 5) + lk8]);
      acc[0][0] = __builtin_amdgcn_mfma_f32_16x16x32_bf16(af0, bf0, acc[0][0], 0, 0, 0);
      acc[0][1] = __builtin_amdgcn_mfma_f32_16x16x32_bf16(af0, bf1, acc[0][1], 0, 0, 0);
      acc[1][0] = __builtin_amdgcn_mfma_f32_16x16x32_bf16(af1, bf0, acc[1][0], 0, 0, 0);
      acc[1][1] = __builtin_amdgcn_mfma_f32_16x16x32_bf16(af1, bf1, acc[1][1], 0, 0, 0);
    }
  }
  const int crow0 = bm + wr + ((lane >> 4) << 2);
  const int ccol0 = bn + wc + lrow;
#pragma unroll
  for (int mi = 0; mi < 2; ++mi)
#pragma unroll
    for (int ni = 0; ni < 2; ++ni) {
      int colc = ccol0 + (ni << 4);
      if (colc < N) {
#pragma unroll
        for (int r = 0; r < 4; ++r) {
          int rowc = crow0 + (mi << 4) + r;
          float v = acc[mi][ni][r];
          if (ADD) v += src[(size_t)rowc * ldc + colc];
          C[(size_t)rowc * ldc + colc] = v;
        }
      }
    }
}

// ------- 128(M)x64(N) bf16 SwiGLU GEMM: 4 waves, per-wave 64x32 u AND v -----
__global__ __launch_bounds__(256) void mgemm_glu(const short* __restrict__ A,
    const short* __restrict__ Bw, short* __restrict__ C,
    int M, int N, int K, int lda, int ldb, int ldc) {
  __shared__ short As[128][72];
  __shared__ short Bu[64][72];
  __shared__ short Bv[64][72];
  const int bm = blockIdx.y * 128, bn = blockIdx.x * 64;
  const int tid = threadIdx.x;
  const int w = tid >> 6, lane = tid & 63;
  const int wr = (w >> 1) << 6, wc = (w & 1) << 5;
  const int arow = bm + (tid >> 1), ac = (tid & 1) << 5;
  const int brow = bn + (tid >> 2), bc = (tid & 3) << 4;
  const int lrow = lane & 15, lk8 = (lane >> 4) << 3;
  f32x4 au[4][2], av[4][2];
#pragma unroll
  for (int i = 0; i < 4; ++i)
#pragma unroll
    for (int j = 0; j < 2; ++j) {
      au[i][j] = (f32x4){0.f, 0.f, 0.f, 0.f};
      av[i][j] = (f32x4){0.f, 0.f, 0.f, 0.f};
    }
  bf16x8 ra[4], ru[2], rv[2];
  {
    const short* ap = A + (size_t)arow * lda + ac;
    const short* up = Bw + (size_t)brow * ldb + bc;
    const short* vp = Bw + (size_t)(N + brow) * ldb + bc;
#pragma unroll
    for (int e = 0; e < 4; ++e) ra[e] = *reinterpret_cast<const bf16x8*>(ap + (e << 3));
    ru[0] = *reinterpret_cast<const bf16x8*>(up);
    ru[1] = *reinterpret_cast<const bf16x8*>(up + 8);
    rv[0] = *reinterpret_cast<const bf16x8*>(vp);
    rv[1] = *reinterpret_cast<const bf16x8*>(vp + 8);
  }
  for (int k0 = 0; k0 < K; k0 += 64) {
    __syncthreads();
#pragma unroll
    for (int e = 0; e < 4; ++e)
      *reinterpret_cast<bf16x8*>(&As[tid >> 1][ac + (e << 3)]) = ra[e];
    *reinterpret_cast<bf16x8*>(&Bu[tid >> 2][bc])     = ru[0];
    *reinterpret_cast<bf16x8*>(&Bu[tid >> 2][bc + 8]) = ru[1];
    *reinterpret_cast<bf16x8*>(&Bv[tid >> 2][bc])     = rv[0];
    *reinterpret_cast<bf16x8*>(&Bv[tid >> 2][bc + 8]) = rv[1];
    __syncthreads();
    const int kn = k0 + 64;
    if (kn < K) {
      const short* ap = A + (size_t)arow * lda + kn + ac;
      const short* up = Bw + (size_t)brow * ldb + kn + bc;
      const short* vp = Bw + (size_t)(N + brow) * ldb + kn + bc;
#pragma unroll
      for (int e = 0; e < 4; ++e) ra[e] = *reinterpret_cast<const bf16x8*>(ap + (e << 3));
      ru[0] = *reinterpret_cast<const bf16x8*>(up);
      ru[1] = *reinterpret_cast<const bf16x8*>(up + 8);
      rv[0] = *reinterpret_cast<const bf16x8*>(vp);
      rv[1] = *reinterpret_cast<const bf16x8*>(vp + 8);
    }
#pragma unroll
    for (int kk = 0; kk < 2; ++kk) {
      bf16x8 af[4], uf[2], vf[2];
#pragma unroll
      for (int i = 0; i < 4; ++i)
        af[i] = *reinterpret_cast<bf16x8*>(&As[wr + (i << 4) + lrow][(kk << 5) + lk8]);
#pragma unroll
      for (int j = 0; j < 2; ++j) {
        uf[j] = *reinterpret_cast<bf16x8*>(&Bu[wc + (j << 4) + lrow][(kk << 5) + lk8]);
        vf[j] = *reinterpret_cast<bf16x8*>(&Bv[wc + (j << 4) + lrow][(kk << 5) + lk8]);
      }
#pragma unroll
      for (int i = 0; i < 4; ++i)
#pragma unroll
        for (int j = 0; j < 2; ++j) {
          au[i][j] = __builtin_amdgcn_mfma_f32_16x16x32_bf16(af[i], uf[j], au[i][j], 0, 0, 0);
          av[i][j] = __builtin_amdgcn_mfma_f32_16x16x32_bf16(af[i], vf[j], av[i][j], 0, 0, 0);
        }
    }
  }
  const int crow0 = bm + wr + ((lane >> 4) << 2);
  const int ccol0 = bn + wc + lrow;
#pragma unroll
  for (int mi = 0; mi < 4; ++mi)
#pragma unroll
    for (int ni = 0; ni < 2; ++ni) {
      int colc = ccol0 + (ni << 4);
#pragma unroll
      for (int r = 0; r < 4; ++r) {
        int rowc = crow0 + (mi << 4) + r;
        float uu = au[mi][ni][r], vg = av[mi][ni][r];
        float sig = 1.0f / (1.0f + __expf(-vg));
        C[(size_t)rowc * ldc + colc] = cvt_bf16(uu * vg * sig);
      }
    }
}

// ---------------- Build Q/K (split heads + RoPE) -> bf16 ----------------
__global__ __launch_bounds__(256) void build_qk(const float* __restrict__ qf,
    const float* __restrict__ kvb, const float* __restrict__ ckv,
    const float* __restrict__ fc, const float* __restrict__ fs,
    short* __restrict__ Qb, short* __restrict__ Kb) {
  int t = blockIdx.x * 256 + threadIdx.x;
  int h2 = blockIdx.y;
  if (t >= S) return;
  int hh = h2 >> 1, par = h2 & 1;
  const float* qrow = qf + (size_t)t*1536 + hh*96;
  const float* krow = kvb + (size_t)t*2048 + hh*128;
  unsigned qu[24], ku[24];
#pragma unroll
  for (int xq = 0; xq < 8; ++xq) {
    float4 qv = *reinterpret_cast<const float4*>(qrow + par*32 + (xq<<2));
    float4 kv = *reinterpret_cast<const float4*>(krow + par*32 + (xq<<2));
    qu[xq*2]   = pk2(qv.x, qv.y); qu[xq*2+1] = pk2(qv.z, qv.w);
    ku[xq*2]   = pk2(kv.x, kv.y); ku[xq*2+1] = pk2(kv.z, kv.w);
  }
  int p = t >> 2;
  const float* qr = qrow + 64 + par*16;
  const float* kr = ckv + (size_t)t*288 + 256 + par*16;
#pragma unroll
  for (int mq = 0; mq < 8; ++mq) {
    float c = 1.f, sn = 0.f;
    if (p > 0) { c = fc[(p-1)*8 + mq]; sn = fs[(p-1)*8 + mq]; }
    float q0 = qr[2*mq], q1 = qr[2*mq+1];
    qu[16 + mq] = pk2(q0*c - q1*sn, q0*sn + q1*c);
    float k0 = kr[2*mq], k1 = kr[2*mq+1];
    ku[16 + mq] = pk2(k0*c - k1*sn, k0*sn + k1*c);
  }
  unsigned* qo = (unsigned*)(Qb + ((size_t)h2*S + t)*DQK);
  unsigned* ko = (unsigned*)(Kb + ((size_t)h2*S + t)*DQK);
#pragma unroll
  for (int e = 0; e < 6; ++e) {
    *reinterpret_cast<uint4*>(qo + (e<<2)) = make_uint4(qu[e*4], qu[e*4+1], qu[e*4+2], qu[e*4+3]);
    *reinterpret_cast<uint4*>(ko + (e<<2)) = make_uint4(ku[e*4], ku[e*4+1], ku[e*4+2], ku[e*4+3]);
  }
}

// ---------------- V transpose to bf16: Vt[hh][d][t] ----------------
__global__ __launch_bounds__(256) void vt_build(const float* __restrict__ kvb,
    short* __restrict__ Vt) {
  const int hh = blockIdx.x;
  const int t0 = blockIdx.y << 7;
  __shared__ short Ts[128][74];
  const int tl = threadIdx.x >> 3, dp = (threadIdx.x & 7) << 3;
#pragma unroll
  for (int pass = 0; pass < 4; ++pass) {
    int t = t0 + (pass << 5) + tl;
    const float* vp = kvb + (size_t)t*2048 + hh*128 + 64 + dp;
    float4 a = *reinterpret_cast<const float4*>(vp);
    float4 b = *reinterpret_cast<const float4*>(vp + 4);
    *reinterpret_cast<bf16x8*>(&Ts[(pass << 5) + tl][dp]) = cvt8(a, b);
  }
  __syncthreads();
  for (int idx = threadIdx.x; idx < 1024; idx += 256) {
    int d = idx >> 4, tseg = (idx & 15) << 3;
    bf16x8 v;
#pragma unroll
    for (int e = 0; e < 8; ++e) v[e] = Ts[tseg + e][d];
    *reinterpret_cast<bf16x8*>(Vt + ((size_t)hh*HD + d)*S + t0 + tseg) = v;
  }
}

// ---------------- lambda scalar ----------------
__global__ void compute_lam(const float* __restrict__ lq1, const float* __restrict__ lk1,
                            const float* __restrict__ lq2, const float* __restrict__ lk2,
                            float* __restrict__ lamp) {
  int t = threadIdx.x;
  float a = lq1[t]*lk1[t];
  float b = lq2[t]*lk2[t];
#pragma unroll
  for (int mm = 1; mm < 32; mm <<= 1) { a += __shfl_xor(a, mm, 32); b += __shfl_xor(b, mm, 32); }
  if (t == 0) lamp[0] = expf(a) - expf(b) + 0.2f;
}

// ------- MFMA flash attention: NO-LDS fragments direct from L2 ----------
// grid (12, 32, 2); block bx = cq*3 + k; wave w owns residue q-tile qi=k+3w.
// No barriers; waves fully independent; K/V tiles are L2-resident.
__global__ __launch_bounds__(256) void flash_mfma(const short* __restrict__ Qb,
    const short* __restrict__ Kb, const short* __restrict__ Vg,
    float* __restrict__ Ob, float* __restrict__ rowm, float* __restrict__ rowl,
    float* __restrict__ Ob1a, float* __restrict__ Ob1b,
    float* __restrict__ rm1, float* __restrict__ rl1) {
  const int h2 = blockIdx.y;
  const int hh = h2 >> 1;
  const int z  = blockIdx.z;
  const int tid = threadIdx.x;
  const int w = tid >> 6, lane = tid & 63;
  const int ql = lane & 31, h = lane >> 5;
  const int cq = blockIdx.x / 3, k = blockIdx.x % 3;
  const int qi = k + 3*w;
  const int qbase = cq*SPP + (qi << 5);
  const int ri0w = qi << 5;

  __shared__ __align__(16) float Ot[4][32][36];

  bf16x8 qf0, qf1, qf2;
  {
    const short* qp = Qb + ((size_t)h2*S + qbase + ql)*DQK + (h << 3);
    qf0 = *reinterpret_cast<const bf16x8*>(qp);
    qf1 = *reinterpret_cast<const bf16x8*>(qp + 16);
    qf2 = *reinterpret_cast<const bf16x8*>(qp + 32);
  }
  const short* Kbase = Kb + (size_t)h2*S*DQK + (h << 3);
  const short* V0 = Vg + ((size_t)hh*HD + ql)*S + (h << 3);
  const short* V1 = Vg + ((size_t)hh*HD + 32 + ql)*S + (h << 3);

  float m = -1e30f, l = 0.f;
  f32x16 o0, o1;
#pragma unroll
  for (int r = 0; r < 16; ++r) { o0[r] = 0.f; o1[r] = 0.f; }

  for (int c = (z << 1); c < (z << 1) + 2; ++c) {
    for (int jr = 0; jr <= ri0w; jr += 32) {
      const int j0 = c*SPP + jr;
      const bool diag = (jr == ri0w);
      // direct global fragment loads (L2-resident)
      const short* kp = Kbase + (size_t)(j0 + ql)*DQK;
      bf16x8 kf0 = *reinterpret_cast<const bf16x8*>(kp);
      bf16x8 kf1 = *reinterpret_cast<const bf16x8*>(kp + 16);
      bf16x8 kf2 = *reinterpret_cast<const bf16x8*>(kp + 32);
      bf16x8 v00 = *reinterpret_cast<const bf16x8*>(V0 + j0);
      bf16x8 v01 = *reinterpret_cast<const bf16x8*>(V0 + j0 + 16);
      bf16x8 v10 = *reinterpret_cast<const bf16x8*>(V1 + j0);
      bf16x8 v11 = *reinterpret_cast<const bf16x8*>(V1 + j0 + 16);

      f32x16 st;
#pragma unroll
      for (int r = 0; r < 16; ++r) st[r] = 0.f;
      st = __builtin_amdgcn_mfma_f32_32x32x16_bf16(kf0, qf0, st, 0, 0, 0);
      st = __builtin_amdgcn_mfma_f32_32x32x16_bf16(kf1, qf1, st, 0, 0, 0);
      st = __builtin_amdgcn_mfma_f32_32x32x16_bf16(kf2, qf2, st, 0, 0, 0);

      if (diag) {
#pragma unroll
        for (int r = 0; r < 16; ++r) {
          int kl = (r & 3) + ((r >> 2) << 3) + (h << 2);
          st[r] = (kl <= ql) ? st[r] * SCALING : -1e30f;
        }
      } else {
#pragma unroll
        for (int r = 0; r < 16; ++r) st[r] *= SCALING;
      }

      // defer-max (T13)
      float tm = st[0];
#pragma unroll
      for (int r = 1; r < 16; ++r) tm = fmaxf(tm, st[r]);
      tm = fmaxf(tm, __shfl_xor(tm, 32));
      if (__any(tm > m + 8.0f)) {
        float mnew = fmaxf(m, tm);
        float sc = __expf(m - mnew);
        m = mnew;
        l *= sc;
#pragma unroll
        for (int r = 0; r < 16; ++r) { o0[r] *= sc; o1[r] *= sc; }
      }
      float ps = 0.f;
#pragma unroll
      for (int r = 0; r < 16; ++r) { float p = __expf(st[r] - m); st[r] = p; ps += p; }
      ps += __shfl_xor(ps, 32);
      l += ps;

      unsigned A0 = pk2(st[0],  st[1]),  B0 = pk2(st[2],  st[3]);
      unsigned C0 = pk2(st[4],  st[5]),  D0 = pk2(st[6],  st[7]);
      unsigned A1 = pk2(st[8],  st[9]),  B1 = pk2(st[10], st[11]);
      unsigned C1 = pk2(st[12], st[13]), D1 = pk2(st[14], st[15]);
      unsigned xA0 = (unsigned)__shfl_xor((int)A0, 32), xB0 = (unsigned)__shfl_xor((int)B0, 32);
      unsigned xC0 = (unsigned)__shfl_xor((int)C0, 32), xD0 = (unsigned)__shfl_xor((int)D0, 32);
      unsigned xA1 = (unsigned)__shfl_xor((int)A1, 32), xB1 = (unsigned)__shfl_xor((int)B1, 32);
      unsigned xC1 = (unsigned)__shfl_xor((int)C1, 32), xD1 = (unsigned)__shfl_xor((int)D1, 32);
      union { unsigned u[4]; bf16x8 v; } P0, P1;
      P0.u[0] = h ? xC0 : A0;  P0.u[1] = h ? xD0 : B0;
      P0.u[2] = h ? C0 : xA0;  P0.u[3] = h ? D0 : xB0;
      P1.u[0] = h ? xC1 : A1;  P1.u[1] = h ? xD1 : B1;
      P1.u[2] = h ? C1 : xA1;  P1.u[3] = h ? D1 : xB1;

      o0 = __builtin_amdgcn_mfma_f32_32x32x16_bf16(v00, P0.v, o0, 0, 0, 0);
      o0 = __builtin_amdgcn_mfma_f32_32x32x16_bf16(v01, P1.v, o0, 0, 0, 0);
      o1 = __builtin_amdgcn_mfma_f32_32x32x16_bf16(v10, P0.v, o1, 0, 0, 0);
      o1 = __builtin_amdgcn_mfma_f32_32x32x16_bf16(v11, P1.v, o1, 0, 0, 0);
    }
  }

  // epilogue: two-pass transpose through half-size wave-private LDS
  float* ot = &Ot[w][0][0];
  float* orow;
  if (z == 0) orow = Ob + ((size_t)h2*S + qbase)*HD;
  else orow = (h2 < 16) ? Ob1a + ((size_t)h2*S + qbase)*HD
                        : Ob1b + ((size_t)(h2 - 16)*S + qbase)*HD;
#pragma unroll
  for (int r = 0; r < 16; ++r) {
    int dl = (r & 3) + ((r >> 2) << 3) + (h << 2);
    ot[ql*36 + dl] = o0[r];
  }
#pragma unroll
  for (int it = 0; it < 4; ++it) {   // same-wave LDS: in-order, no barrier
    int idx = lane + (it << 6);
    int row = idx >> 3, c4 = (idx & 7) << 2;
    float4 v = *reinterpret_cast<float4*>(&ot[row*36 + c4]);
    *reinterpret_cast<float4*>(&orow[(size_t)row*HD + c4]) = v;
  }
#pragma unroll
  for (int r = 0; r < 16; ++r) {
    int dl = (r & 3) + ((r >> 2) << 3) + (h << 2);
    ot[ql*36 + dl] = o1[r];
  }
#pragma unroll
  for (int it = 0; it < 4; ++it) {
    int idx = lane + (it << 6);
    int row = idx >> 3, c4 = (idx & 7) << 2;
    float4 v = *reinterpret_cast<float4*>(&ot[row*36 + c4]);
    *reinterpret_cast<float4*>(&orow[(size_t)row*HD + 32 + c4]) = v;
  }
  if (lane < 32) {
    if (z == 0) { rowm[h2*S + qbase + lane] = m; rowl[h2*S + qbase + lane] = l; }
    else        { rm1[h2*S + qbase + lane] = m;  rl1[h2*S + qbase + lane] = l; }
  }
}

// ---------------- merge the two flash partials, normalize ----------------
__global__ __launch_bounds__(256) void merge_flash(float* __restrict__ Ob,
    float* __restrict__ rowm, float* __restrict__ rowl,
    const float* __restrict__ Ob1a, const float* __restrict__ Ob1b,
    const float* __restrict__ rm1, const float* __restrict__ rl1) {
  const int gid = blockIdx.x * 4 + (threadIdx.x >> 6);
  const int d = threadIdx.x & 63;
  const int h2 = gid / S;
  float m0 = rowm[gid], l0 = rowl[gid], m1 = rm1[gid], l1 = rl1[gid];
  float m = fmaxf(m0, m1);
  float w0 = __expf(m0 - m), w1 = __expf(m1 - m);
  float linv = 1.0f / (l0*w0 + l1*w1);
  const float* o1 = (h2 < 16) ? (Ob1a + (size_t)gid*HD)
                              : (Ob1b + ((size_t)gid - (size_t)16*S)*HD);
  float v0 = Ob[(size_t)gid*HD + d];
  float v1 = o1[d];
  Ob[(size_t)gid*HD + d] = (v0*w0 + v1*w1) * linv;
  if (d == 0) { rowm[gid] = m; rowl[gid] = l0*w0 + l1*w1; }
}

// ---------------- colsum via MFMA (bf16 inputs) ----------------
__global__ __launch_bounds__(256) void colsum_mfma(const short* __restrict__ Qb,
    const short* __restrict__ Kb, const float* __restrict__ rowm,
    const float* __restrict__ rowl, float* __restrict__ gcol) {
  const int jt = blockIdx.x;
  const int hh = blockIdx.y, h2 = hh << 1;
  const int cK = jt / 12, jr32 = jt % 12;
  const int jr = jr32 << 5;
  const int j0 = cK*SPP + jr;
  const int tid = threadIdx.x;
  const int w = tid >> 6, lane = tid & 63;
  const int ql = lane & 31, h = lane >> 5;

  bf16x8 kf0, kf1, kf2;
  {
    const short* kp = Kb + ((size_t)h2*S + j0 + ql)*DQK + (h << 3);
    kf0 = *reinterpret_cast<const bf16x8*>(kp);
    kf1 = *reinterpret_cast<const bf16x8*>(kp + 16);
    kf2 = *reinterpret_cast<const bf16x8*>(kp + 32);
  }
  const int nt = 12 - jr32;
  const int T = nt << 2;
  float gs[16];
#pragma unroll
  for (int r = 0; r < 16; ++r) gs[r] = 0.f;

  for (int tt = w; tt < T; tt += 4) {
    int cq = tt / nt, qrem = tt - cq*nt;
    int qi = jr32 + qrem;
    int i0 = cq*SPP + (qi << 5);
    const bool diag = (qrem == 0);
    const short* qp = Qb + ((size_t)h2*S + i0 + ql)*DQK + (h << 3);
    bf16x8 qf0 = *reinterpret_cast<const bf16x8*>(qp);
    bf16x8 qf1 = *reinterpret_cast<const bf16x8*>(qp + 16);
    bf16x8 qf2 = *reinterpret_cast<const bf16x8*>(qp + 32);
    f32x16 st;
#pragma unroll
    for (int r = 0; r < 16; ++r) st[r] = 0.f;
    st = __builtin_amdgcn_mfma_f32_32x32x16_bf16(kf0, qf0, st, 0, 0, 0);
    st = __builtin_amdgcn_mfma_f32_32x32x16_bf16(kf1, qf1, st, 0, 0, 0);
    st = __builtin_amdgcn_mfma_f32_32x32x16_bf16(kf2, qf2, st, 0, 0, 0);
    float Mq = rowm[h2*S + i0 + ql];
    float Lq = 1.0f / rowl[h2*S + i0 + ql];
    if (diag) {
#pragma unroll
      for (int r = 0; r < 16; ++r) {
        int kl = (r & 3) + ((r >> 2) << 3) + (h << 2);
        if (kl <= ql) gs[r] += __expf(st[r]*SCALING - Mq) * Lq;
      }
    } else {
#pragma unroll
      for (int r = 0; r < 16; ++r) gs[r] += __expf(st[r]*SCALING - Mq) * Lq;
    }
  }
  __shared__ float gw[4][32];
#pragma unroll
  for (int r = 0; r < 16; ++r) {
    float v = gs[r];
#pragma unroll
    for (int mm = 1; mm < 32; mm <<= 1) v += __shfl_xor(v, mm, 32);
    if (ql == 0) gw[w][(r & 3) + ((r >> 2) << 3) + (h << 2)] = v;
  }
  __syncthreads();
  if (tid < 32) {
    float s = gw[0][tid] + gw[1][tid] + gw[2][tid] + gw[3][tid];
    gcol[hh*S + j0 + tid] = s * (1.0f / (float)S);
  }
}

// ---------------- Wpre: masked prefix of g-weighted V ----------------
__global__ __launch_bounds__(256) void build_wpre(const float* __restrict__ gcol,
    const float* __restrict__ kvb, float* __restrict__ Wpre) {
  const int hh = blockIdx.x >> 2;
  const int dq = (blockIdx.x & 3) << 4;
  __shared__ float Wt[SPP][16];
  const int tid = threadIdx.x;
  for (int idx = tid; idx < SPP*16; idx += 256) {
    int r = idx >> 4, dd = idx & 15;
    float val = 0.f;
#pragma unroll
    for (int b2 = 0; b2 < 4; ++b2) {
      int j = b2*SPP + r;
      val = fmaf(gcol[hh*S + j], kvb[(size_t)j*2048 + hh*128 + 64 + dq + dd], val);
    }
    Wt[r][dd] = val;
  }
  __syncthreads();
  if (tid < 16) {
    float run = 0.f;
    for (int r = 0; r < SPP; ++r) { run += Wt[r][tid]; Wt[r][tid] = run; }
  }
  __syncthreads();
  for (int idx = tid; idx < SPP*16; idx += 256) {
    int r = idx >> 4, dd = idx & 15;
    Wpre[((size_t)hh*SPP + r)*HD + dq + dd] = Wt[r][dd];
  }
}

// ------- combine (diff-attn) + per-head RMSNorm + scrambled reshape -> bf16 ---
__global__ __launch_bounds__(64) void combine_rms(const float* __restrict__ Ob,
    const float* __restrict__ Wpre, const float* __restrict__ lamp,
    const float* __restrict__ anw, short* __restrict__ attno) {
  const int t = blockIdx.x, h = blockIdx.y, d = threadIdx.x;
  const float lam = lamp[0];
  const float o1 = Ob[((size_t)(2*h)*S + t)*HD + d];
  const float o2 = Ob[((size_t)(2*h+1)*S + t)*HD + d];
  const float w3 = Wpre[((size_t)h*SPP + (t % SPP))*HD + d];
  float val = o1 - lam*o2 + lam*w3;
  float ss = val*val;
#pragma unroll
  for (int mm = 1; mm < 64; mm <<= 1) ss += __shfl_xor(ss, mm, 64);
  float scale = rsqrtf(ss * (1.0f/HD) + ATTN_EPS) * anw[d];
  int tn = h*96 + (t >> 4);
  int cn = ((t & 15) << 6) + d;
  attno[(size_t)tn*DM + cn] = cvt_bf16(val * scale);
}

// =========================== launch ===========================
extern "C" void kernel_launch(void* const* d_in, const int* in_sizes, int n_in,
                              void* d_out, int out_size, void* d_ws, size_t ws_size,
                              hipStream_t stream) {
  (void)in_sizes; (void)n_in; (void)out_size;
  const float* x    = (const float*)d_in[0];
  const float* fc   = (const float*)d_in[1];
  const float* fs   = (const float*)d_in[2];
  const float* n1w  = (const float*)d_in[3];
  const float* n2w  = (const float*)d_in[4];
  const float* kvdw = (const float*)d_in[5];
  const float* qdw  = (const float*)d_in[6];
  const float* kvnw = (const float*)d_in[7];
  const float* qnw  = (const float*)d_in[8];
  const float* kvuw = (const float*)d_in[9];
  const float* quw  = (const float*)d_in[10];
  const float* lq1  = (const float*)d_in[11];
  const float* lk1  = (const float*)d_in[12];
  const float* lq2  = (const float*)d_in[13];
  const float* lk2  = (const float*)d_in[14];
  const float* anw  = (const float*)d_in[15];
  const float* ow   = (const float*)d_in[16];
  const float* ffiw = (const float*)d_in[17];
  const float* ffow = (const float*)d_in[18];
  float* out = (float*)d_out;
  float* ws  = (float*)d_ws;

  float* xin   = ws;
  float* ckv   = xin   + (size_t)S*DM;
  float* qmid  = ckv   + (size_t)S*288;
  float* kvb   = qmid  + (size_t)S*QC;
  float* qf    = kvb   + (size_t)S*2048;
  float* Qb    = qf    + (size_t)S*1536;
  float* Kb    = Qb    + (size_t)H2N*S*DQK;
  float* Obuf  = Kb    + (size_t)H2N*S*DQK;
  float* rowm  = Obuf  + (size_t)H2N*S*HD;
  float* rowl  = rowm  + (size_t)H2N*S;
  float* gcol  = rowl  + (size_t)H2N*S;
  float* Wpre  = gcol  + (size_t)NH*S;
  float* attno = Wpre  + (size_t)NH*SPP*HD;
  float* lamp  = attno + (size_t)S*DM;
  short* fbufs = (short*)kvb;     // bf16 FFN activation overlays kv region
  float* Ob1a = xin;
  float* Ob1b = qf;
  float* rm1  = qf + (size_t)16*S*HD;
  float* rl1  = rm1 + (size_t)H2N*S;
  short* Qb_bf = (short*)Qb;
  short* Kb_bf = (short*)Kb;
  short* Vt_bf = (short*)Qb + 2359296;
  short* xin_bf  = (short*)xin;
  short* ckv_bf  = (short*)Obuf;
  short* qmid_bf = ckv_bf + (size_t)S*KVC;
  short* h_bf    = (short*)xin;
  short* attno_bf = (short*)attno;
  short* kvdw_bf = (short*)attno;
  short* qdw_bf  = kvdw_bf + 294912;
  short* kvuw_bf = qdw_bf  + 393216;
  short* quw_bf  = kvuw_bf + 524288;
  short* ffiw_bf = (short*)Qb;
  short* ow_bf   = ffiw_bf + 8388608;
  short* ffow_bf = (short*)Obuf;
  if (ws_size < (size_t)18063376 * sizeof(float)) return;

  cvt_w4<<<880, 256, 0, stream>>>(kvdw, 294912, qdw, 393216, kvuw, 524288, quw, 589824, kvdw_bf);
  rmsnorm_bf<<<S, 256, 0, stream>>>(x, n1w, xin_bf, DM, DM, DM, EPS_RMS);
  { dim3 g(5, 24);  mgemm_nt<0><<<g, 256, 0, stream>>>(xin_bf, kvdw_bf, nullptr, ckv, S, 288, DM, DM, DM, 288); }
  { dim3 g(6, 24);  mgemm_nt<0><<<g, 256, 0, stream>>>(xin_bf, qdw_bf,  nullptr, qmid, S, QC, DM, DM, DM, QC); }
  rmsnorm_bf<<<S, 256, 0, stream>>>(ckv,  kvnw, ckv_bf,  KVC, 288, KVC, EPS_RMS);
  rmsnorm_bf<<<S, 256, 0, stream>>>(qmid, qnw,  qmid_bf, QC,  QC,  QC,  EPS_RMS);
  { dim3 g(32, 24); mgemm_nt<0><<<g, 256, 0, stream>>>(ckv_bf,  kvuw_bf, nullptr, kvb, S, 2048, KVC, KVC, KVC, 2048); }
  { dim3 g(24, 24); mgemm_nt<0><<<g, 256, 0, stream>>>(qmid_bf, quw_bf,  nullptr, qf,  S, 1536, QC,  QC,  QC,  1536); }
  { dim3 g(6, 32);  build_qk<<<g, 256, 0, stream>>>(qf, kvb, ckv, fc, fs, Qb_bf, Kb_bf); }
  { dim3 g(16, 12); vt_build<<<g, 256, 0, stream>>>(kvb, Vt_bf); }
  compute_lam<<<1, 32, 0, stream>>>(lq1, lk1, lq2, lk2, lamp);
  { dim3 g(12, 32, 2); flash_mfma<<<g, 256, 0, stream>>>(Qb_bf, Kb_bf, Vt_bf, Obuf, rowm, rowl,
                                                         Ob1a, Ob1b, rm1, rl1); }
  merge_flash<<<(H2N*S)/4, 256, 0, stream>>>(Obuf, rowm, rowl, Ob1a, Ob1b, rm1, rl1);
  { dim3 g(48, 16); colsum_mfma<<<g, 256, 0, stream>>>(Qb_bf, Kb_bf, rowm, rowl, gcol); }
  cvt_w4<<<4608, 256, 0, stream>>>(ffiw, 8388608, ow, 1048576, nullptr, 0, nullptr, 0, ffiw_bf);
  build_wpre<<<64, 256, 0, stream>>>(gcol, kvb, Wpre);
  { dim3 g(S, 16);  combine_rms<<<g, 64, 0, stream>>>(Obuf, Wpre, lamp, anw, attno_bf); }
  cvt_w4<<<2048, 256, 0, stream>>>(ffow, 4194304, nullptr, 0, nullptr, 0, nullptr, 0, ffow_bf);
  { dim3 g(16, 24); mgemm_nt<1><<<g, 256, 0, stream>>>(attno_bf, ow_bf, x, out, S, DM, DM, DM, DM, DM); }
  rmsnorm_bf<<<S, 256, 0, stream>>>(out, n2w, h_bf, DM, DM, DM, EPS_RMS);
  { dim3 g(64, 12); mgemm_glu<<<g, 256, 0, stream>>>(h_bf, ffiw_bf, fbufs, S, DFF, DM, DM, DM, DFF); }
  { dim3 g(16, 24); mgemm_nt<1><<<g, 256, 0, stream>>>(fbufs, ffow_bf, out, out, S, DM, DFF, DFF, DFF, DM); }
}

// Round 14
// 235.925 us; speedup vs baseline: 10.0628x; 1.0335x over previous
//
#include <hip/hip_runtime.h>
#include <math.h>

#define S     1536
#define DM    1024
#define NH    16
#define H2N   32
#define HD    64
#define KVC   256
#define QC    384
#define DFF   4096
#define SPP   384
#define DQK   48
#define EPS_RMS  1.1920929e-07f
#define ATTN_EPS 1e-5f
#define SCALING  0.14433756729740643f   /* 48^-0.5 */

typedef float f32x4 __attribute__((ext_vector_type(4)));
typedef float f32x16 __attribute__((ext_vector_type(16)));
typedef short bf16x8 __attribute__((ext_vector_type(8)));

__device__ __forceinline__ short cvt_bf16(float f) {
  union { float f; unsigned u; } x; x.f = f;
  unsigned r = x.u + 0x7FFFu + ((x.u >> 16) & 1u);
  return (short)(r >> 16);
}
__device__ __forceinline__ unsigned pk2(float a, float b) { // HW RNE pack
  unsigned r;
  asm("v_cvt_pk_bf16_f32 %0, %1, %2" : "=v"(r) : "v"(a), "v"(b));
  return r;
}
__device__ __forceinline__ bf16x8 cvt8(float4 a, float4 b) {
  union { unsigned u[4]; bf16x8 v; } r;
  r.u[0] = pk2(a.x, a.y); r.u[1] = pk2(a.z, a.w);
  r.u[2] = pk2(b.x, b.y); r.u[3] = pk2(b.z, b.w);
  return r.v;
}

// ---------------- weight fp32 -> bf16 (up to 4 segments, sizes %2048==0) ----
__global__ __launch_bounds__(256) void cvt_w4(const float* __restrict__ s0, int n0,
    const float* __restrict__ s1, int n1, const float* __restrict__ s2, int n2,
    const float* __restrict__ s3, int n3, short* __restrict__ dst) {
  long base = (long)blockIdx.x * 2048 + (long)threadIdx.x * 8;
  const float* src; long off;
  if (base < n0) { src = s0; off = base; }
  else if (base < (long)n0 + n1) { src = s1; off = base - n0; }
  else if (base < (long)n0 + n1 + n2) { src = s2; off = base - n0 - n1; }
  else { src = s3; off = base - n0 - n1 - n2; }
  float4 a = *reinterpret_cast<const float4*>(src + off);
  float4 b = *reinterpret_cast<const float4*>(src + off + 4);
  *reinterpret_cast<bf16x8*>(dst + base) = cvt8(a, b);
}

// ---------------- RMSNorm -> bf16 out ----------------
__global__ __launch_bounds__(256) void rmsnorm_bf(const float* __restrict__ in,
    const float* __restrict__ w, short* __restrict__ out,
    int cols, int ldin, int ldout, float eps) {
  const int row = blockIdx.x;
  const float* xr = in + (size_t)row * ldin;
  short* yr = out + (size_t)row * ldout;
  const int tid = threadIdx.x;
  float ss = 0.f;
  for (int c = tid << 2; c < cols; c += 1024) {
    float4 v = *reinterpret_cast<const float4*>(xr + c);
    ss += v.x*v.x + v.y*v.y + v.z*v.z + v.w*v.w;
  }
#pragma unroll
  for (int mm = 1; mm < 64; mm <<= 1) ss += __shfl_xor(ss, mm, 64);
  __shared__ float red[4];
  if ((tid & 63) == 0) red[tid >> 6] = ss;
  __syncthreads();
  float tot = red[0] + red[1] + red[2] + red[3];
  float scale = rsqrtf(tot / (float)cols + eps);
  for (int c = tid << 2; c < cols; c += 1024) {
    float4 v = *reinterpret_cast<const float4*>(xr + c);
    float4 wv = *reinterpret_cast<const float4*>(w + c);
    uint2 p;
    p.x = pk2(v.x*scale*wv.x, v.y*scale*wv.y);
    p.y = pk2(v.z*scale*wv.z, v.w*scale*wv.w);
    *reinterpret_cast<uint2*>(yr + c) = p;
  }
}

// ------ RMSNorm over (p0+p1+xres), writes residual fp32 AND bf16 norm -------
// cols == DM == 1024: exactly one float4 per thread.
__global__ __launch_bounds__(256) void rmsnorm_sum_bf(const float* __restrict__ p0,
    const float* __restrict__ p1, const float* __restrict__ xres,
    const float* __restrict__ w, float* __restrict__ outw, short* __restrict__ yb,
    float eps) {
  const int row = blockIdx.x;
  const int c = threadIdx.x << 2;
  const size_t base = (size_t)row * DM + c;
  float4 a = *reinterpret_cast<const float4*>(p0 + base);
  float4 b = *reinterpret_cast<const float4*>(p1 + base);
  float4 xv = *reinterpret_cast<const float4*>(xres + base);
  float4 v = make_float4(a.x+b.x+xv.x, a.y+b.y+xv.y, a.z+b.z+xv.z, a.w+b.w+xv.w);
  *reinterpret_cast<float4*>(outw + base) = v;
  float ss = v.x*v.x + v.y*v.y + v.z*v.z + v.w*v.w;
#pragma unroll
  for (int mm = 1; mm < 64; mm <<= 1) ss += __shfl_xor(ss, mm, 64);
  __shared__ float red[4];
  if ((threadIdx.x & 63) == 0) red[threadIdx.x >> 6] = ss;
  __syncthreads();
  float tot = red[0] + red[1] + red[2] + red[3];
  float scale = rsqrtf(tot * (1.0f / (float)DM) + eps);
  float4 wv = *reinterpret_cast<const float4*>(w + c);
  uint2 p;
  p.x = pk2(v.x*scale*wv.x, v.y*scale*wv.y);
  p.y = pk2(v.z*scale*wv.z, v.w*scale*wv.w);
  *reinterpret_cast<uint2*>(yb + base) = p;
}

// ---------------- out += p0 + p1 (grid: S*DM/1024) ----------------
__global__ __launch_bounds__(256) void fadd2(float* __restrict__ out,
    const float* __restrict__ p0, const float* __restrict__ p1) {
  size_t i = ((size_t)blockIdx.x * 256 + threadIdx.x) << 2;
  float4 o = *reinterpret_cast<float4*>(out + i);
  float4 a = *reinterpret_cast<const float4*>(p0 + i);
  float4 b = *reinterpret_cast<const float4*>(p1 + i);
  o.x += a.x + b.x; o.y += a.y + b.y; o.z += a.z + b.z; o.w += a.w + b.w;
  *reinterpret_cast<float4*>(out + i) = o;
}

// ------------- bf16 MFMA GEMM, BK=64, register-prefetch; A,B bf16 ----------
template<int ADD>
__global__ __launch_bounds__(256) void mgemm_nt(const short* __restrict__ A,
    const short* __restrict__ B, const float* __restrict__ src, float* __restrict__ C,
    int M, int N, int K, int lda, int ldb, int ldc) {
  __shared__ short As[64][72];
  __shared__ short Bs[64][72];
  const int bm = blockIdx.y * 64, bn = blockIdx.x * 64;
  const int tid = threadIdx.x;
  const int w = tid >> 6, lane = tid & 63;
  const int wr = (w >> 1) << 5, wc = (w & 1) << 5;
  const int srow = tid >> 2, sk = (tid & 3) << 4;
  const int lrow = lane & 15, lk8 = (lane >> 4) << 3;
  const int arow = bm + srow, brow = bn + srow;
  const bool bvalid = brow < N;
  f32x4 acc[2][2];
#pragma unroll
  for (int i = 0; i < 2; ++i)
#pragma unroll
    for (int j = 0; j < 2; ++j) acc[i][j] = (f32x4){0.f, 0.f, 0.f, 0.f};

  bf16x8 rah0, rah1, rbh0, rbh1;
  {
    const short* ap = A + (size_t)arow * lda + sk;
    rah0 = *reinterpret_cast<const bf16x8*>(ap);
    rah1 = *reinterpret_cast<const bf16x8*>(ap + 8);
  }
  rbh0 = (bf16x8){0,0,0,0,0,0,0,0}; rbh1 = rbh0;
  if (bvalid) {
    const short* bp = B + (size_t)brow * ldb + sk;
    rbh0 = *reinterpret_cast<const bf16x8*>(bp);
    rbh1 = *reinterpret_cast<const bf16x8*>(bp + 8);
  }

  for (int k0 = 0; k0 < K; k0 += 64) {
    bf16x8 va0 = rah0, va1 = rah1, vb0 = rbh0, vb1 = rbh1;
    __syncthreads();
    *reinterpret_cast<bf16x8*>(&As[srow][sk])     = va0;
    *reinterpret_cast<bf16x8*>(&As[srow][sk + 8]) = va1;
    *reinterpret_cast<bf16x8*>(&Bs[srow][sk])     = vb0;
    *reinterpret_cast<bf16x8*>(&Bs[srow][sk + 8]) = vb1;
    __syncthreads();
    const int kn = k0 + 64;
    if (kn < K) {
      const short* ap = A + (size_t)arow * lda + kn + sk;
      rah0 = *reinterpret_cast<const bf16x8*>(ap);
      rah1 = *reinterpret_cast<const bf16x8*>(ap + 8);
      if (bvalid) {
        const short* bp = B + (size_t)brow * ldb + kn + sk;
        rbh0 = *reinterpret_cast<const bf16x8*>(bp);
        rbh1 = *reinterpret_cast<const bf16x8*>(bp + 8);
      }
    }
#pragma unroll
    for (int kk = 0; kk < 2; ++kk) {
      bf16x8 af0 = *reinterpret_cast<bf16x8*>(&As[wr + lrow][(kk << 5) + lk8]);
      bf16x8 af1 = *reinterpret_cast<bf16x8*>(&As[wr + 16 + lrow][(kk << 5) + lk8]);
      bf16x8 bf0 = *reinterpret_cast<bf16x8*>(&Bs[wc + lrow][(kk << 5) + lk8]);
      bf16x8 bf1 = *reinterpret_cast<bf16x8*>(&Bs[wc + 16 + lrow][(kk << 5) + lk8]);
      acc[0][0] = __builtin_amdgcn_mfma_f32_16x16x32_bf16(af0, bf0, acc[0][0], 0, 0, 0);
      acc[0][1] = __builtin_amdgcn_mfma_f32_16x16x32_bf16(af0, bf1, acc[0][1], 0, 0, 0);
      acc[1][0] = __builtin_amdgcn_mfma_f32_16x16x32_bf16(af1, bf0, acc[1][0], 0, 0, 0);
      acc[1][1] = __builtin_amdgcn_mfma_f32_16x16x32_bf16(af1, bf1, acc[1][1], 0, 0, 0);
    }
  }
  const int crow0 = bm + wr + ((lane >> 4) << 2);
  const int ccol0 = bn + wc + lrow;
#pragma unroll
  for (int mi = 0; mi < 2; ++mi)
#pragma unroll
    for (int ni = 0; ni < 2; ++ni) {
      int colc = ccol0 + (ni << 4);
      if (colc < N) {
#pragma unroll
        for (int r = 0; r < 4; ++r) {
          int rowc = crow0 + (mi << 4) + r;
          float v = acc[mi][ni][r];
          if (ADD) v += src[(size_t)rowc * ldc + colc];
          C[(size_t)rowc * ldc + colc] = v;
        }
      }
    }
}

// ------- split-K=2 bf16 GEMM: z-half of K -> fp32 partial (P0 or P1) --------
__global__ __launch_bounds__(256) void mgemm_sk(const short* __restrict__ A,
    const short* __restrict__ B, float* __restrict__ P0, float* __restrict__ P1,
    int M, int N, int K2, int lda, int ldb, int ldc) {
  __shared__ short As[64][72];
  __shared__ short Bs[64][72];
  const int bm = blockIdx.y * 64, bn = blockIdx.x * 64;
  const int koff = blockIdx.z * K2;
  float* C = blockIdx.z ? P1 : P0;
  const int tid = threadIdx.x;
  const int w = tid >> 6, lane = tid & 63;
  const int wr = (w >> 1) << 5, wc = (w & 1) << 5;
  const int srow = tid >> 2, sk = (tid & 3) << 4;
  const int lrow = lane & 15, lk8 = (lane >> 4) << 3;
  const int arow = bm + srow, brow = bn + srow;
  f32x4 acc[2][2];
#pragma unroll
  for (int i = 0; i < 2; ++i)
#pragma unroll
    for (int j = 0; j < 2; ++j) acc[i][j] = (f32x4){0.f, 0.f, 0.f, 0.f};

  bf16x8 rah0, rah1, rbh0, rbh1;
  {
    const short* ap = A + (size_t)arow * lda + koff + sk;
    rah0 = *reinterpret_cast<const bf16x8*>(ap);
    rah1 = *reinterpret_cast<const bf16x8*>(ap + 8);
    const short* bp = B + (size_t)brow * ldb + koff + sk;
    rbh0 = *reinterpret_cast<const bf16x8*>(bp);
    rbh1 = *reinterpret_cast<const bf16x8*>(bp + 8);
  }
  const int kend = koff + K2;
  for (int k0 = koff; k0 < kend; k0 += 64) {
    bf16x8 va0 = rah0, va1 = rah1, vb0 = rbh0, vb1 = rbh1;
    __syncthreads();
    *reinterpret_cast<bf16x8*>(&As[srow][sk])     = va0;
    *reinterpret_cast<bf16x8*>(&As[srow][sk + 8]) = va1;
    *reinterpret_cast<bf16x8*>(&Bs[srow][sk])     = vb0;
    *reinterpret_cast<bf16x8*>(&Bs[srow][sk + 8]) = vb1;
    __syncthreads();
    const int kn = k0 + 64;
    if (kn < kend) {
      const short* ap = A + (size_t)arow * lda + kn + sk;
      rah0 = *reinterpret_cast<const bf16x8*>(ap);
      rah1 = *reinterpret_cast<const bf16x8*>(ap + 8);
      const short* bp = B + (size_t)brow * ldb + kn + sk;
      rbh0 = *reinterpret_cast<const bf16x8*>(bp);
      rbh1 = *reinterpret_cast<const bf16x8*>(bp + 8);
    }
#pragma unroll
    for (int kk = 0; kk < 2; ++kk) {
      bf16x8 af0 = *reinterpret_cast<bf16x8*>(&As[wr + lrow][(kk << 5) + lk8]);
      bf16x8 af1 = *reinterpret_cast<bf16x8*>(&As[wr + 16 + lrow][(kk << 5) + lk8]);
      bf16x8 bf0 = *reinterpret_cast<bf16x8*>(&Bs[wc + lrow][(kk << 5) + lk8]);
      bf16x8 bf1 = *reinterpret_cast<bf16x8*>(&Bs[wc + 16 + lrow][(kk << 5) + lk8]);
      acc[0][0] = __builtin_amdgcn_mfma_f32_16x16x32_bf16(af0, bf0, acc[0][0], 0, 0, 0);
      acc[0][1] = __builtin_amdgcn_mfma_f32_16x16x32_bf16(af0, bf1, acc[0][1], 0, 0, 0);
      acc[1][0] = __builtin_amdgcn_mfma_f32_16x16x32_bf16(af1, bf0, acc[1][0], 0, 0, 0);
      acc[1][1] = __builtin_amdgcn_mfma_f32_16x16x32_bf16(af1, bf1, acc[1][1], 0, 0, 0);
    }
  }
  const int crow0 = bm + wr + ((lane >> 4) << 2);
  const int ccol0 = bn + wc + lrow;
#pragma unroll
  for (int mi = 0; mi < 2; ++mi)
#pragma unroll
    for (int ni = 0; ni < 2; ++ni) {
      int colc = ccol0 + (ni << 4);
#pragma unroll
      for (int r = 0; r < 4; ++r) {
        int rowc = crow0 + (mi << 4) + r;
        C[(size_t)rowc * ldc + colc] = acc[mi][ni][r];
      }
    }
}

// ------- 128(M)x64(N) bf16 SwiGLU GEMM: 4 waves, per-wave 64x32 u AND v -----
__global__ __launch_bounds__(256) void mgemm_glu(const short* __restrict__ A,
    const short* __restrict__ Bw, short* __restrict__ C,
    int M, int N, int K, int lda, int ldb, int ldc) {
  __shared__ short As[128][72];
  __shared__ short Bu[64][72];
  __shared__ short Bv[64][72];
  const int bm = blockIdx.y * 128, bn = blockIdx.x * 64;
  const int tid = threadIdx.x;
  const int w = tid >> 6, lane = tid & 63;
  const int wr = (w >> 1) << 6, wc = (w & 1) << 5;
  const int arow = bm + (tid >> 1), ac = (tid & 1) << 5;
  const int brow = bn + (tid >> 2), bc = (tid & 3) << 4;
  const int lrow = lane & 15, lk8 = (lane >> 4) << 3;
  f32x4 au[4][2], av[4][2];
#pragma unroll
  for (int i = 0; i < 4; ++i)
#pragma unroll
    for (int j = 0; j < 2; ++j) {
      au[i][j] = (f32x4){0.f, 0.f, 0.f, 0.f};
      av[i][j] = (f32x4){0.f, 0.f, 0.f, 0.f};
    }
  bf16x8 ra[4], ru[2], rv[2];
  {
    const short* ap = A + (size_t)arow * lda + ac;
    const short* up = Bw + (size_t)brow * ldb + bc;
    const short* vp = Bw + (size_t)(N + brow) * ldb + bc;
#pragma unroll
    for (int e = 0; e < 4; ++e) ra[e] = *reinterpret_cast<const bf16x8*>(ap + (e << 3));
    ru[0] = *reinterpret_cast<const bf16x8*>(up);
    ru[1] = *reinterpret_cast<const bf16x8*>(up + 8);
    rv[0] = *reinterpret_cast<const bf16x8*>(vp);
    rv[1] = *reinterpret_cast<const bf16x8*>(vp + 8);
  }
  for (int k0 = 0; k0 < K; k0 += 64) {
    __syncthreads();
#pragma unroll
    for (int e = 0; e < 4; ++e)
      *reinterpret_cast<bf16x8*>(&As[tid >> 1][ac + (e << 3)]) = ra[e];
    *reinterpret_cast<bf16x8*>(&Bu[tid >> 2][bc])     = ru[0];
    *reinterpret_cast<bf16x8*>(&Bu[tid >> 2][bc + 8]) = ru[1];
    *reinterpret_cast<bf16x8*>(&Bv[tid >> 2][bc])     = rv[0];
    *reinterpret_cast<bf16x8*>(&Bv[tid >> 2][bc + 8]) = rv[1];
    __syncthreads();
    const int kn = k0 + 64;
    if (kn < K) {
      const short* ap = A + (size_t)arow * lda + kn + ac;
      const short* up = Bw + (size_t)brow * ldb + kn + bc;
      const short* vp = Bw + (size_t)(N + brow) * ldb + kn + bc;
#pragma unroll
      for (int e = 0; e < 4; ++e) ra[e] = *reinterpret_cast<const bf16x8*>(ap + (e << 3));
      ru[0] = *reinterpret_cast<const bf16x8*>(up);
      ru[1] = *reinterpret_cast<const bf16x8*>(up + 8);
      rv[0] = *reinterpret_cast<const bf16x8*>(vp);
      rv[1] = *reinterpret_cast<const bf16x8*>(vp + 8);
    }
#pragma unroll
    for (int kk = 0; kk < 2; ++kk) {
      bf16x8 af[4], uf[2], vf[2];
#pragma unroll
      for (int i = 0; i < 4; ++i)
        af[i] = *reinterpret_cast<bf16x8*>(&As[wr + (i << 4) + lrow][(kk << 5) + lk8]);
#pragma unroll
      for (int j = 0; j < 2; ++j) {
        uf[j] = *reinterpret_cast<bf16x8*>(&Bu[wc + (j << 4) + lrow][(kk << 5) + lk8]);
        vf[j] = *reinterpret_cast<bf16x8*>(&Bv[wc + (j << 4) + lrow][(kk << 5) + lk8]);
      }
#pragma unroll
      for (int i = 0; i < 4; ++i)
#pragma unroll
        for (int j = 0; j < 2; ++j) {
          au[i][j] = __builtin_amdgcn_mfma_f32_16x16x32_bf16(af[i], uf[j], au[i][j], 0, 0, 0);
          av[i][j] = __builtin_amdgcn_mfma_f32_16x16x32_bf16(af[i], vf[j], av[i][j], 0, 0, 0);
        }
    }
  }
  const int crow0 = bm + wr + ((lane >> 4) << 2);
  const int ccol0 = bn + wc + lrow;
#pragma unroll
  for (int mi = 0; mi < 4; ++mi)
#pragma unroll
    for (int ni = 0; ni < 2; ++ni) {
      int colc = ccol0 + (ni << 4);
#pragma unroll
      for (int r = 0; r < 4; ++r) {
        int rowc = crow0 + (mi << 4) + r;
        float uu = au[mi][ni][r], vg = av[mi][ni][r];
        float sig = 1.0f / (1.0f + __expf(-vg));
        C[(size_t)rowc * ldc + colc] = cvt_bf16(uu * vg * sig);
      }
    }
}

// ---------------- Build Q/K (split heads + RoPE) -> bf16 ----------------
__global__ __launch_bounds__(256) void build_qk(const float* __restrict__ qf,
    const float* __restrict__ kvb, const float* __restrict__ ckv,
    const float* __restrict__ fc, const float* __restrict__ fs,
    short* __restrict__ Qb, short* __restrict__ Kb) {
  int t = blockIdx.x * 256 + threadIdx.x;
  int h2 = blockIdx.y;
  if (t >= S) return;
  int hh = h2 >> 1, par = h2 & 1;
  const float* qrow = qf + (size_t)t*1536 + hh*96;
  const float* krow = kvb + (size_t)t*2048 + hh*128;
  unsigned qu[24], ku[24];
#pragma unroll
  for (int xq = 0; xq < 8; ++xq) {
    float4 qv = *reinterpret_cast<const float4*>(qrow + par*32 + (xq<<2));
    float4 kv = *reinterpret_cast<const float4*>(krow + par*32 + (xq<<2));
    qu[xq*2]   = pk2(qv.x, qv.y); qu[xq*2+1] = pk2(qv.z, qv.w);
    ku[xq*2]   = pk2(kv.x, kv.y); ku[xq*2+1] = pk2(kv.z, kv.w);
  }
  int p = t >> 2;
  const float* qr = qrow + 64 + par*16;
  const float* kr = ckv + (size_t)t*288 + 256 + par*16;
#pragma unroll
  for (int mq = 0; mq < 8; ++mq) {
    float c = 1.f, sn = 0.f;
    if (p > 0) { c = fc[(p-1)*8 + mq]; sn = fs[(p-1)*8 + mq]; }
    float q0 = qr[2*mq], q1 = qr[2*mq+1];
    qu[16 + mq] = pk2(q0*c - q1*sn, q0*sn + q1*c);
    float k0 = kr[2*mq], k1 = kr[2*mq+1];
    ku[16 + mq] = pk2(k0*c - k1*sn, k0*sn + k1*c);
  }
  unsigned* qo = (unsigned*)(Qb + ((size_t)h2*S + t)*DQK);
  unsigned* ko = (unsigned*)(Kb + ((size_t)h2*S + t)*DQK);
#pragma unroll
  for (int e = 0; e < 6; ++e) {
    *reinterpret_cast<uint4*>(qo + (e<<2)) = make_uint4(qu[e*4], qu[e*4+1], qu[e*4+2], qu[e*4+3]);
    *reinterpret_cast<uint4*>(ko + (e<<2)) = make_uint4(ku[e*4], ku[e*4+1], ku[e*4+2], ku[e*4+3]);
  }
}

// ---------------- V transpose to bf16: Vt[hh][d][t] ----------------
__global__ __launch_bounds__(256) void vt_build(const float* __restrict__ kvb,
    short* __restrict__ Vt) {
  const int hh = blockIdx.x;
  const int t0 = blockIdx.y << 7;
  __shared__ short Ts[128][74];
  const int tl = threadIdx.x >> 3, dp = (threadIdx.x & 7) << 3;
#pragma unroll
  for (int pass = 0; pass < 4; ++pass) {
    int t = t0 + (pass << 5) + tl;
    const float* vp = kvb + (size_t)t*2048 + hh*128 + 64 + dp;
    float4 a = *reinterpret_cast<const float4*>(vp);
    float4 b = *reinterpret_cast<const float4*>(vp + 4);
    *reinterpret_cast<bf16x8*>(&Ts[(pass << 5) + tl][dp]) = cvt8(a, b);
  }
  __syncthreads();
  for (int idx = threadIdx.x; idx < 1024; idx += 256) {
    int d = idx >> 4, tseg = (idx & 15) << 3;
    bf16x8 v;
#pragma unroll
    for (int e = 0; e < 8; ++e) v[e] = Ts[tseg + e][d];
    *reinterpret_cast<bf16x8*>(Vt + ((size_t)hh*HD + d)*S + t0 + tseg) = v;
  }
}

// ---------------- lambda scalar ----------------
__global__ void compute_lam(const float* __restrict__ lq1, const float* __restrict__ lk1,
                            const float* __restrict__ lq2, const float* __restrict__ lk2,
                            float* __restrict__ lamp) {
  int t = threadIdx.x;
  float a = lq1[t]*lk1[t];
  float b = lq2[t]*lk2[t];
#pragma unroll
  for (int mm = 1; mm < 32; mm <<= 1) { a += __shfl_xor(a, mm, 32); b += __shfl_xor(b, mm, 32); }
  if (t == 0) lamp[0] = expf(a) - expf(b) + 0.2f;
}

// ------- MFMA flash attention: NO-LDS fragments direct from L2 ----------
__global__ __launch_bounds__(256) void flash_mfma(const short* __restrict__ Qb,
    const short* __restrict__ Kb, const short* __restrict__ Vg,
    float* __restrict__ Ob, float* __restrict__ rowm, float* __restrict__ rowl,
    float* __restrict__ Ob1a, float* __restrict__ Ob1b,
    float* __restrict__ rm1, float* __restrict__ rl1) {
  const int h2 = blockIdx.y;
  const int hh = h2 >> 1;
  const int z  = blockIdx.z;
  const int tid = threadIdx.x;
  const int w = tid >> 6, lane = tid & 63;
  const int ql = lane & 31, h = lane >> 5;
  const int cq = blockIdx.x / 3, k = blockIdx.x % 3;
  const int qi = k + 3*w;
  const int qbase = cq*SPP + (qi << 5);
  const int ri0w = qi << 5;

  __shared__ __align__(16) float Ot[4][32][36];

  bf16x8 qf0, qf1, qf2;
  {
    const short* qp = Qb + ((size_t)h2*S + qbase + ql)*DQK + (h << 3);
    qf0 = *reinterpret_cast<const bf16x8*>(qp);
    qf1 = *reinterpret_cast<const bf16x8*>(qp + 16);
    qf2 = *reinterpret_cast<const bf16x8*>(qp + 32);
  }
  const short* Kbase = Kb + (size_t)h2*S*DQK + (h << 3);
  const short* V0 = Vg + ((size_t)hh*HD + ql)*S + (h << 3);
  const short* V1 = Vg + ((size_t)hh*HD + 32 + ql)*S + (h << 3);

  float m = -1e30f, l = 0.f;
  f32x16 o0, o1;
#pragma unroll
  for (int r = 0; r < 16; ++r) { o0[r] = 0.f; o1[r] = 0.f; }

  for (int c = (z << 1); c < (z << 1) + 2; ++c) {
    for (int jr = 0; jr <= ri0w; jr += 32) {
      const int j0 = c*SPP + jr;
      const bool diag = (jr == ri0w);
      const short* kp = Kbase + (size_t)(j0 + ql)*DQK;
      bf16x8 kf0 = *reinterpret_cast<const bf16x8*>(kp);
      bf16x8 kf1 = *reinterpret_cast<const bf16x8*>(kp + 16);
      bf16x8 kf2 = *reinterpret_cast<const bf16x8*>(kp + 32);
      bf16x8 v00 = *reinterpret_cast<const bf16x8*>(V0 + j0);
      bf16x8 v01 = *reinterpret_cast<const bf16x8*>(V0 + j0 + 16);
      bf16x8 v10 = *reinterpret_cast<const bf16x8*>(V1 + j0);
      bf16x8 v11 = *reinterpret_cast<const bf16x8*>(V1 + j0 + 16);

      f32x16 st;
#pragma unroll
      for (int r = 0; r < 16; ++r) st[r] = 0.f;
      st = __builtin_amdgcn_mfma_f32_32x32x16_bf16(kf0, qf0, st, 0, 0, 0);
      st = __builtin_amdgcn_mfma_f32_32x32x16_bf16(kf1, qf1, st, 0, 0, 0);
      st = __builtin_amdgcn_mfma_f32_32x32x16_bf16(kf2, qf2, st, 0, 0, 0);

      if (diag) {
#pragma unroll
        for (int r = 0; r < 16; ++r) {
          int kl = (r & 3) + ((r >> 2) << 3) + (h << 2);
          st[r] = (kl <= ql) ? st[r] * SCALING : -1e30f;
        }
      } else {
#pragma unroll
        for (int r = 0; r < 16; ++r) st[r] *= SCALING;
      }

      float tm = st[0];
#pragma unroll
      for (int r = 1; r < 16; ++r) tm = fmaxf(tm, st[r]);
      tm = fmaxf(tm, __shfl_xor(tm, 32));
      if (__any(tm > m + 8.0f)) {
        float mnew = fmaxf(m, tm);
        float sc = __expf(m - mnew);
        m = mnew;
        l *= sc;
#pragma unroll
        for (int r = 0; r < 16; ++r) { o0[r] *= sc; o1[r] *= sc; }
      }
      float ps = 0.f;
#pragma unroll
      for (int r = 0; r < 16; ++r) { float p = __expf(st[r] - m); st[r] = p; ps += p; }
      ps += __shfl_xor(ps, 32);
      l += ps;

      unsigned A0 = pk2(st[0],  st[1]),  B0 = pk2(st[2],  st[3]);
      unsigned C0 = pk2(st[4],  st[5]),  D0 = pk2(st[6],  st[7]);
      unsigned A1 = pk2(st[8],  st[9]),  B1 = pk2(st[10], st[11]);
      unsigned C1 = pk2(st[12], st[13]), D1 = pk2(st[14], st[15]);
      unsigned xA0 = (unsigned)__shfl_xor((int)A0, 32), xB0 = (unsigned)__shfl_xor((int)B0, 32);
      unsigned xC0 = (unsigned)__shfl_xor((int)C0, 32), xD0 = (unsigned)__shfl_xor((int)D0, 32);
      unsigned xA1 = (unsigned)__shfl_xor((int)A1, 32), xB1 = (unsigned)__shfl_xor((int)B1, 32);
      unsigned xC1 = (unsigned)__shfl_xor((int)C1, 32), xD1 = (unsigned)__shfl_xor((int)D1, 32);
      union { unsigned u[4]; bf16x8 v; } P0, P1;
      P0.u[0] = h ? xC0 : A0;  P0.u[1] = h ? xD0 : B0;
      P0.u[2] = h ? C0 : xA0;  P0.u[3] = h ? D0 : xB0;
      P1.u[0] = h ? xC1 : A1;  P1.u[1] = h ? xD1 : B1;
      P1.u[2] = h ? C1 : xA1;  P1.u[3] = h ? D1 : xB1;

      o0 = __builtin_amdgcn_mfma_f32_32x32x16_bf16(v00, P0.v, o0, 0, 0, 0);
      o0 = __builtin_amdgcn_mfma_f32_32x32x16_bf16(v01, P1.v, o0, 0, 0, 0);
      o1 = __builtin_amdgcn_mfma_f32_32x32x16_bf16(v10, P0.v, o1, 0, 0, 0);
      o1 = __builtin_amdgcn_mfma_f32_32x32x16_bf16(v11, P1.v, o1, 0, 0, 0);
    }
  }

  float* ot = &Ot[w][0][0];
  float* orow;
  if (z == 0) orow = Ob + ((size_t)h2*S + qbase)*HD;
  else orow = (h2 < 16) ? Ob1a + ((size_t)h2*S + qbase)*HD
                        : Ob1b + ((size_t)(h2 - 16)*S + qbase)*HD;
#pragma unroll
  for (int r = 0; r < 16; ++r) {
    int dl = (r & 3) + ((r >> 2) << 3) + (h << 2);
    ot[ql*36 + dl] = o0[r];
  }
#pragma unroll
  for (int it = 0; it < 4; ++it) {
    int idx = lane + (it << 6);
    int row = idx >> 3, c4 = (idx & 7) << 2;
    float4 v = *reinterpret_cast<float4*>(&ot[row*36 + c4]);
    *reinterpret_cast<float4*>(&orow[(size_t)row*HD + c4]) = v;
  }
#pragma unroll
  for (int r = 0; r < 16; ++r) {
    int dl = (r & 3) + ((r >> 2) << 3) + (h << 2);
    ot[ql*36 + dl] = o1[r];
  }
#pragma unroll
  for (int it = 0; it < 4; ++it) {
    int idx = lane + (it << 6);
    int row = idx >> 3, c4 = (idx & 7) << 2;
    float4 v = *reinterpret_cast<float4*>(&ot[row*36 + c4]);
    *reinterpret_cast<float4*>(&orow[(size_t)row*HD + 32 + c4]) = v;
  }
  if (lane < 32) {
    if (z == 0) { rowm[h2*S + qbase + lane] = m; rowl[h2*S + qbase + lane] = l; }
    else        { rm1[h2*S + qbase + lane] = m;  rl1[h2*S + qbase + lane] = l; }
  }
}

// ---------------- merge the two flash partials, normalize ----------------
__global__ __launch_bounds__(256) void merge_flash(float* __restrict__ Ob,
    float* __restrict__ rowm, float* __restrict__ rowl,
    const float* __restrict__ Ob1a, const float* __restrict__ Ob1b,
    const float* __restrict__ rm1, const float* __restrict__ rl1) {
  const int gid = blockIdx.x * 4 + (threadIdx.x >> 6);
  const int d = threadIdx.x & 63;
  const int h2 = gid / S;
  float m0 = rowm[gid], l0 = rowl[gid], m1 = rm1[gid], l1 = rl1[gid];
  float m = fmaxf(m0, m1);
  float w0 = __expf(m0 - m), w1 = __expf(m1 - m);
  float linv = 1.0f / (l0*w0 + l1*w1);
  const float* o1 = (h2 < 16) ? (Ob1a + (size_t)gid*HD)
                              : (Ob1b + ((size_t)gid - (size_t)16*S)*HD);
  float v0 = Ob[(size_t)gid*HD + d];
  float v1 = o1[d];
  Ob[(size_t)gid*HD + d] = (v0*w0 + v1*w1) * linv;
  if (d == 0) { rowm[gid] = m; rowl[gid] = l0*w0 + l1*w1; }
}

// ---------------- colsum via MFMA (bf16 inputs) ----------------
__global__ __launch_bounds__(256) void colsum_mfma(const short* __restrict__ Qb,
    const short* __restrict__ Kb, const float* __restrict__ rowm,
    const float* __restrict__ rowl, float* __restrict__ gcol) {
  const int jt = blockIdx.x;
  const int hh = blockIdx.y, h2 = hh << 1;
  const int cK = jt / 12, jr32 = jt % 12;
  const int jr = jr32 << 5;
  const int j0 = cK*SPP + jr;
  const int tid = threadIdx.x;
  const int w = tid >> 6, lane = tid & 63;
  const int ql = lane & 31, h = lane >> 5;

  bf16x8 kf0, kf1, kf2;
  {
    const short* kp = Kb + ((size_t)h2*S + j0 + ql)*DQK + (h << 3);
    kf0 = *reinterpret_cast<const bf16x8*>(kp);
    kf1 = *reinterpret_cast<const bf16x8*>(kp + 16);
    kf2 = *reinterpret_cast<const bf16x8*>(kp + 32);
  }
  const int nt = 12 - jr32;
  const int T = nt << 2;
  float gs[16];
#pragma unroll
  for (int r = 0; r < 16; ++r) gs[r] = 0.f;

  for (int tt = w; tt < T; tt += 4) {
    int cq = tt / nt, qrem = tt - cq*nt;
    int qi = jr32 + qrem;
    int i0 = cq*SPP + (qi << 5);
    const bool diag = (qrem == 0);
    const short* qp = Qb + ((size_t)h2*S + i0 + ql)*DQK + (h << 3);
    bf16x8 qf0 = *reinterpret_cast<const bf16x8*>(qp);
    bf16x8 qf1 = *reinterpret_cast<const bf16x8*>(qp + 16);
    bf16x8 qf2 = *reinterpret_cast<const bf16x8*>(qp + 32);
    f32x16 st;
#pragma unroll
    for (int r = 0; r < 16; ++r) st[r] = 0.f;
    st = __builtin_amdgcn_mfma_f32_32x32x16_bf16(kf0, qf0, st, 0, 0, 0);
    st = __builtin_amdgcn_mfma_f32_32x32x16_bf16(kf1, qf1, st, 0, 0, 0);
    st = __builtin_amdgcn_mfma_f32_32x32x16_bf16(kf2, qf2, st, 0, 0, 0);
    float Mq = rowm[h2*S + i0 + ql];
    float Lq = 1.0f / rowl[h2*S + i0 + ql];
    if (diag) {
#pragma unroll
      for (int r = 0; r < 16; ++r) {
        int kl = (r & 3) + ((r >> 2) << 3) + (h << 2);
        if (kl <= ql) gs[r] += __expf(st[r]*SCALING - Mq) * Lq;
      }
    } else {
#pragma unroll
      for (int r = 0; r < 16; ++r) gs[r] += __expf(st[r]*SCALING - Mq) * Lq;
    }
  }
  __shared__ float gw[4][32];
#pragma unroll
  for (int r = 0; r < 16; ++r) {
    float v = gs[r];
#pragma unroll
    for (int mm = 1; mm < 32; mm <<= 1) v += __shfl_xor(v, mm, 32);
    if (ql == 0) gw[w][(r & 3) + ((r >> 2) << 3) + (h << 2)] = v;
  }
  __syncthreads();
  if (tid < 32) {
    float s = gw[0][tid] + gw[1][tid] + gw[2][tid] + gw[3][tid];
    gcol[hh*S + j0 + tid] = s * (1.0f / (float)S);
  }
}

// ---------------- Wpre: masked prefix of g-weighted V ----------------
__global__ __launch_bounds__(256) void build_wpre(const float* __restrict__ gcol,
    const float* __restrict__ kvb, float* __restrict__ Wpre) {
  const int hh = blockIdx.x >> 2;
  const int dq = (blockIdx.x & 3) << 4;
  __shared__ float Wt[SPP][16];
  const int tid = threadIdx.x;
  for (int idx = tid; idx < SPP*16; idx += 256) {
    int r = idx >> 4, dd = idx & 15;
    float val = 0.f;
#pragma unroll
    for (int b2 = 0; b2 < 4; ++b2) {
      int j = b2*SPP + r;
      val = fmaf(gcol[hh*S + j], kvb[(size_t)j*2048 + hh*128 + 64 + dq + dd], val);
    }
    Wt[r][dd] = val;
  }
  __syncthreads();
  if (tid < 16) {
    float run = 0.f;
    for (int r = 0; r < SPP; ++r) { run += Wt[r][tid]; Wt[r][tid] = run; }
  }
  __syncthreads();
  for (int idx = tid; idx < SPP*16; idx += 256) {
    int r = idx >> 4, dd = idx & 15;
    Wpre[((size_t)hh*SPP + r)*HD + dq + dd] = Wt[r][dd];
  }
}

// ------- combine (diff-attn) + per-head RMSNorm + scrambled reshape -> bf16 ---
__global__ __launch_bounds__(64) void combine_rms(const float* __restrict__ Ob,
    const float* __restrict__ Wpre, const float* __restrict__ lamp,
    const float* __restrict__ anw, short* __restrict__ attno) {
  const int t = blockIdx.x, h = blockIdx.y, d = threadIdx.x;
  const float lam = lamp[0];
  const float o1 = Ob[((size_t)(2*h)*S + t)*HD + d];
  const float o2 = Ob[((size_t)(2*h+1)*S + t)*HD + d];
  const float w3 = Wpre[((size_t)h*SPP + (t % SPP))*HD + d];
  float val = o1 - lam*o2 + lam*w3;
  float ss = val*val;
#pragma unroll
  for (int mm = 1; mm < 64; mm <<= 1) ss += __shfl_xor(ss, mm, 64);
  float scale = rsqrtf(ss * (1.0f/HD) + ATTN_EPS) * anw[d];
  int tn = h*96 + (t >> 4);
  int cn = ((t & 15) << 6) + d;
  attno[(size_t)tn*DM + cn] = cvt_bf16(val * scale);
}

// =========================== launch ===========================
extern "C" void kernel_launch(void* const* d_in, const int* in_sizes, int n_in,
                              void* d_out, int out_size, void* d_ws, size_t ws_size,
                              hipStream_t stream) {
  (void)in_sizes; (void)n_in; (void)out_size;
  const float* x    = (const float*)d_in[0];
  const float* fc   = (const float*)d_in[1];
  const float* fs   = (const float*)d_in[2];
  const float* n1w  = (const float*)d_in[3];
  const float* n2w  = (const float*)d_in[4];
  const float* kvdw = (const float*)d_in[5];
  const float* qdw  = (const float*)d_in[6];
  const float* kvnw = (const float*)d_in[7];
  const float* qnw  = (const float*)d_in[8];
  const float* kvuw = (const float*)d_in[9];
  const float* quw  = (const float*)d_in[10];
  const float* lq1  = (const float*)d_in[11];
  const float* lk1  = (const float*)d_in[12];
  const float* lq2  = (const float*)d_in[13];
  const float* lk2  = (const float*)d_in[14];
  const float* anw  = (const float*)d_in[15];
  const float* ow   = (const float*)d_in[16];
  const float* ffiw = (const float*)d_in[17];
  const float* ffow = (const float*)d_in[18];
  float* out = (float*)d_out;
  float* ws  = (float*)d_ws;

  float* xin   = ws;
  float* ckv   = xin   + (size_t)S*DM;
  float* qmid  = ckv   + (size_t)S*288;
  float* kvb   = qmid  + (size_t)S*QC;
  float* qf    = kvb   + (size_t)S*2048;
  float* Qb    = qf    + (size_t)S*1536;
  float* Kb    = Qb    + (size_t)H2N*S*DQK;
  float* Obuf  = Kb    + (size_t)H2N*S*DQK;
  float* rowm  = Obuf  + (size_t)H2N*S*HD;
  float* rowl  = rowm  + (size_t)H2N*S;
  float* gcol  = rowl  + (size_t)H2N*S;
  float* Wpre  = gcol  + (size_t)NH*S;
  float* attno = Wpre  + (size_t)NH*SPP*HD;
  float* lamp  = attno + (size_t)S*DM;
  short* fbufs = (short*)kvb;     // bf16 FFN activation overlays kv region
  float* Ob1a = xin;
  float* Ob1b = qf;
  float* rm1  = qf + (size_t)16*S*HD;
  float* rl1  = rm1 + (size_t)H2N*S;
  short* Qb_bf = (short*)Qb;
  short* Kb_bf = (short*)Kb;
  short* Vt_bf = (short*)Qb + 2359296;
  short* xin_bf  = (short*)xin;
  short* ckv_bf  = (short*)Obuf;
  short* qmid_bf = ckv_bf + (size_t)S*KVC;
  short* h_bf    = (short*)ckv;   // rmsnorm2 out: ckv+qmid region (dead), avoids p0 alias
  short* attno_bf = (short*)attno;
  short* kvdw_bf = (short*)attno;
  short* qdw_bf  = kvdw_bf + 294912;
  short* kvuw_bf = qdw_bf  + 393216;
  short* quw_bf  = kvuw_bf + 524288;
  short* ffiw_bf = (short*)Qb;
  short* ow_bf   = ffiw_bf + 8388608;
  short* ffow_bf = (short*)Obuf;
  float* psum0 = xin;             // split-K partials: dead windows at call sites
  float* psum1 = qf;
  if (ws_size < (size_t)18063376 * sizeof(float)) return;

  cvt_w4<<<880, 256, 0, stream>>>(kvdw, 294912, qdw, 393216, kvuw, 524288, quw, 589824, kvdw_bf);
  rmsnorm_bf<<<S, 256, 0, stream>>>(x, n1w, xin_bf, DM, DM, DM, EPS_RMS);
  { dim3 g(5, 24);  mgemm_nt<0><<<g, 256, 0, stream>>>(xin_bf, kvdw_bf, nullptr, ckv, S, 288, DM, DM, DM, 288); }
  { dim3 g(6, 24);  mgemm_nt<0><<<g, 256, 0, stream>>>(xin_bf, qdw_bf,  nullptr, qmid, S, QC, DM, DM, DM, QC); }
  rmsnorm_bf<<<S, 256, 0, stream>>>(ckv,  kvnw, ckv_bf,  KVC, 288, KVC, EPS_RMS);
  rmsnorm_bf<<<S, 256, 0, stream>>>(qmid, qnw,  qmid_bf, QC,  QC,  QC,  EPS_RMS);
  { dim3 g(32, 24); mgemm_nt<0><<<g, 256, 0, stream>>>(ckv_bf,  kvuw_bf, nullptr, kvb, S, 2048, KVC, KVC, KVC, 2048); }
  { dim3 g(24, 24); mgemm_nt<0><<<g, 256, 0, stream>>>(qmid_bf, quw_bf,  nullptr, qf,  S, 1536, QC,  QC,  QC,  1536); }
  { dim3 g(6, 32);  build_qk<<<g, 256, 0, stream>>>(qf, kvb, ckv, fc, fs, Qb_bf, Kb_bf); }
  { dim3 g(16, 12); vt_build<<<g, 256, 0, stream>>>(kvb, Vt_bf); }
  compute_lam<<<1, 32, 0, stream>>>(lq1, lk1, lq2, lk2, lamp);
  { dim3 g(12, 32, 2); flash_mfma<<<g, 256, 0, stream>>>(Qb_bf, Kb_bf, Vt_bf, Obuf, rowm, rowl,
                                                         Ob1a, Ob1b, rm1, rl1); }
  merge_flash<<<(H2N*S)/4, 256, 0, stream>>>(Obuf, rowm, rowl, Ob1a, Ob1b, rm1, rl1);
  { dim3 g(48, 16); colsum_mfma<<<g, 256, 0, stream>>>(Qb_bf, Kb_bf, rowm, rowl, gcol); }
  cvt_w4<<<4608, 256, 0, stream>>>(ffiw, 8388608, ow, 1048576, nullptr, 0, nullptr, 0, ffiw_bf);
  build_wpre<<<64, 256, 0, stream>>>(gcol, kvb, Wpre);
  { dim3 g(S, 16);  combine_rms<<<g, 64, 0, stream>>>(Obuf, Wpre, lamp, anw, attno_bf); }
  cvt_w4<<<2048, 256, 0, stream>>>(ffow, 4194304, nullptr, 0, nullptr, 0, nullptr, 0, ffow_bf);
  // o-proj split-K=2 -> partials; reduce fused into rmsnorm_sum_bf (out = p0+p1+x)
  { dim3 g(16, 24, 2); mgemm_sk<<<g, 256, 0, stream>>>(attno_bf, ow_bf, psum0, psum1, S, DM, 512, DM, DM, DM); }
  rmsnorm_sum_bf<<<S, 256, 0, stream>>>(psum0, psum1, x, n2w, out, h_bf, EPS_RMS);
  { dim3 g(64, 12); mgemm_glu<<<g, 256, 0, stream>>>(h_bf, ffiw_bf, fbufs, S, DFF, DM, DM, DM, DFF); }
  // ff_out split-K=2 -> partials; out += p0 + p1
  { dim3 g(16, 24, 2); mgemm_sk<<<g, 256, 0, stream>>>(fbufs, ffow_bf, psum0, psum1, S, DM, 2048, DFF, DFF, DM); }
  fadd2<<<1536, 256, 0, stream>>>(out, psum0, psum1);
}